// Round 1
// baseline (2252.544 us; speedup 1.0000x reference)
//
#include <hip/hip_runtime.h>
#include <math.h>

// Problem constants (B=1 throughout)
#define S_   4096
#define D_   2048
#define M_   4
#define NC_  1024
#define TOPK_ 512
#define NH_  16
#define C_   64
#define DC_  512
#define NG_  4
#define DG_  512
#define CI_  64
#define NHI_ 4
#define ROPE_ 32
#define EPS_ 1e-6f

// ---------------------------------------------------------------------------
// Generic fp32 tiled GEMM: C = A @ B,  A (M x K, lda), B (K x N, ldb), C (ldc)
// BM=BN=64, BK=16, 256 threads, 4x4 microtile. M,N multiples of 64, K of 16.
// ---------------------------------------------------------------------------
#define BM 64
#define BN 64
#define BK 16
__global__ __launch_bounds__(256) void gemm_f32(
    const float* __restrict__ A, const float* __restrict__ B,
    float* __restrict__ C, int K, int lda, int ldb, int ldc) {
  __shared__ float As[BK][BM + 4];
  __shared__ float Bs[BK][BN + 4];
  int tid = threadIdx.x;
  int bm = blockIdx.y * BM;
  int bn = blockIdx.x * BN;
  int tr = tid >> 4;   // 0..15
  int tc = tid & 15;   // 0..15
  float acc[4][4] = {{0.f}};
  for (int k0 = 0; k0 < K; k0 += BK) {
    // load A tile (64 rows x 16 k), transposed into As[k][m]
    int ac = tid & 15;
    int ar0 = tid >> 4;
#pragma unroll
    for (int i = 0; i < 4; ++i) {
      int r = ar0 + 16 * i;
      As[ac][r] = A[(size_t)(bm + r) * lda + k0 + ac];
    }
    // load B tile (16 k x 64 cols)
    int bc = tid & 63;
    int br0 = tid >> 6;
#pragma unroll
    for (int i = 0; i < 4; ++i) {
      int r = br0 + 4 * i;
      Bs[r][bc] = B[(size_t)(k0 + r) * ldb + bn + bc];
    }
    __syncthreads();
#pragma unroll
    for (int kk = 0; kk < BK; ++kk) {
      float4 av = *(const float4*)&As[kk][tr * 4];
      float4 bv = *(const float4*)&Bs[kk][tc * 4];
      float a[4] = {av.x, av.y, av.z, av.w};
      float b[4] = {bv.x, bv.y, bv.z, bv.w};
#pragma unroll
      for (int i = 0; i < 4; ++i)
#pragma unroll
        for (int j = 0; j < 4; ++j) acc[i][j] += a[i] * b[j];
    }
    __syncthreads();
  }
#pragma unroll
  for (int i = 0; i < 4; ++i) {
    float4 v = make_float4(acc[i][0], acc[i][1], acc[i][2], acc[i][3]);
    *(float4*)&C[(size_t)(bm + tr * 4 + i) * ldc + bn + tc * 4] = v;
  }
}

// k_orig[j,d] = mean over 4 tokens
__global__ void mean4_kernel(const float* __restrict__ x, float* __restrict__ ko) {
  int i = blockIdx.x * 256 + threadIdx.x;
  if (i >= NC_ * D_) return;
  int j = i >> 11, d = i & (D_ - 1);
  const float* p = x + (size_t)j * 4 * D_ + d;
  ko[i] = 0.25f * (p[0] + p[D_] + p[2 * D_] + p[3 * D_]);
}

// hw = x @ w_w  (S x 4)
__global__ void hw_kernel(const float* __restrict__ x, const float* __restrict__ ww,
                          float* __restrict__ hw) {
  int i = blockIdx.x * 256 + threadIdx.x;
  if (i >= S_ * NHI_) return;
  int s = i >> 2, h = i & 3;
  const float* xr = x + (size_t)s * D_;
  float acc = 0.f;
  for (int k = 0; k < D_; ++k) acc += xr[k] * ww[k * NHI_ + h];
  hw[i] = acc;
}

// gating softmax over 2M entries -> compressed (NC x C)
__global__ void gate_kernel(const float* __restrict__ ca, const float* __restrict__ cb,
                            const float* __restrict__ za, const float* __restrict__ zb,
                            const float* __restrict__ ba, const float* __restrict__ bb,
                            float* __restrict__ comp) {
  int i = blockIdx.x * 256 + threadIdx.x;
  if (i >= NC_ * C_) return;
  int j = i >> 6, c = i & 63;
  float lg[8], vv[8];
#pragma unroll
  for (int m = 0; m < 4; ++m) {
    if (j == 0) {
      lg[m] = -1e30f + bb[m * C_ + c];
      vv[m] = 0.f;
    } else {
      int row = (j - 1) * 4 + m;
      lg[m] = zb[row * C_ + c] + bb[m * C_ + c];
      vv[m] = cb[row * C_ + c];
    }
    int row2 = j * 4 + m;
    lg[4 + m] = za[row2 * C_ + c] + ba[m * C_ + c];
    vv[4 + m] = ca[row2 * C_ + c];
  }
  float mx = lg[0];
#pragma unroll
  for (int t = 1; t < 8; ++t) mx = fmaxf(mx, lg[t]);
  float se = 0.f, acc = 0.f;
#pragma unroll
  for (int t = 0; t < 8; ++t) {
    float e = expf(lg[t] - mx);
    se += e;
    acc += e * vv[t];
  }
  comp[i] = acc / se;
}

__device__ inline float wave_sum64(float v) {
#pragma unroll
  for (int off = 32; off > 0; off >>= 1) v += __shfl_xor(v, off, 64);
  return v;
}

// LayerNorm over C=64; one wave per row; block = 4 rows
__global__ void ln_kernel(const float* __restrict__ in, const float* __restrict__ w,
                          const float* __restrict__ b, float* __restrict__ out) {
  int row = blockIdx.x * 4 + (threadIdx.x >> 6);
  int c = threadIdx.x & 63;
  float v = in[(size_t)row * C_ + c];
  float mu = wave_sum64(v) * (1.f / 64.f);
  float d = v - mu;
  float var = wave_sum64(d * d) * (1.f / 64.f);
  out[(size_t)row * C_ + c] = d * (1.f / sqrtf(var + EPS_)) * w[c] + b[c];
}

// LN + RoPE for q. Rows = s*16+h, one wave per row.
__global__ void ln_rope_q_kernel(const float* __restrict__ quq, const float* __restrict__ w,
                                 const float* __restrict__ b, float* __restrict__ q) {
  int row = blockIdx.x * 4 + (threadIdx.x >> 6);  // s*16 + h
  int s = row >> 4;
  int c = threadIdx.x & 63;
  float v = quq[(size_t)row * C_ + c];
  float mu = wave_sum64(v) * (1.f / 64.f);
  float d = v - mu;
  float var = wave_sum64(d * d) * (1.f / 64.f);
  float y = d * (1.f / sqrtf(var + EPS_)) * w[c] + b[c];
  float outv;
  float partner = __shfl_xor(y, 1, 64);
  if (c < C_ - ROPE_) {
    outv = y;
  } else {
    int p = (c - (C_ - ROPE_)) >> 1;
    float inv = powf(10000.f, -(2.f * (float)p) / (float)ROPE_);
    float ang = (float)s * inv;
    float cs = cosf(ang), sn = sinf(ang);
    if ((c & 1) == 0)
      outv = y * cs - partner * sn;   // r = x0*cos - x1*sin
    else
      outv = partner * sn + y * cs;   // i = x0*sin + x1*cos
  }
  q[(size_t)row * C_ + c] = outv;
}

// indexer scores: iscores[s,k] = sum_h relu(q_i[s,h]·k_proj[k]) * hw[s,h], mask k<s
__global__ __launch_bounds__(256) void iscores_kernel(
    const float* __restrict__ qi, const float* __restrict__ kp,
    const float* __restrict__ hw, float* __restrict__ isc) {
  int s = blockIdx.x;
  __shared__ float qs[NHI_ * CI_];
  __shared__ float hws[NHI_];
  int tid = threadIdx.x;
  qs[tid] = qi[(size_t)s * NHI_ * CI_ + tid];
  if (tid < NHI_) hws[tid] = hw[s * NHI_ + tid];
  __syncthreads();
  for (int k = tid; k < NC_; k += 256) {
    float sc = 0.f;
    const float* krow = kp + (size_t)k * CI_;
#pragma unroll
    for (int h = 0; h < NHI_; ++h) {
      float d = 0.f;
      const float* qrow = &qs[h * CI_];
#pragma unroll 16
      for (int c = 0; c < CI_; c += 4) {
        float4 qv = *(const float4*)&qrow[c];
        float4 kv = *(const float4*)&krow[c];
        d += qv.x * kv.x + qv.y * kv.y + qv.z * kv.z + qv.w * kv.w;
      }
      sc += fmaxf(d, 0.f) * hws[h];
    }
    isc[(size_t)s * NC_ + k] = (k < s) ? sc : -__builtin_inff();
  }
}

// top-512 of 1024 via bitonic sort on key=(~monotone(val)<<32)|idx, ascending.
// Reproduces jax.lax.top_k set incl. lower-index-first tie-breaking.
__global__ __launch_bounds__(512) void topk_kernel(const float* __restrict__ isc,
                                                   int* __restrict__ tidx) {
  __shared__ unsigned long long keys[NC_];
  int s = blockIdx.x;
  int tid = threadIdx.x;
  for (int i = tid; i < NC_; i += 512) {
    float v = isc[(size_t)s * NC_ + i];
    unsigned u = __float_as_uint(v);
    unsigned m = (u & 0x80000000u) ? ~u : (u | 0x80000000u);
    keys[i] = ((unsigned long long)(~m) << 32) | (unsigned)i;
  }
  __syncthreads();
  for (int k = 2; k <= NC_; k <<= 1) {
    for (int j = k >> 1; j > 0; j >>= 1) {
      for (int i = tid; i < NC_; i += 512) {
        int ixj = i ^ j;
        if (ixj > i) {
          unsigned long long a = keys[i], bke = keys[ixj];
          bool up = ((i & k) == 0);
          if ((a > bke) == up) {
            keys[i] = bke;
            keys[ixj] = a;
          }
        }
      }
      __syncthreads();
    }
  }
  if (tid < TOPK_) tidx[(size_t)s * TOPK_ + tid] = (int)(keys[tid] & 0xFFFFFFFFu);
}

// attention: block per s, 256 threads. out[s, h*64+c] (fp32)
__global__ __launch_bounds__(256) void attn_kernel(
    const float* __restrict__ q, const float* __restrict__ kc,
    const int* __restrict__ tidx, const float* __restrict__ sink,
    float* __restrict__ out) {
  int s = blockIdx.x;
  int tid = threadIdx.x;
  __shared__ float qs[NH_ * C_];       // 4 KB
  __shared__ int idxs[TOPK_];          // 2 KB
  __shared__ float tile[64 * 68];      // 17 KB, row stride 68
  __shared__ float ev[NH_ * TOPK_];    // 32 KB
  __shared__ float denom[NH_];
  for (int i = tid; i < NH_ * C_; i += 256) qs[i] = q[(size_t)s * NH_ * C_ + i];
  for (int i = tid; i < TOPK_; i += 256) idxs[i] = tidx[(size_t)s * TOPK_ + i];
  __syncthreads();
  int h = tid >> 4;  // 0..15
  int l = tid & 15;  // 0..15
  float dpart = 0.f;
  for (int t0 = 0; t0 < TOPK_; t0 += 64) {
    for (int i = tid; i < 64 * 64; i += 256) {
      int r = i >> 6, c = i & 63;
      tile[r * 68 + c] = kc[(size_t)idxs[t0 + r] * C_ + c];
    }
    __syncthreads();
#pragma unroll
    for (int jj = 0; jj < 4; ++jj) {
      int kk = l + 16 * jj;
      int ksel = idxs[t0 + kk];
      float sc = 0.f;
      const float* qrow = &qs[h * C_];
      const float* krow = &tile[kk * 68];
#pragma unroll 16
      for (int c = 0; c < C_; c += 4) {
        float4 qv = *(const float4*)&qrow[c];
        float4 kv = *(const float4*)&krow[c];
        sc += qv.x * kv.x + qv.y * kv.y + qv.z * kv.z + qv.w * kv.w;
      }
      sc *= 0.125f;  // 1/sqrt(64)
      float e = (s < ksel * M_) ? expf(sc) : 0.f;  // cmask, exp(-inf)=0
      ev[h * TOPK_ + t0 + kk] = e;
      dpart += e;
    }
    __syncthreads();
  }
#pragma unroll
  for (int off = 8; off > 0; off >>= 1) dpart += __shfl_xor(dpart, off, 64);
  if (l == 0) denom[h] = dpart + expf(sink[h]);
  __syncthreads();
  // second pass: out[h][c] = sum_k ev[h][k] * kc_sel[k][c]
  int c0 = (tid & 15) * 4;
  float oa[4] = {0.f, 0.f, 0.f, 0.f};
  for (int t0 = 0; t0 < TOPK_; t0 += 64) {
    for (int i = tid; i < 64 * 64; i += 256) {
      int r = i >> 6, c = i & 63;
      tile[r * 68 + c] = kc[(size_t)idxs[t0 + r] * C_ + c];
    }
    __syncthreads();
#pragma unroll 8
    for (int kk = 0; kk < 64; ++kk) {
      float e = ev[h * TOPK_ + t0 + kk];
      const float* krow = &tile[kk * 68 + c0];
      float4 kv = *(const float4*)krow;
      oa[0] += e * kv.x;
      oa[1] += e * kv.y;
      oa[2] += e * kv.z;
      oa[3] += e * kv.w;
    }
    __syncthreads();
  }
  float dn = denom[h];
  float4 r = make_float4(oa[0] / dn, oa[1] / dn, oa[2] / dn, oa[3] / dn);
  *(float4*)&out[(size_t)s * NH_ * C_ + h * C_ + c0] = r;
}

// ---------------------------------------------------------------------------
// Workspace layout (float offsets)
// ---------------------------------------------------------------------------
#define OFF_CA 0u
#define OFF_CB 262144u
#define OFF_ZA 524288u
#define OFF_ZB 786432u
#define OFF_CQ 1048576u           // 4096*512
#define OFF_QI 3145728u           // 4096*256
#define OFF_HW 4194304u           // 4096*4
#define OFF_KP 4210688u           // 1024*64
#define OFF_COMP 4276224u         // 1024*64
#define OFF_KC 4341760u           // 1024*64
#define OFF_KO 4407296u           // 1024*2048
#define OFF_ISC 6504448u          // 4096*1024 (reused as attn_out)
#define OFF_TIDX 10698752u        // 4096*512 ints
#define OFF_QUQ 12795904u         // 4096*1024 (reused as g_buf: 4096*2048)
#define OFF_Q 16990208u           // 4096*1024

extern "C" void kernel_launch(void* const* d_in, const int* in_sizes, int n_in,
                              void* d_out, int out_size, void* d_ws, size_t ws_size,
                              hipStream_t stream) {
  const float* x      = (const float*)d_in[0];
  const float* w_kv_a = (const float*)d_in[1];
  const float* w_kv_b = (const float*)d_in[2];
  const float* w_z_a  = (const float*)d_in[3];
  const float* w_z_b  = (const float*)d_in[4];
  const float* b_a    = (const float*)d_in[5];
  const float* b_b    = (const float*)d_in[6];
  const float* w_dq   = (const float*)d_in[7];
  const float* w_iuq  = (const float*)d_in[8];
  const float* w_w    = (const float*)d_in[9];
  const float* w_k    = (const float*)d_in[10];
  const float* w_uq   = (const float*)d_in[11];
  const float* o_down = (const float*)d_in[12];
  const float* o_up   = (const float*)d_in[13];
  const float* kvn_w  = (const float*)d_in[14];
  const float* kvn_b  = (const float*)d_in[15];
  const float* qn_w   = (const float*)d_in[16];
  const float* qn_b   = (const float*)d_in[17];
  const float* sink   = (const float*)d_in[18];
  float* out = (float*)d_out;
  float* ws = (float*)d_ws;

  float* c_a  = ws + OFF_CA;
  float* c_b  = ws + OFF_CB;
  float* z_a  = ws + OFF_ZA;
  float* z_b  = ws + OFF_ZB;
  float* c_q  = ws + OFF_CQ;
  float* q_i  = ws + OFF_QI;
  float* hw   = ws + OFF_HW;
  float* k_pr = ws + OFF_KP;
  float* comp = ws + OFF_COMP;
  float* kc   = ws + OFF_KC;
  float* k_or = ws + OFF_KO;
  float* isc  = ws + OFF_ISC;
  float* attn_out = ws + OFF_ISC;  // reuse (iscores dead after topk)
  int*   tidx = (int*)(ws + OFF_TIDX);
  float* q_uq = ws + OFF_QUQ;
  float* q    = ws + OFF_Q;
  float* g_buf = ws + OFF_QUQ;     // reuse q_uq+q region (dead after attn)

  dim3 blk(256);

  // token projections (K = 2048)
  gemm_f32<<<dim3(1, 64), blk, 0, stream>>>(x, w_kv_a, c_a, D_, D_, C_, C_);
  gemm_f32<<<dim3(1, 64), blk, 0, stream>>>(x, w_kv_b, c_b, D_, D_, C_, C_);
  gemm_f32<<<dim3(1, 64), blk, 0, stream>>>(x, w_z_a, z_a, D_, D_, C_, C_);
  gemm_f32<<<dim3(1, 64), blk, 0, stream>>>(x, w_z_b, z_b, D_, D_, C_, C_);
  gemm_f32<<<dim3(8, 64), blk, 0, stream>>>(x, w_dq, c_q, D_, D_, DC_, DC_);
  hw_kernel<<<64, blk, 0, stream>>>(x, w_w, hw);
  mean4_kernel<<<8192, blk, 0, stream>>>(x, k_or);
  gemm_f32<<<dim3(1, 16), blk, 0, stream>>>(k_or, w_k, k_pr, D_, D_, CI_, CI_);
  gemm_f32<<<dim3(4, 64), blk, 0, stream>>>(c_q, w_iuq, q_i, DC_, DC_, NHI_ * CI_, NHI_ * CI_);
  gemm_f32<<<dim3(16, 64), blk, 0, stream>>>(c_q, w_uq, q_uq, DC_, DC_, NH_ * C_, NH_ * C_);

  // gating -> compressed -> kc (LN)
  gate_kernel<<<256, blk, 0, stream>>>(c_a, c_b, z_a, z_b, b_a, b_b, comp);
  ln_kernel<<<256, blk, 0, stream>>>(comp, kvn_w, kvn_b, kc);

  // q: LN + RoPE
  ln_rope_q_kernel<<<16384, blk, 0, stream>>>(q_uq, qn_w, qn_b, q);

  // indexer scores + top-k
  iscores_kernel<<<S_, blk, 0, stream>>>(q_i, k_pr, hw, isc);
  topk_kernel<<<S_, dim3(512), 0, stream>>>(isc, tidx);

  // sparse attention (writes attn_out, aliases isc)
  attn_kernel<<<S_, blk, 0, stream>>>(q, kc, tidx, sink, attn_out);

  // o_down per group, then o_up
  for (int g = 0; g < NG_; ++g) {
    gemm_f32<<<dim3(8, 64), blk, 0, stream>>>(
        attn_out + g * 256, o_down + (size_t)g * 256 * DG_, g_buf + g * DG_,
        256, NH_ * C_, DG_, NG_ * DG_);
  }
  gemm_f32<<<dim3(32, 64), blk, 0, stream>>>(g_buf, o_up, out, NG_ * DG_, NG_ * DG_, D_, D_);
}

// Round 3
// 1376.851 us; speedup vs baseline: 1.6360x; 1.6360x over previous
//
#include <hip/hip_runtime.h>
#include <math.h>

// Problem constants (B=1 throughout)
#define S_   4096
#define D_   2048
#define M_   4
#define NC_  1024
#define TOPK_ 512
#define NH_  16
#define C_   64
#define DC_  512
#define NG_  4
#define DG_  512
#define CI_  64
#define NHI_ 4
#define ROPE_ 32
#define EPS_ 1e-6f

typedef __attribute__((ext_vector_type(8))) short short8;
typedef __attribute__((ext_vector_type(4))) float floatx4;

__device__ inline unsigned short f2bf(float f) {
  unsigned u = __float_as_uint(f);
  u += 0x7fff + ((u >> 16) & 1);   // round-to-nearest-even
  return (unsigned short)(u >> 16);
}
__device__ inline float bf2f(unsigned short h) {
  return __uint_as_float(((unsigned)h) << 16);
}

// ---------------------------------------------------------------------------
// bf16 MFMA GEMM (m97 structure): C = A @ Bt^T.
// A: M x K bf16 row-major (lda). Bt: N x K bf16 row-major (ldb) -- i.e. B^T.
// Tile 128x128, BK=32, 256 threads = 4 waves, each wave 64x64 via 4x4 frags of
// 16x16x32. Staging via global_load_lds width=16 with XOR chunk swizzle.
// Output: fp32 to Cf if Cb==null, else bf16 to Cb.
// ---------------------------------------------------------------------------
__global__ __launch_bounds__(256) void gemm_bf16(
    const unsigned short* __restrict__ A, const unsigned short* __restrict__ Bt,
    float* __restrict__ Cf, unsigned short* __restrict__ Cb,
    int K, int lda, int ldb, int ldc) {
  __shared__ unsigned short As[128 * 32];
  __shared__ unsigned short Bs[128 * 32];
  int tid = threadIdx.x;
  int bm = blockIdx.y * 128, bn = blockIdx.x * 128;
  int lane = tid & 63, wid = tid >> 6;
  int wm = (wid >> 1) * 64, wn = (wid & 1) * 64;
  int qd = lane >> 4, m16 = lane & 15;

  floatx4 acc[4][4];
#pragma unroll
  for (int i = 0; i < 4; ++i)
#pragma unroll
    for (int j = 0; j < 4; ++j) acc[i][j] = (floatx4){0.f, 0.f, 0.f, 0.f};

  for (int k0 = 0; k0 < K; k0 += 32) {
#pragma unroll
    for (int i = 0; i < 2; ++i) {
      int idx = tid + 256 * i;
      int r = idx >> 2, s = idx & 3;
      int g = s ^ ((r >> 1) & 3);
      __builtin_amdgcn_global_load_lds(
          (const __attribute__((address_space(1))) unsigned int*)(A + (size_t)(bm + r) * lda + k0 + g * 8),
          (__attribute__((address_space(3))) unsigned int*)(&As[idx * 8]), 16, 0, 0);
    }
#pragma unroll
    for (int i = 0; i < 2; ++i) {
      int idx = tid + 256 * i;
      int r = idx >> 2, s = idx & 3;
      int g = s ^ ((r >> 1) & 3);
      __builtin_amdgcn_global_load_lds(
          (const __attribute__((address_space(1))) unsigned int*)(Bt + (size_t)(bn + r) * ldb + k0 + g * 8),
          (__attribute__((address_space(3))) unsigned int*)(&Bs[idx * 8]), 16, 0, 0);
    }
    __syncthreads();
    short8 af[4], bfr[4];
#pragma unroll
    for (int mi = 0; mi < 4; ++mi) {
      int r = wm + mi * 16 + m16;
      int slot = qd ^ ((r >> 1) & 3);
      af[mi] = *(const short8*)&As[r * 32 + slot * 8];
    }
#pragma unroll
    for (int ni = 0; ni < 4; ++ni) {
      int r = wn + ni * 16 + m16;
      int slot = qd ^ ((r >> 1) & 3);
      bfr[ni] = *(const short8*)&Bs[r * 32 + slot * 8];
    }
#pragma unroll
    for (int mi = 0; mi < 4; ++mi)
#pragma unroll
      for (int ni = 0; ni < 4; ++ni)
        acc[mi][ni] = __builtin_amdgcn_mfma_f32_16x16x32_bf16(af[mi], bfr[ni], acc[mi][ni], 0, 0, 0);
    __syncthreads();
  }
#pragma unroll
  for (int mi = 0; mi < 4; ++mi)
#pragma unroll
    for (int ni = 0; ni < 4; ++ni) {
      int col = bn + wn + ni * 16 + m16;
#pragma unroll
      for (int rg = 0; rg < 4; ++rg) {
        int row = bm + wm + mi * 16 + qd * 4 + rg;
        if (Cb)
          Cb[(size_t)row * ldc + col] = f2bf(acc[mi][ni][rg]);
        else
          Cf[(size_t)row * ldc + col] = acc[mi][ni][rg];
      }
    }
}

// ---------------------------------------------------------------------------
// Split-bf16 MFMA GEMM: fp32-accurate C = A @ Bt^T via
// Ah·Bh + Ah·Bl + Al·Bh  (A = Ah + Al, B = Bh + Bl; ~17 mantissa bits).
// Used for the top-k-feeding path where selection is precision-critical.
// ---------------------------------------------------------------------------
__global__ __launch_bounds__(256) void gemm_bf16_split(
    const unsigned short* __restrict__ Ah, const unsigned short* __restrict__ Al,
    const unsigned short* __restrict__ Bh, const unsigned short* __restrict__ Bl,
    float* __restrict__ Cf, int K, int lda, int ldb, int ldc) {
  __shared__ unsigned short Ash[128 * 32];
  __shared__ unsigned short Asl[128 * 32];
  __shared__ unsigned short Bsh[128 * 32];
  __shared__ unsigned short Bsl[128 * 32];
  int tid = threadIdx.x;
  int bm = blockIdx.y * 128, bn = blockIdx.x * 128;
  int lane = tid & 63, wid = tid >> 6;
  int wm = (wid >> 1) * 64, wn = (wid & 1) * 64;
  int qd = lane >> 4, m16 = lane & 15;

  floatx4 acc[4][4];
#pragma unroll
  for (int i = 0; i < 4; ++i)
#pragma unroll
    for (int j = 0; j < 4; ++j) acc[i][j] = (floatx4){0.f, 0.f, 0.f, 0.f};

  for (int k0 = 0; k0 < K; k0 += 32) {
#pragma unroll
    for (int i = 0; i < 2; ++i) {
      int idx = tid + 256 * i;
      int r = idx >> 2, s = idx & 3;
      int g = s ^ ((r >> 1) & 3);
      size_t aoff = (size_t)(bm + r) * lda + k0 + g * 8;
      size_t boff = (size_t)(bn + r) * ldb + k0 + g * 8;
      __builtin_amdgcn_global_load_lds(
          (const __attribute__((address_space(1))) unsigned int*)(Ah + aoff),
          (__attribute__((address_space(3))) unsigned int*)(&Ash[idx * 8]), 16, 0, 0);
      __builtin_amdgcn_global_load_lds(
          (const __attribute__((address_space(1))) unsigned int*)(Al + aoff),
          (__attribute__((address_space(3))) unsigned int*)(&Asl[idx * 8]), 16, 0, 0);
      __builtin_amdgcn_global_load_lds(
          (const __attribute__((address_space(1))) unsigned int*)(Bh + boff),
          (__attribute__((address_space(3))) unsigned int*)(&Bsh[idx * 8]), 16, 0, 0);
      __builtin_amdgcn_global_load_lds(
          (const __attribute__((address_space(1))) unsigned int*)(Bl + boff),
          (__attribute__((address_space(3))) unsigned int*)(&Bsl[idx * 8]), 16, 0, 0);
    }
    __syncthreads();
    short8 afh[4], afl[4], bfh[4], bfl[4];
#pragma unroll
    for (int mi = 0; mi < 4; ++mi) {
      int r = wm + mi * 16 + m16;
      int slot = qd ^ ((r >> 1) & 3);
      afh[mi] = *(const short8*)&Ash[r * 32 + slot * 8];
      afl[mi] = *(const short8*)&Asl[r * 32 + slot * 8];
    }
#pragma unroll
    for (int ni = 0; ni < 4; ++ni) {
      int r = wn + ni * 16 + m16;
      int slot = qd ^ ((r >> 1) & 3);
      bfh[ni] = *(const short8*)&Bsh[r * 32 + slot * 8];
      bfl[ni] = *(const short8*)&Bsl[r * 32 + slot * 8];
    }
#pragma unroll
    for (int mi = 0; mi < 4; ++mi)
#pragma unroll
      for (int ni = 0; ni < 4; ++ni) {
        acc[mi][ni] = __builtin_amdgcn_mfma_f32_16x16x32_bf16(afh[mi], bfh[ni], acc[mi][ni], 0, 0, 0);
        acc[mi][ni] = __builtin_amdgcn_mfma_f32_16x16x32_bf16(afh[mi], bfl[ni], acc[mi][ni], 0, 0, 0);
        acc[mi][ni] = __builtin_amdgcn_mfma_f32_16x16x32_bf16(afl[mi], bfh[ni], acc[mi][ni], 0, 0, 0);
      }
    __syncthreads();
  }
#pragma unroll
  for (int mi = 0; mi < 4; ++mi)
#pragma unroll
    for (int ni = 0; ni < 4; ++ni) {
      int col = bn + wn + ni * 16 + m16;
#pragma unroll
      for (int rg = 0; rg < 4; ++rg) {
        int row = bm + wm + mi * 16 + qd * 4 + rg;
        Cf[(size_t)row * ldc + col] = acc[mi][ni][rg];
      }
    }
}

// ---------------------------------------------------------------------------
// fp32 tiled GEMM (kept for the tiny k_proj GEMM, N=64)
// ---------------------------------------------------------------------------
#define BM 64
#define BN 64
#define BK 16
__global__ __launch_bounds__(256) void gemm_f32(
    const float* __restrict__ A, const float* __restrict__ B,
    float* __restrict__ C, int K, int lda, int ldb, int ldc) {
  __shared__ float As[BK][BM + 4];
  __shared__ float Bs[BK][BN + 4];
  int tid = threadIdx.x;
  int bm = blockIdx.y * BM;
  int bn = blockIdx.x * BN;
  int tr = tid >> 4;
  int tc = tid & 15;
  float acc[4][4] = {{0.f}};
  for (int k0 = 0; k0 < K; k0 += BK) {
    int ac = tid & 15;
    int ar0 = tid >> 4;
#pragma unroll
    for (int i = 0; i < 4; ++i) {
      int r = ar0 + 16 * i;
      As[ac][r] = A[(size_t)(bm + r) * lda + k0 + ac];
    }
    int bc = tid & 63;
    int br0 = tid >> 6;
#pragma unroll
    for (int i = 0; i < 4; ++i) {
      int r = br0 + 4 * i;
      Bs[r][bc] = B[(size_t)(k0 + r) * ldb + bn + bc];
    }
    __syncthreads();
#pragma unroll
    for (int kk = 0; kk < BK; ++kk) {
      float4 av = *(const float4*)&As[kk][tr * 4];
      float4 bv = *(const float4*)&Bs[kk][tc * 4];
      float a[4] = {av.x, av.y, av.z, av.w};
      float b[4] = {bv.x, bv.y, bv.z, bv.w};
#pragma unroll
      for (int i = 0; i < 4; ++i)
#pragma unroll
        for (int j = 0; j < 4; ++j) acc[i][j] += a[i] * b[j];
    }
    __syncthreads();
  }
#pragma unroll
  for (int i = 0; i < 4; ++i) {
    float4 v = make_float4(acc[i][0], acc[i][1], acc[i][2], acc[i][3]);
    *(float4*)&C[(size_t)(bm + tr * 4 + i) * ldc + bn + tc * 4] = v;
  }
}

// fp32 -> (bf16 hi, bf16 lo) element-wise split (n multiple of 4)
__global__ void cast_split(const float* __restrict__ in, unsigned short* __restrict__ hi,
                           unsigned short* __restrict__ lo, int n) {
  int i = (blockIdx.x * 256 + threadIdx.x) * 4;
  if (i >= n) return;
  float4 v = *(const float4*)&in[i];
  ushort4 h = make_ushort4(f2bf(v.x), f2bf(v.y), f2bf(v.z), f2bf(v.w));
  ushort4 l = make_ushort4(f2bf(v.x - bf2f(h.x)), f2bf(v.y - bf2f(h.y)),
                           f2bf(v.z - bf2f(h.z)), f2bf(v.w - bf2f(h.w)));
  *(ushort4*)&hi[i] = h;
  *(ushort4*)&lo[i] = l;
}

// fp32 (K x N) -> bf16 transpose (N x K). K,N multiples of 32.
__global__ __launch_bounds__(256) void transpose_cast(
    const float* __restrict__ in, unsigned short* __restrict__ out, int K, int N) {
  __shared__ float t[32][33];
  int k0 = blockIdx.x * 32, n0 = blockIdx.y * 32;
  int tx = threadIdx.x & 31, ty = threadIdx.x >> 5;
#pragma unroll
  for (int i = 0; i < 4; ++i)
    t[ty * 4 + i][tx] = in[(size_t)(k0 + ty * 4 + i) * N + n0 + tx];
  __syncthreads();
#pragma unroll
  for (int i = 0; i < 4; ++i)
    out[(size_t)(n0 + ty * 4 + i) * K + k0 + tx] = f2bf(t[tx][ty * 4 + i]);
}

// fp32 (K x N) -> bf16 transpose split (N x K, hi+lo)
__global__ __launch_bounds__(256) void transpose_cast_split(
    const float* __restrict__ in, unsigned short* __restrict__ outh,
    unsigned short* __restrict__ outl, int K, int N) {
  __shared__ float t[32][33];
  int k0 = blockIdx.x * 32, n0 = blockIdx.y * 32;
  int tx = threadIdx.x & 31, ty = threadIdx.x >> 5;
#pragma unroll
  for (int i = 0; i < 4; ++i)
    t[ty * 4 + i][tx] = in[(size_t)(k0 + ty * 4 + i) * N + n0 + tx];
  __syncthreads();
#pragma unroll
  for (int i = 0; i < 4; ++i) {
    float v = t[tx][ty * 4 + i];
    unsigned short h = f2bf(v);
    outh[(size_t)(n0 + ty * 4 + i) * K + k0 + tx] = h;
    outl[(size_t)(n0 + ty * 4 + i) * K + k0 + tx] = f2bf(v - bf2f(h));
  }
}

// k_orig[j,d] = mean over 4 tokens
__global__ void mean4_kernel(const float* __restrict__ x, float* __restrict__ ko) {
  int i = blockIdx.x * 256 + threadIdx.x;
  if (i >= NC_ * D_) return;
  int j = i >> 11, d = i & (D_ - 1);
  const float* p = x + (size_t)j * 4 * D_ + d;
  ko[i] = 0.25f * (p[0] + p[D_] + p[2 * D_] + p[3 * D_]);
}

// hw = x @ w_w  (S x 4)
__global__ void hw_kernel(const float* __restrict__ x, const float* __restrict__ ww,
                          float* __restrict__ hw) {
  int i = blockIdx.x * 256 + threadIdx.x;
  if (i >= S_ * NHI_) return;
  int s = i >> 2, h = i & 3;
  const float* xr = x + (size_t)s * D_;
  float acc = 0.f;
  for (int k = 0; k < D_; ++k) acc += xr[k] * ww[k * NHI_ + h];
  hw[i] = acc;
}

// gating softmax; reads packed c4 (S x 256: [c_a|c_b|z_a|z_b])
__global__ void gate_kernel(const float* __restrict__ c4,
                            const float* __restrict__ ba, const float* __restrict__ bb,
                            float* __restrict__ comp) {
  int i = blockIdx.x * 256 + threadIdx.x;
  if (i >= NC_ * C_) return;
  int j = i >> 6, c = i & 63;
  float lg[8], vv[8];
#pragma unroll
  for (int m = 0; m < 4; ++m) {
    if (j == 0) {
      lg[m] = -1e30f + bb[m * C_ + c];
      vv[m] = 0.f;
    } else {
      int row = (j - 1) * 4 + m;
      lg[m] = c4[(size_t)row * 256 + 192 + c] + bb[m * C_ + c];
      vv[m] = c4[(size_t)row * 256 + 64 + c];
    }
    int row2 = j * 4 + m;
    lg[4 + m] = c4[(size_t)row2 * 256 + 128 + c] + ba[m * C_ + c];
    vv[4 + m] = c4[(size_t)row2 * 256 + 0 + c];
  }
  float mx = lg[0];
#pragma unroll
  for (int t = 1; t < 8; ++t) mx = fmaxf(mx, lg[t]);
  float se = 0.f, acc = 0.f;
#pragma unroll
  for (int t = 0; t < 8; ++t) {
    float e = expf(lg[t] - mx);
    se += e;
    acc += e * vv[t];
  }
  comp[i] = acc / se;
}

__device__ inline float wave_sum64(float v) {
#pragma unroll
  for (int off = 32; off > 0; off >>= 1) v += __shfl_xor(v, off, 64);
  return v;
}

// LayerNorm over C=64; one wave per row; block = 4 rows
__global__ void ln_kernel(const float* __restrict__ in, const float* __restrict__ w,
                          const float* __restrict__ b, float* __restrict__ out) {
  int row = blockIdx.x * 4 + (threadIdx.x >> 6);
  int c = threadIdx.x & 63;
  float v = in[(size_t)row * C_ + c];
  float mu = wave_sum64(v) * (1.f / 64.f);
  float d = v - mu;
  float var = wave_sum64(d * d) * (1.f / 64.f);
  out[(size_t)row * C_ + c] = d * (1.f / sqrtf(var + EPS_)) * w[c] + b[c];
}

// LN + RoPE for q. Rows = s*16+h, one wave per row.
__global__ void ln_rope_q_kernel(const float* __restrict__ quq, const float* __restrict__ w,
                                 const float* __restrict__ b, float* __restrict__ q) {
  int row = blockIdx.x * 4 + (threadIdx.x >> 6);  // s*16 + h
  int s = row >> 4;
  int c = threadIdx.x & 63;
  float v = quq[(size_t)row * C_ + c];
  float mu = wave_sum64(v) * (1.f / 64.f);
  float d = v - mu;
  float var = wave_sum64(d * d) * (1.f / 64.f);
  float y = d * (1.f / sqrtf(var + EPS_)) * w[c] + b[c];
  float outv;
  float partner = __shfl_xor(y, 1, 64);
  if (c < C_ - ROPE_) {
    outv = y;
  } else {
    int p = (c - (C_ - ROPE_)) >> 1;
    float inv = powf(10000.f, -(2.f * (float)p) / (float)ROPE_);
    float ang = (float)s * inv;
    float cs = cosf(ang), sn = sinf(ang);
    if ((c & 1) == 0)
      outv = y * cs - partner * sn;
    else
      outv = partner * sn + y * cs;
  }
  q[(size_t)row * C_ + c] = outv;
}

// indexer scores
__global__ __launch_bounds__(256) void iscores_kernel(
    const float* __restrict__ qi, const float* __restrict__ kp,
    const float* __restrict__ hw, float* __restrict__ isc) {
  int s = blockIdx.x;
  __shared__ float qs[NHI_ * CI_];
  __shared__ float hws[NHI_];
  int tid = threadIdx.x;
  qs[tid] = qi[(size_t)s * NHI_ * CI_ + tid];
  if (tid < NHI_) hws[tid] = hw[s * NHI_ + tid];
  __syncthreads();
  for (int k = tid; k < NC_; k += 256) {
    float sc = 0.f;
    const float* krow = kp + (size_t)k * CI_;
#pragma unroll
    for (int h = 0; h < NHI_; ++h) {
      float d = 0.f;
      const float* qrow = &qs[h * CI_];
#pragma unroll 16
      for (int c = 0; c < CI_; c += 4) {
        float4 qv = *(const float4*)&qrow[c];
        float4 kv = *(const float4*)&krow[c];
        d += qv.x * kv.x + qv.y * kv.y + qv.z * kv.z + qv.w * kv.w;
      }
      sc += fmaxf(d, 0.f) * hws[h];
    }
    isc[(size_t)s * NC_ + k] = (k < s) ? sc : -__builtin_inff();
  }
}

// top-512 of 1024 via bitonic sort (matches jax.lax.top_k tie semantics)
__global__ __launch_bounds__(512) void topk_kernel(const float* __restrict__ isc,
                                                   int* __restrict__ tidx) {
  __shared__ unsigned long long keys[NC_];
  int s = blockIdx.x;
  int tid = threadIdx.x;
  for (int i = tid; i < NC_; i += 512) {
    float v = isc[(size_t)s * NC_ + i];
    unsigned u = __float_as_uint(v);
    unsigned m = (u & 0x80000000u) ? ~u : (u | 0x80000000u);
    keys[i] = ((unsigned long long)(~m) << 32) | (unsigned)i;
  }
  __syncthreads();
  for (int k = 2; k <= NC_; k <<= 1) {
    for (int j = k >> 1; j > 0; j >>= 1) {
      for (int i = tid; i < NC_; i += 512) {
        int ixj = i ^ j;
        if (ixj > i) {
          unsigned long long a = keys[i], bke = keys[ixj];
          bool up = ((i & k) == 0);
          if ((a > bke) == up) {
            keys[i] = bke;
            keys[ixj] = a;
          }
        }
      }
      __syncthreads();
    }
  }
  if (tid < TOPK_) tidx[(size_t)s * TOPK_ + tid] = (int)(keys[tid] & 0xFFFFFFFFu);
}

// attention: block per s, 256 threads. Writes bf16 output for o_down GEMM.
__global__ __launch_bounds__(256) void attn_kernel(
    const float* __restrict__ q, const float* __restrict__ kc,
    const int* __restrict__ tidx, const float* __restrict__ sink,
    unsigned short* __restrict__ out) {
  int s = blockIdx.x;
  int tid = threadIdx.x;
  __shared__ float qs[NH_ * C_];
  __shared__ int idxs[TOPK_];
  __shared__ float tile[64 * 68];
  __shared__ float ev[NH_ * TOPK_];
  __shared__ float denom[NH_];
  for (int i = tid; i < NH_ * C_; i += 256) qs[i] = q[(size_t)s * NH_ * C_ + i];
  for (int i = tid; i < TOPK_; i += 256) idxs[i] = tidx[(size_t)s * TOPK_ + i];
  __syncthreads();
  int h = tid >> 4;
  int l = tid & 15;
  float dpart = 0.f;
  for (int t0 = 0; t0 < TOPK_; t0 += 64) {
    for (int i = tid; i < 64 * 64; i += 256) {
      int r = i >> 6, c = i & 63;
      tile[r * 68 + c] = kc[(size_t)idxs[t0 + r] * C_ + c];
    }
    __syncthreads();
#pragma unroll
    for (int jj = 0; jj < 4; ++jj) {
      int kk = l + 16 * jj;
      int ksel = idxs[t0 + kk];
      float sc = 0.f;
      const float* qrow = &qs[h * C_];
      const float* krow = &tile[kk * 68];
#pragma unroll 16
      for (int c = 0; c < C_; c += 4) {
        float4 qv = *(const float4*)&qrow[c];
        float4 kv = *(const float4*)&krow[c];
        sc += qv.x * kv.x + qv.y * kv.y + qv.z * kv.z + qv.w * kv.w;
      }
      sc *= 0.125f;
      float e = (s < ksel * M_) ? expf(sc) : 0.f;
      ev[h * TOPK_ + t0 + kk] = e;
      dpart += e;
    }
    __syncthreads();
  }
#pragma unroll
  for (int off = 8; off > 0; off >>= 1) dpart += __shfl_xor(dpart, off, 64);
  if (l == 0) denom[h] = dpart + expf(sink[h]);
  __syncthreads();
  int c0 = (tid & 15) * 4;
  float oa[4] = {0.f, 0.f, 0.f, 0.f};
  for (int t0 = 0; t0 < TOPK_; t0 += 64) {
    for (int i = tid; i < 64 * 64; i += 256) {
      int r = i >> 6, c = i & 63;
      tile[r * 68 + c] = kc[(size_t)idxs[t0 + r] * C_ + c];
    }
    __syncthreads();
#pragma unroll 8
    for (int kk = 0; kk < 64; ++kk) {
      float e = ev[h * TOPK_ + t0 + kk];
      const float* krow = &tile[kk * 68 + c0];
      float4 kv = *(const float4*)krow;
      oa[0] += e * kv.x;
      oa[1] += e * kv.y;
      oa[2] += e * kv.z;
      oa[3] += e * kv.w;
    }
    __syncthreads();
  }
  float dn = denom[h];
  ushort4 r = make_ushort4(f2bf(oa[0] / dn), f2bf(oa[1] / dn), f2bf(oa[2] / dn), f2bf(oa[3] / dn));
  *(ushort4*)&out[(size_t)s * NH_ * C_ + h * C_ + c0] = r;
}

// ---------------------------------------------------------------------------
// Workspace layout (float offsets)
// ---------------------------------------------------------------------------
#define OFF_QUQ    0u          // 4194304 f : quq fp32 -> reused as isc
#define OFF_Q      4194304u    // 4194304 f : q fp32
#define OFF_XH     8388608u    // 4194304 f : xh bf16 -> reused as gb
#define OFF_XL     12582912u   // 4194304 f : xl bf16
#define OFF_TIDX   16777216u   // 2097152 f : int
#define OFF_KO     18874368u   // 2097152 f : k_or fp32 -> reused as attnb bf16
#define OFF_C4     20971520u   // 1048576 f
#define OFF_CQF    22020096u   // 2097152 f : c_q fp32
#define OFF_QI     24117248u   // 1048576 f
#define OFF_CQH    25165824u   // 1048576 f : c_q hi bf16
#define OFF_CQL    26214400u   // 1048576 f : c_q lo bf16
#define OFF_WPACKT 27262976u   // 262144 f
#define OFF_WDQTH  27525120u   // 524288 f
#define OFF_WDQTL  28049408u   // 524288 f
#define OFF_WIUQTH 28573696u   // 65536 f
#define OFF_WIUQTL 28639232u   // 65536 f
#define OFF_WUQT   28704768u   // 262144 f
#define OFF_ODOWNT 28966912u   // 262144 f
#define OFF_OUPT   29229056u   // 2097152 f
#define OFF_HW     31326208u   // 16384 f
#define OFF_COMP   31342592u   // 65536 f
#define OFF_KC     31408128u   // 65536 f
#define OFF_KPR    31473664u   // 65536 f

extern "C" void kernel_launch(void* const* d_in, const int* in_sizes, int n_in,
                              void* d_out, int out_size, void* d_ws, size_t ws_size,
                              hipStream_t stream) {
  const float* x      = (const float*)d_in[0];
  const float* w_kv_a = (const float*)d_in[1];
  const float* w_kv_b = (const float*)d_in[2];
  const float* w_z_a  = (const float*)d_in[3];
  const float* w_z_b  = (const float*)d_in[4];
  const float* b_a    = (const float*)d_in[5];
  const float* b_b    = (const float*)d_in[6];
  const float* w_dq   = (const float*)d_in[7];
  const float* w_iuq  = (const float*)d_in[8];
  const float* w_w    = (const float*)d_in[9];
  const float* w_k    = (const float*)d_in[10];
  const float* w_uq   = (const float*)d_in[11];
  const float* o_down = (const float*)d_in[12];
  const float* o_up   = (const float*)d_in[13];
  const float* kvn_w  = (const float*)d_in[14];
  const float* kvn_b  = (const float*)d_in[15];
  const float* qn_w   = (const float*)d_in[16];
  const float* qn_b   = (const float*)d_in[17];
  const float* sink   = (const float*)d_in[18];
  float* out = (float*)d_out;
  float* ws = (float*)d_ws;

  float* quq   = ws + OFF_QUQ;
  float* isc   = ws + OFF_QUQ;           // reuse (quq dead after ln_rope)
  float* q     = ws + OFF_Q;
  unsigned short* xh = (unsigned short*)(ws + OFF_XH);
  unsigned short* gb = (unsigned short*)(ws + OFF_XH);  // reuse (xh dead after c_q)
  unsigned short* xl = (unsigned short*)(ws + OFF_XL);
  int*   tidx  = (int*)(ws + OFF_TIDX);
  float* k_or  = ws + OFF_KO;
  unsigned short* attnb = (unsigned short*)(ws + OFF_KO);  // reuse
  float* c4    = ws + OFF_C4;
  float* cqf   = ws + OFF_CQF;
  float* q_i   = ws + OFF_QI;
  unsigned short* cqh = (unsigned short*)(ws + OFF_CQH);
  unsigned short* cql = (unsigned short*)(ws + OFF_CQL);
  unsigned short* wpackT = (unsigned short*)(ws + OFF_WPACKT);
  unsigned short* wdqTh  = (unsigned short*)(ws + OFF_WDQTH);
  unsigned short* wdqTl  = (unsigned short*)(ws + OFF_WDQTL);
  unsigned short* wiuqTh = (unsigned short*)(ws + OFF_WIUQTH);
  unsigned short* wiuqTl = (unsigned short*)(ws + OFF_WIUQTL);
  unsigned short* wuqT   = (unsigned short*)(ws + OFF_WUQT);
  unsigned short* odownT = (unsigned short*)(ws + OFF_ODOWNT);
  unsigned short* oupT   = (unsigned short*)(ws + OFF_OUPT);
  float* hw    = ws + OFF_HW;
  float* comp  = ws + OFF_COMP;
  float* kc    = ws + OFF_KC;
  float* k_pr  = ws + OFF_KPR;

  dim3 blk(256);

  // --- casts & weight transposes ---
  cast_split<<<8192, blk, 0, stream>>>(x, xh, xl, S_ * D_);
  transpose_cast<<<dim3(64, 2), blk, 0, stream>>>(w_kv_a, wpackT + 0 * 64 * 2048, D_, C_);
  transpose_cast<<<dim3(64, 2), blk, 0, stream>>>(w_kv_b, wpackT + 1 * 64 * 2048, D_, C_);
  transpose_cast<<<dim3(64, 2), blk, 0, stream>>>(w_z_a,  wpackT + 2 * 64 * 2048, D_, C_);
  transpose_cast<<<dim3(64, 2), blk, 0, stream>>>(w_z_b,  wpackT + 3 * 64 * 2048, D_, C_);
  transpose_cast_split<<<dim3(64, 16), blk, 0, stream>>>(w_dq, wdqTh, wdqTl, D_, DC_);
  transpose_cast_split<<<dim3(16, 8), blk, 0, stream>>>(w_iuq, wiuqTh, wiuqTl, DC_, NHI_ * CI_);
  transpose_cast<<<dim3(16, 32), blk, 0, stream>>>(w_uq, wuqT, DC_, NH_ * C_);
  for (int g = 0; g < NG_; ++g)
    transpose_cast<<<dim3(8, 16), blk, 0, stream>>>(o_down + (size_t)g * 256 * DG_,
                                                    odownT + (size_t)g * DG_ * 256, 256, DG_);
  transpose_cast<<<dim3(64, 64), blk, 0, stream>>>(o_up, oupT, NG_ * DG_, D_);

  // --- fp32 indexer-side path: k_orig -> k_proj, hw ---
  mean4_kernel<<<8192, blk, 0, stream>>>(x, k_or);
  gemm_f32<<<dim3(1, 16), blk, 0, stream>>>(k_or, w_k, k_pr, D_, D_, CI_, CI_);
  hw_kernel<<<64, blk, 0, stream>>>(x, w_w, hw);

  // --- MFMA GEMMs ---
  gemm_bf16<<<dim3(2, 32), blk, 0, stream>>>(xh, wpackT, c4, nullptr, D_, D_, D_, 256);
  // c_q in fp32-accurate split precision (feeds top-k path)
  gemm_bf16_split<<<dim3(4, 32), blk, 0, stream>>>(xh, xl, wdqTh, wdqTl, cqf, D_, D_, D_, DC_);
  cast_split<<<2048, blk, 0, stream>>>(cqf, cqh, cql, S_ * DC_);
  gemm_bf16_split<<<dim3(2, 32), blk, 0, stream>>>(cqh, cql, wiuqTh, wiuqTl, q_i, DC_, DC_, DC_, NHI_ * CI_);
  gemm_bf16<<<dim3(8, 32), blk, 0, stream>>>(cqh, wuqT, quq, nullptr, DC_, DC_, DC_, NH_ * C_);

  // --- gating -> compressed -> kc (LN) ---
  gate_kernel<<<256, blk, 0, stream>>>(c4, b_a, b_b, comp);
  ln_kernel<<<256, blk, 0, stream>>>(comp, kvn_w, kvn_b, kc);

  // --- q: LN + RoPE (consumes quq; must precede iscores which overwrites it) ---
  ln_rope_q_kernel<<<16384, blk, 0, stream>>>(quq, qn_w, qn_b, q);

  // --- indexer scores + top-k ---
  iscores_kernel<<<S_, blk, 0, stream>>>(q_i, k_pr, hw, isc);
  topk_kernel<<<S_, dim3(512), 0, stream>>>(isc, tidx);

  // --- sparse attention (bf16 out) ---
  attn_kernel<<<S_, blk, 0, stream>>>(q, kc, tidx, sink, attnb);

  // --- o_down (4 groups) -> o_up ---
  for (int g = 0; g < NG_; ++g)
    gemm_bf16<<<dim3(4, 32), blk, 0, stream>>>(attnb + g * 256, odownT + (size_t)g * DG_ * 256,
                                               nullptr, gb + g * DG_, 256, NH_ * C_, 256, NG_ * DG_);
  gemm_bf16<<<dim3(16, 32), blk, 0, stream>>>(gb, oupT, out, nullptr, NG_ * DG_, NG_ * DG_, NG_ * DG_, D_);
}

// Round 4
// 981.630 us; speedup vs baseline: 2.2947x; 1.4026x over previous
//
#include <hip/hip_runtime.h>
#include <math.h>

// Problem constants (B=1 throughout)
#define S_   4096
#define D_   2048
#define M_   4
#define NC_  1024
#define TOPK_ 512
#define NH_  16
#define C_   64
#define DC_  512
#define NG_  4
#define DG_  512
#define CI_  64
#define NHI_ 4
#define ROPE_ 32
#define EPS_ 1e-6f

typedef __attribute__((ext_vector_type(8))) short short8;
typedef __attribute__((ext_vector_type(4))) short short4v;
typedef __attribute__((ext_vector_type(4))) float floatx4;

__device__ inline unsigned short f2bf(float f) {
  unsigned u = __float_as_uint(f);
  u += 0x7fff + ((u >> 16) & 1);   // round-to-nearest-even
  return (unsigned short)(u >> 16);
}
__device__ inline float bf2f(unsigned short h) {
  return __uint_as_float(((unsigned)h) << 16);
}

// ---------------------------------------------------------------------------
// bf16 MFMA GEMM (m97 structure): C = A @ Bt^T.
// ---------------------------------------------------------------------------
__global__ __launch_bounds__(256) void gemm_bf16(
    const unsigned short* __restrict__ A, const unsigned short* __restrict__ Bt,
    float* __restrict__ Cf, unsigned short* __restrict__ Cb,
    int K, int lda, int ldb, int ldc) {
  __shared__ unsigned short As[128 * 32];
  __shared__ unsigned short Bs[128 * 32];
  int tid = threadIdx.x;
  int bm = blockIdx.y * 128, bn = blockIdx.x * 128;
  int lane = tid & 63, wid = tid >> 6;
  int wm = (wid >> 1) * 64, wn = (wid & 1) * 64;
  int qd = lane >> 4, m16 = lane & 15;

  floatx4 acc[4][4];
#pragma unroll
  for (int i = 0; i < 4; ++i)
#pragma unroll
    for (int j = 0; j < 4; ++j) acc[i][j] = (floatx4){0.f, 0.f, 0.f, 0.f};

  for (int k0 = 0; k0 < K; k0 += 32) {
#pragma unroll
    for (int i = 0; i < 2; ++i) {
      int idx = tid + 256 * i;
      int r = idx >> 2, s = idx & 3;
      int g = s ^ ((r >> 1) & 3);
      __builtin_amdgcn_global_load_lds(
          (const __attribute__((address_space(1))) unsigned int*)(A + (size_t)(bm + r) * lda + k0 + g * 8),
          (__attribute__((address_space(3))) unsigned int*)(&As[idx * 8]), 16, 0, 0);
    }
#pragma unroll
    for (int i = 0; i < 2; ++i) {
      int idx = tid + 256 * i;
      int r = idx >> 2, s = idx & 3;
      int g = s ^ ((r >> 1) & 3);
      __builtin_amdgcn_global_load_lds(
          (const __attribute__((address_space(1))) unsigned int*)(Bt + (size_t)(bn + r) * ldb + k0 + g * 8),
          (__attribute__((address_space(3))) unsigned int*)(&Bs[idx * 8]), 16, 0, 0);
    }
    __syncthreads();
    short8 af[4], bfr[4];
#pragma unroll
    for (int mi = 0; mi < 4; ++mi) {
      int r = wm + mi * 16 + m16;
      int slot = qd ^ ((r >> 1) & 3);
      af[mi] = *(const short8*)&As[r * 32 + slot * 8];
    }
#pragma unroll
    for (int ni = 0; ni < 4; ++ni) {
      int r = wn + ni * 16 + m16;
      int slot = qd ^ ((r >> 1) & 3);
      bfr[ni] = *(const short8*)&Bs[r * 32 + slot * 8];
    }
#pragma unroll
    for (int mi = 0; mi < 4; ++mi)
#pragma unroll
      for (int ni = 0; ni < 4; ++ni)
        acc[mi][ni] = __builtin_amdgcn_mfma_f32_16x16x32_bf16(af[mi], bfr[ni], acc[mi][ni], 0, 0, 0);
    __syncthreads();
  }
#pragma unroll
  for (int mi = 0; mi < 4; ++mi)
#pragma unroll
    for (int ni = 0; ni < 4; ++ni) {
      int col = bn + wn + ni * 16 + m16;
#pragma unroll
      for (int rg = 0; rg < 4; ++rg) {
        int row = bm + wm + mi * 16 + qd * 4 + rg;
        if (Cb)
          Cb[(size_t)row * ldc + col] = f2bf(acc[mi][ni][rg]);
        else
          Cf[(size_t)row * ldc + col] = acc[mi][ni][rg];
      }
    }
}

// ---------------------------------------------------------------------------
// Split-bf16 MFMA GEMM: fp32-accurate C = A @ Bt^T (top-k-feeding path).
// ---------------------------------------------------------------------------
__global__ __launch_bounds__(256) void gemm_bf16_split(
    const unsigned short* __restrict__ Ah, const unsigned short* __restrict__ Al,
    const unsigned short* __restrict__ Bh, const unsigned short* __restrict__ Bl,
    float* __restrict__ Cf, int K, int lda, int ldb, int ldc) {
  __shared__ unsigned short Ash[128 * 32];
  __shared__ unsigned short Asl[128 * 32];
  __shared__ unsigned short Bsh[128 * 32];
  __shared__ unsigned short Bsl[128 * 32];
  int tid = threadIdx.x;
  int bm = blockIdx.y * 128, bn = blockIdx.x * 128;
  int lane = tid & 63, wid = tid >> 6;
  int wm = (wid >> 1) * 64, wn = (wid & 1) * 64;
  int qd = lane >> 4, m16 = lane & 15;

  floatx4 acc[4][4];
#pragma unroll
  for (int i = 0; i < 4; ++i)
#pragma unroll
    for (int j = 0; j < 4; ++j) acc[i][j] = (floatx4){0.f, 0.f, 0.f, 0.f};

  for (int k0 = 0; k0 < K; k0 += 32) {
#pragma unroll
    for (int i = 0; i < 2; ++i) {
      int idx = tid + 256 * i;
      int r = idx >> 2, s = idx & 3;
      int g = s ^ ((r >> 1) & 3);
      size_t aoff = (size_t)(bm + r) * lda + k0 + g * 8;
      size_t boff = (size_t)(bn + r) * ldb + k0 + g * 8;
      __builtin_amdgcn_global_load_lds(
          (const __attribute__((address_space(1))) unsigned int*)(Ah + aoff),
          (__attribute__((address_space(3))) unsigned int*)(&Ash[idx * 8]), 16, 0, 0);
      __builtin_amdgcn_global_load_lds(
          (const __attribute__((address_space(1))) unsigned int*)(Al + aoff),
          (__attribute__((address_space(3))) unsigned int*)(&Asl[idx * 8]), 16, 0, 0);
      __builtin_amdgcn_global_load_lds(
          (const __attribute__((address_space(1))) unsigned int*)(Bh + boff),
          (__attribute__((address_space(3))) unsigned int*)(&Bsh[idx * 8]), 16, 0, 0);
      __builtin_amdgcn_global_load_lds(
          (const __attribute__((address_space(1))) unsigned int*)(Bl + boff),
          (__attribute__((address_space(3))) unsigned int*)(&Bsl[idx * 8]), 16, 0, 0);
    }
    __syncthreads();
    short8 afh[4], afl[4], bfh[4], bfl[4];
#pragma unroll
    for (int mi = 0; mi < 4; ++mi) {
      int r = wm + mi * 16 + m16;
      int slot = qd ^ ((r >> 1) & 3);
      afh[mi] = *(const short8*)&Ash[r * 32 + slot * 8];
      afl[mi] = *(const short8*)&Asl[r * 32 + slot * 8];
    }
#pragma unroll
    for (int ni = 0; ni < 4; ++ni) {
      int r = wn + ni * 16 + m16;
      int slot = qd ^ ((r >> 1) & 3);
      bfh[ni] = *(const short8*)&Bsh[r * 32 + slot * 8];
      bfl[ni] = *(const short8*)&Bsl[r * 32 + slot * 8];
    }
#pragma unroll
    for (int mi = 0; mi < 4; ++mi)
#pragma unroll
      for (int ni = 0; ni < 4; ++ni) {
        acc[mi][ni] = __builtin_amdgcn_mfma_f32_16x16x32_bf16(afh[mi], bfh[ni], acc[mi][ni], 0, 0, 0);
        acc[mi][ni] = __builtin_amdgcn_mfma_f32_16x16x32_bf16(afh[mi], bfl[ni], acc[mi][ni], 0, 0, 0);
        acc[mi][ni] = __builtin_amdgcn_mfma_f32_16x16x32_bf16(afl[mi], bfh[ni], acc[mi][ni], 0, 0, 0);
      }
    __syncthreads();
  }
#pragma unroll
  for (int mi = 0; mi < 4; ++mi)
#pragma unroll
    for (int ni = 0; ni < 4; ++ni) {
      int col = bn + wn + ni * 16 + m16;
#pragma unroll
      for (int rg = 0; rg < 4; ++rg) {
        int row = bm + wm + mi * 16 + qd * 4 + rg;
        Cf[(size_t)row * ldc + col] = acc[mi][ni][rg];
      }
    }
}

// ---------------------------------------------------------------------------
// fp32 tiled GEMM (kept for the tiny k_proj GEMM, N=64)
// ---------------------------------------------------------------------------
#define BM 64
#define BN 64
#define BK 16
__global__ __launch_bounds__(256) void gemm_f32(
    const float* __restrict__ A, const float* __restrict__ B,
    float* __restrict__ C, int K, int lda, int ldb, int ldc) {
  __shared__ float As[BK][BM + 4];
  __shared__ float Bs[BK][BN + 4];
  int tid = threadIdx.x;
  int bm = blockIdx.y * BM;
  int bn = blockIdx.x * BN;
  int tr = tid >> 4;
  int tc = tid & 15;
  float acc[4][4] = {{0.f}};
  for (int k0 = 0; k0 < K; k0 += BK) {
    int ac = tid & 15;
    int ar0 = tid >> 4;
#pragma unroll
    for (int i = 0; i < 4; ++i) {
      int r = ar0 + 16 * i;
      As[ac][r] = A[(size_t)(bm + r) * lda + k0 + ac];
    }
    int bc = tid & 63;
    int br0 = tid >> 6;
#pragma unroll
    for (int i = 0; i < 4; ++i) {
      int r = br0 + 4 * i;
      Bs[r][bc] = B[(size_t)(k0 + r) * ldb + bn + bc];
    }
    __syncthreads();
#pragma unroll
    for (int kk = 0; kk < BK; ++kk) {
      float4 av = *(const float4*)&As[kk][tr * 4];
      float4 bv = *(const float4*)&Bs[kk][tc * 4];
      float a[4] = {av.x, av.y, av.z, av.w};
      float b[4] = {bv.x, bv.y, bv.z, bv.w};
#pragma unroll
      for (int i = 0; i < 4; ++i)
#pragma unroll
        for (int j = 0; j < 4; ++j) acc[i][j] += a[i] * b[j];
    }
    __syncthreads();
  }
#pragma unroll
  for (int i = 0; i < 4; ++i) {
    float4 v = make_float4(acc[i][0], acc[i][1], acc[i][2], acc[i][3]);
    *(float4*)&C[(size_t)(bm + tr * 4 + i) * ldc + bn + tc * 4] = v;
  }
}

// fp32 -> (bf16 hi, bf16 lo) element-wise split (n multiple of 4)
__global__ void cast_split(const float* __restrict__ in, unsigned short* __restrict__ hi,
                           unsigned short* __restrict__ lo, int n) {
  int i = (blockIdx.x * 256 + threadIdx.x) * 4;
  if (i >= n) return;
  float4 v = *(const float4*)&in[i];
  ushort4 h = make_ushort4(f2bf(v.x), f2bf(v.y), f2bf(v.z), f2bf(v.w));
  ushort4 l = make_ushort4(f2bf(v.x - bf2f(h.x)), f2bf(v.y - bf2f(h.y)),
                           f2bf(v.z - bf2f(h.z)), f2bf(v.w - bf2f(h.w)));
  *(ushort4*)&hi[i] = h;
  *(ushort4*)&lo[i] = l;
}

// fp32 (K x N) -> bf16 transpose (N x K). K,N multiples of 32.
__global__ __launch_bounds__(256) void transpose_cast(
    const float* __restrict__ in, unsigned short* __restrict__ out, int K, int N) {
  __shared__ float t[32][33];
  int k0 = blockIdx.x * 32, n0 = blockIdx.y * 32;
  int tx = threadIdx.x & 31, ty = threadIdx.x >> 5;
#pragma unroll
  for (int i = 0; i < 4; ++i)
    t[ty * 4 + i][tx] = in[(size_t)(k0 + ty * 4 + i) * N + n0 + tx];
  __syncthreads();
#pragma unroll
  for (int i = 0; i < 4; ++i)
    out[(size_t)(n0 + ty * 4 + i) * K + k0 + tx] = f2bf(t[tx][ty * 4 + i]);
}

// fp32 (K x N) -> bf16 transpose split (N x K, hi+lo)
__global__ __launch_bounds__(256) void transpose_cast_split(
    const float* __restrict__ in, unsigned short* __restrict__ outh,
    unsigned short* __restrict__ outl, int K, int N) {
  __shared__ float t[32][33];
  int k0 = blockIdx.x * 32, n0 = blockIdx.y * 32;
  int tx = threadIdx.x & 31, ty = threadIdx.x >> 5;
#pragma unroll
  for (int i = 0; i < 4; ++i)
    t[ty * 4 + i][tx] = in[(size_t)(k0 + ty * 4 + i) * N + n0 + tx];
  __syncthreads();
#pragma unroll
  for (int i = 0; i < 4; ++i) {
    float v = t[tx][ty * 4 + i];
    unsigned short h = f2bf(v);
    outh[(size_t)(n0 + ty * 4 + i) * K + k0 + tx] = h;
    outl[(size_t)(n0 + ty * 4 + i) * K + k0 + tx] = f2bf(v - bf2f(h));
  }
}

// k_orig[j,d] = mean over 4 tokens
__global__ void mean4_kernel(const float* __restrict__ x, float* __restrict__ ko) {
  int i = blockIdx.x * 256 + threadIdx.x;
  if (i >= NC_ * D_) return;
  int j = i >> 11, d = i & (D_ - 1);
  const float* p = x + (size_t)j * 4 * D_ + d;
  ko[i] = 0.25f * (p[0] + p[D_] + p[2 * D_] + p[3 * D_]);
}

// hw = x @ w_w  (S x 4)
__global__ void hw_kernel(const float* __restrict__ x, const float* __restrict__ ww,
                          float* __restrict__ hw) {
  int i = blockIdx.x * 256 + threadIdx.x;
  if (i >= S_ * NHI_) return;
  int s = i >> 2, h = i & 3;
  const float* xr = x + (size_t)s * D_;
  float acc = 0.f;
  for (int k = 0; k < D_; ++k) acc += xr[k] * ww[k * NHI_ + h];
  hw[i] = acc;
}

// gating softmax; reads packed c4 (S x 256: [c_a|c_b|z_a|z_b])
__global__ void gate_kernel(const float* __restrict__ c4,
                            const float* __restrict__ ba, const float* __restrict__ bb,
                            float* __restrict__ comp) {
  int i = blockIdx.x * 256 + threadIdx.x;
  if (i >= NC_ * C_) return;
  int j = i >> 6, c = i & 63;
  float lg[8], vv[8];
#pragma unroll
  for (int m = 0; m < 4; ++m) {
    if (j == 0) {
      lg[m] = -1e30f + bb[m * C_ + c];
      vv[m] = 0.f;
    } else {
      int row = (j - 1) * 4 + m;
      lg[m] = c4[(size_t)row * 256 + 192 + c] + bb[m * C_ + c];
      vv[m] = c4[(size_t)row * 256 + 64 + c];
    }
    int row2 = j * 4 + m;
    lg[4 + m] = c4[(size_t)row2 * 256 + 128 + c] + ba[m * C_ + c];
    vv[4 + m] = c4[(size_t)row2 * 256 + 0 + c];
  }
  float mx = lg[0];
#pragma unroll
  for (int t = 1; t < 8; ++t) mx = fmaxf(mx, lg[t]);
  float se = 0.f, acc = 0.f;
#pragma unroll
  for (int t = 0; t < 8; ++t) {
    float e = expf(lg[t] - mx);
    se += e;
    acc += e * vv[t];
  }
  comp[i] = acc / se;
}

__device__ inline float wave_sum64(float v) {
#pragma unroll
  for (int off = 32; off > 0; off >>= 1) v += __shfl_xor(v, off, 64);
  return v;
}

// LayerNorm over C=64 -> bf16 row-major + bf16 transposed (for attention MFMA)
__global__ void ln_kc_kernel(const float* __restrict__ in, const float* __restrict__ w,
                             const float* __restrict__ b, unsigned short* __restrict__ kcb,
                             unsigned short* __restrict__ kcbT) {
  int row = blockIdx.x * 4 + (threadIdx.x >> 6);
  int c = threadIdx.x & 63;
  float v = in[(size_t)row * C_ + c];
  float mu = wave_sum64(v) * (1.f / 64.f);
  float d = v - mu;
  float var = wave_sum64(d * d) * (1.f / 64.f);
  float y = d * (1.f / sqrtf(var + EPS_)) * w[c] + b[c];
  unsigned short h = f2bf(y);
  kcb[(size_t)row * C_ + c] = h;
  kcbT[(size_t)c * NC_ + row] = h;
}

// LN + RoPE for q -> bf16, pre-scaled by 1/sqrt(C)=0.125 (only attention uses q)
__global__ void ln_rope_q_kernel(const float* __restrict__ quq, const float* __restrict__ w,
                                 const float* __restrict__ b, unsigned short* __restrict__ qb) {
  int row = blockIdx.x * 4 + (threadIdx.x >> 6);  // s*16 + h
  int s = row >> 4;
  int c = threadIdx.x & 63;
  float v = quq[(size_t)row * C_ + c];
  float mu = wave_sum64(v) * (1.f / 64.f);
  float d = v - mu;
  float var = wave_sum64(d * d) * (1.f / 64.f);
  float y = d * (1.f / sqrtf(var + EPS_)) * w[c] + b[c];
  float outv;
  float partner = __shfl_xor(y, 1, 64);
  if (c < C_ - ROPE_) {
    outv = y;
  } else {
    int p = (c - (C_ - ROPE_)) >> 1;
    float inv = powf(10000.f, -(2.f * (float)p) / (float)ROPE_);
    float ang = (float)s * inv;
    float cs = cosf(ang), sn = sinf(ang);
    if ((c & 1) == 0)
      outv = y * cs - partner * sn;
    else
      outv = partner * sn + y * cs;
  }
  qb[(size_t)row * C_ + c] = f2bf(outv * 0.125f);
}

// indexer scores
__global__ __launch_bounds__(256) void iscores_kernel(
    const float* __restrict__ qi, const float* __restrict__ kp,
    const float* __restrict__ hw, float* __restrict__ isc) {
  int s = blockIdx.x;
  __shared__ float qs[NHI_ * CI_];
  __shared__ float hws[NHI_];
  int tid = threadIdx.x;
  qs[tid] = qi[(size_t)s * NHI_ * CI_ + tid];
  if (tid < NHI_) hws[tid] = hw[s * NHI_ + tid];
  __syncthreads();
  for (int k = tid; k < NC_; k += 256) {
    float sc = 0.f;
    const float* krow = kp + (size_t)k * CI_;
#pragma unroll
    for (int h = 0; h < NHI_; ++h) {
      float d = 0.f;
      const float* qrow = &qs[h * CI_];
#pragma unroll 16
      for (int c = 0; c < CI_; c += 4) {
        float4 qv = *(const float4*)&qrow[c];
        float4 kv = *(const float4*)&krow[c];
        d += qv.x * kv.x + qv.y * kv.y + qv.z * kv.z + qv.w * kv.w;
      }
      sc += fmaxf(d, 0.f) * hws[h];
    }
    isc[(size_t)s * NC_ + k] = (k < s) ? sc : -__builtin_inff();
  }
}

// top-512 of 1024 via bitonic sort (matches jax.lax.top_k tie semantics)
__global__ __launch_bounds__(512) void topk_kernel(const float* __restrict__ isc,
                                                   int* __restrict__ tidx) {
  __shared__ unsigned long long keys[NC_];
  int s = blockIdx.x;
  int tid = threadIdx.x;
  for (int i = tid; i < NC_; i += 512) {
    float v = isc[(size_t)s * NC_ + i];
    unsigned u = __float_as_uint(v);
    unsigned m = (u & 0x80000000u) ? ~u : (u | 0x80000000u);
    keys[i] = ((unsigned long long)(~m) << 32) | (unsigned)i;
  }
  __syncthreads();
  for (int k = 2; k <= NC_; k <<= 1) {
    for (int j = k >> 1; j > 0; j >>= 1) {
      for (int i = tid; i < NC_; i += 512) {
        int ixj = i ^ j;
        if (ixj > i) {
          unsigned long long a = keys[i], bke = keys[ixj];
          bool up = ((i & k) == 0);
          if ((a > bke) == up) {
            keys[i] = bke;
            keys[ixj] = a;
          }
        }
      }
      __syncthreads();
    }
  }
  if (tid < TOPK_) tidx[(size_t)s * TOPK_ + tid] = (int)(keys[tid] & 0xFFFFFFFFu);
}

// selection bitmap: sel[s][0..31] bits over 1024 chunks
__global__ void selmask_kernel(const int* __restrict__ tidx, unsigned* __restrict__ sel) {
  int s = blockIdx.x, tid = threadIdx.x;
  __shared__ unsigned wbuf[32];
  if (tid < 32) wbuf[tid] = 0u;
  __syncthreads();
  for (int i = tid; i < TOPK_; i += 64) {
    int idx = tidx[(size_t)s * TOPK_ + i];
    atomicOr(&wbuf[idx >> 5], 1u << (idx & 31));
  }
  __syncthreads();
  if (tid < 32) sel[(size_t)s * 32 + tid] = wbuf[tid];
}

// ---------------------------------------------------------------------------
// Dense-masked flash attention on MFMA.
// Block: 8 tokens x 16 heads = 128 rows; 256 threads = 4 waves (2 tokens/wave).
// Computes S^T = kc_tile @ q^T per 64-chunk tile (so P lands [row][chunk] and
// re-enters PV as a contiguous A-fragment); e = sel&causal ? exp(s) : 0;
// no max-subtraction in ref softmax -> single-pass accumulate denom and e*V.
// ---------------------------------------------------------------------------
#define TS_ 8
__global__ __launch_bounds__(256) void attn_mfma_kernel(
    const unsigned short* __restrict__ qb, const unsigned short* __restrict__ kcb,
    const unsigned short* __restrict__ kcbT, const unsigned* __restrict__ sel,
    const float* __restrict__ sink, unsigned short* __restrict__ out) {
  __shared__ unsigned short kc_s[64 * 72];    // [chunk][dim]
  __shared__ unsigned short kct_s[64 * 72];   // [dim][chunk]
  __shared__ unsigned short p_s[128 * 72];    // [row][chunk] per-wave rows
  __shared__ unsigned selw[TS_][32];
  __shared__ float dls[4][2][16];
  int tid = threadIdx.x;
  int s0 = blockIdx.x * TS_;
  int lane = tid & 63, w = tid >> 6;
  int qd = lane >> 4, m16 = lane & 15;

  for (int i = tid; i < TS_ * 32; i += 256)
    selw[i >> 5][i & 31] = sel[(size_t)(s0 + (i >> 5)) * 32 + (i & 31)];

  // q B-fragments: token tk (2 per wave), k-step ks (dims 0..31 / 32..63)
  short8 qf[2][2];
#pragma unroll
  for (int tk = 0; tk < 2; ++tk)
#pragma unroll
    for (int ks = 0; ks < 2; ++ks)
      qf[tk][ks] = *(const short8*)&qb[(size_t)(s0 + 2 * w + tk) * 1024 + m16 * 64 + ks * 32 + qd * 8];

  floatx4 of[2][4];
#pragma unroll
  for (int i = 0; i < 2; ++i)
#pragma unroll
    for (int j = 0; j < 4; ++j) of[i][j] = (floatx4){0.f, 0.f, 0.f, 0.f};
  float dsum[2] = {0.f, 0.f};

  for (int ct = 0; ct < 16; ++ct) {
    int c0 = ct * 64;
    __syncthreads();
    {
      int r = tid >> 2, cc = (tid & 3) * 16;
      *(short8*)&kc_s[r * 72 + cc]      = *(const short8*)&kcb[(size_t)(c0 + r) * 64 + cc];
      *(short8*)&kc_s[r * 72 + cc + 8]  = *(const short8*)&kcb[(size_t)(c0 + r) * 64 + cc + 8];
      *(short8*)&kct_s[r * 72 + cc]     = *(const short8*)&kcbT[(size_t)r * NC_ + c0 + cc];
      *(short8*)&kct_s[r * 72 + cc + 8] = *(const short8*)&kcbT[(size_t)r * NC_ + c0 + cc + 8];
    }
    __syncthreads();
    // QK^T (transposed): m-tiles = chunks (4), n-tiles = tokens (2)
#pragma unroll
    for (int mc = 0; mc < 4; ++mc) {
      short8 a0 = *(const short8*)&kc_s[(mc * 16 + m16) * 72 + qd * 8];
      short8 a1 = *(const short8*)&kc_s[(mc * 16 + m16) * 72 + 32 + qd * 8];
#pragma unroll
      for (int nt = 0; nt < 2; ++nt) {
        floatx4 sc = (floatx4){0.f, 0.f, 0.f, 0.f};
        sc = __builtin_amdgcn_mfma_f32_16x16x32_bf16(a0, qf[nt][0], sc, 0, 0, 0);
        sc = __builtin_amdgcn_mfma_f32_16x16x32_bf16(a1, qf[nt][1], sc, 0, 0, 0);
        int tokL = 2 * w + nt;
        int sG = s0 + tokL;
        short4v pv;
#pragma unroll
        for (int rg = 0; rg < 4; ++rg) {
          int cG = c0 + mc * 16 + qd * 4 + rg;
          bool ok = (((selw[tokL][cG >> 5] >> (cG & 31)) & 1u) != 0u) && (sG < cG * 4);
          float e = ok ? __expf(sc[rg]) : 0.f;
          dsum[nt] += e;
          pv[rg] = (short)f2bf(e);
        }
        *(short4v*)&p_s[(tokL * 16 + m16) * 72 + mc * 16 + qd * 4] = pv;
      }
    }
    // PV: wave-private p rows (no barrier needed; compiler orders LDS deps)
#pragma unroll
    for (int ks = 0; ks < 2; ++ks) {
      short8 pa0 = *(const short8*)&p_s[((2 * w + 0) * 16 + m16) * 72 + ks * 32 + qd * 8];
      short8 pa1 = *(const short8*)&p_s[((2 * w + 1) * 16 + m16) * 72 + ks * 32 + qd * 8];
#pragma unroll
      for (int nt = 0; nt < 4; ++nt) {
        short8 bv = *(const short8*)&kct_s[(nt * 16 + m16) * 72 + ks * 32 + qd * 8];
        of[0][nt] = __builtin_amdgcn_mfma_f32_16x16x32_bf16(pa0, bv, of[0][nt], 0, 0, 0);
        of[1][nt] = __builtin_amdgcn_mfma_f32_16x16x32_bf16(pa1, bv, of[1][nt], 0, 0, 0);
      }
    }
  }
  // denominators: reduce across quads (lane holds (token nt, head lane&15))
#pragma unroll
  for (int nt = 0; nt < 2; ++nt) {
    dsum[nt] += __shfl_xor(dsum[nt], 16, 64);
    dsum[nt] += __shfl_xor(dsum[nt], 32, 64);
  }
  if (lane < 16) {
    float sk = __expf(sink[lane]);
    dls[w][0][lane] = dsum[0] + sk;
    dls[w][1][lane] = dsum[1] + sk;
  }
  // O: col = dim(lane&15) within n-tile, row = head (qd*4+rg)
#pragma unroll
  for (int tk = 0; tk < 2; ++tk)
#pragma unroll
    for (int nt = 0; nt < 4; ++nt) {
      floatx4 o = of[tk][nt];
#pragma unroll
      for (int rg = 0; rg < 4; ++rg) {
        int head = qd * 4 + rg;
        float dn = dls[w][tk][head];
        out[(size_t)(s0 + 2 * w + tk) * 1024 + head * 64 + nt * 16 + m16] = f2bf(o[rg] / dn);
      }
    }
}

// ---------------------------------------------------------------------------
// Workspace layout (float offsets)
// ---------------------------------------------------------------------------
#define OFF_QUQ    0u          // 4194304 f : quq fp32 -> reused as isc
#define OFF_Q      4194304u    // 4194304 f : qb bf16 (2M shorts)
#define OFF_XH     8388608u    // 4194304 f : xh bf16 -> reused as gb
#define OFF_XL     12582912u   // 4194304 f : xl bf16 -> reused as sel bitmap
#define OFF_TIDX   16777216u   // 2097152 f : int
#define OFF_KO     18874368u   // 2097152 f : k_or fp32 -> reused as attnb bf16
#define OFF_C4     20971520u   // 1048576 f
#define OFF_CQF    22020096u   // 2097152 f : c_q fp32
#define OFF_QI     24117248u   // 1048576 f
#define OFF_CQH    25165824u   // 1048576 f : c_q hi bf16
#define OFF_CQL    26214400u   // 1048576 f : c_q lo bf16
#define OFF_WPACKT 27262976u   // 262144 f
#define OFF_WDQTH  27525120u   // 524288 f
#define OFF_WDQTL  28049408u   // 524288 f
#define OFF_WIUQTH 28573696u   // 65536 f
#define OFF_WIUQTL 28639232u   // 65536 f
#define OFF_WUQT   28704768u   // 262144 f
#define OFF_ODOWNT 28966912u   // 262144 f
#define OFF_OUPT   29229056u   // 2097152 f
#define OFF_HW     31326208u   // 16384 f
#define OFF_COMP   31342592u   // 65536 f
#define OFF_KC     31408128u   // 65536 f : kcb (32768 f) + kcbT (32768 f)
#define OFF_KPR    31473664u   // 65536 f

extern "C" void kernel_launch(void* const* d_in, const int* in_sizes, int n_in,
                              void* d_out, int out_size, void* d_ws, size_t ws_size,
                              hipStream_t stream) {
  const float* x      = (const float*)d_in[0];
  const float* w_kv_a = (const float*)d_in[1];
  const float* w_kv_b = (const float*)d_in[2];
  const float* w_z_a  = (const float*)d_in[3];
  const float* w_z_b  = (const float*)d_in[4];
  const float* b_a    = (const float*)d_in[5];
  const float* b_b    = (const float*)d_in[6];
  const float* w_dq   = (const float*)d_in[7];
  const float* w_iuq  = (const float*)d_in[8];
  const float* w_w    = (const float*)d_in[9];
  const float* w_k    = (const float*)d_in[10];
  const float* w_uq   = (const float*)d_in[11];
  const float* o_down = (const float*)d_in[12];
  const float* o_up   = (const float*)d_in[13];
  const float* kvn_w  = (const float*)d_in[14];
  const float* kvn_b  = (const float*)d_in[15];
  const float* qn_w   = (const float*)d_in[16];
  const float* qn_b   = (const float*)d_in[17];
  const float* sink   = (const float*)d_in[18];
  float* out = (float*)d_out;
  float* ws = (float*)d_ws;

  float* quq   = ws + OFF_QUQ;
  float* isc   = ws + OFF_QUQ;           // reuse (quq dead after ln_rope)
  unsigned short* qb = (unsigned short*)(ws + OFF_Q);
  unsigned short* xh = (unsigned short*)(ws + OFF_XH);
  unsigned short* gb = (unsigned short*)(ws + OFF_XH);  // reuse (xh dead after c_q)
  unsigned short* xl = (unsigned short*)(ws + OFF_XL);
  unsigned* sel = (unsigned*)(ws + OFF_XL);             // reuse (xl dead after cqf)
  int*   tidx  = (int*)(ws + OFF_TIDX);
  float* k_or  = ws + OFF_KO;
  unsigned short* attnb = (unsigned short*)(ws + OFF_KO);  // reuse
  float* c4    = ws + OFF_C4;
  float* cqf   = ws + OFF_CQF;
  float* q_i   = ws + OFF_QI;
  unsigned short* cqh = (unsigned short*)(ws + OFF_CQH);
  unsigned short* cql = (unsigned short*)(ws + OFF_CQL);
  unsigned short* wpackT = (unsigned short*)(ws + OFF_WPACKT);
  unsigned short* wdqTh  = (unsigned short*)(ws + OFF_WDQTH);
  unsigned short* wdqTl  = (unsigned short*)(ws + OFF_WDQTL);
  unsigned short* wiuqTh = (unsigned short*)(ws + OFF_WIUQTH);
  unsigned short* wiuqTl = (unsigned short*)(ws + OFF_WIUQTL);
  unsigned short* wuqT   = (unsigned short*)(ws + OFF_WUQT);
  unsigned short* odownT = (unsigned short*)(ws + OFF_ODOWNT);
  unsigned short* oupT   = (unsigned short*)(ws + OFF_OUPT);
  float* hw    = ws + OFF_HW;
  float* comp  = ws + OFF_COMP;
  unsigned short* kcb  = (unsigned short*)(ws + OFF_KC);
  unsigned short* kcbT = kcb + NC_ * C_;
  float* k_pr  = ws + OFF_KPR;

  dim3 blk(256);

  // --- casts & weight transposes ---
  cast_split<<<8192, blk, 0, stream>>>(x, xh, xl, S_ * D_);
  transpose_cast<<<dim3(64, 2), blk, 0, stream>>>(w_kv_a, wpackT + 0 * 64 * 2048, D_, C_);
  transpose_cast<<<dim3(64, 2), blk, 0, stream>>>(w_kv_b, wpackT + 1 * 64 * 2048, D_, C_);
  transpose_cast<<<dim3(64, 2), blk, 0, stream>>>(w_z_a,  wpackT + 2 * 64 * 2048, D_, C_);
  transpose_cast<<<dim3(64, 2), blk, 0, stream>>>(w_z_b,  wpackT + 3 * 64 * 2048, D_, C_);
  transpose_cast_split<<<dim3(64, 16), blk, 0, stream>>>(w_dq, wdqTh, wdqTl, D_, DC_);
  transpose_cast_split<<<dim3(16, 8), blk, 0, stream>>>(w_iuq, wiuqTh, wiuqTl, DC_, NHI_ * CI_);
  transpose_cast<<<dim3(16, 32), blk, 0, stream>>>(w_uq, wuqT, DC_, NH_ * C_);
  for (int g = 0; g < NG_; ++g)
    transpose_cast<<<dim3(8, 16), blk, 0, stream>>>(o_down + (size_t)g * 256 * DG_,
                                                    odownT + (size_t)g * DG_ * 256, 256, DG_);
  transpose_cast<<<dim3(64, 64), blk, 0, stream>>>(o_up, oupT, NG_ * DG_, D_);

  // --- fp32 indexer-side path: k_orig -> k_proj, hw ---
  mean4_kernel<<<8192, blk, 0, stream>>>(x, k_or);
  gemm_f32<<<dim3(1, 16), blk, 0, stream>>>(k_or, w_k, k_pr, D_, D_, CI_, CI_);
  hw_kernel<<<64, blk, 0, stream>>>(x, w_w, hw);

  // --- MFMA GEMMs ---
  gemm_bf16<<<dim3(2, 32), blk, 0, stream>>>(xh, wpackT, c4, nullptr, D_, D_, D_, 256);
  gemm_bf16_split<<<dim3(4, 32), blk, 0, stream>>>(xh, xl, wdqTh, wdqTl, cqf, D_, D_, D_, DC_);
  cast_split<<<2048, blk, 0, stream>>>(cqf, cqh, cql, S_ * DC_);
  gemm_bf16_split<<<dim3(2, 32), blk, 0, stream>>>(cqh, cql, wiuqTh, wiuqTl, q_i, DC_, DC_, DC_, NHI_ * CI_);
  gemm_bf16<<<dim3(8, 32), blk, 0, stream>>>(cqh, wuqT, quq, nullptr, DC_, DC_, DC_, NH_ * C_);

  // --- gating -> compressed -> kc (LN, bf16 row-major + transposed) ---
  gate_kernel<<<256, blk, 0, stream>>>(c4, b_a, b_b, comp);
  ln_kc_kernel<<<256, blk, 0, stream>>>(comp, kvn_w, kvn_b, kcb, kcbT);

  // --- q: LN + RoPE -> bf16 scaled by 1/8 (consumes quq; precedes iscores) ---
  ln_rope_q_kernel<<<16384, blk, 0, stream>>>(quq, qn_w, qn_b, qb);

  // --- indexer scores + top-k + selection bitmap ---
  iscores_kernel<<<S_, blk, 0, stream>>>(q_i, k_pr, hw, isc);
  topk_kernel<<<S_, dim3(512), 0, stream>>>(isc, tidx);
  selmask_kernel<<<S_, dim3(64), 0, stream>>>(tidx, sel);

  // --- dense-masked flash attention (MFMA) ---
  attn_mfma_kernel<<<S_ / TS_, blk, 0, stream>>>(qb, kcb, kcbT, sel, sink, attnb);

  // --- o_down (4 groups) -> o_up ---
  for (int g = 0; g < NG_; ++g)
    gemm_bf16<<<dim3(4, 32), blk, 0, stream>>>(attnb + g * 256, odownT + (size_t)g * DG_ * 256,
                                               nullptr, gb + g * DG_, 256, NH_ * C_, 256, NG_ * DG_);
  gemm_bf16<<<dim3(16, 32), blk, 0, stream>>>(gb, oupT, out, nullptr, NG_ * DG_, NG_ * DG_, NG_ * DG_, D_);
}

// Round 5
// 824.336 us; speedup vs baseline: 2.7326x; 1.1908x over previous
//
#include <hip/hip_runtime.h>
#include <math.h>

// Problem constants (B=1 throughout)
#define S_   4096
#define D_   2048
#define M_   4
#define NC_  1024
#define TOPK_ 512
#define NH_  16
#define C_   64
#define DC_  512
#define NG_  4
#define DG_  512
#define CI_  64
#define NHI_ 4
#define ROPE_ 32
#define EPS_ 1e-6f

typedef __attribute__((ext_vector_type(8))) short short8;
typedef __attribute__((ext_vector_type(4))) short short4v;
typedef __attribute__((ext_vector_type(4))) float floatx4;

__device__ inline unsigned short f2bf(float f) {
  unsigned u = __float_as_uint(f);
  u += 0x7fff + ((u >> 16) & 1);   // round-to-nearest-even
  return (unsigned short)(u >> 16);
}
__device__ inline float bf2f(unsigned short h) {
  return __uint_as_float(((unsigned)h) << 16);
}

// ---------------------------------------------------------------------------
// bf16 MFMA GEMM (m97 structure): C = A @ Bt^T.
// ---------------------------------------------------------------------------
__global__ __launch_bounds__(256) void gemm_bf16(
    const unsigned short* __restrict__ A, const unsigned short* __restrict__ Bt,
    float* __restrict__ Cf, unsigned short* __restrict__ Cb,
    int K, int lda, int ldb, int ldc) {
  __shared__ unsigned short As[128 * 32];
  __shared__ unsigned short Bs[128 * 32];
  int tid = threadIdx.x;
  int bm = blockIdx.y * 128, bn = blockIdx.x * 128;
  int lane = tid & 63, wid = tid >> 6;
  int wm = (wid >> 1) * 64, wn = (wid & 1) * 64;
  int qd = lane >> 4, m16 = lane & 15;

  floatx4 acc[4][4];
#pragma unroll
  for (int i = 0; i < 4; ++i)
#pragma unroll
    for (int j = 0; j < 4; ++j) acc[i][j] = (floatx4){0.f, 0.f, 0.f, 0.f};

  for (int k0 = 0; k0 < K; k0 += 32) {
#pragma unroll
    for (int i = 0; i < 2; ++i) {
      int idx = tid + 256 * i;
      int r = idx >> 2, s = idx & 3;
      int g = s ^ ((r >> 1) & 3);
      __builtin_amdgcn_global_load_lds(
          (const __attribute__((address_space(1))) unsigned int*)(A + (size_t)(bm + r) * lda + k0 + g * 8),
          (__attribute__((address_space(3))) unsigned int*)(&As[idx * 8]), 16, 0, 0);
    }
#pragma unroll
    for (int i = 0; i < 2; ++i) {
      int idx = tid + 256 * i;
      int r = idx >> 2, s = idx & 3;
      int g = s ^ ((r >> 1) & 3);
      __builtin_amdgcn_global_load_lds(
          (const __attribute__((address_space(1))) unsigned int*)(Bt + (size_t)(bn + r) * ldb + k0 + g * 8),
          (__attribute__((address_space(3))) unsigned int*)(&Bs[idx * 8]), 16, 0, 0);
    }
    __syncthreads();
    short8 af[4], bfr[4];
#pragma unroll
    for (int mi = 0; mi < 4; ++mi) {
      int r = wm + mi * 16 + m16;
      int slot = qd ^ ((r >> 1) & 3);
      af[mi] = *(const short8*)&As[r * 32 + slot * 8];
    }
#pragma unroll
    for (int ni = 0; ni < 4; ++ni) {
      int r = wn + ni * 16 + m16;
      int slot = qd ^ ((r >> 1) & 3);
      bfr[ni] = *(const short8*)&Bs[r * 32 + slot * 8];
    }
#pragma unroll
    for (int mi = 0; mi < 4; ++mi)
#pragma unroll
      for (int ni = 0; ni < 4; ++ni)
        acc[mi][ni] = __builtin_amdgcn_mfma_f32_16x16x32_bf16(af[mi], bfr[ni], acc[mi][ni], 0, 0, 0);
    __syncthreads();
  }
#pragma unroll
  for (int mi = 0; mi < 4; ++mi)
#pragma unroll
    for (int ni = 0; ni < 4; ++ni) {
      int col = bn + wn + ni * 16 + m16;
#pragma unroll
      for (int rg = 0; rg < 4; ++rg) {
        int row = bm + wm + mi * 16 + qd * 4 + rg;
        if (Cb)
          Cb[(size_t)row * ldc + col] = f2bf(acc[mi][ni][rg]);
        else
          Cf[(size_t)row * ldc + col] = acc[mi][ni][rg];
      }
    }
}

// ---------------------------------------------------------------------------
// Split-bf16 MFMA GEMM: fp32-accurate C = A @ Bt^T (top-k-feeding path).
// ---------------------------------------------------------------------------
__global__ __launch_bounds__(256) void gemm_bf16_split(
    const unsigned short* __restrict__ Ah, const unsigned short* __restrict__ Al,
    const unsigned short* __restrict__ Bh, const unsigned short* __restrict__ Bl,
    float* __restrict__ Cf, int K, int lda, int ldb, int ldc) {
  __shared__ unsigned short Ash[128 * 32];
  __shared__ unsigned short Asl[128 * 32];
  __shared__ unsigned short Bsh[128 * 32];
  __shared__ unsigned short Bsl[128 * 32];
  int tid = threadIdx.x;
  int bm = blockIdx.y * 128, bn = blockIdx.x * 128;
  int lane = tid & 63, wid = tid >> 6;
  int wm = (wid >> 1) * 64, wn = (wid & 1) * 64;
  int qd = lane >> 4, m16 = lane & 15;

  floatx4 acc[4][4];
#pragma unroll
  for (int i = 0; i < 4; ++i)
#pragma unroll
    for (int j = 0; j < 4; ++j) acc[i][j] = (floatx4){0.f, 0.f, 0.f, 0.f};

  for (int k0 = 0; k0 < K; k0 += 32) {
#pragma unroll
    for (int i = 0; i < 2; ++i) {
      int idx = tid + 256 * i;
      int r = idx >> 2, s = idx & 3;
      int g = s ^ ((r >> 1) & 3);
      size_t aoff = (size_t)(bm + r) * lda + k0 + g * 8;
      size_t boff = (size_t)(bn + r) * ldb + k0 + g * 8;
      __builtin_amdgcn_global_load_lds(
          (const __attribute__((address_space(1))) unsigned int*)(Ah + aoff),
          (__attribute__((address_space(3))) unsigned int*)(&Ash[idx * 8]), 16, 0, 0);
      __builtin_amdgcn_global_load_lds(
          (const __attribute__((address_space(1))) unsigned int*)(Al + aoff),
          (__attribute__((address_space(3))) unsigned int*)(&Asl[idx * 8]), 16, 0, 0);
      __builtin_amdgcn_global_load_lds(
          (const __attribute__((address_space(1))) unsigned int*)(Bh + boff),
          (__attribute__((address_space(3))) unsigned int*)(&Bsh[idx * 8]), 16, 0, 0);
      __builtin_amdgcn_global_load_lds(
          (const __attribute__((address_space(1))) unsigned int*)(Bl + boff),
          (__attribute__((address_space(3))) unsigned int*)(&Bsl[idx * 8]), 16, 0, 0);
    }
    __syncthreads();
    short8 afh[4], afl[4], bfh[4], bfl[4];
#pragma unroll
    for (int mi = 0; mi < 4; ++mi) {
      int r = wm + mi * 16 + m16;
      int slot = qd ^ ((r >> 1) & 3);
      afh[mi] = *(const short8*)&Ash[r * 32 + slot * 8];
      afl[mi] = *(const short8*)&Asl[r * 32 + slot * 8];
    }
#pragma unroll
    for (int ni = 0; ni < 4; ++ni) {
      int r = wn + ni * 16 + m16;
      int slot = qd ^ ((r >> 1) & 3);
      bfh[ni] = *(const short8*)&Bsh[r * 32 + slot * 8];
      bfl[ni] = *(const short8*)&Bsl[r * 32 + slot * 8];
    }
#pragma unroll
    for (int mi = 0; mi < 4; ++mi)
#pragma unroll
      for (int ni = 0; ni < 4; ++ni) {
        acc[mi][ni] = __builtin_amdgcn_mfma_f32_16x16x32_bf16(afh[mi], bfh[ni], acc[mi][ni], 0, 0, 0);
        acc[mi][ni] = __builtin_amdgcn_mfma_f32_16x16x32_bf16(afh[mi], bfl[ni], acc[mi][ni], 0, 0, 0);
        acc[mi][ni] = __builtin_amdgcn_mfma_f32_16x16x32_bf16(afl[mi], bfh[ni], acc[mi][ni], 0, 0, 0);
      }
    __syncthreads();
  }
#pragma unroll
  for (int mi = 0; mi < 4; ++mi)
#pragma unroll
    for (int ni = 0; ni < 4; ++ni) {
      int col = bn + wn + ni * 16 + m16;
#pragma unroll
      for (int rg = 0; rg < 4; ++rg) {
        int row = bm + wm + mi * 16 + qd * 4 + rg;
        Cf[(size_t)row * ldc + col] = acc[mi][ni][rg];
      }
    }
}

// ---------------------------------------------------------------------------
// Indexer scores on split-bf16 MFMA.
// A = q_i rows (s*4+h) x 64; B = k_proj 1024 x 64. C/D row = qd*4+rg puts the
// 4 heads of one token in one lane's 4 acc regs -> relu*hw reduce in-register.
// isc[tok][col] = col<tok ? sum_h relu(dot)*hw[tok][h] : -inf
// ---------------------------------------------------------------------------
__global__ __launch_bounds__(256) void iscores_mfma(
    const unsigned short* __restrict__ Ah, const unsigned short* __restrict__ Al,
    const unsigned short* __restrict__ Bh, const unsigned short* __restrict__ Bl,
    const float* __restrict__ hw, float* __restrict__ isc) {
  __shared__ unsigned short Ash[128 * 32];
  __shared__ unsigned short Asl[128 * 32];
  __shared__ unsigned short Bsh[128 * 32];
  __shared__ unsigned short Bsl[128 * 32];
  int tid = threadIdx.x;
  int bm = blockIdx.y * 128, bn = blockIdx.x * 128;
  int lane = tid & 63, wid = tid >> 6;
  int wm = (wid >> 1) * 64, wn = (wid & 1) * 64;
  int qd = lane >> 4, m16 = lane & 15;

  floatx4 acc[4][4];
#pragma unroll
  for (int i = 0; i < 4; ++i)
#pragma unroll
    for (int j = 0; j < 4; ++j) acc[i][j] = (floatx4){0.f, 0.f, 0.f, 0.f};

#pragma unroll
  for (int k0 = 0; k0 < 64; k0 += 32) {
#pragma unroll
    for (int i = 0; i < 2; ++i) {
      int idx = tid + 256 * i;
      int r = idx >> 2, s = idx & 3;
      int g = s ^ ((r >> 1) & 3);
      size_t aoff = (size_t)(bm + r) * 64 + k0 + g * 8;
      size_t boff = (size_t)(bn + r) * 64 + k0 + g * 8;
      __builtin_amdgcn_global_load_lds(
          (const __attribute__((address_space(1))) unsigned int*)(Ah + aoff),
          (__attribute__((address_space(3))) unsigned int*)(&Ash[idx * 8]), 16, 0, 0);
      __builtin_amdgcn_global_load_lds(
          (const __attribute__((address_space(1))) unsigned int*)(Al + aoff),
          (__attribute__((address_space(3))) unsigned int*)(&Asl[idx * 8]), 16, 0, 0);
      __builtin_amdgcn_global_load_lds(
          (const __attribute__((address_space(1))) unsigned int*)(Bh + boff),
          (__attribute__((address_space(3))) unsigned int*)(&Bsh[idx * 8]), 16, 0, 0);
      __builtin_amdgcn_global_load_lds(
          (const __attribute__((address_space(1))) unsigned int*)(Bl + boff),
          (__attribute__((address_space(3))) unsigned int*)(&Bsl[idx * 8]), 16, 0, 0);
    }
    __syncthreads();
    short8 afh[4], afl[4], bfh[4], bfl[4];
#pragma unroll
    for (int mi = 0; mi < 4; ++mi) {
      int r = wm + mi * 16 + m16;
      int slot = qd ^ ((r >> 1) & 3);
      afh[mi] = *(const short8*)&Ash[r * 32 + slot * 8];
      afl[mi] = *(const short8*)&Asl[r * 32 + slot * 8];
    }
#pragma unroll
    for (int ni = 0; ni < 4; ++ni) {
      int r = wn + ni * 16 + m16;
      int slot = qd ^ ((r >> 1) & 3);
      bfh[ni] = *(const short8*)&Bsh[r * 32 + slot * 8];
      bfl[ni] = *(const short8*)&Bsl[r * 32 + slot * 8];
    }
#pragma unroll
    for (int mi = 0; mi < 4; ++mi)
#pragma unroll
      for (int ni = 0; ni < 4; ++ni) {
        acc[mi][ni] = __builtin_amdgcn_mfma_f32_16x16x32_bf16(afh[mi], bfh[ni], acc[mi][ni], 0, 0, 0);
        acc[mi][ni] = __builtin_amdgcn_mfma_f32_16x16x32_bf16(afh[mi], bfl[ni], acc[mi][ni], 0, 0, 0);
        acc[mi][ni] = __builtin_amdgcn_mfma_f32_16x16x32_bf16(afl[mi], bfh[ni], acc[mi][ni], 0, 0, 0);
      }
    __syncthreads();
  }
#pragma unroll
  for (int mi = 0; mi < 4; ++mi) {
    int tok = ((bm + wm + mi * 16) >> 2) + qd;
    float4 hwv = *(const float4*)&hw[tok * 4];
#pragma unroll
    for (int ni = 0; ni < 4; ++ni) {
      floatx4 a = acc[mi][ni];
      float v = fmaxf(a[0], 0.f) * hwv.x + fmaxf(a[1], 0.f) * hwv.y +
                fmaxf(a[2], 0.f) * hwv.z + fmaxf(a[3], 0.f) * hwv.w;
      int col = bn + wn + ni * 16 + m16;
      isc[(size_t)tok * NC_ + col] = (col < tok) ? v : -__builtin_inff();
    }
  }
}

// ---------------------------------------------------------------------------
// fp32 tiled GEMM (kept for the tiny k_proj GEMM, N=64)
// ---------------------------------------------------------------------------
#define BM 64
#define BN 64
#define BK 16
__global__ __launch_bounds__(256) void gemm_f32(
    const float* __restrict__ A, const float* __restrict__ B,
    float* __restrict__ C, int K, int lda, int ldb, int ldc) {
  __shared__ float As[BK][BM + 4];
  __shared__ float Bs[BK][BN + 4];
  int tid = threadIdx.x;
  int bm = blockIdx.y * BM;
  int bn = blockIdx.x * BN;
  int tr = tid >> 4;
  int tc = tid & 15;
  float acc[4][4] = {{0.f}};
  for (int k0 = 0; k0 < K; k0 += BK) {
    int ac = tid & 15;
    int ar0 = tid >> 4;
#pragma unroll
    for (int i = 0; i < 4; ++i) {
      int r = ar0 + 16 * i;
      As[ac][r] = A[(size_t)(bm + r) * lda + k0 + ac];
    }
    int bc = tid & 63;
    int br0 = tid >> 6;
#pragma unroll
    for (int i = 0; i < 4; ++i) {
      int r = br0 + 4 * i;
      Bs[r][bc] = B[(size_t)(k0 + r) * ldb + bn + bc];
    }
    __syncthreads();
#pragma unroll
    for (int kk = 0; kk < BK; ++kk) {
      float4 av = *(const float4*)&As[kk][tr * 4];
      float4 bv = *(const float4*)&Bs[kk][tc * 4];
      float a[4] = {av.x, av.y, av.z, av.w};
      float b[4] = {bv.x, bv.y, bv.z, bv.w};
#pragma unroll
      for (int i = 0; i < 4; ++i)
#pragma unroll
        for (int j = 0; j < 4; ++j) acc[i][j] += a[i] * b[j];
    }
    __syncthreads();
  }
#pragma unroll
  for (int i = 0; i < 4; ++i) {
    float4 v = make_float4(acc[i][0], acc[i][1], acc[i][2], acc[i][3]);
    *(float4*)&C[(size_t)(bm + tr * 4 + i) * ldc + bn + tc * 4] = v;
  }
}

// fp32 -> (bf16 hi, bf16 lo) element-wise split (n multiple of 4)
__global__ void cast_split(const float* __restrict__ in, unsigned short* __restrict__ hi,
                           unsigned short* __restrict__ lo, int n) {
  int i = (blockIdx.x * 256 + threadIdx.x) * 4;
  if (i >= n) return;
  float4 v = *(const float4*)&in[i];
  ushort4 h = make_ushort4(f2bf(v.x), f2bf(v.y), f2bf(v.z), f2bf(v.w));
  ushort4 l = make_ushort4(f2bf(v.x - bf2f(h.x)), f2bf(v.y - bf2f(h.y)),
                           f2bf(v.z - bf2f(h.z)), f2bf(v.w - bf2f(h.w)));
  *(ushort4*)&hi[i] = h;
  *(ushort4*)&lo[i] = l;
}

// fp32 (K x N) -> bf16 transpose (N x K). K,N multiples of 32.
__global__ __launch_bounds__(256) void transpose_cast(
    const float* __restrict__ in, unsigned short* __restrict__ out, int K, int N) {
  __shared__ float t[32][33];
  int k0 = blockIdx.x * 32, n0 = blockIdx.y * 32;
  int tx = threadIdx.x & 31, ty = threadIdx.x >> 5;
#pragma unroll
  for (int i = 0; i < 4; ++i)
    t[ty * 4 + i][tx] = in[(size_t)(k0 + ty * 4 + i) * N + n0 + tx];
  __syncthreads();
#pragma unroll
  for (int i = 0; i < 4; ++i)
    out[(size_t)(n0 + ty * 4 + i) * K + k0 + tx] = f2bf(t[tx][ty * 4 + i]);
}

// fp32 (K x N) -> bf16 transpose split (N x K, hi+lo)
__global__ __launch_bounds__(256) void transpose_cast_split(
    const float* __restrict__ in, unsigned short* __restrict__ outh,
    unsigned short* __restrict__ outl, int K, int N) {
  __shared__ float t[32][33];
  int k0 = blockIdx.x * 32, n0 = blockIdx.y * 32;
  int tx = threadIdx.x & 31, ty = threadIdx.x >> 5;
#pragma unroll
  for (int i = 0; i < 4; ++i)
    t[ty * 4 + i][tx] = in[(size_t)(k0 + ty * 4 + i) * N + n0 + tx];
  __syncthreads();
#pragma unroll
  for (int i = 0; i < 4; ++i) {
    float v = t[tx][ty * 4 + i];
    unsigned short h = f2bf(v);
    outh[(size_t)(n0 + ty * 4 + i) * K + k0 + tx] = h;
    outl[(size_t)(n0 + ty * 4 + i) * K + k0 + tx] = f2bf(v - bf2f(h));
  }
}

// k_orig[j,d] = mean over 4 tokens
__global__ void mean4_kernel(const float* __restrict__ x, float* __restrict__ ko) {
  int i = blockIdx.x * 256 + threadIdx.x;
  if (i >= NC_ * D_) return;
  int j = i >> 11, d = i & (D_ - 1);
  const float* p = x + (size_t)j * 4 * D_ + d;
  ko[i] = 0.25f * (p[0] + p[D_] + p[2 * D_] + p[3 * D_]);
}

// hw = x @ w_w  (S x 4)
__global__ void hw_kernel(const float* __restrict__ x, const float* __restrict__ ww,
                          float* __restrict__ hw) {
  int i = blockIdx.x * 256 + threadIdx.x;
  if (i >= S_ * NHI_) return;
  int s = i >> 2, h = i & 3;
  const float* xr = x + (size_t)s * D_;
  float acc = 0.f;
  for (int k = 0; k < D_; ++k) acc += xr[k] * ww[k * NHI_ + h];
  hw[i] = acc;
}

// gating softmax; reads packed c4 (S x 256: [c_a|c_b|z_a|z_b])
__global__ void gate_kernel(const float* __restrict__ c4,
                            const float* __restrict__ ba, const float* __restrict__ bb,
                            float* __restrict__ comp) {
  int i = blockIdx.x * 256 + threadIdx.x;
  if (i >= NC_ * C_) return;
  int j = i >> 6, c = i & 63;
  float lg[8], vv[8];
#pragma unroll
  for (int m = 0; m < 4; ++m) {
    if (j == 0) {
      lg[m] = -1e30f + bb[m * C_ + c];
      vv[m] = 0.f;
    } else {
      int row = (j - 1) * 4 + m;
      lg[m] = c4[(size_t)row * 256 + 192 + c] + bb[m * C_ + c];
      vv[m] = c4[(size_t)row * 256 + 64 + c];
    }
    int row2 = j * 4 + m;
    lg[4 + m] = c4[(size_t)row2 * 256 + 128 + c] + ba[m * C_ + c];
    vv[4 + m] = c4[(size_t)row2 * 256 + 0 + c];
  }
  float mx = lg[0];
#pragma unroll
  for (int t = 1; t < 8; ++t) mx = fmaxf(mx, lg[t]);
  float se = 0.f, acc = 0.f;
#pragma unroll
  for (int t = 0; t < 8; ++t) {
    float e = expf(lg[t] - mx);
    se += e;
    acc += e * vv[t];
  }
  comp[i] = acc / se;
}

__device__ inline float wave_sum64(float v) {
#pragma unroll
  for (int off = 32; off > 0; off >>= 1) v += __shfl_xor(v, off, 64);
  return v;
}

// LayerNorm over C=64 -> bf16 row-major + bf16 transposed (for attention MFMA)
__global__ void ln_kc_kernel(const float* __restrict__ in, const float* __restrict__ w,
                             const float* __restrict__ b, unsigned short* __restrict__ kcb,
                             unsigned short* __restrict__ kcbT) {
  int row = blockIdx.x * 4 + (threadIdx.x >> 6);
  int c = threadIdx.x & 63;
  float v = in[(size_t)row * C_ + c];
  float mu = wave_sum64(v) * (1.f / 64.f);
  float d = v - mu;
  float var = wave_sum64(d * d) * (1.f / 64.f);
  float y = d * (1.f / sqrtf(var + EPS_)) * w[c] + b[c];
  unsigned short h = f2bf(y);
  kcb[(size_t)row * C_ + c] = h;
  kcbT[(size_t)c * NC_ + row] = h;
}

// LN + RoPE for q -> bf16, pre-scaled by 1/sqrt(C)=0.125 (only attention uses q)
__global__ void ln_rope_q_kernel(const float* __restrict__ quq, const float* __restrict__ w,
                                 const float* __restrict__ b, unsigned short* __restrict__ qb) {
  int row = blockIdx.x * 4 + (threadIdx.x >> 6);  // s*16 + h
  int s = row >> 4;
  int c = threadIdx.x & 63;
  float v = quq[(size_t)row * C_ + c];
  float mu = wave_sum64(v) * (1.f / 64.f);
  float d = v - mu;
  float var = wave_sum64(d * d) * (1.f / 64.f);
  float y = d * (1.f / sqrtf(var + EPS_)) * w[c] + b[c];
  float outv;
  float partner = __shfl_xor(y, 1, 64);
  if (c < C_ - ROPE_) {
    outv = y;
  } else {
    int p = (c - (C_ - ROPE_)) >> 1;
    float inv = powf(10000.f, -(2.f * (float)p) / (float)ROPE_);
    float ang = (float)s * inv;
    float cs = cosf(ang), sn = sinf(ang);
    if ((c & 1) == 0)
      outv = y * cs - partner * sn;
    else
      outv = partner * sn + y * cs;
  }
  qb[(size_t)row * C_ + c] = f2bf(outv * 0.125f);
}

// top-512 of 1024 via bitonic sort (matches jax.lax.top_k tie semantics)
__global__ __launch_bounds__(512) void topk_kernel(const float* __restrict__ isc,
                                                   int* __restrict__ tidx) {
  __shared__ unsigned long long keys[NC_];
  int s = blockIdx.x;
  int tid = threadIdx.x;
  for (int i = tid; i < NC_; i += 512) {
    float v = isc[(size_t)s * NC_ + i];
    unsigned u = __float_as_uint(v);
    unsigned m = (u & 0x80000000u) ? ~u : (u | 0x80000000u);
    keys[i] = ((unsigned long long)(~m) << 32) | (unsigned)i;
  }
  __syncthreads();
  for (int k = 2; k <= NC_; k <<= 1) {
    for (int j = k >> 1; j > 0; j >>= 1) {
      for (int i = tid; i < NC_; i += 512) {
        int ixj = i ^ j;
        if (ixj > i) {
          unsigned long long a = keys[i], bke = keys[ixj];
          bool up = ((i & k) == 0);
          if ((a > bke) == up) {
            keys[i] = bke;
            keys[ixj] = a;
          }
        }
      }
      __syncthreads();
    }
  }
  if (tid < TOPK_) tidx[(size_t)s * TOPK_ + tid] = (int)(keys[tid] & 0xFFFFFFFFu);
}

// selection bitmap: sel[s][0..31] bits over 1024 chunks
__global__ void selmask_kernel(const int* __restrict__ tidx, unsigned* __restrict__ sel) {
  int s = blockIdx.x, tid = threadIdx.x;
  __shared__ unsigned wbuf[32];
  if (tid < 32) wbuf[tid] = 0u;
  __syncthreads();
  for (int i = tid; i < TOPK_; i += 64) {
    int idx = tidx[(size_t)s * TOPK_ + i];
    atomicOr(&wbuf[idx >> 5], 1u << (idx & 31));
  }
  __syncthreads();
  if (tid < 32) sel[(size_t)s * 32 + tid] = wbuf[tid];
}

// ---------------------------------------------------------------------------
// Dense-masked flash attention on MFMA.
// ---------------------------------------------------------------------------
#define TS_ 8
__global__ __launch_bounds__(256) void attn_mfma_kernel(
    const unsigned short* __restrict__ qb, const unsigned short* __restrict__ kcb,
    const unsigned short* __restrict__ kcbT, const unsigned* __restrict__ sel,
    const float* __restrict__ sink, unsigned short* __restrict__ out) {
  __shared__ unsigned short kc_s[64 * 72];    // [chunk][dim]
  __shared__ unsigned short kct_s[64 * 72];   // [dim][chunk]
  __shared__ unsigned short p_s[128 * 72];    // [row][chunk] per-wave rows
  __shared__ unsigned selw[TS_][32];
  __shared__ float dls[4][2][16];
  int tid = threadIdx.x;
  int s0 = blockIdx.x * TS_;
  int lane = tid & 63, w = tid >> 6;
  int qd = lane >> 4, m16 = lane & 15;

  for (int i = tid; i < TS_ * 32; i += 256)
    selw[i >> 5][i & 31] = sel[(size_t)(s0 + (i >> 5)) * 32 + (i & 31)];

  short8 qf[2][2];
#pragma unroll
  for (int tk = 0; tk < 2; ++tk)
#pragma unroll
    for (int ks = 0; ks < 2; ++ks)
      qf[tk][ks] = *(const short8*)&qb[(size_t)(s0 + 2 * w + tk) * 1024 + m16 * 64 + ks * 32 + qd * 8];

  floatx4 of[2][4];
#pragma unroll
  for (int i = 0; i < 2; ++i)
#pragma unroll
    for (int j = 0; j < 4; ++j) of[i][j] = (floatx4){0.f, 0.f, 0.f, 0.f};
  float dsum[2] = {0.f, 0.f};

  for (int ct = 0; ct < 16; ++ct) {
    int c0 = ct * 64;
    __syncthreads();
    {
      int r = tid >> 2, cc = (tid & 3) * 16;
      *(short8*)&kc_s[r * 72 + cc]      = *(const short8*)&kcb[(size_t)(c0 + r) * 64 + cc];
      *(short8*)&kc_s[r * 72 + cc + 8]  = *(const short8*)&kcb[(size_t)(c0 + r) * 64 + cc + 8];
      *(short8*)&kct_s[r * 72 + cc]     = *(const short8*)&kcbT[(size_t)r * NC_ + c0 + cc];
      *(short8*)&kct_s[r * 72 + cc + 8] = *(const short8*)&kcbT[(size_t)r * NC_ + c0 + cc + 8];
    }
    __syncthreads();
#pragma unroll
    for (int mc = 0; mc < 4; ++mc) {
      short8 a0 = *(const short8*)&kc_s[(mc * 16 + m16) * 72 + qd * 8];
      short8 a1 = *(const short8*)&kc_s[(mc * 16 + m16) * 72 + 32 + qd * 8];
#pragma unroll
      for (int nt = 0; nt < 2; ++nt) {
        floatx4 sc = (floatx4){0.f, 0.f, 0.f, 0.f};
        sc = __builtin_amdgcn_mfma_f32_16x16x32_bf16(a0, qf[nt][0], sc, 0, 0, 0);
        sc = __builtin_amdgcn_mfma_f32_16x16x32_bf16(a1, qf[nt][1], sc, 0, 0, 0);
        int tokL = 2 * w + nt;
        int sG = s0 + tokL;
        short4v pv;
#pragma unroll
        for (int rg = 0; rg < 4; ++rg) {
          int cG = c0 + mc * 16 + qd * 4 + rg;
          bool ok = (((selw[tokL][cG >> 5] >> (cG & 31)) & 1u) != 0u) && (sG < cG * 4);
          float e = ok ? __expf(sc[rg]) : 0.f;
          dsum[nt] += e;
          pv[rg] = (short)f2bf(e);
        }
        *(short4v*)&p_s[(tokL * 16 + m16) * 72 + mc * 16 + qd * 4] = pv;
      }
    }
#pragma unroll
    for (int ks = 0; ks < 2; ++ks) {
      short8 pa0 = *(const short8*)&p_s[((2 * w + 0) * 16 + m16) * 72 + ks * 32 + qd * 8];
      short8 pa1 = *(const short8*)&p_s[((2 * w + 1) * 16 + m16) * 72 + ks * 32 + qd * 8];
#pragma unroll
      for (int nt = 0; nt < 4; ++nt) {
        short8 bv = *(const short8*)&kct_s[(nt * 16 + m16) * 72 + ks * 32 + qd * 8];
        of[0][nt] = __builtin_amdgcn_mfma_f32_16x16x32_bf16(pa0, bv, of[0][nt], 0, 0, 0);
        of[1][nt] = __builtin_amdgcn_mfma_f32_16x16x32_bf16(pa1, bv, of[1][nt], 0, 0, 0);
      }
    }
  }
#pragma unroll
  for (int nt = 0; nt < 2; ++nt) {
    dsum[nt] += __shfl_xor(dsum[nt], 16, 64);
    dsum[nt] += __shfl_xor(dsum[nt], 32, 64);
  }
  if (lane < 16) {
    float sk = __expf(sink[lane]);
    dls[w][0][lane] = dsum[0] + sk;
    dls[w][1][lane] = dsum[1] + sk;
  }
#pragma unroll
  for (int tk = 0; tk < 2; ++tk)
#pragma unroll
    for (int nt = 0; nt < 4; ++nt) {
      floatx4 o = of[tk][nt];
#pragma unroll
      for (int rg = 0; rg < 4; ++rg) {
        int head = qd * 4 + rg;
        float dn = dls[w][tk][head];
        out[(size_t)(s0 + 2 * w + tk) * 1024 + head * 64 + nt * 16 + m16] = f2bf(o[rg] / dn);
      }
    }
}

// ---------------------------------------------------------------------------
// Workspace layout (float offsets)
// ---------------------------------------------------------------------------
#define OFF_QUQ    0u          // 4194304 f : quq fp32 -> reused as isc
#define OFF_Q      4194304u    // 4194304 f : qb bf16
#define OFF_XH     8388608u    // 4194304 f : xh bf16 -> reused as gb
#define OFF_XL     12582912u   // 4194304 f : xl bf16 -> reused as sel bitmap
#define OFF_TIDX   16777216u   // 2097152 f : int
#define OFF_KO     18874368u   // 2097152 f : k_or fp32 -> reused as attnb bf16
#define OFF_C4     20971520u   // 1048576 f
#define OFF_CQF    22020096u   // 2097152 f : c_q fp32 -> reused as qih/qil/kph/kpl
#define OFF_QI     24117248u   // 1048576 f
#define OFF_CQH    25165824u   // 1048576 f : c_q hi bf16
#define OFF_CQL    26214400u   // 1048576 f : c_q lo bf16
#define OFF_WPACKT 27262976u   // 262144 f
#define OFF_WDQTH  27525120u   // 524288 f
#define OFF_WDQTL  28049408u   // 524288 f
#define OFF_WIUQTH 28573696u   // 65536 f
#define OFF_WIUQTL 28639232u   // 65536 f
#define OFF_WUQT   28704768u   // 262144 f
#define OFF_ODOWNT 28966912u   // 262144 f
#define OFF_OUPT   29229056u   // 2097152 f
#define OFF_HW     31326208u   // 16384 f
#define OFF_COMP   31342592u   // 65536 f
#define OFF_KC     31408128u   // 65536 f : kcb + kcbT
#define OFF_KPR    31473664u   // 65536 f

extern "C" void kernel_launch(void* const* d_in, const int* in_sizes, int n_in,
                              void* d_out, int out_size, void* d_ws, size_t ws_size,
                              hipStream_t stream) {
  const float* x      = (const float*)d_in[0];
  const float* w_kv_a = (const float*)d_in[1];
  const float* w_kv_b = (const float*)d_in[2];
  const float* w_z_a  = (const float*)d_in[3];
  const float* w_z_b  = (const float*)d_in[4];
  const float* b_a    = (const float*)d_in[5];
  const float* b_b    = (const float*)d_in[6];
  const float* w_dq   = (const float*)d_in[7];
  const float* w_iuq  = (const float*)d_in[8];
  const float* w_w    = (const float*)d_in[9];
  const float* w_k    = (const float*)d_in[10];
  const float* w_uq   = (const float*)d_in[11];
  const float* o_down = (const float*)d_in[12];
  const float* o_up   = (const float*)d_in[13];
  const float* kvn_w  = (const float*)d_in[14];
  const float* kvn_b  = (const float*)d_in[15];
  const float* qn_w   = (const float*)d_in[16];
  const float* qn_b   = (const float*)d_in[17];
  const float* sink   = (const float*)d_in[18];
  float* out = (float*)d_out;
  float* ws = (float*)d_ws;

  float* quq   = ws + OFF_QUQ;
  float* isc   = ws + OFF_QUQ;           // reuse (quq dead after ln_rope)
  unsigned short* qb = (unsigned short*)(ws + OFF_Q);
  unsigned short* xh = (unsigned short*)(ws + OFF_XH);
  unsigned short* gb = (unsigned short*)(ws + OFF_XH);  // reuse (xh dead after c_q)
  unsigned short* xl = (unsigned short*)(ws + OFF_XL);
  unsigned* sel = (unsigned*)(ws + OFF_XL);             // reuse (xl dead after cqf)
  int*   tidx  = (int*)(ws + OFF_TIDX);
  float* k_or  = ws + OFF_KO;
  unsigned short* attnb = (unsigned short*)(ws + OFF_KO);  // reuse
  float* c4    = ws + OFF_C4;
  float* cqf   = ws + OFF_CQF;
  // overlay in cqf region once cqf is consumed:
  unsigned short* qih = (unsigned short*)(ws + OFF_CQF);
  unsigned short* qil = qih + S_ * NHI_ * CI_;
  unsigned short* kph = qil + S_ * NHI_ * CI_;
  unsigned short* kpl = kph + NC_ * CI_;
  float* q_i   = ws + OFF_QI;
  unsigned short* cqh = (unsigned short*)(ws + OFF_CQH);
  unsigned short* cql = (unsigned short*)(ws + OFF_CQL);
  unsigned short* wpackT = (unsigned short*)(ws + OFF_WPACKT);
  unsigned short* wdqTh  = (unsigned short*)(ws + OFF_WDQTH);
  unsigned short* wdqTl  = (unsigned short*)(ws + OFF_WDQTL);
  unsigned short* wiuqTh = (unsigned short*)(ws + OFF_WIUQTH);
  unsigned short* wiuqTl = (unsigned short*)(ws + OFF_WIUQTL);
  unsigned short* wuqT   = (unsigned short*)(ws + OFF_WUQT);
  unsigned short* odownT = (unsigned short*)(ws + OFF_ODOWNT);
  unsigned short* oupT   = (unsigned short*)(ws + OFF_OUPT);
  float* hw    = ws + OFF_HW;
  float* comp  = ws + OFF_COMP;
  unsigned short* kcb  = (unsigned short*)(ws + OFF_KC);
  unsigned short* kcbT = kcb + NC_ * C_;
  float* k_pr  = ws + OFF_KPR;

  dim3 blk(256);

  // --- casts & weight transposes ---
  cast_split<<<8192, blk, 0, stream>>>(x, xh, xl, S_ * D_);
  transpose_cast<<<dim3(64, 2), blk, 0, stream>>>(w_kv_a, wpackT + 0 * 64 * 2048, D_, C_);
  transpose_cast<<<dim3(64, 2), blk, 0, stream>>>(w_kv_b, wpackT + 1 * 64 * 2048, D_, C_);
  transpose_cast<<<dim3(64, 2), blk, 0, stream>>>(w_z_a,  wpackT + 2 * 64 * 2048, D_, C_);
  transpose_cast<<<dim3(64, 2), blk, 0, stream>>>(w_z_b,  wpackT + 3 * 64 * 2048, D_, C_);
  transpose_cast_split<<<dim3(64, 16), blk, 0, stream>>>(w_dq, wdqTh, wdqTl, D_, DC_);
  transpose_cast_split<<<dim3(16, 8), blk, 0, stream>>>(w_iuq, wiuqTh, wiuqTl, DC_, NHI_ * CI_);
  transpose_cast<<<dim3(16, 32), blk, 0, stream>>>(w_uq, wuqT, DC_, NH_ * C_);
  for (int g = 0; g < NG_; ++g)
    transpose_cast<<<dim3(8, 16), blk, 0, stream>>>(o_down + (size_t)g * 256 * DG_,
                                                    odownT + (size_t)g * DG_ * 256, 256, DG_);
  transpose_cast<<<dim3(64, 64), blk, 0, stream>>>(o_up, oupT, NG_ * DG_, D_);

  // --- fp32 indexer-side path: k_orig -> k_proj, hw ---
  mean4_kernel<<<8192, blk, 0, stream>>>(x, k_or);
  gemm_f32<<<dim3(1, 16), blk, 0, stream>>>(k_or, w_k, k_pr, D_, D_, CI_, CI_);
  hw_kernel<<<64, blk, 0, stream>>>(x, w_w, hw);

  // --- MFMA GEMMs ---
  gemm_bf16<<<dim3(2, 32), blk, 0, stream>>>(xh, wpackT, c4, nullptr, D_, D_, D_, 256);
  gemm_bf16_split<<<dim3(4, 32), blk, 0, stream>>>(xh, xl, wdqTh, wdqTl, cqf, D_, D_, D_, DC_);
  cast_split<<<2048, blk, 0, stream>>>(cqf, cqh, cql, S_ * DC_);
  // cqf is now dead; its region is reused for qih/qil/kph/kpl below.
  gemm_bf16_split<<<dim3(2, 32), blk, 0, stream>>>(cqh, cql, wiuqTh, wiuqTl, q_i, DC_, DC_, DC_, NHI_ * CI_);
  gemm_bf16<<<dim3(8, 32), blk, 0, stream>>>(cqh, wuqT, quq, nullptr, DC_, DC_, DC_, NH_ * C_);

  // --- gating -> compressed -> kc (LN, bf16 row-major + transposed) ---
  gate_kernel<<<256, blk, 0, stream>>>(c4, b_a, b_b, comp);
  ln_kc_kernel<<<256, blk, 0, stream>>>(comp, kvn_w, kvn_b, kcb, kcbT);

  // --- q: LN + RoPE -> bf16 scaled by 1/8 (consumes quq; precedes iscores) ---
  ln_rope_q_kernel<<<16384, blk, 0, stream>>>(quq, qn_w, qn_b, qb);

  // --- indexer scores (split-bf16 MFMA) + top-k + selection bitmap ---
  cast_split<<<1024, blk, 0, stream>>>(q_i, qih, qil, S_ * NHI_ * CI_);
  cast_split<<<64, blk, 0, stream>>>(k_pr, kph, kpl, NC_ * CI_);
  iscores_mfma<<<dim3(8, 128), blk, 0, stream>>>(qih, qil, kph, kpl, hw, isc);
  topk_kernel<<<S_, dim3(512), 0, stream>>>(isc, tidx);
  selmask_kernel<<<S_, dim3(64), 0, stream>>>(tidx, sel);

  // --- dense-masked flash attention (MFMA) ---
  attn_mfma_kernel<<<S_ / TS_, blk, 0, stream>>>(qb, kcb, kcbT, sel, sink, attnb);

  // --- o_down (4 groups) -> o_up ---
  for (int g = 0; g < NG_; ++g)
    gemm_bf16<<<dim3(4, 32), blk, 0, stream>>>(attnb + g * 256, odownT + (size_t)g * DG_ * 256,
                                               nullptr, gb + g * DG_, 256, NH_ * C_, 256, NG_ * DG_);
  gemm_bf16<<<dim3(16, 32), blk, 0, stream>>>(gb, oupT, out, nullptr, NG_ * DG_, NG_ * DG_, NG_ * DG_, D_);
}

// Round 6
// 595.356 us; speedup vs baseline: 3.7835x; 1.3846x over previous
//
#include <hip/hip_runtime.h>
#include <math.h>

// Problem constants (B=1 throughout)
#define S_   4096
#define D_   2048
#define M_   4
#define NC_  1024
#define TOPK_ 512
#define NH_  16
#define C_   64
#define DC_  512
#define NG_  4
#define DG_  512
#define CI_  64
#define NHI_ 4
#define ROPE_ 32
#define EPS_ 1e-6f

typedef __attribute__((ext_vector_type(8))) short short8;
typedef __attribute__((ext_vector_type(4))) short short4v;
typedef __attribute__((ext_vector_type(4))) float floatx4;

__device__ inline unsigned short f2bf(float f) {
  unsigned u = __float_as_uint(f);
  u += 0x7fff + ((u >> 16) & 1);   // round-to-nearest-even
  return (unsigned short)(u >> 16);
}
__device__ inline float bf2f(unsigned short h) {
  return __uint_as_float(((unsigned)h) << 16);
}

// ---------------------------------------------------------------------------
// bf16 MFMA GEMM (m97 structure): C = A @ Bt^T.
// ---------------------------------------------------------------------------
__global__ __launch_bounds__(256) void gemm_bf16(
    const unsigned short* __restrict__ A, const unsigned short* __restrict__ Bt,
    float* __restrict__ Cf, unsigned short* __restrict__ Cb,
    int K, int lda, int ldb, int ldc) {
  __shared__ unsigned short As[128 * 32];
  __shared__ unsigned short Bs[128 * 32];
  int tid = threadIdx.x;
  int bm = blockIdx.y * 128, bn = blockIdx.x * 128;
  int lane = tid & 63, wid = tid >> 6;
  int wm = (wid >> 1) * 64, wn = (wid & 1) * 64;
  int qd = lane >> 4, m16 = lane & 15;

  floatx4 acc[4][4];
#pragma unroll
  for (int i = 0; i < 4; ++i)
#pragma unroll
    for (int j = 0; j < 4; ++j) acc[i][j] = (floatx4){0.f, 0.f, 0.f, 0.f};

  for (int k0 = 0; k0 < K; k0 += 32) {
#pragma unroll
    for (int i = 0; i < 2; ++i) {
      int idx = tid + 256 * i;
      int r = idx >> 2, s = idx & 3;
      int g = s ^ ((r >> 1) & 3);
      __builtin_amdgcn_global_load_lds(
          (const __attribute__((address_space(1))) unsigned int*)(A + (size_t)(bm + r) * lda + k0 + g * 8),
          (__attribute__((address_space(3))) unsigned int*)(&As[idx * 8]), 16, 0, 0);
    }
#pragma unroll
    for (int i = 0; i < 2; ++i) {
      int idx = tid + 256 * i;
      int r = idx >> 2, s = idx & 3;
      int g = s ^ ((r >> 1) & 3);
      __builtin_amdgcn_global_load_lds(
          (const __attribute__((address_space(1))) unsigned int*)(Bt + (size_t)(bn + r) * ldb + k0 + g * 8),
          (__attribute__((address_space(3))) unsigned int*)(&Bs[idx * 8]), 16, 0, 0);
    }
    __syncthreads();
    short8 af[4], bfr[4];
#pragma unroll
    for (int mi = 0; mi < 4; ++mi) {
      int r = wm + mi * 16 + m16;
      int slot = qd ^ ((r >> 1) & 3);
      af[mi] = *(const short8*)&As[r * 32 + slot * 8];
    }
#pragma unroll
    for (int ni = 0; ni < 4; ++ni) {
      int r = wn + ni * 16 + m16;
      int slot = qd ^ ((r >> 1) & 3);
      bfr[ni] = *(const short8*)&Bs[r * 32 + slot * 8];
    }
#pragma unroll
    for (int mi = 0; mi < 4; ++mi)
#pragma unroll
      for (int ni = 0; ni < 4; ++ni)
        acc[mi][ni] = __builtin_amdgcn_mfma_f32_16x16x32_bf16(af[mi], bfr[ni], acc[mi][ni], 0, 0, 0);
    __syncthreads();
  }
#pragma unroll
  for (int mi = 0; mi < 4; ++mi)
#pragma unroll
    for (int ni = 0; ni < 4; ++ni) {
      int col = bn + wn + ni * 16 + m16;
#pragma unroll
      for (int rg = 0; rg < 4; ++rg) {
        int row = bm + wm + mi * 16 + qd * 4 + rg;
        if (Cb)
          Cb[(size_t)row * ldc + col] = f2bf(acc[mi][ni][rg]);
        else
          Cf[(size_t)row * ldc + col] = acc[mi][ni][rg];
      }
    }
}

// ---------------------------------------------------------------------------
// Split-bf16 MFMA GEMM: fp32-accurate C = A @ Bt^T (top-k-feeding path).
// ---------------------------------------------------------------------------
__global__ __launch_bounds__(256) void gemm_bf16_split(
    const unsigned short* __restrict__ Ah, const unsigned short* __restrict__ Al,
    const unsigned short* __restrict__ Bh, const unsigned short* __restrict__ Bl,
    float* __restrict__ Cf, int K, int lda, int ldb, int ldc) {
  __shared__ unsigned short Ash[128 * 32];
  __shared__ unsigned short Asl[128 * 32];
  __shared__ unsigned short Bsh[128 * 32];
  __shared__ unsigned short Bsl[128 * 32];
  int tid = threadIdx.x;
  int bm = blockIdx.y * 128, bn = blockIdx.x * 128;
  int lane = tid & 63, wid = tid >> 6;
  int wm = (wid >> 1) * 64, wn = (wid & 1) * 64;
  int qd = lane >> 4, m16 = lane & 15;

  floatx4 acc[4][4];
#pragma unroll
  for (int i = 0; i < 4; ++i)
#pragma unroll
    for (int j = 0; j < 4; ++j) acc[i][j] = (floatx4){0.f, 0.f, 0.f, 0.f};

  for (int k0 = 0; k0 < K; k0 += 32) {
#pragma unroll
    for (int i = 0; i < 2; ++i) {
      int idx = tid + 256 * i;
      int r = idx >> 2, s = idx & 3;
      int g = s ^ ((r >> 1) & 3);
      size_t aoff = (size_t)(bm + r) * lda + k0 + g * 8;
      size_t boff = (size_t)(bn + r) * ldb + k0 + g * 8;
      __builtin_amdgcn_global_load_lds(
          (const __attribute__((address_space(1))) unsigned int*)(Ah + aoff),
          (__attribute__((address_space(3))) unsigned int*)(&Ash[idx * 8]), 16, 0, 0);
      __builtin_amdgcn_global_load_lds(
          (const __attribute__((address_space(1))) unsigned int*)(Al + aoff),
          (__attribute__((address_space(3))) unsigned int*)(&Asl[idx * 8]), 16, 0, 0);
      __builtin_amdgcn_global_load_lds(
          (const __attribute__((address_space(1))) unsigned int*)(Bh + boff),
          (__attribute__((address_space(3))) unsigned int*)(&Bsh[idx * 8]), 16, 0, 0);
      __builtin_amdgcn_global_load_lds(
          (const __attribute__((address_space(1))) unsigned int*)(Bl + boff),
          (__attribute__((address_space(3))) unsigned int*)(&Bsl[idx * 8]), 16, 0, 0);
    }
    __syncthreads();
    short8 afh[4], afl[4], bfh[4], bfl[4];
#pragma unroll
    for (int mi = 0; mi < 4; ++mi) {
      int r = wm + mi * 16 + m16;
      int slot = qd ^ ((r >> 1) & 3);
      afh[mi] = *(const short8*)&Ash[r * 32 + slot * 8];
      afl[mi] = *(const short8*)&Asl[r * 32 + slot * 8];
    }
#pragma unroll
    for (int ni = 0; ni < 4; ++ni) {
      int r = wn + ni * 16 + m16;
      int slot = qd ^ ((r >> 1) & 3);
      bfh[ni] = *(const short8*)&Bsh[r * 32 + slot * 8];
      bfl[ni] = *(const short8*)&Bsl[r * 32 + slot * 8];
    }
#pragma unroll
    for (int mi = 0; mi < 4; ++mi)
#pragma unroll
      for (int ni = 0; ni < 4; ++ni) {
        acc[mi][ni] = __builtin_amdgcn_mfma_f32_16x16x32_bf16(afh[mi], bfh[ni], acc[mi][ni], 0, 0, 0);
        acc[mi][ni] = __builtin_amdgcn_mfma_f32_16x16x32_bf16(afh[mi], bfl[ni], acc[mi][ni], 0, 0, 0);
        acc[mi][ni] = __builtin_amdgcn_mfma_f32_16x16x32_bf16(afl[mi], bfh[ni], acc[mi][ni], 0, 0, 0);
      }
    __syncthreads();
  }
#pragma unroll
  for (int mi = 0; mi < 4; ++mi)
#pragma unroll
    for (int ni = 0; ni < 4; ++ni) {
      int col = bn + wn + ni * 16 + m16;
#pragma unroll
      for (int rg = 0; rg < 4; ++rg) {
        int row = bm + wm + mi * 16 + qd * 4 + rg;
        Cf[(size_t)row * ldc + col] = acc[mi][ni][rg];
      }
    }
}

// ---------------------------------------------------------------------------
// Indexer scores on split-bf16 MFMA (relu*hw epilogue in-register).
// ---------------------------------------------------------------------------
__global__ __launch_bounds__(256) void iscores_mfma(
    const unsigned short* __restrict__ Ah, const unsigned short* __restrict__ Al,
    const unsigned short* __restrict__ Bh, const unsigned short* __restrict__ Bl,
    const float* __restrict__ hw, float* __restrict__ isc) {
  __shared__ unsigned short Ash[128 * 32];
  __shared__ unsigned short Asl[128 * 32];
  __shared__ unsigned short Bsh[128 * 32];
  __shared__ unsigned short Bsl[128 * 32];
  int tid = threadIdx.x;
  int bm = blockIdx.y * 128, bn = blockIdx.x * 128;
  int lane = tid & 63, wid = tid >> 6;
  int wm = (wid >> 1) * 64, wn = (wid & 1) * 64;
  int qd = lane >> 4, m16 = lane & 15;

  floatx4 acc[4][4];
#pragma unroll
  for (int i = 0; i < 4; ++i)
#pragma unroll
    for (int j = 0; j < 4; ++j) acc[i][j] = (floatx4){0.f, 0.f, 0.f, 0.f};

#pragma unroll
  for (int k0 = 0; k0 < 64; k0 += 32) {
#pragma unroll
    for (int i = 0; i < 2; ++i) {
      int idx = tid + 256 * i;
      int r = idx >> 2, s = idx & 3;
      int g = s ^ ((r >> 1) & 3);
      size_t aoff = (size_t)(bm + r) * 64 + k0 + g * 8;
      size_t boff = (size_t)(bn + r) * 64 + k0 + g * 8;
      __builtin_amdgcn_global_load_lds(
          (const __attribute__((address_space(1))) unsigned int*)(Ah + aoff),
          (__attribute__((address_space(3))) unsigned int*)(&Ash[idx * 8]), 16, 0, 0);
      __builtin_amdgcn_global_load_lds(
          (const __attribute__((address_space(1))) unsigned int*)(Al + aoff),
          (__attribute__((address_space(3))) unsigned int*)(&Asl[idx * 8]), 16, 0, 0);
      __builtin_amdgcn_global_load_lds(
          (const __attribute__((address_space(1))) unsigned int*)(Bh + boff),
          (__attribute__((address_space(3))) unsigned int*)(&Bsh[idx * 8]), 16, 0, 0);
      __builtin_amdgcn_global_load_lds(
          (const __attribute__((address_space(1))) unsigned int*)(Bl + boff),
          (__attribute__((address_space(3))) unsigned int*)(&Bsl[idx * 8]), 16, 0, 0);
    }
    __syncthreads();
    short8 afh[4], afl[4], bfh[4], bfl[4];
#pragma unroll
    for (int mi = 0; mi < 4; ++mi) {
      int r = wm + mi * 16 + m16;
      int slot = qd ^ ((r >> 1) & 3);
      afh[mi] = *(const short8*)&Ash[r * 32 + slot * 8];
      afl[mi] = *(const short8*)&Asl[r * 32 + slot * 8];
    }
#pragma unroll
    for (int ni = 0; ni < 4; ++ni) {
      int r = wn + ni * 16 + m16;
      int slot = qd ^ ((r >> 1) & 3);
      bfh[ni] = *(const short8*)&Bsh[r * 32 + slot * 8];
      bfl[ni] = *(const short8*)&Bsl[r * 32 + slot * 8];
    }
#pragma unroll
    for (int mi = 0; mi < 4; ++mi)
#pragma unroll
      for (int ni = 0; ni < 4; ++ni) {
        acc[mi][ni] = __builtin_amdgcn_mfma_f32_16x16x32_bf16(afh[mi], bfh[ni], acc[mi][ni], 0, 0, 0);
        acc[mi][ni] = __builtin_amdgcn_mfma_f32_16x16x32_bf16(afh[mi], bfl[ni], acc[mi][ni], 0, 0, 0);
        acc[mi][ni] = __builtin_amdgcn_mfma_f32_16x16x32_bf16(afl[mi], bfh[ni], acc[mi][ni], 0, 0, 0);
      }
    __syncthreads();
  }
#pragma unroll
  for (int mi = 0; mi < 4; ++mi) {
    int tok = ((bm + wm + mi * 16) >> 2) + qd;
    float4 hwv = *(const float4*)&hw[tok * 4];
#pragma unroll
    for (int ni = 0; ni < 4; ++ni) {
      floatx4 a = acc[mi][ni];
      float v = fmaxf(a[0], 0.f) * hwv.x + fmaxf(a[1], 0.f) * hwv.y +
                fmaxf(a[2], 0.f) * hwv.z + fmaxf(a[3], 0.f) * hwv.w;
      int col = bn + wn + ni * 16 + m16;
      isc[(size_t)tok * NC_ + col] = (col < tok) ? v : -__builtin_inff();
    }
  }
}

// ---------------------------------------------------------------------------
// Split-K fp32 GEMM for k_proj: P[slice] = A[:,slice] @ B[slice,:] (64x64 tile)
// grid (KS slices, M/64). N fixed = 64. Partials then reduced.
// ---------------------------------------------------------------------------
#define BM 64
#define BN 64
#define BK 16
#define KSL_ 16
#define KSLICE_ 128
__global__ __launch_bounds__(256) void gemm_f32_splitk(
    const float* __restrict__ A, const float* __restrict__ B,
    float* __restrict__ P, int lda, int ldb) {
  __shared__ float As[BK][BM + 4];
  __shared__ float Bs[BK][BN + 4];
  int tid = threadIdx.x;
  int bm = blockIdx.y * BM;
  int kbase = blockIdx.x * KSLICE_;
  int tr = tid >> 4;
  int tc = tid & 15;
  float acc[4][4] = {{0.f}};
  for (int k0 = kbase; k0 < kbase + KSLICE_; k0 += BK) {
    int ac = tid & 15;
    int ar0 = tid >> 4;
#pragma unroll
    for (int i = 0; i < 4; ++i) {
      int r = ar0 + 16 * i;
      As[ac][r] = A[(size_t)(bm + r) * lda + k0 + ac];
    }
    int bc = tid & 63;
    int br0 = tid >> 6;
#pragma unroll
    for (int i = 0; i < 4; ++i) {
      int r = br0 + 4 * i;
      Bs[r][bc] = B[(size_t)(k0 + r) * ldb + bc];
    }
    __syncthreads();
#pragma unroll
    for (int kk = 0; kk < BK; ++kk) {
      float4 av = *(const float4*)&As[kk][tr * 4];
      float4 bv = *(const float4*)&Bs[kk][tc * 4];
      float a[4] = {av.x, av.y, av.z, av.w};
      float b[4] = {bv.x, bv.y, bv.z, bv.w};
#pragma unroll
      for (int i = 0; i < 4; ++i)
#pragma unroll
        for (int j = 0; j < 4; ++j) acc[i][j] += a[i] * b[j];
    }
    __syncthreads();
  }
  float* Pb = P + (size_t)blockIdx.x * (NC_ * CI_);
#pragma unroll
  for (int i = 0; i < 4; ++i) {
    float4 v = make_float4(acc[i][0], acc[i][1], acc[i][2], acc[i][3]);
    *(float4*)&Pb[(size_t)(bm + tr * 4 + i) * CI_ + tc * 4] = v;
  }
}

__global__ void reduce_splitk(const float* __restrict__ P, float* __restrict__ C) {
  int i = blockIdx.x * 256 + threadIdx.x;
  if (i >= NC_ * CI_) return;
  float a = 0.f;
#pragma unroll
  for (int s = 0; s < KSL_; ++s) a += P[(size_t)s * (NC_ * CI_) + i];
  C[i] = a;
}

// fp32 -> (bf16 hi, bf16 lo) element-wise split (n multiple of 4)
__global__ void cast_split(const float* __restrict__ in, unsigned short* __restrict__ hi,
                           unsigned short* __restrict__ lo, int n) {
  int i = (blockIdx.x * 256 + threadIdx.x) * 4;
  if (i >= n) return;
  float4 v = *(const float4*)&in[i];
  ushort4 h = make_ushort4(f2bf(v.x), f2bf(v.y), f2bf(v.z), f2bf(v.w));
  ushort4 l = make_ushort4(f2bf(v.x - bf2f(h.x)), f2bf(v.y - bf2f(h.y)),
                           f2bf(v.z - bf2f(h.z)), f2bf(v.w - bf2f(h.w)));
  *(ushort4*)&hi[i] = h;
  *(ushort4*)&lo[i] = l;
}

// fp32 (K x N) -> bf16 transpose (N x K). K,N multiples of 32.
__global__ __launch_bounds__(256) void transpose_cast(
    const float* __restrict__ in, unsigned short* __restrict__ out, int K, int N) {
  __shared__ float t[32][33];
  int k0 = blockIdx.x * 32, n0 = blockIdx.y * 32;
  int tx = threadIdx.x & 31, ty = threadIdx.x >> 5;
#pragma unroll
  for (int i = 0; i < 4; ++i)
    t[ty * 4 + i][tx] = in[(size_t)(k0 + ty * 4 + i) * N + n0 + tx];
  __syncthreads();
#pragma unroll
  for (int i = 0; i < 4; ++i)
    out[(size_t)(n0 + ty * 4 + i) * K + k0 + tx] = f2bf(t[tx][ty * 4 + i]);
}

// fp32 (K x N) -> bf16 transpose split (N x K, hi+lo)
__global__ __launch_bounds__(256) void transpose_cast_split(
    const float* __restrict__ in, unsigned short* __restrict__ outh,
    unsigned short* __restrict__ outl, int K, int N) {
  __shared__ float t[32][33];
  int k0 = blockIdx.x * 32, n0 = blockIdx.y * 32;
  int tx = threadIdx.x & 31, ty = threadIdx.x >> 5;
#pragma unroll
  for (int i = 0; i < 4; ++i)
    t[ty * 4 + i][tx] = in[(size_t)(k0 + ty * 4 + i) * N + n0 + tx];
  __syncthreads();
#pragma unroll
  for (int i = 0; i < 4; ++i) {
    float v = t[tx][ty * 4 + i];
    unsigned short h = f2bf(v);
    outh[(size_t)(n0 + ty * 4 + i) * K + k0 + tx] = h;
    outl[(size_t)(n0 + ty * 4 + i) * K + k0 + tx] = f2bf(v - bf2f(h));
  }
}

// k_orig[j,d] = mean over 4 tokens
__global__ void mean4_kernel(const float* __restrict__ x, float* __restrict__ ko) {
  int i = blockIdx.x * 256 + threadIdx.x;
  if (i >= NC_ * D_) return;
  int j = i >> 11, d = i & (D_ - 1);
  const float* p = x + (size_t)j * 4 * D_ + d;
  ko[i] = 0.25f * (p[0] + p[D_] + p[2 * D_] + p[3 * D_]);
}

__device__ inline float wave_sum64(float v) {
#pragma unroll
  for (int off = 32; off > 0; off >>= 1) v += __shfl_xor(v, off, 64);
  return v;
}

// hw = x @ w_w (S x 4): one wave per token, coalesced x reads
__global__ void hw_kernel(const float* __restrict__ x, const float* __restrict__ ww,
                          float* __restrict__ hw) {
  int w = threadIdx.x >> 6, lane = threadIdx.x & 63;
  int s = blockIdx.x * 4 + w;
  const float* xr = x + (size_t)s * D_;
  float a0 = 0.f, a1 = 0.f, a2 = 0.f, a3 = 0.f;
  for (int k = lane; k < D_; k += 64) {
    float xv = xr[k];
    float4 wv = *(const float4*)&ww[k * 4];
    a0 += xv * wv.x; a1 += xv * wv.y; a2 += xv * wv.z; a3 += xv * wv.w;
  }
  a0 = wave_sum64(a0); a1 = wave_sum64(a1);
  a2 = wave_sum64(a2); a3 = wave_sum64(a3);
  if (lane == 0) {
    float4 o = make_float4(a0, a1, a2, a3);
    *(float4*)&hw[s * 4] = o;
  }
}

// gating softmax; reads packed c4 (S x 256: [c_a|c_b|z_a|z_b])
__global__ void gate_kernel(const float* __restrict__ c4,
                            const float* __restrict__ ba, const float* __restrict__ bb,
                            float* __restrict__ comp) {
  int i = blockIdx.x * 256 + threadIdx.x;
  if (i >= NC_ * C_) return;
  int j = i >> 6, c = i & 63;
  float lg[8], vv[8];
#pragma unroll
  for (int m = 0; m < 4; ++m) {
    if (j == 0) {
      lg[m] = -1e30f + bb[m * C_ + c];
      vv[m] = 0.f;
    } else {
      int row = (j - 1) * 4 + m;
      lg[m] = c4[(size_t)row * 256 + 192 + c] + bb[m * C_ + c];
      vv[m] = c4[(size_t)row * 256 + 64 + c];
    }
    int row2 = j * 4 + m;
    lg[4 + m] = c4[(size_t)row2 * 256 + 128 + c] + ba[m * C_ + c];
    vv[4 + m] = c4[(size_t)row2 * 256 + 0 + c];
  }
  float mx = lg[0];
#pragma unroll
  for (int t = 1; t < 8; ++t) mx = fmaxf(mx, lg[t]);
  float se = 0.f, acc = 0.f;
#pragma unroll
  for (int t = 0; t < 8; ++t) {
    float e = expf(lg[t] - mx);
    se += e;
    acc += e * vv[t];
  }
  comp[i] = acc / se;
}

// LayerNorm over C=64 -> bf16 row-major + bf16 transposed (for attention MFMA)
__global__ void ln_kc_kernel(const float* __restrict__ in, const float* __restrict__ w,
                             const float* __restrict__ b, unsigned short* __restrict__ kcb,
                             unsigned short* __restrict__ kcbT) {
  int row = blockIdx.x * 4 + (threadIdx.x >> 6);
  int c = threadIdx.x & 63;
  float v = in[(size_t)row * C_ + c];
  float mu = wave_sum64(v) * (1.f / 64.f);
  float d = v - mu;
  float var = wave_sum64(d * d) * (1.f / 64.f);
  float y = d * (1.f / sqrtf(var + EPS_)) * w[c] + b[c];
  unsigned short h = f2bf(y);
  kcb[(size_t)row * C_ + c] = h;
  kcbT[(size_t)c * NC_ + row] = h;
}

// LN + RoPE for q -> bf16, pre-scaled by 1/sqrt(C)=0.125 (only attention uses q)
__global__ void ln_rope_q_kernel(const float* __restrict__ quq, const float* __restrict__ w,
                                 const float* __restrict__ b, unsigned short* __restrict__ qb) {
  int row = blockIdx.x * 4 + (threadIdx.x >> 6);  // s*16 + h
  int s = row >> 4;
  int c = threadIdx.x & 63;
  float v = quq[(size_t)row * C_ + c];
  float mu = wave_sum64(v) * (1.f / 64.f);
  float d = v - mu;
  float var = wave_sum64(d * d) * (1.f / 64.f);
  float y = d * (1.f / sqrtf(var + EPS_)) * w[c] + b[c];
  float outv;
  float partner = __shfl_xor(y, 1, 64);
  if (c < C_ - ROPE_) {
    outv = y;
  } else {
    int p = (c - (C_ - ROPE_)) >> 1;
    float inv = powf(10000.f, -(2.f * (float)p) / (float)ROPE_);
    float ang = (float)s * inv;
    float cs = cosf(ang), sn = sinf(ang);
    if ((c & 1) == 0)
      outv = y * cs - partner * sn;
    else
      outv = partner * sn + y * cs;
  }
  qb[(size_t)row * C_ + c] = f2bf(outv * 0.125f);
}

// ---------------------------------------------------------------------------
// Top-512-of-1024 exact radix-select -> selection bitmap (replaces bitonic
// sort + selmask). Matches jax.lax.top_k set semantics: value desc, index asc
// within the threshold-value tie group. One block (256 thr) per row.
// ---------------------------------------------------------------------------
__global__ __launch_bounds__(256) void topk_select_kernel(
    const float* __restrict__ isc, unsigned* __restrict__ sel) {
  __shared__ unsigned mv[NC_];
  __shared__ unsigned bins[256];
  __shared__ unsigned scan[256];
  __shared__ unsigned sB, sR;
  __shared__ unsigned selw[32];
  int s = blockIdx.x;
  int tid = threadIdx.x;
  for (int i = tid; i < NC_; i += 256) {
    unsigned u = __float_as_uint(isc[(size_t)s * NC_ + i]);
    mv[i] = (u & 0x80000000u) ? ~u : (u | 0x80000000u);
  }
  __syncthreads();
  unsigned K_rem = TOPK_;
  unsigned prefix = 0u;
  for (int lvl = 0; lvl < 4; ++lvl) {
    int shift = 24 - 8 * lvl;
    unsigned pm = (lvl == 0) ? 0u : (0xFFFFFFFFu << (32 - 8 * lvl));
    bins[tid] = 0u;
    __syncthreads();
    for (int i = tid; i < NC_; i += 256) {
      unsigned m = mv[i];
      if ((m & pm) == prefix) atomicAdd(&bins[(m >> shift) & 0xFFu], 1u);
    }
    __syncthreads();
    unsigned v = bins[tid];
    scan[tid] = v;
    __syncthreads();
    // inclusive suffix sum: scan[t] = sum_{b>=t} bins[b]
    for (int off = 1; off < 256; off <<= 1) {
      unsigned add = (tid + off < 256) ? scan[tid + off] : 0u;
      __syncthreads();
      scan[tid] += add;
      __syncthreads();
    }
    unsigned gt = scan[tid] - v;
    if (gt < K_rem && K_rem <= gt + v) { sB = (unsigned)tid; sR = K_rem - gt; }
    __syncthreads();
    prefix |= (sB << shift);
    K_rem = sR;
    __syncthreads();
  }
  unsigned vstar = prefix;
  // per-thread 4 contiguous indices: rank equals by index order
  unsigned eq = 0;
#pragma unroll
  for (int j = 0; j < 4; ++j) eq += (mv[4 * tid + j] == vstar);
  scan[tid] = eq;
  __syncthreads();
  for (int off = 1; off < 256; off <<= 1) {
    unsigned add = (tid >= off) ? scan[tid - off] : 0u;
    __syncthreads();
    scan[tid] += add;
    __syncthreads();
  }
  unsigned rank0 = scan[tid] - eq;  // exclusive prefix of equals
  if (tid < 32) selw[tid] = 0u;
  __syncthreads();
  unsigned local = 0, bits = 0;
#pragma unroll
  for (int j = 0; j < 4; ++j) {
    unsigned m = mv[4 * tid + j];
    bool sb = (m > vstar) || (m == vstar && (rank0 + local) < K_rem);
    local += (m == vstar);
    if (sb) bits |= (1u << ((4 * tid + j) & 31));
  }
  if (bits) atomicOr(&selw[tid >> 3], bits);
  __syncthreads();
  if (tid < 32) sel[(size_t)s * 32 + tid] = selw[tid];
}

// ---------------------------------------------------------------------------
// Dense-masked flash attention on MFMA.
// ---------------------------------------------------------------------------
#define TS_ 8
__global__ __launch_bounds__(256) void attn_mfma_kernel(
    const unsigned short* __restrict__ qb, const unsigned short* __restrict__ kcb,
    const unsigned short* __restrict__ kcbT, const unsigned* __restrict__ sel,
    const float* __restrict__ sink, unsigned short* __restrict__ out) {
  __shared__ unsigned short kc_s[64 * 72];
  __shared__ unsigned short kct_s[64 * 72];
  __shared__ unsigned short p_s[128 * 72];
  __shared__ unsigned selw[TS_][32];
  __shared__ float dls[4][2][16];
  int tid = threadIdx.x;
  int s0 = blockIdx.x * TS_;
  int lane = tid & 63, w = tid >> 6;
  int qd = lane >> 4, m16 = lane & 15;

  for (int i = tid; i < TS_ * 32; i += 256)
    selw[i >> 5][i & 31] = sel[(size_t)(s0 + (i >> 5)) * 32 + (i & 31)];

  short8 qf[2][2];
#pragma unroll
  for (int tk = 0; tk < 2; ++tk)
#pragma unroll
    for (int ks = 0; ks < 2; ++ks)
      qf[tk][ks] = *(const short8*)&qb[(size_t)(s0 + 2 * w + tk) * 1024 + m16 * 64 + ks * 32 + qd * 8];

  floatx4 of[2][4];
#pragma unroll
  for (int i = 0; i < 2; ++i)
#pragma unroll
    for (int j = 0; j < 4; ++j) of[i][j] = (floatx4){0.f, 0.f, 0.f, 0.f};
  float dsum[2] = {0.f, 0.f};

  for (int ct = 0; ct < 16; ++ct) {
    int c0 = ct * 64;
    __syncthreads();
    {
      int r = tid >> 2, cc = (tid & 3) * 16;
      *(short8*)&kc_s[r * 72 + cc]      = *(const short8*)&kcb[(size_t)(c0 + r) * 64 + cc];
      *(short8*)&kc_s[r * 72 + cc + 8]  = *(const short8*)&kcb[(size_t)(c0 + r) * 64 + cc + 8];
      *(short8*)&kct_s[r * 72 + cc]     = *(const short8*)&kcbT[(size_t)r * NC_ + c0 + cc];
      *(short8*)&kct_s[r * 72 + cc + 8] = *(const short8*)&kcbT[(size_t)r * NC_ + c0 + cc + 8];
    }
    __syncthreads();
#pragma unroll
    for (int mc = 0; mc < 4; ++mc) {
      short8 a0 = *(const short8*)&kc_s[(mc * 16 + m16) * 72 + qd * 8];
      short8 a1 = *(const short8*)&kc_s[(mc * 16 + m16) * 72 + 32 + qd * 8];
#pragma unroll
      for (int nt = 0; nt < 2; ++nt) {
        floatx4 sc = (floatx4){0.f, 0.f, 0.f, 0.f};
        sc = __builtin_amdgcn_mfma_f32_16x16x32_bf16(a0, qf[nt][0], sc, 0, 0, 0);
        sc = __builtin_amdgcn_mfma_f32_16x16x32_bf16(a1, qf[nt][1], sc, 0, 0, 0);
        int tokL = 2 * w + nt;
        int sG = s0 + tokL;
        short4v pv;
#pragma unroll
        for (int rg = 0; rg < 4; ++rg) {
          int cG = c0 + mc * 16 + qd * 4 + rg;
          bool ok = (((selw[tokL][cG >> 5] >> (cG & 31)) & 1u) != 0u) && (sG < cG * 4);
          float e = ok ? __expf(sc[rg]) : 0.f;
          dsum[nt] += e;
          pv[rg] = (short)f2bf(e);
        }
        *(short4v*)&p_s[(tokL * 16 + m16) * 72 + mc * 16 + qd * 4] = pv;
      }
    }
#pragma unroll
    for (int ks = 0; ks < 2; ++ks) {
      short8 pa0 = *(const short8*)&p_s[((2 * w + 0) * 16 + m16) * 72 + ks * 32 + qd * 8];
      short8 pa1 = *(const short8*)&p_s[((2 * w + 1) * 16 + m16) * 72 + ks * 32 + qd * 8];
#pragma unroll
      for (int nt = 0; nt < 4; ++nt) {
        short8 bv = *(const short8*)&kct_s[(nt * 16 + m16) * 72 + ks * 32 + qd * 8];
        of[0][nt] = __builtin_amdgcn_mfma_f32_16x16x32_bf16(pa0, bv, of[0][nt], 0, 0, 0);
        of[1][nt] = __builtin_amdgcn_mfma_f32_16x16x32_bf16(pa1, bv, of[1][nt], 0, 0, 0);
      }
    }
  }
#pragma unroll
  for (int nt = 0; nt < 2; ++nt) {
    dsum[nt] += __shfl_xor(dsum[nt], 16, 64);
    dsum[nt] += __shfl_xor(dsum[nt], 32, 64);
  }
  if (lane < 16) {
    float sk = __expf(sink[lane]);
    dls[w][0][lane] = dsum[0] + sk;
    dls[w][1][lane] = dsum[1] + sk;
  }
#pragma unroll
  for (int tk = 0; tk < 2; ++tk)
#pragma unroll
    for (int nt = 0; nt < 4; ++nt) {
      floatx4 o = of[tk][nt];
#pragma unroll
      for (int rg = 0; rg < 4; ++rg) {
        int head = qd * 4 + rg;
        float dn = dls[w][tk][head];
        out[(size_t)(s0 + 2 * w + tk) * 1024 + head * 64 + nt * 16 + m16] = f2bf(o[rg] / dn);
      }
    }
}

// ---------------------------------------------------------------------------
// Workspace layout (float offsets)
// ---------------------------------------------------------------------------
#define OFF_QUQ    0u          // 4194304 f : quq fp32 -> reused as isc
#define OFF_Q      4194304u    // 4194304 f : qb bf16
#define OFF_XH     8388608u    // 4194304 f : xh bf16 -> reused as gb
#define OFF_XL     12582912u   // 4194304 f : xl bf16 -> reused as sel bitmap
#define OFF_TIDX   16777216u   // 2097152 f : splitk partials (16*65536 f)
#define OFF_KO     18874368u   // 2097152 f : k_or fp32 -> reused as attnb bf16
#define OFF_C4     20971520u   // 1048576 f
#define OFF_CQF    22020096u   // 2097152 f : c_q fp32 -> reused as qih/qil/kph/kpl
#define OFF_QI     24117248u   // 1048576 f
#define OFF_CQH    25165824u   // 1048576 f
#define OFF_CQL    26214400u   // 1048576 f
#define OFF_WPACKT 27262976u   // 262144 f
#define OFF_WDQTH  27525120u   // 524288 f
#define OFF_WDQTL  28049408u   // 524288 f
#define OFF_WIUQTH 28573696u   // 65536 f
#define OFF_WIUQTL 28639232u   // 65536 f
#define OFF_WUQT   28704768u   // 262144 f
#define OFF_ODOWNT 28966912u   // 262144 f
#define OFF_OUPT   29229056u   // 2097152 f
#define OFF_HW     31326208u   // 16384 f
#define OFF_COMP   31342592u   // 65536 f
#define OFF_KC     31408128u   // 65536 f : kcb + kcbT
#define OFF_KPR    31473664u   // 65536 f

extern "C" void kernel_launch(void* const* d_in, const int* in_sizes, int n_in,
                              void* d_out, int out_size, void* d_ws, size_t ws_size,
                              hipStream_t stream) {
  const float* x      = (const float*)d_in[0];
  const float* w_kv_a = (const float*)d_in[1];
  const float* w_kv_b = (const float*)d_in[2];
  const float* w_z_a  = (const float*)d_in[3];
  const float* w_z_b  = (const float*)d_in[4];
  const float* b_a    = (const float*)d_in[5];
  const float* b_b    = (const float*)d_in[6];
  const float* w_dq   = (const float*)d_in[7];
  const float* w_iuq  = (const float*)d_in[8];
  const float* w_w    = (const float*)d_in[9];
  const float* w_k    = (const float*)d_in[10];
  const float* w_uq   = (const float*)d_in[11];
  const float* o_down = (const float*)d_in[12];
  const float* o_up   = (const float*)d_in[13];
  const float* kvn_w  = (const float*)d_in[14];
  const float* kvn_b  = (const float*)d_in[15];
  const float* qn_w   = (const float*)d_in[16];
  const float* qn_b   = (const float*)d_in[17];
  const float* sink   = (const float*)d_in[18];
  float* out = (float*)d_out;
  float* ws = (float*)d_ws;

  float* quq   = ws + OFF_QUQ;
  float* isc   = ws + OFF_QUQ;           // reuse (quq dead after ln_rope)
  unsigned short* qb = (unsigned short*)(ws + OFF_Q);
  unsigned short* xh = (unsigned short*)(ws + OFF_XH);
  unsigned short* gb = (unsigned short*)(ws + OFF_XH);  // reuse (xh dead after c_q)
  unsigned short* xl = (unsigned short*)(ws + OFF_XL);
  unsigned* sel = (unsigned*)(ws + OFF_XL);             // reuse (xl dead after cqf)
  float* partials = ws + OFF_TIDX;
  float* k_or  = ws + OFF_KO;
  unsigned short* attnb = (unsigned short*)(ws + OFF_KO);  // reuse
  float* c4    = ws + OFF_C4;
  float* cqf   = ws + OFF_CQF;
  unsigned short* qih = (unsigned short*)(ws + OFF_CQF);   // overlay after cqf dead
  unsigned short* qil = qih + S_ * NHI_ * CI_;
  unsigned short* kph = qil + S_ * NHI_ * CI_;
  unsigned short* kpl = kph + NC_ * CI_;
  float* q_i   = ws + OFF_QI;
  unsigned short* cqh = (unsigned short*)(ws + OFF_CQH);
  unsigned short* cql = (unsigned short*)(ws + OFF_CQL);
  unsigned short* wpackT = (unsigned short*)(ws + OFF_WPACKT);
  unsigned short* wdqTh  = (unsigned short*)(ws + OFF_WDQTH);
  unsigned short* wdqTl  = (unsigned short*)(ws + OFF_WDQTL);
  unsigned short* wiuqTh = (unsigned short*)(ws + OFF_WIUQTH);
  unsigned short* wiuqTl = (unsigned short*)(ws + OFF_WIUQTL);
  unsigned short* wuqT   = (unsigned short*)(ws + OFF_WUQT);
  unsigned short* odownT = (unsigned short*)(ws + OFF_ODOWNT);
  unsigned short* oupT   = (unsigned short*)(ws + OFF_OUPT);
  float* hw    = ws + OFF_HW;
  float* comp  = ws + OFF_COMP;
  unsigned short* kcb  = (unsigned short*)(ws + OFF_KC);
  unsigned short* kcbT = kcb + NC_ * C_;
  float* k_pr  = ws + OFF_KPR;

  dim3 blk(256);

  // --- casts & weight transposes ---
  cast_split<<<8192, blk, 0, stream>>>(x, xh, xl, S_ * D_);
  transpose_cast<<<dim3(64, 2), blk, 0, stream>>>(w_kv_a, wpackT + 0 * 64 * 2048, D_, C_);
  transpose_cast<<<dim3(64, 2), blk, 0, stream>>>(w_kv_b, wpackT + 1 * 64 * 2048, D_, C_);
  transpose_cast<<<dim3(64, 2), blk, 0, stream>>>(w_z_a,  wpackT + 2 * 64 * 2048, D_, C_);
  transpose_cast<<<dim3(64, 2), blk, 0, stream>>>(w_z_b,  wpackT + 3 * 64 * 2048, D_, C_);
  transpose_cast_split<<<dim3(64, 16), blk, 0, stream>>>(w_dq, wdqTh, wdqTl, D_, DC_);
  transpose_cast_split<<<dim3(16, 8), blk, 0, stream>>>(w_iuq, wiuqTh, wiuqTl, DC_, NHI_ * CI_);
  transpose_cast<<<dim3(16, 32), blk, 0, stream>>>(w_uq, wuqT, DC_, NH_ * C_);
  for (int g = 0; g < NG_; ++g)
    transpose_cast<<<dim3(8, 16), blk, 0, stream>>>(o_down + (size_t)g * 256 * DG_,
                                                    odownT + (size_t)g * DG_ * 256, 256, DG_);
  transpose_cast<<<dim3(64, 64), blk, 0, stream>>>(o_up, oupT, NG_ * DG_, D_);

  // --- fp32 indexer-side path: k_orig -> k_proj (split-K), hw ---
  mean4_kernel<<<8192, blk, 0, stream>>>(x, k_or);
  gemm_f32_splitk<<<dim3(KSL_, 16), blk, 0, stream>>>(k_or, w_k, partials, D_, CI_);
  reduce_splitk<<<256, blk, 0, stream>>>(partials, k_pr);
  hw_kernel<<<1024, blk, 0, stream>>>(x, w_w, hw);

  // --- MFMA GEMMs ---
  gemm_bf16<<<dim3(2, 32), blk, 0, stream>>>(xh, wpackT, c4, nullptr, D_, D_, D_, 256);
  gemm_bf16_split<<<dim3(4, 32), blk, 0, stream>>>(xh, xl, wdqTh, wdqTl, cqf, D_, D_, D_, DC_);
  cast_split<<<2048, blk, 0, stream>>>(cqf, cqh, cql, S_ * DC_);
  // cqf dead; region reused for qih/qil/kph/kpl
  gemm_bf16_split<<<dim3(2, 32), blk, 0, stream>>>(cqh, cql, wiuqTh, wiuqTl, q_i, DC_, DC_, DC_, NHI_ * CI_);
  gemm_bf16<<<dim3(8, 32), blk, 0, stream>>>(cqh, wuqT, quq, nullptr, DC_, DC_, DC_, NH_ * C_);

  // --- gating -> compressed -> kc (LN, bf16 row-major + transposed) ---
  gate_kernel<<<256, blk, 0, stream>>>(c4, b_a, b_b, comp);
  ln_kc_kernel<<<256, blk, 0, stream>>>(comp, kvn_w, kvn_b, kcb, kcbT);

  // --- q: LN + RoPE -> bf16 scaled by 1/8 (consumes quq; precedes iscores) ---
  ln_rope_q_kernel<<<16384, blk, 0, stream>>>(quq, qn_w, qn_b, qb);

  // --- indexer scores (split-bf16 MFMA) + exact radix-select bitmap ---
  cast_split<<<1024, blk, 0, stream>>>(q_i, qih, qil, S_ * NHI_ * CI_);
  cast_split<<<64, blk, 0, stream>>>(k_pr, kph, kpl, NC_ * CI_);
  iscores_mfma<<<dim3(8, 128), blk, 0, stream>>>(qih, qil, kph, kpl, hw, isc);
  topk_select_kernel<<<S_, blk, 0, stream>>>(isc, sel);

  // --- dense-masked flash attention (MFMA) ---
  attn_mfma_kernel<<<S_ / TS_, blk, 0, stream>>>(qb, kcb, kcbT, sel, sink, attnb);

  // --- o_down (4 groups) -> o_up ---
  for (int g = 0; g < NG_; ++g)
    gemm_bf16<<<dim3(4, 32), blk, 0, stream>>>(attnb + g * 256, odownT + (size_t)g * DG_ * 256,
                                               nullptr, gb + g * DG_, 256, NH_ * C_, 256, NG_ * DG_);
  gemm_bf16<<<dim3(16, 32), blk, 0, stream>>>(gb, oupT, out, nullptr, NG_ * DG_, NG_ * DG_, NG_ * DG_, D_);
}

// Round 7
// 507.370 us; speedup vs baseline: 4.4396x; 1.1734x over previous
//
#include <hip/hip_runtime.h>
#include <math.h>

// Problem constants (B=1 throughout)
#define S_   4096
#define D_   2048
#define M_   4
#define NC_  1024
#define TOPK_ 512
#define NH_  16
#define C_   64
#define DC_  512
#define NG_  4
#define DG_  512
#define CI_  64
#define NHI_ 4
#define ROPE_ 32
#define EPS_ 1e-6f

typedef __attribute__((ext_vector_type(8))) short short8;
typedef __attribute__((ext_vector_type(4))) short short4v;
typedef __attribute__((ext_vector_type(4))) float floatx4;

__device__ inline unsigned short f2bf(float f) {
  unsigned u = __float_as_uint(f);
  u += 0x7fff + ((u >> 16) & 1);   // round-to-nearest-even
  return (unsigned short)(u >> 16);
}
__device__ inline float bf2f(unsigned short h) {
  return __uint_as_float(((unsigned)h) << 16);
}

// ---------------------------------------------------------------------------
// bf16 MFMA GEMM (m97 structure): C = A @ Bt^T, with grid.z batching/split-K:
// A += z*Az, Bt += z*Bz, C += z*Cz. Split-K = (Az=Bz=Kslice, Cz=M*ldc, K=Kslice).
// ---------------------------------------------------------------------------
__global__ __launch_bounds__(256) void gemm_bf16(
    const unsigned short* __restrict__ A, const unsigned short* __restrict__ Bt,
    float* __restrict__ Cf, unsigned short* __restrict__ Cb,
    int K, int lda, int ldb, int ldc,
    long long Az, long long Bz, long long Cz) {
  int zz = blockIdx.z;
  A += (size_t)zz * Az;
  Bt += (size_t)zz * Bz;
  if (Cf) Cf += (size_t)zz * Cz;
  if (Cb) Cb += (size_t)zz * Cz;
  __shared__ unsigned short As[128 * 32];
  __shared__ unsigned short Bs[128 * 32];
  int tid = threadIdx.x;
  int bm = blockIdx.y * 128, bn = blockIdx.x * 128;
  int lane = tid & 63, wid = tid >> 6;
  int wm = (wid >> 1) * 64, wn = (wid & 1) * 64;
  int qd = lane >> 4, m16 = lane & 15;

  floatx4 acc[4][4];
#pragma unroll
  for (int i = 0; i < 4; ++i)
#pragma unroll
    for (int j = 0; j < 4; ++j) acc[i][j] = (floatx4){0.f, 0.f, 0.f, 0.f};

  for (int k0 = 0; k0 < K; k0 += 32) {
#pragma unroll
    for (int i = 0; i < 2; ++i) {
      int idx = tid + 256 * i;
      int r = idx >> 2, s = idx & 3;
      int g = s ^ ((r >> 1) & 3);
      __builtin_amdgcn_global_load_lds(
          (const __attribute__((address_space(1))) unsigned int*)(A + (size_t)(bm + r) * lda + k0 + g * 8),
          (__attribute__((address_space(3))) unsigned int*)(&As[idx * 8]), 16, 0, 0);
    }
#pragma unroll
    for (int i = 0; i < 2; ++i) {
      int idx = tid + 256 * i;
      int r = idx >> 2, s = idx & 3;
      int g = s ^ ((r >> 1) & 3);
      __builtin_amdgcn_global_load_lds(
          (const __attribute__((address_space(1))) unsigned int*)(Bt + (size_t)(bn + r) * ldb + k0 + g * 8),
          (__attribute__((address_space(3))) unsigned int*)(&Bs[idx * 8]), 16, 0, 0);
    }
    __syncthreads();
    short8 af[4], bfr[4];
#pragma unroll
    for (int mi = 0; mi < 4; ++mi) {
      int r = wm + mi * 16 + m16;
      int slot = qd ^ ((r >> 1) & 3);
      af[mi] = *(const short8*)&As[r * 32 + slot * 8];
    }
#pragma unroll
    for (int ni = 0; ni < 4; ++ni) {
      int r = wn + ni * 16 + m16;
      int slot = qd ^ ((r >> 1) & 3);
      bfr[ni] = *(const short8*)&Bs[r * 32 + slot * 8];
    }
#pragma unroll
    for (int mi = 0; mi < 4; ++mi)
#pragma unroll
      for (int ni = 0; ni < 4; ++ni)
        acc[mi][ni] = __builtin_amdgcn_mfma_f32_16x16x32_bf16(af[mi], bfr[ni], acc[mi][ni], 0, 0, 0);
    __syncthreads();
  }
#pragma unroll
  for (int mi = 0; mi < 4; ++mi)
#pragma unroll
    for (int ni = 0; ni < 4; ++ni) {
      int col = bn + wn + ni * 16 + m16;
#pragma unroll
      for (int rg = 0; rg < 4; ++rg) {
        int row = bm + wm + mi * 16 + qd * 4 + rg;
        if (Cb)
          Cb[(size_t)row * ldc + col] = f2bf(acc[mi][ni][rg]);
        else
          Cf[(size_t)row * ldc + col] = acc[mi][ni][rg];
      }
    }
}

// ---------------------------------------------------------------------------
// Split-bf16 MFMA GEMM (fp32-accurate, 3 MFMA terms), grid.z split-K strides.
// ---------------------------------------------------------------------------
__global__ __launch_bounds__(256) void gemm_bf16_split(
    const unsigned short* __restrict__ Ah, const unsigned short* __restrict__ Al,
    const unsigned short* __restrict__ Bh, const unsigned short* __restrict__ Bl,
    float* __restrict__ Cf, int K, int lda, int ldb, int ldc,
    long long Az, long long Bz, long long Cz) {
  int zz = blockIdx.z;
  Ah += (size_t)zz * Az; Al += (size_t)zz * Az;
  Bh += (size_t)zz * Bz; Bl += (size_t)zz * Bz;
  Cf += (size_t)zz * Cz;
  __shared__ unsigned short Ash[128 * 32];
  __shared__ unsigned short Asl[128 * 32];
  __shared__ unsigned short Bsh[128 * 32];
  __shared__ unsigned short Bsl[128 * 32];
  int tid = threadIdx.x;
  int bm = blockIdx.y * 128, bn = blockIdx.x * 128;
  int lane = tid & 63, wid = tid >> 6;
  int wm = (wid >> 1) * 64, wn = (wid & 1) * 64;
  int qd = lane >> 4, m16 = lane & 15;

  floatx4 acc[4][4];
#pragma unroll
  for (int i = 0; i < 4; ++i)
#pragma unroll
    for (int j = 0; j < 4; ++j) acc[i][j] = (floatx4){0.f, 0.f, 0.f, 0.f};

  for (int k0 = 0; k0 < K; k0 += 32) {
#pragma unroll
    for (int i = 0; i < 2; ++i) {
      int idx = tid + 256 * i;
      int r = idx >> 2, s = idx & 3;
      int g = s ^ ((r >> 1) & 3);
      size_t aoff = (size_t)(bm + r) * lda + k0 + g * 8;
      size_t boff = (size_t)(bn + r) * ldb + k0 + g * 8;
      __builtin_amdgcn_global_load_lds(
          (const __attribute__((address_space(1))) unsigned int*)(Ah + aoff),
          (__attribute__((address_space(3))) unsigned int*)(&Ash[idx * 8]), 16, 0, 0);
      __builtin_amdgcn_global_load_lds(
          (const __attribute__((address_space(1))) unsigned int*)(Al + aoff),
          (__attribute__((address_space(3))) unsigned int*)(&Asl[idx * 8]), 16, 0, 0);
      __builtin_amdgcn_global_load_lds(
          (const __attribute__((address_space(1))) unsigned int*)(Bh + boff),
          (__attribute__((address_space(3))) unsigned int*)(&Bsh[idx * 8]), 16, 0, 0);
      __builtin_amdgcn_global_load_lds(
          (const __attribute__((address_space(1))) unsigned int*)(Bl + boff),
          (__attribute__((address_space(3))) unsigned int*)(&Bsl[idx * 8]), 16, 0, 0);
    }
    __syncthreads();
    short8 afh[4], afl[4], bfh[4], bfl[4];
#pragma unroll
    for (int mi = 0; mi < 4; ++mi) {
      int r = wm + mi * 16 + m16;
      int slot = qd ^ ((r >> 1) & 3);
      afh[mi] = *(const short8*)&Ash[r * 32 + slot * 8];
      afl[mi] = *(const short8*)&Asl[r * 32 + slot * 8];
    }
#pragma unroll
    for (int ni = 0; ni < 4; ++ni) {
      int r = wn + ni * 16 + m16;
      int slot = qd ^ ((r >> 1) & 3);
      bfh[ni] = *(const short8*)&Bsh[r * 32 + slot * 8];
      bfl[ni] = *(const short8*)&Bsl[r * 32 + slot * 8];
    }
#pragma unroll
    for (int mi = 0; mi < 4; ++mi)
#pragma unroll
      for (int ni = 0; ni < 4; ++ni) {
        acc[mi][ni] = __builtin_amdgcn_mfma_f32_16x16x32_bf16(afh[mi], bfh[ni], acc[mi][ni], 0, 0, 0);
        acc[mi][ni] = __builtin_amdgcn_mfma_f32_16x16x32_bf16(afh[mi], bfl[ni], acc[mi][ni], 0, 0, 0);
        acc[mi][ni] = __builtin_amdgcn_mfma_f32_16x16x32_bf16(afl[mi], bfh[ni], acc[mi][ni], 0, 0, 0);
      }
    __syncthreads();
  }
#pragma unroll
  for (int mi = 0; mi < 4; ++mi)
#pragma unroll
    for (int ni = 0; ni < 4; ++ni) {
      int col = bn + wn + ni * 16 + m16;
#pragma unroll
      for (int rg = 0; rg < 4; ++rg) {
        int row = bm + wm + mi * 16 + qd * 4 + rg;
        Cf[(size_t)row * ldc + col] = acc[mi][ni][rg];
      }
    }
}

// reduce z fp32 slices -> fp32
__global__ void reduce_f32(const float* __restrict__ P, float* __restrict__ C, int n, int z) {
  int i = (blockIdx.x * 256 + threadIdx.x) * 4;
  if (i >= n) return;
  float4 a = *(const float4*)&P[i];
  for (int s = 1; s < z; ++s) {
    float4 b = *(const float4*)&P[(size_t)s * n + i];
    a.x += b.x; a.y += b.y; a.z += b.z; a.w += b.w;
  }
  *(float4*)&C[i] = a;
}

// reduce z fp32 slices -> (bf16 hi, bf16 lo)
__global__ void reduce_cast_split(const float* __restrict__ P, unsigned short* __restrict__ hi,
                                  unsigned short* __restrict__ lo, int n, int z) {
  int i = (blockIdx.x * 256 + threadIdx.x) * 4;
  if (i >= n) return;
  float4 a = *(const float4*)&P[i];
  for (int s = 1; s < z; ++s) {
    float4 b = *(const float4*)&P[(size_t)s * n + i];
    a.x += b.x; a.y += b.y; a.z += b.z; a.w += b.w;
  }
  ushort4 h = make_ushort4(f2bf(a.x), f2bf(a.y), f2bf(a.z), f2bf(a.w));
  ushort4 l = make_ushort4(f2bf(a.x - bf2f(h.x)), f2bf(a.y - bf2f(h.y)),
                           f2bf(a.z - bf2f(h.z)), f2bf(a.w - bf2f(h.w)));
  *(ushort4*)&hi[i] = h;
  *(ushort4*)&lo[i] = l;
}

// ---------------------------------------------------------------------------
// Indexer scores on split-bf16 MFMA (relu*hw epilogue in-register).
// ---------------------------------------------------------------------------
__global__ __launch_bounds__(256) void iscores_mfma(
    const unsigned short* __restrict__ Ah, const unsigned short* __restrict__ Al,
    const unsigned short* __restrict__ Bh, const unsigned short* __restrict__ Bl,
    const float* __restrict__ hw, float* __restrict__ isc) {
  __shared__ unsigned short Ash[128 * 32];
  __shared__ unsigned short Asl[128 * 32];
  __shared__ unsigned short Bsh[128 * 32];
  __shared__ unsigned short Bsl[128 * 32];
  int tid = threadIdx.x;
  int bm = blockIdx.y * 128, bn = blockIdx.x * 128;
  int lane = tid & 63, wid = tid >> 6;
  int wm = (wid >> 1) * 64, wn = (wid & 1) * 64;
  int qd = lane >> 4, m16 = lane & 15;

  floatx4 acc[4][4];
#pragma unroll
  for (int i = 0; i < 4; ++i)
#pragma unroll
    for (int j = 0; j < 4; ++j) acc[i][j] = (floatx4){0.f, 0.f, 0.f, 0.f};

#pragma unroll
  for (int k0 = 0; k0 < 64; k0 += 32) {
#pragma unroll
    for (int i = 0; i < 2; ++i) {
      int idx = tid + 256 * i;
      int r = idx >> 2, s = idx & 3;
      int g = s ^ ((r >> 1) & 3);
      size_t aoff = (size_t)(bm + r) * 64 + k0 + g * 8;
      size_t boff = (size_t)(bn + r) * 64 + k0 + g * 8;
      __builtin_amdgcn_global_load_lds(
          (const __attribute__((address_space(1))) unsigned int*)(Ah + aoff),
          (__attribute__((address_space(3))) unsigned int*)(&Ash[idx * 8]), 16, 0, 0);
      __builtin_amdgcn_global_load_lds(
          (const __attribute__((address_space(1))) unsigned int*)(Al + aoff),
          (__attribute__((address_space(3))) unsigned int*)(&Asl[idx * 8]), 16, 0, 0);
      __builtin_amdgcn_global_load_lds(
          (const __attribute__((address_space(1))) unsigned int*)(Bh + boff),
          (__attribute__((address_space(3))) unsigned int*)(&Bsh[idx * 8]), 16, 0, 0);
      __builtin_amdgcn_global_load_lds(
          (const __attribute__((address_space(1))) unsigned int*)(Bl + boff),
          (__attribute__((address_space(3))) unsigned int*)(&Bsl[idx * 8]), 16, 0, 0);
    }
    __syncthreads();
    short8 afh[4], afl[4], bfh[4], bfl[4];
#pragma unroll
    for (int mi = 0; mi < 4; ++mi) {
      int r = wm + mi * 16 + m16;
      int slot = qd ^ ((r >> 1) & 3);
      afh[mi] = *(const short8*)&Ash[r * 32 + slot * 8];
      afl[mi] = *(const short8*)&Asl[r * 32 + slot * 8];
    }
#pragma unroll
    for (int ni = 0; ni < 4; ++ni) {
      int r = wn + ni * 16 + m16;
      int slot = qd ^ ((r >> 1) & 3);
      bfh[ni] = *(const short8*)&Bsh[r * 32 + slot * 8];
      bfl[ni] = *(const short8*)&Bsl[r * 32 + slot * 8];
    }
#pragma unroll
    for (int mi = 0; mi < 4; ++mi)
#pragma unroll
      for (int ni = 0; ni < 4; ++ni) {
        acc[mi][ni] = __builtin_amdgcn_mfma_f32_16x16x32_bf16(afh[mi], bfh[ni], acc[mi][ni], 0, 0, 0);
        acc[mi][ni] = __builtin_amdgcn_mfma_f32_16x16x32_bf16(afh[mi], bfl[ni], acc[mi][ni], 0, 0, 0);
        acc[mi][ni] = __builtin_amdgcn_mfma_f32_16x16x32_bf16(afl[mi], bfh[ni], acc[mi][ni], 0, 0, 0);
      }
    __syncthreads();
  }
#pragma unroll
  for (int mi = 0; mi < 4; ++mi) {
    int tok = ((bm + wm + mi * 16) >> 2) + qd;
    float4 hwv = *(const float4*)&hw[tok * 4];
#pragma unroll
    for (int ni = 0; ni < 4; ++ni) {
      floatx4 a = acc[mi][ni];
      float v = fmaxf(a[0], 0.f) * hwv.x + fmaxf(a[1], 0.f) * hwv.y +
                fmaxf(a[2], 0.f) * hwv.z + fmaxf(a[3], 0.f) * hwv.w;
      int col = bn + wn + ni * 16 + m16;
      isc[(size_t)tok * NC_ + col] = (col < tok) ? v : -__builtin_inff();
    }
  }
}

// ---------------------------------------------------------------------------
// Split-K fp32 GEMM for k_proj (N=64) + reduce
// ---------------------------------------------------------------------------
#define BM 64
#define BN 64
#define BK 16
#define KSL_ 16
#define KSLICE_ 128
__global__ __launch_bounds__(256) void gemm_f32_splitk(
    const float* __restrict__ A, const float* __restrict__ B,
    float* __restrict__ P, int lda, int ldb) {
  __shared__ float As[BK][BM + 4];
  __shared__ float Bs[BK][BN + 4];
  int tid = threadIdx.x;
  int bm = blockIdx.y * BM;
  int kbase = blockIdx.x * KSLICE_;
  int tr = tid >> 4;
  int tc = tid & 15;
  float acc[4][4] = {{0.f}};
  for (int k0 = kbase; k0 < kbase + KSLICE_; k0 += BK) {
    int ac = tid & 15;
    int ar0 = tid >> 4;
#pragma unroll
    for (int i = 0; i < 4; ++i) {
      int r = ar0 + 16 * i;
      As[ac][r] = A[(size_t)(bm + r) * lda + k0 + ac];
    }
    int bc = tid & 63;
    int br0 = tid >> 6;
#pragma unroll
    for (int i = 0; i < 4; ++i) {
      int r = br0 + 4 * i;
      Bs[r][bc] = B[(size_t)(k0 + r) * ldb + bc];
    }
    __syncthreads();
#pragma unroll
    for (int kk = 0; kk < BK; ++kk) {
      float4 av = *(const float4*)&As[kk][tr * 4];
      float4 bv = *(const float4*)&Bs[kk][tc * 4];
      float a[4] = {av.x, av.y, av.z, av.w};
      float b[4] = {bv.x, bv.y, bv.z, bv.w};
#pragma unroll
      for (int i = 0; i < 4; ++i)
#pragma unroll
        for (int j = 0; j < 4; ++j) acc[i][j] += a[i] * b[j];
    }
    __syncthreads();
  }
  float* Pb = P + (size_t)blockIdx.x * (NC_ * CI_);
#pragma unroll
  for (int i = 0; i < 4; ++i) {
    float4 v = make_float4(acc[i][0], acc[i][1], acc[i][2], acc[i][3]);
    *(float4*)&Pb[(size_t)(bm + tr * 4 + i) * CI_ + tc * 4] = v;
  }
}

__global__ void reduce_splitk(const float* __restrict__ P, float* __restrict__ C) {
  int i = blockIdx.x * 256 + threadIdx.x;
  if (i >= NC_ * CI_) return;
  float a = 0.f;
#pragma unroll
  for (int s = 0; s < KSL_; ++s) a += P[(size_t)s * (NC_ * CI_) + i];
  C[i] = a;
}

// fp32 -> (bf16 hi, bf16 lo) element-wise split (n multiple of 4)
__global__ void cast_split(const float* __restrict__ in, unsigned short* __restrict__ hi,
                           unsigned short* __restrict__ lo, int n) {
  int i = (blockIdx.x * 256 + threadIdx.x) * 4;
  if (i >= n) return;
  float4 v = *(const float4*)&in[i];
  ushort4 h = make_ushort4(f2bf(v.x), f2bf(v.y), f2bf(v.z), f2bf(v.w));
  ushort4 l = make_ushort4(f2bf(v.x - bf2f(h.x)), f2bf(v.y - bf2f(h.y)),
                           f2bf(v.z - bf2f(h.z)), f2bf(v.w - bf2f(h.w)));
  *(ushort4*)&hi[i] = h;
  *(ushort4*)&lo[i] = l;
}

// fp32 (K x N) -> bf16 transpose (N x K). K,N multiples of 32.
__global__ __launch_bounds__(256) void transpose_cast(
    const float* __restrict__ in, unsigned short* __restrict__ out, int K, int N) {
  __shared__ float t[32][33];
  int k0 = blockIdx.x * 32, n0 = blockIdx.y * 32;
  int tx = threadIdx.x & 31, ty = threadIdx.x >> 5;
#pragma unroll
  for (int i = 0; i < 4; ++i)
    t[ty * 4 + i][tx] = in[(size_t)(k0 + ty * 4 + i) * N + n0 + tx];
  __syncthreads();
#pragma unroll
  for (int i = 0; i < 4; ++i)
    out[(size_t)(n0 + ty * 4 + i) * K + k0 + tx] = f2bf(t[tx][ty * 4 + i]);
}

// fp32 (K x N) -> bf16 transpose split (N x K, hi+lo)
__global__ __launch_bounds__(256) void transpose_cast_split(
    const float* __restrict__ in, unsigned short* __restrict__ outh,
    unsigned short* __restrict__ outl, int K, int N) {
  __shared__ float t[32][33];
  int k0 = blockIdx.x * 32, n0 = blockIdx.y * 32;
  int tx = threadIdx.x & 31, ty = threadIdx.x >> 5;
#pragma unroll
  for (int i = 0; i < 4; ++i)
    t[ty * 4 + i][tx] = in[(size_t)(k0 + ty * 4 + i) * N + n0 + tx];
  __syncthreads();
#pragma unroll
  for (int i = 0; i < 4; ++i) {
    float v = t[tx][ty * 4 + i];
    unsigned short h = f2bf(v);
    outh[(size_t)(n0 + ty * 4 + i) * K + k0 + tx] = h;
    outl[(size_t)(n0 + ty * 4 + i) * K + k0 + tx] = f2bf(v - bf2f(h));
  }
}

// k_orig[j,d] = mean over 4 tokens
__global__ void mean4_kernel(const float* __restrict__ x, float* __restrict__ ko) {
  int i = blockIdx.x * 256 + threadIdx.x;
  if (i >= NC_ * D_) return;
  int j = i >> 11, d = i & (D_ - 1);
  const float* p = x + (size_t)j * 4 * D_ + d;
  ko[i] = 0.25f * (p[0] + p[D_] + p[2 * D_] + p[3 * D_]);
}

__device__ inline float wave_sum64(float v) {
#pragma unroll
  for (int off = 32; off > 0; off >>= 1) v += __shfl_xor(v, off, 64);
  return v;
}

// hw = x @ w_w (S x 4): one wave per token, coalesced x reads
__global__ void hw_kernel(const float* __restrict__ x, const float* __restrict__ ww,
                          float* __restrict__ hw) {
  int w = threadIdx.x >> 6, lane = threadIdx.x & 63;
  int s = blockIdx.x * 4 + w;
  const float* xr = x + (size_t)s * D_;
  float a0 = 0.f, a1 = 0.f, a2 = 0.f, a3 = 0.f;
  for (int k = lane; k < D_; k += 64) {
    float xv = xr[k];
    float4 wv = *(const float4*)&ww[k * 4];
    a0 += xv * wv.x; a1 += xv * wv.y; a2 += xv * wv.z; a3 += xv * wv.w;
  }
  a0 = wave_sum64(a0); a1 = wave_sum64(a1);
  a2 = wave_sum64(a2); a3 = wave_sum64(a3);
  if (lane == 0) {
    float4 o = make_float4(a0, a1, a2, a3);
    *(float4*)&hw[s * 4] = o;
  }
}

// gating softmax; reads packed c4 (S x 256: [c_a|c_b|z_a|z_b])
__global__ void gate_kernel(const float* __restrict__ c4,
                            const float* __restrict__ ba, const float* __restrict__ bb,
                            float* __restrict__ comp) {
  int i = blockIdx.x * 256 + threadIdx.x;
  if (i >= NC_ * C_) return;
  int j = i >> 6, c = i & 63;
  float lg[8], vv[8];
#pragma unroll
  for (int m = 0; m < 4; ++m) {
    if (j == 0) {
      lg[m] = -1e30f + bb[m * C_ + c];
      vv[m] = 0.f;
    } else {
      int row = (j - 1) * 4 + m;
      lg[m] = c4[(size_t)row * 256 + 192 + c] + bb[m * C_ + c];
      vv[m] = c4[(size_t)row * 256 + 64 + c];
    }
    int row2 = j * 4 + m;
    lg[4 + m] = c4[(size_t)row2 * 256 + 128 + c] + ba[m * C_ + c];
    vv[4 + m] = c4[(size_t)row2 * 256 + 0 + c];
  }
  float mx = lg[0];
#pragma unroll
  for (int t = 1; t < 8; ++t) mx = fmaxf(mx, lg[t]);
  float se = 0.f, acc = 0.f;
#pragma unroll
  for (int t = 0; t < 8; ++t) {
    float e = expf(lg[t] - mx);
    se += e;
    acc += e * vv[t];
  }
  comp[i] = acc / se;
}

// LayerNorm over C=64 -> bf16 row-major + bf16 transposed (for attention MFMA)
__global__ void ln_kc_kernel(const float* __restrict__ in, const float* __restrict__ w,
                             const float* __restrict__ b, unsigned short* __restrict__ kcb,
                             unsigned short* __restrict__ kcbT) {
  int row = blockIdx.x * 4 + (threadIdx.x >> 6);
  int c = threadIdx.x & 63;
  float v = in[(size_t)row * C_ + c];
  float mu = wave_sum64(v) * (1.f / 64.f);
  float d = v - mu;
  float var = wave_sum64(d * d) * (1.f / 64.f);
  float y = d * (1.f / sqrtf(var + EPS_)) * w[c] + b[c];
  unsigned short h = f2bf(y);
  kcb[(size_t)row * C_ + c] = h;
  kcbT[(size_t)c * NC_ + row] = h;
}

// LN + RoPE for q -> bf16, pre-scaled by 1/sqrt(C)=0.125 (only attention uses q)
__global__ void ln_rope_q_kernel(const float* __restrict__ quq, const float* __restrict__ w,
                                 const float* __restrict__ b, unsigned short* __restrict__ qb) {
  int row = blockIdx.x * 4 + (threadIdx.x >> 6);  // s*16 + h
  int s = row >> 4;
  int c = threadIdx.x & 63;
  float v = quq[(size_t)row * C_ + c];
  float mu = wave_sum64(v) * (1.f / 64.f);
  float d = v - mu;
  float var = wave_sum64(d * d) * (1.f / 64.f);
  float y = d * (1.f / sqrtf(var + EPS_)) * w[c] + b[c];
  float outv;
  float partner = __shfl_xor(y, 1, 64);
  if (c < C_ - ROPE_) {
    outv = y;
  } else {
    int p = (c - (C_ - ROPE_)) >> 1;
    float inv = powf(10000.f, -(2.f * (float)p) / (float)ROPE_);
    float ang = (float)s * inv;
    float cs = cosf(ang), sn = sinf(ang);
    if ((c & 1) == 0)
      outv = y * cs - partner * sn;
    else
      outv = partner * sn + y * cs;
  }
  qb[(size_t)row * C_ + c] = f2bf(outv * 0.125f);
}

// ---------------------------------------------------------------------------
// Top-512-of-1024 exact radix-select -> selection bitmap.
// ---------------------------------------------------------------------------
__global__ __launch_bounds__(256) void topk_select_kernel(
    const float* __restrict__ isc, unsigned* __restrict__ sel) {
  __shared__ unsigned mv[NC_];
  __shared__ unsigned bins[256];
  __shared__ unsigned scan[256];
  __shared__ unsigned sB, sR;
  __shared__ unsigned selw[32];
  int s = blockIdx.x;
  int tid = threadIdx.x;
  for (int i = tid; i < NC_; i += 256) {
    unsigned u = __float_as_uint(isc[(size_t)s * NC_ + i]);
    mv[i] = (u & 0x80000000u) ? ~u : (u | 0x80000000u);
  }
  __syncthreads();
  unsigned K_rem = TOPK_;
  unsigned prefix = 0u;
  for (int lvl = 0; lvl < 4; ++lvl) {
    int shift = 24 - 8 * lvl;
    unsigned pm = (lvl == 0) ? 0u : (0xFFFFFFFFu << (32 - 8 * lvl));
    bins[tid] = 0u;
    __syncthreads();
    for (int i = tid; i < NC_; i += 256) {
      unsigned m = mv[i];
      if ((m & pm) == prefix) atomicAdd(&bins[(m >> shift) & 0xFFu], 1u);
    }
    __syncthreads();
    unsigned v = bins[tid];
    scan[tid] = v;
    __syncthreads();
    for (int off = 1; off < 256; off <<= 1) {
      unsigned add = (tid + off < 256) ? scan[tid + off] : 0u;
      __syncthreads();
      scan[tid] += add;
      __syncthreads();
    }
    unsigned gt = scan[tid] - v;
    if (gt < K_rem && K_rem <= gt + v) { sB = (unsigned)tid; sR = K_rem - gt; }
    __syncthreads();
    prefix |= (sB << shift);
    K_rem = sR;
    __syncthreads();
  }
  unsigned vstar = prefix;
  unsigned eq = 0;
#pragma unroll
  for (int j = 0; j < 4; ++j) eq += (mv[4 * tid + j] == vstar);
  scan[tid] = eq;
  __syncthreads();
  for (int off = 1; off < 256; off <<= 1) {
    unsigned add = (tid >= off) ? scan[tid - off] : 0u;
    __syncthreads();
    scan[tid] += add;
    __syncthreads();
  }
  unsigned rank0 = scan[tid] - eq;
  if (tid < 32) selw[tid] = 0u;
  __syncthreads();
  unsigned local = 0, bits = 0;
#pragma unroll
  for (int j = 0; j < 4; ++j) {
    unsigned m = mv[4 * tid + j];
    bool sb = (m > vstar) || (m == vstar && (rank0 + local) < K_rem);
    local += (m == vstar);
    if (sb) bits |= (1u << ((4 * tid + j) & 31));
  }
  if (bits) atomicOr(&selw[tid >> 3], bits);
  __syncthreads();
  if (tid < 32) sel[(size_t)s * 32 + tid] = selw[tid];
}

// ---------------------------------------------------------------------------
// Dense-masked flash attention on MFMA.
// ---------------------------------------------------------------------------
#define TS_ 8
__global__ __launch_bounds__(256) void attn_mfma_kernel(
    const unsigned short* __restrict__ qb, const unsigned short* __restrict__ kcb,
    const unsigned short* __restrict__ kcbT, const unsigned* __restrict__ sel,
    const float* __restrict__ sink, unsigned short* __restrict__ out) {
  __shared__ unsigned short kc_s[64 * 72];
  __shared__ unsigned short kct_s[64 * 72];
  __shared__ unsigned short p_s[128 * 72];
  __shared__ unsigned selw[TS_][32];
  __shared__ float dls[4][2][16];
  int tid = threadIdx.x;
  int s0 = blockIdx.x * TS_;
  int lane = tid & 63, w = tid >> 6;
  int qd = lane >> 4, m16 = lane & 15;

  for (int i = tid; i < TS_ * 32; i += 256)
    selw[i >> 5][i & 31] = sel[(size_t)(s0 + (i >> 5)) * 32 + (i & 31)];

  short8 qf[2][2];
#pragma unroll
  for (int tk = 0; tk < 2; ++tk)
#pragma unroll
    for (int ks = 0; ks < 2; ++ks)
      qf[tk][ks] = *(const short8*)&qb[(size_t)(s0 + 2 * w + tk) * 1024 + m16 * 64 + ks * 32 + qd * 8];

  floatx4 of[2][4];
#pragma unroll
  for (int i = 0; i < 2; ++i)
#pragma unroll
    for (int j = 0; j < 4; ++j) of[i][j] = (floatx4){0.f, 0.f, 0.f, 0.f};
  float dsum[2] = {0.f, 0.f};

  for (int ct = 0; ct < 16; ++ct) {
    int c0 = ct * 64;
    __syncthreads();
    {
      int r = tid >> 2, cc = (tid & 3) * 16;
      *(short8*)&kc_s[r * 72 + cc]      = *(const short8*)&kcb[(size_t)(c0 + r) * 64 + cc];
      *(short8*)&kc_s[r * 72 + cc + 8]  = *(const short8*)&kcb[(size_t)(c0 + r) * 64 + cc + 8];
      *(short8*)&kct_s[r * 72 + cc]     = *(const short8*)&kcbT[(size_t)r * NC_ + c0 + cc];
      *(short8*)&kct_s[r * 72 + cc + 8] = *(const short8*)&kcbT[(size_t)r * NC_ + c0 + cc + 8];
    }
    __syncthreads();
#pragma unroll
    for (int mc = 0; mc < 4; ++mc) {
      short8 a0 = *(const short8*)&kc_s[(mc * 16 + m16) * 72 + qd * 8];
      short8 a1 = *(const short8*)&kc_s[(mc * 16 + m16) * 72 + 32 + qd * 8];
#pragma unroll
      for (int nt = 0; nt < 2; ++nt) {
        floatx4 sc = (floatx4){0.f, 0.f, 0.f, 0.f};
        sc = __builtin_amdgcn_mfma_f32_16x16x32_bf16(a0, qf[nt][0], sc, 0, 0, 0);
        sc = __builtin_amdgcn_mfma_f32_16x16x32_bf16(a1, qf[nt][1], sc, 0, 0, 0);
        int tokL = 2 * w + nt;
        int sG = s0 + tokL;
        short4v pv;
#pragma unroll
        for (int rg = 0; rg < 4; ++rg) {
          int cG = c0 + mc * 16 + qd * 4 + rg;
          bool ok = (((selw[tokL][cG >> 5] >> (cG & 31)) & 1u) != 0u) && (sG < cG * 4);
          float e = ok ? __expf(sc[rg]) : 0.f;
          dsum[nt] += e;
          pv[rg] = (short)f2bf(e);
        }
        *(short4v*)&p_s[(tokL * 16 + m16) * 72 + mc * 16 + qd * 4] = pv;
      }
    }
#pragma unroll
    for (int ks = 0; ks < 2; ++ks) {
      short8 pa0 = *(const short8*)&p_s[((2 * w + 0) * 16 + m16) * 72 + ks * 32 + qd * 8];
      short8 pa1 = *(const short8*)&p_s[((2 * w + 1) * 16 + m16) * 72 + ks * 32 + qd * 8];
#pragma unroll
      for (int nt = 0; nt < 4; ++nt) {
        short8 bv = *(const short8*)&kct_s[(nt * 16 + m16) * 72 + ks * 32 + qd * 8];
        of[0][nt] = __builtin_amdgcn_mfma_f32_16x16x32_bf16(pa0, bv, of[0][nt], 0, 0, 0);
        of[1][nt] = __builtin_amdgcn_mfma_f32_16x16x32_bf16(pa1, bv, of[1][nt], 0, 0, 0);
      }
    }
  }
#pragma unroll
  for (int nt = 0; nt < 2; ++nt) {
    dsum[nt] += __shfl_xor(dsum[nt], 16, 64);
    dsum[nt] += __shfl_xor(dsum[nt], 32, 64);
  }
  if (lane < 16) {
    float sk = __expf(sink[lane]);
    dls[w][0][lane] = dsum[0] + sk;
    dls[w][1][lane] = dsum[1] + sk;
  }
#pragma unroll
  for (int tk = 0; tk < 2; ++tk)
#pragma unroll
    for (int nt = 0; nt < 4; ++nt) {
      floatx4 o = of[tk][nt];
#pragma unroll
      for (int rg = 0; rg < 4; ++rg) {
        int head = qd * 4 + rg;
        float dn = dls[w][tk][head];
        out[(size_t)(s0 + 2 * w + tk) * 1024 + head * 64 + nt * 16 + m16] = f2bf(o[rg] / dn);
      }
    }
}

// ---------------------------------------------------------------------------
// Workspace layout (float offsets)
// ---------------------------------------------------------------------------
#define OFF_QUQ    0u          // 4194304 f : quq fp32 -> reused as isc
#define OFF_Q      4194304u    // 4194304 f : qb bf16
#define OFF_XH     8388608u    // 4194304 f : xh bf16 -> reused as gb
#define OFF_XL     12582912u   // 4194304 f : xl bf16 -> reused as sel bitmap
#define OFF_PART   16777216u   // 4194304 f : k_proj partials / k_or / GEMM split-K partials / attnb
#define OFF_KO     18874368u   //   (k_or lives in upper half of PART early; attnb later)
#define OFF_C4     20971520u   // 1048576 f
#define OFF_CQF    22020096u   // 2097152 f : qih/qil/kph/kpl overlays
#define OFF_QI     24117248u   // 1048576 f (unused now)
#define OFF_CQH    25165824u   // 1048576 f
#define OFF_CQL    26214400u   // 1048576 f
#define OFF_WPACKT 27262976u   // 262144 f
#define OFF_WDQTH  27525120u   // 524288 f
#define OFF_WDQTL  28049408u   // 524288 f
#define OFF_WIUQTH 28573696u   // 65536 f
#define OFF_WIUQTL 28639232u   // 65536 f
#define OFF_WUQT   28704768u   // 262144 f
#define OFF_ODOWNT 28966912u   // 262144 f
#define OFF_OUPT   29229056u   // 2097152 f
#define OFF_HW     31326208u   // 16384 f
#define OFF_COMP   31342592u   // 65536 f
#define OFF_KC     31408128u   // 65536 f : kcb + kcbT
#define OFF_KPR    31473664u   // 65536 f

extern "C" void kernel_launch(void* const* d_in, const int* in_sizes, int n_in,
                              void* d_out, int out_size, void* d_ws, size_t ws_size,
                              hipStream_t stream) {
  const float* x      = (const float*)d_in[0];
  const float* w_kv_a = (const float*)d_in[1];
  const float* w_kv_b = (const float*)d_in[2];
  const float* w_z_a  = (const float*)d_in[3];
  const float* w_z_b  = (const float*)d_in[4];
  const float* b_a    = (const float*)d_in[5];
  const float* b_b    = (const float*)d_in[6];
  const float* w_dq   = (const float*)d_in[7];
  const float* w_iuq  = (const float*)d_in[8];
  const float* w_w    = (const float*)d_in[9];
  const float* w_k    = (const float*)d_in[10];
  const float* w_uq   = (const float*)d_in[11];
  const float* o_down = (const float*)d_in[12];
  const float* o_up   = (const float*)d_in[13];
  const float* kvn_w  = (const float*)d_in[14];
  const float* kvn_b  = (const float*)d_in[15];
  const float* qn_w   = (const float*)d_in[16];
  const float* qn_b   = (const float*)d_in[17];
  const float* sink   = (const float*)d_in[18];
  float* out = (float*)d_out;
  float* ws = (float*)d_ws;

  float* quq   = ws + OFF_QUQ;
  float* isc   = ws + OFF_QUQ;           // reuse (quq dead after ln_rope)
  unsigned short* qb = (unsigned short*)(ws + OFF_Q);
  unsigned short* xh = (unsigned short*)(ws + OFF_XH);
  unsigned short* gb = (unsigned short*)(ws + OFF_XH);  // reuse (xh dead after c_q)
  unsigned short* xl = (unsigned short*)(ws + OFF_XL);
  unsigned* sel = (unsigned*)(ws + OFF_XL);             // reuse (xl dead after c_q)
  float* part  = ws + OFF_PART;                          // 16.8 MB split-K partials
  float* k_or  = ws + OFF_KO;                            // early only
  unsigned short* attnb = (unsigned short*)(ws + OFF_KO);  // reuse late
  float* c4    = ws + OFF_C4;
  unsigned short* qih = (unsigned short*)(ws + OFF_CQF);
  unsigned short* qil = qih + S_ * NHI_ * CI_;
  unsigned short* kph = qil + S_ * NHI_ * CI_;
  unsigned short* kpl = kph + NC_ * CI_;
  unsigned short* cqh = (unsigned short*)(ws + OFF_CQH);
  unsigned short* cql = (unsigned short*)(ws + OFF_CQL);
  unsigned short* wpackT = (unsigned short*)(ws + OFF_WPACKT);
  unsigned short* wdqTh  = (unsigned short*)(ws + OFF_WDQTH);
  unsigned short* wdqTl  = (unsigned short*)(ws + OFF_WDQTL);
  unsigned short* wiuqTh = (unsigned short*)(ws + OFF_WIUQTH);
  unsigned short* wiuqTl = (unsigned short*)(ws + OFF_WIUQTL);
  unsigned short* wuqT   = (unsigned short*)(ws + OFF_WUQT);
  unsigned short* odownT = (unsigned short*)(ws + OFF_ODOWNT);
  unsigned short* oupT   = (unsigned short*)(ws + OFF_OUPT);
  float* hw    = ws + OFF_HW;
  float* comp  = ws + OFF_COMP;
  unsigned short* kcb  = (unsigned short*)(ws + OFF_KC);
  unsigned short* kcbT = kcb + NC_ * C_;
  float* k_pr  = ws + OFF_KPR;

  dim3 blk(256);

  // --- casts & weight transposes ---
  cast_split<<<8192, blk, 0, stream>>>(x, xh, xl, S_ * D_);
  transpose_cast<<<dim3(64, 2), blk, 0, stream>>>(w_kv_a, wpackT + 0 * 64 * 2048, D_, C_);
  transpose_cast<<<dim3(64, 2), blk, 0, stream>>>(w_kv_b, wpackT + 1 * 64 * 2048, D_, C_);
  transpose_cast<<<dim3(64, 2), blk, 0, stream>>>(w_z_a,  wpackT + 2 * 64 * 2048, D_, C_);
  transpose_cast<<<dim3(64, 2), blk, 0, stream>>>(w_z_b,  wpackT + 3 * 64 * 2048, D_, C_);
  transpose_cast_split<<<dim3(64, 16), blk, 0, stream>>>(w_dq, wdqTh, wdqTl, D_, DC_);
  transpose_cast_split<<<dim3(16, 8), blk, 0, stream>>>(w_iuq, wiuqTh, wiuqTl, DC_, NHI_ * CI_);
  transpose_cast<<<dim3(16, 32), blk, 0, stream>>>(w_uq, wuqT, DC_, NH_ * C_);
  for (int g = 0; g < NG_; ++g)
    transpose_cast<<<dim3(8, 16), blk, 0, stream>>>(o_down + (size_t)g * 256 * DG_,
                                                    odownT + (size_t)g * DG_ * 256, 256, DG_);
  transpose_cast<<<dim3(64, 64), blk, 0, stream>>>(o_up, oupT, NG_ * DG_, D_);

  // --- fp32 indexer-side path: k_orig -> k_proj (split-K), hw ---
  mean4_kernel<<<8192, blk, 0, stream>>>(x, k_or);
  gemm_f32_splitk<<<dim3(KSL_, 16), blk, 0, stream>>>(k_or, w_k, part, D_, CI_);
  reduce_splitk<<<256, blk, 0, stream>>>(part, k_pr);
  hw_kernel<<<1024, blk, 0, stream>>>(x, w_w, hw);

  // --- MFMA GEMMs (all >=256 blocks via split-K / batching) ---
  // c4: K=2048 -> 4 slices of 512 (grid 2x32x4)
  gemm_bf16<<<dim3(2, 32, 4), blk, 0, stream>>>(xh, wpackT, part, nullptr,
                                                512, D_, D_, 256, 512, 512, (long long)S_ * 256);
  reduce_f32<<<1024, blk, 0, stream>>>(part, c4, S_ * 256, 4);
  // c_q: K=2048 -> 2 slices of 1024 (grid 4x32x2); fused reduce+hi/lo split
  gemm_bf16_split<<<dim3(4, 32, 2), blk, 0, stream>>>(xh, xl, wdqTh, wdqTl, part,
                                                      1024, D_, D_, DC_, 1024, 1024, (long long)S_ * DC_);
  reduce_cast_split<<<2048, blk, 0, stream>>>(part, cqh, cql, S_ * DC_, 2);
  // q_i: K=512 -> 4 slices of 128 (grid 2x32x4); fused reduce+hi/lo split
  gemm_bf16_split<<<dim3(2, 32, 4), blk, 0, stream>>>(cqh, cql, wiuqTh, wiuqTl, part,
                                                      128, DC_, DC_, 256, 128, 128, (long long)S_ * 256);
  reduce_cast_split<<<1024, blk, 0, stream>>>(part, qih, qil, S_ * 256, 4);
  // quq: grid 8x32 (256 blocks) already
  gemm_bf16<<<dim3(8, 32, 1), blk, 0, stream>>>(cqh, wuqT, quq, nullptr,
                                                DC_, DC_, DC_, NH_ * C_, 0, 0, 0);

  // --- gating -> compressed -> kc (LN, bf16 row-major + transposed) ---
  gate_kernel<<<256, blk, 0, stream>>>(c4, b_a, b_b, comp);
  ln_kc_kernel<<<256, blk, 0, stream>>>(comp, kvn_w, kvn_b, kcb, kcbT);

  // --- q: LN + RoPE -> bf16 scaled by 1/8 (consumes quq; precedes iscores) ---
  ln_rope_q_kernel<<<16384, blk, 0, stream>>>(quq, qn_w, qn_b, qb);

  // --- indexer scores (split-bf16 MFMA) + exact radix-select bitmap ---
  cast_split<<<64, blk, 0, stream>>>(k_pr, kph, kpl, NC_ * CI_);
  iscores_mfma<<<dim3(8, 128), blk, 0, stream>>>(qih, qil, kph, kpl, hw, isc);
  topk_select_kernel<<<S_, blk, 0, stream>>>(isc, sel);

  // --- dense-masked flash attention (MFMA) ---
  attn_mfma_kernel<<<S_ / TS_, blk, 0, stream>>>(qb, kcb, kcbT, sel, sink, attnb);

  // --- o_down: 4 groups batched via grid.z (512 blocks) -> o_up ---
  gemm_bf16<<<dim3(4, 32, 4), blk, 0, stream>>>(attnb, odownT, nullptr, gb,
                                                256, NH_ * C_, 256, NG_ * DG_,
                                                256, (long long)DG_ * 256, DG_);
  gemm_bf16<<<dim3(16, 32, 1), blk, 0, stream>>>(gb, oupT, out, nullptr,
                                                 NG_ * DG_, NG_ * DG_, NG_ * DG_, D_, 0, 0, 0);
}

// Round 8
// 506.927 us; speedup vs baseline: 4.4435x; 1.0009x over previous
//
#include <hip/hip_runtime.h>
#include <math.h>

// Problem constants (B=1 throughout)
#define S_   4096
#define D_   2048
#define M_   4
#define NC_  1024
#define TOPK_ 512
#define NH_  16
#define C_   64
#define DC_  512
#define NG_  4
#define DG_  512
#define CI_  64
#define NHI_ 4
#define ROPE_ 32
#define EPS_ 1e-6f

typedef __attribute__((ext_vector_type(8))) short short8;
typedef __attribute__((ext_vector_type(4))) short short4v;
typedef __attribute__((ext_vector_type(4))) float floatx4;

__device__ inline unsigned short f2bf(float f) {
  unsigned u = __float_as_uint(f);
  u += 0x7fff + ((u >> 16) & 1);   // round-to-nearest-even
  return (unsigned short)(u >> 16);
}
__device__ inline float bf2f(unsigned short h) {
  return __uint_as_float(((unsigned)h) << 16);
}

// ---------------------------------------------------------------------------
// bf16 MFMA GEMM (m97 structure): C = A @ Bt^T, with grid.z batching/split-K:
// A += z*Az, Bt += z*Bz, C += z*Cz. Split-K = (Az=Bz=Kslice, Cz=slice stride).
// ---------------------------------------------------------------------------
__global__ __launch_bounds__(256) void gemm_bf16(
    const unsigned short* __restrict__ A, const unsigned short* __restrict__ Bt,
    float* __restrict__ Cf, unsigned short* __restrict__ Cb,
    int K, int lda, int ldb, int ldc,
    long long Az, long long Bz, long long Cz) {
  int zz = blockIdx.z;
  A += (size_t)zz * Az;
  Bt += (size_t)zz * Bz;
  if (Cf) Cf += (size_t)zz * Cz;
  if (Cb) Cb += (size_t)zz * Cz;
  __shared__ unsigned short As[128 * 32];
  __shared__ unsigned short Bs[128 * 32];
  int tid = threadIdx.x;
  int bm = blockIdx.y * 128, bn = blockIdx.x * 128;
  int lane = tid & 63, wid = tid >> 6;
  int wm = (wid >> 1) * 64, wn = (wid & 1) * 64;
  int qd = lane >> 4, m16 = lane & 15;

  floatx4 acc[4][4];
#pragma unroll
  for (int i = 0; i < 4; ++i)
#pragma unroll
    for (int j = 0; j < 4; ++j) acc[i][j] = (floatx4){0.f, 0.f, 0.f, 0.f};

  for (int k0 = 0; k0 < K; k0 += 32) {
#pragma unroll
    for (int i = 0; i < 2; ++i) {
      int idx = tid + 256 * i;
      int r = idx >> 2, s = idx & 3;
      int g = s ^ ((r >> 1) & 3);
      __builtin_amdgcn_global_load_lds(
          (const __attribute__((address_space(1))) unsigned int*)(A + (size_t)(bm + r) * lda + k0 + g * 8),
          (__attribute__((address_space(3))) unsigned int*)(&As[idx * 8]), 16, 0, 0);
    }
#pragma unroll
    for (int i = 0; i < 2; ++i) {
      int idx = tid + 256 * i;
      int r = idx >> 2, s = idx & 3;
      int g = s ^ ((r >> 1) & 3);
      __builtin_amdgcn_global_load_lds(
          (const __attribute__((address_space(1))) unsigned int*)(Bt + (size_t)(bn + r) * ldb + k0 + g * 8),
          (__attribute__((address_space(3))) unsigned int*)(&Bs[idx * 8]), 16, 0, 0);
    }
    __syncthreads();
    short8 af[4], bfr[4];
#pragma unroll
    for (int mi = 0; mi < 4; ++mi) {
      int r = wm + mi * 16 + m16;
      int slot = qd ^ ((r >> 1) & 3);
      af[mi] = *(const short8*)&As[r * 32 + slot * 8];
    }
#pragma unroll
    for (int ni = 0; ni < 4; ++ni) {
      int r = wn + ni * 16 + m16;
      int slot = qd ^ ((r >> 1) & 3);
      bfr[ni] = *(const short8*)&Bs[r * 32 + slot * 8];
    }
#pragma unroll
    for (int mi = 0; mi < 4; ++mi)
#pragma unroll
      for (int ni = 0; ni < 4; ++ni)
        acc[mi][ni] = __builtin_amdgcn_mfma_f32_16x16x32_bf16(af[mi], bfr[ni], acc[mi][ni], 0, 0, 0);
    __syncthreads();
  }
#pragma unroll
  for (int mi = 0; mi < 4; ++mi)
#pragma unroll
    for (int ni = 0; ni < 4; ++ni) {
      int col = bn + wn + ni * 16 + m16;
#pragma unroll
      for (int rg = 0; rg < 4; ++rg) {
        int row = bm + wm + mi * 16 + qd * 4 + rg;
        if (Cb)
          Cb[(size_t)row * ldc + col] = f2bf(acc[mi][ni][rg]);
        else
          Cf[(size_t)row * ldc + col] = acc[mi][ni][rg];
      }
    }
}

// ---------------------------------------------------------------------------
// Split-bf16 MFMA GEMM (fp32-accurate, 3 MFMA terms), grid.z split-K strides.
// ---------------------------------------------------------------------------
__global__ __launch_bounds__(256) void gemm_bf16_split(
    const unsigned short* __restrict__ Ah, const unsigned short* __restrict__ Al,
    const unsigned short* __restrict__ Bh, const unsigned short* __restrict__ Bl,
    float* __restrict__ Cf, int K, int lda, int ldb, int ldc,
    long long Az, long long Bz, long long Cz) {
  int zz = blockIdx.z;
  Ah += (size_t)zz * Az; Al += (size_t)zz * Az;
  Bh += (size_t)zz * Bz; Bl += (size_t)zz * Bz;
  Cf += (size_t)zz * Cz;
  __shared__ unsigned short Ash[128 * 32];
  __shared__ unsigned short Asl[128 * 32];
  __shared__ unsigned short Bsh[128 * 32];
  __shared__ unsigned short Bsl[128 * 32];
  int tid = threadIdx.x;
  int bm = blockIdx.y * 128, bn = blockIdx.x * 128;
  int lane = tid & 63, wid = tid >> 6;
  int wm = (wid >> 1) * 64, wn = (wid & 1) * 64;
  int qd = lane >> 4, m16 = lane & 15;

  floatx4 acc[4][4];
#pragma unroll
  for (int i = 0; i < 4; ++i)
#pragma unroll
    for (int j = 0; j < 4; ++j) acc[i][j] = (floatx4){0.f, 0.f, 0.f, 0.f};

  for (int k0 = 0; k0 < K; k0 += 32) {
#pragma unroll
    for (int i = 0; i < 2; ++i) {
      int idx = tid + 256 * i;
      int r = idx >> 2, s = idx & 3;
      int g = s ^ ((r >> 1) & 3);
      size_t aoff = (size_t)(bm + r) * lda + k0 + g * 8;
      size_t boff = (size_t)(bn + r) * ldb + k0 + g * 8;
      __builtin_amdgcn_global_load_lds(
          (const __attribute__((address_space(1))) unsigned int*)(Ah + aoff),
          (__attribute__((address_space(3))) unsigned int*)(&Ash[idx * 8]), 16, 0, 0);
      __builtin_amdgcn_global_load_lds(
          (const __attribute__((address_space(1))) unsigned int*)(Al + aoff),
          (__attribute__((address_space(3))) unsigned int*)(&Asl[idx * 8]), 16, 0, 0);
      __builtin_amdgcn_global_load_lds(
          (const __attribute__((address_space(1))) unsigned int*)(Bh + boff),
          (__attribute__((address_space(3))) unsigned int*)(&Bsh[idx * 8]), 16, 0, 0);
      __builtin_amdgcn_global_load_lds(
          (const __attribute__((address_space(1))) unsigned int*)(Bl + boff),
          (__attribute__((address_space(3))) unsigned int*)(&Bsl[idx * 8]), 16, 0, 0);
    }
    __syncthreads();
    short8 afh[4], afl[4], bfh[4], bfl[4];
#pragma unroll
    for (int mi = 0; mi < 4; ++mi) {
      int r = wm + mi * 16 + m16;
      int slot = qd ^ ((r >> 1) & 3);
      afh[mi] = *(const short8*)&Ash[r * 32 + slot * 8];
      afl[mi] = *(const short8*)&Asl[r * 32 + slot * 8];
    }
#pragma unroll
    for (int ni = 0; ni < 4; ++ni) {
      int r = wn + ni * 16 + m16;
      int slot = qd ^ ((r >> 1) & 3);
      bfh[ni] = *(const short8*)&Bsh[r * 32 + slot * 8];
      bfl[ni] = *(const short8*)&Bsl[r * 32 + slot * 8];
    }
#pragma unroll
    for (int mi = 0; mi < 4; ++mi)
#pragma unroll
      for (int ni = 0; ni < 4; ++ni) {
        acc[mi][ni] = __builtin_amdgcn_mfma_f32_16x16x32_bf16(afh[mi], bfh[ni], acc[mi][ni], 0, 0, 0);
        acc[mi][ni] = __builtin_amdgcn_mfma_f32_16x16x32_bf16(afh[mi], bfl[ni], acc[mi][ni], 0, 0, 0);
        acc[mi][ni] = __builtin_amdgcn_mfma_f32_16x16x32_bf16(afl[mi], bfh[ni], acc[mi][ni], 0, 0, 0);
      }
    __syncthreads();
  }
#pragma unroll
  for (int mi = 0; mi < 4; ++mi)
#pragma unroll
    for (int ni = 0; ni < 4; ++ni) {
      int col = bn + wn + ni * 16 + m16;
#pragma unroll
      for (int rg = 0; rg < 4; ++rg) {
        int row = bm + wm + mi * 16 + qd * 4 + rg;
        Cf[(size_t)row * ldc + col] = acc[mi][ni][rg];
      }
    }
}

// reduce z fp32 slices (contiguous stride n) -> fp32
__global__ void reduce_f32(const float* __restrict__ P, float* __restrict__ C, int n, int z) {
  int i = (blockIdx.x * 256 + threadIdx.x) * 4;
  if (i >= n) return;
  float4 a = *(const float4*)&P[i];
  for (int s = 1; s < z; ++s) {
    float4 b = *(const float4*)&P[(size_t)s * n + i];
    a.x += b.x; a.y += b.y; a.z += b.z; a.w += b.w;
  }
  *(float4*)&C[i] = a;
}

// reduce two fp32 slices at arbitrary offset -> fp32 (o_up epilogue)
__global__ void reduce_f32_pair(const float* __restrict__ P, float* __restrict__ C,
                                int n, long long off) {
  int i = (blockIdx.x * 256 + threadIdx.x) * 4;
  if (i >= n) return;
  float4 a = *(const float4*)&P[i];
  float4 b = *(const float4*)&P[off + i];
  a.x += b.x; a.y += b.y; a.z += b.z; a.w += b.w;
  *(float4*)&C[i] = a;
}

// reduce z fp32 slices -> (bf16 hi, bf16 lo)
__global__ void reduce_cast_split(const float* __restrict__ P, unsigned short* __restrict__ hi,
                                  unsigned short* __restrict__ lo, int n, int z) {
  int i = (blockIdx.x * 256 + threadIdx.x) * 4;
  if (i >= n) return;
  float4 a = *(const float4*)&P[i];
  for (int s = 1; s < z; ++s) {
    float4 b = *(const float4*)&P[(size_t)s * n + i];
    a.x += b.x; a.y += b.y; a.z += b.z; a.w += b.w;
  }
  ushort4 h = make_ushort4(f2bf(a.x), f2bf(a.y), f2bf(a.z), f2bf(a.w));
  ushort4 l = make_ushort4(f2bf(a.x - bf2f(h.x)), f2bf(a.y - bf2f(h.y)),
                           f2bf(a.z - bf2f(h.z)), f2bf(a.w - bf2f(h.w)));
  *(ushort4*)&hi[i] = h;
  *(ushort4*)&lo[i] = l;
}

// ---------------------------------------------------------------------------
// Indexer scores on split-bf16 MFMA (relu*hw epilogue in-register).
// ---------------------------------------------------------------------------
__global__ __launch_bounds__(256) void iscores_mfma(
    const unsigned short* __restrict__ Ah, const unsigned short* __restrict__ Al,
    const unsigned short* __restrict__ Bh, const unsigned short* __restrict__ Bl,
    const float* __restrict__ hw, float* __restrict__ isc) {
  __shared__ unsigned short Ash[128 * 32];
  __shared__ unsigned short Asl[128 * 32];
  __shared__ unsigned short Bsh[128 * 32];
  __shared__ unsigned short Bsl[128 * 32];
  int tid = threadIdx.x;
  int bm = blockIdx.y * 128, bn = blockIdx.x * 128;
  int lane = tid & 63, wid = tid >> 6;
  int wm = (wid >> 1) * 64, wn = (wid & 1) * 64;
  int qd = lane >> 4, m16 = lane & 15;

  floatx4 acc[4][4];
#pragma unroll
  for (int i = 0; i < 4; ++i)
#pragma unroll
    for (int j = 0; j < 4; ++j) acc[i][j] = (floatx4){0.f, 0.f, 0.f, 0.f};

#pragma unroll
  for (int k0 = 0; k0 < 64; k0 += 32) {
#pragma unroll
    for (int i = 0; i < 2; ++i) {
      int idx = tid + 256 * i;
      int r = idx >> 2, s = idx & 3;
      int g = s ^ ((r >> 1) & 3);
      size_t aoff = (size_t)(bm + r) * 64 + k0 + g * 8;
      size_t boff = (size_t)(bn + r) * 64 + k0 + g * 8;
      __builtin_amdgcn_global_load_lds(
          (const __attribute__((address_space(1))) unsigned int*)(Ah + aoff),
          (__attribute__((address_space(3))) unsigned int*)(&Ash[idx * 8]), 16, 0, 0);
      __builtin_amdgcn_global_load_lds(
          (const __attribute__((address_space(1))) unsigned int*)(Al + aoff),
          (__attribute__((address_space(3))) unsigned int*)(&Asl[idx * 8]), 16, 0, 0);
      __builtin_amdgcn_global_load_lds(
          (const __attribute__((address_space(1))) unsigned int*)(Bh + boff),
          (__attribute__((address_space(3))) unsigned int*)(&Bsh[idx * 8]), 16, 0, 0);
      __builtin_amdgcn_global_load_lds(
          (const __attribute__((address_space(1))) unsigned int*)(Bl + boff),
          (__attribute__((address_space(3))) unsigned int*)(&Bsl[idx * 8]), 16, 0, 0);
    }
    __syncthreads();
    short8 afh[4], afl[4], bfh[4], bfl[4];
#pragma unroll
    for (int mi = 0; mi < 4; ++mi) {
      int r = wm + mi * 16 + m16;
      int slot = qd ^ ((r >> 1) & 3);
      afh[mi] = *(const short8*)&Ash[r * 32 + slot * 8];
      afl[mi] = *(const short8*)&Asl[r * 32 + slot * 8];
    }
#pragma unroll
    for (int ni = 0; ni < 4; ++ni) {
      int r = wn + ni * 16 + m16;
      int slot = qd ^ ((r >> 1) & 3);
      bfh[ni] = *(const short8*)&Bsh[r * 32 + slot * 8];
      bfl[ni] = *(const short8*)&Bsl[r * 32 + slot * 8];
    }
#pragma unroll
    for (int mi = 0; mi < 4; ++mi)
#pragma unroll
      for (int ni = 0; ni < 4; ++ni) {
        acc[mi][ni] = __builtin_amdgcn_mfma_f32_16x16x32_bf16(afh[mi], bfh[ni], acc[mi][ni], 0, 0, 0);
        acc[mi][ni] = __builtin_amdgcn_mfma_f32_16x16x32_bf16(afh[mi], bfl[ni], acc[mi][ni], 0, 0, 0);
        acc[mi][ni] = __builtin_amdgcn_mfma_f32_16x16x32_bf16(afl[mi], bfh[ni], acc[mi][ni], 0, 0, 0);
      }
    __syncthreads();
  }
#pragma unroll
  for (int mi = 0; mi < 4; ++mi) {
    int tok = ((bm + wm + mi * 16) >> 2) + qd;
    float4 hwv = *(const float4*)&hw[tok * 4];
#pragma unroll
    for (int ni = 0; ni < 4; ++ni) {
      floatx4 a = acc[mi][ni];
      float v = fmaxf(a[0], 0.f) * hwv.x + fmaxf(a[1], 0.f) * hwv.y +
                fmaxf(a[2], 0.f) * hwv.z + fmaxf(a[3], 0.f) * hwv.w;
      int col = bn + wn + ni * 16 + m16;
      isc[(size_t)tok * NC_ + col] = (col < tok) ? v : -__builtin_inff();
    }
  }
}

// ---------------------------------------------------------------------------
// Split-K fp32 GEMM for k_proj (N=64) + reduce
// ---------------------------------------------------------------------------
#define BM 64
#define BN 64
#define BK 16
#define KSL_ 16
#define KSLICE_ 128
__global__ __launch_bounds__(256) void gemm_f32_splitk(
    const float* __restrict__ A, const float* __restrict__ B,
    float* __restrict__ P, int lda, int ldb) {
  __shared__ float As[BK][BM + 4];
  __shared__ float Bs[BK][BN + 4];
  int tid = threadIdx.x;
  int bm = blockIdx.y * BM;
  int kbase = blockIdx.x * KSLICE_;
  int tr = tid >> 4;
  int tc = tid & 15;
  float acc[4][4] = {{0.f}};
  for (int k0 = kbase; k0 < kbase + KSLICE_; k0 += BK) {
    int ac = tid & 15;
    int ar0 = tid >> 4;
#pragma unroll
    for (int i = 0; i < 4; ++i) {
      int r = ar0 + 16 * i;
      As[ac][r] = A[(size_t)(bm + r) * lda + k0 + ac];
    }
    int bc = tid & 63;
    int br0 = tid >> 6;
#pragma unroll
    for (int i = 0; i < 4; ++i) {
      int r = br0 + 4 * i;
      Bs[r][bc] = B[(size_t)(k0 + r) * ldb + bc];
    }
    __syncthreads();
#pragma unroll
    for (int kk = 0; kk < BK; ++kk) {
      float4 av = *(const float4*)&As[kk][tr * 4];
      float4 bv = *(const float4*)&Bs[kk][tc * 4];
      float a[4] = {av.x, av.y, av.z, av.w};
      float b[4] = {bv.x, bv.y, bv.z, bv.w};
#pragma unroll
      for (int i = 0; i < 4; ++i)
#pragma unroll
        for (int j = 0; j < 4; ++j) acc[i][j] += a[i] * b[j];
    }
    __syncthreads();
  }
  float* Pb = P + (size_t)blockIdx.x * (NC_ * CI_);
#pragma unroll
  for (int i = 0; i < 4; ++i) {
    float4 v = make_float4(acc[i][0], acc[i][1], acc[i][2], acc[i][3]);
    *(float4*)&Pb[(size_t)(bm + tr * 4 + i) * CI_ + tc * 4] = v;
  }
}

__global__ void reduce_splitk(const float* __restrict__ P, float* __restrict__ C) {
  int i = blockIdx.x * 256 + threadIdx.x;
  if (i >= NC_ * CI_) return;
  float a = 0.f;
#pragma unroll
  for (int s = 0; s < KSL_; ++s) a += P[(size_t)s * (NC_ * CI_) + i];
  C[i] = a;
}

// fp32 -> (bf16 hi, bf16 lo) element-wise split (n multiple of 4)
__global__ void cast_split(const float* __restrict__ in, unsigned short* __restrict__ hi,
                           unsigned short* __restrict__ lo, int n) {
  int i = (blockIdx.x * 256 + threadIdx.x) * 4;
  if (i >= n) return;
  float4 v = *(const float4*)&in[i];
  ushort4 h = make_ushort4(f2bf(v.x), f2bf(v.y), f2bf(v.z), f2bf(v.w));
  ushort4 l = make_ushort4(f2bf(v.x - bf2f(h.x)), f2bf(v.y - bf2f(h.y)),
                           f2bf(v.z - bf2f(h.z)), f2bf(v.w - bf2f(h.w)));
  *(ushort4*)&hi[i] = h;
  *(ushort4*)&lo[i] = l;
}

// fp32 (K x N) -> bf16 transpose (N x K). K,N multiples of 32. grid.z batching.
__global__ __launch_bounds__(256) void transpose_cast(
    const float* __restrict__ in, unsigned short* __restrict__ out, int K, int N,
    long long inz, long long outz) {
  in += (size_t)blockIdx.z * inz;
  out += (size_t)blockIdx.z * outz;
  __shared__ float t[32][33];
  int k0 = blockIdx.x * 32, n0 = blockIdx.y * 32;
  int tx = threadIdx.x & 31, ty = threadIdx.x >> 5;
#pragma unroll
  for (int i = 0; i < 4; ++i)
    t[ty * 4 + i][tx] = in[(size_t)(k0 + ty * 4 + i) * N + n0 + tx];
  __syncthreads();
#pragma unroll
  for (int i = 0; i < 4; ++i)
    out[(size_t)(n0 + ty * 4 + i) * K + k0 + tx] = f2bf(t[tx][ty * 4 + i]);
}

// fp32 (K x N) -> bf16 transpose split (N x K, hi+lo)
__global__ __launch_bounds__(256) void transpose_cast_split(
    const float* __restrict__ in, unsigned short* __restrict__ outh,
    unsigned short* __restrict__ outl, int K, int N) {
  __shared__ float t[32][33];
  int k0 = blockIdx.x * 32, n0 = blockIdx.y * 32;
  int tx = threadIdx.x & 31, ty = threadIdx.x >> 5;
#pragma unroll
  for (int i = 0; i < 4; ++i)
    t[ty * 4 + i][tx] = in[(size_t)(k0 + ty * 4 + i) * N + n0 + tx];
  __syncthreads();
#pragma unroll
  for (int i = 0; i < 4; ++i) {
    float v = t[tx][ty * 4 + i];
    unsigned short h = f2bf(v);
    outh[(size_t)(n0 + ty * 4 + i) * K + k0 + tx] = h;
    outl[(size_t)(n0 + ty * 4 + i) * K + k0 + tx] = f2bf(v - bf2f(h));
  }
}

// k_orig[j,d] = mean over 4 tokens
__global__ void mean4_kernel(const float* __restrict__ x, float* __restrict__ ko) {
  int i = blockIdx.x * 256 + threadIdx.x;
  if (i >= NC_ * D_) return;
  int j = i >> 11, d = i & (D_ - 1);
  const float* p = x + (size_t)j * 4 * D_ + d;
  ko[i] = 0.25f * (p[0] + p[D_] + p[2 * D_] + p[3 * D_]);
}

__device__ inline float wave_sum64(float v) {
#pragma unroll
  for (int off = 32; off > 0; off >>= 1) v += __shfl_xor(v, off, 64);
  return v;
}

// hw = x @ w_w (S x 4): one wave per token, coalesced x reads
__global__ void hw_kernel(const float* __restrict__ x, const float* __restrict__ ww,
                          float* __restrict__ hw) {
  int w = threadIdx.x >> 6, lane = threadIdx.x & 63;
  int s = blockIdx.x * 4 + w;
  const float* xr = x + (size_t)s * D_;
  float a0 = 0.f, a1 = 0.f, a2 = 0.f, a3 = 0.f;
  for (int k = lane; k < D_; k += 64) {
    float xv = xr[k];
    float4 wv = *(const float4*)&ww[k * 4];
    a0 += xv * wv.x; a1 += xv * wv.y; a2 += xv * wv.z; a3 += xv * wv.w;
  }
  a0 = wave_sum64(a0); a1 = wave_sum64(a1);
  a2 = wave_sum64(a2); a3 = wave_sum64(a3);
  if (lane == 0) {
    float4 o = make_float4(a0, a1, a2, a3);
    *(float4*)&hw[s * 4] = o;
  }
}

// gating softmax; reads packed c4 (S x 256: [c_a|c_b|z_a|z_b])
__global__ void gate_kernel(const float* __restrict__ c4,
                            const float* __restrict__ ba, const float* __restrict__ bb,
                            float* __restrict__ comp) {
  int i = blockIdx.x * 256 + threadIdx.x;
  if (i >= NC_ * C_) return;
  int j = i >> 6, c = i & 63;
  float lg[8], vv[8];
#pragma unroll
  for (int m = 0; m < 4; ++m) {
    if (j == 0) {
      lg[m] = -1e30f + bb[m * C_ + c];
      vv[m] = 0.f;
    } else {
      int row = (j - 1) * 4 + m;
      lg[m] = c4[(size_t)row * 256 + 192 + c] + bb[m * C_ + c];
      vv[m] = c4[(size_t)row * 256 + 64 + c];
    }
    int row2 = j * 4 + m;
    lg[4 + m] = c4[(size_t)row2 * 256 + 128 + c] + ba[m * C_ + c];
    vv[4 + m] = c4[(size_t)row2 * 256 + 0 + c];
  }
  float mx = lg[0];
#pragma unroll
  for (int t = 1; t < 8; ++t) mx = fmaxf(mx, lg[t]);
  float se = 0.f, acc = 0.f;
#pragma unroll
  for (int t = 0; t < 8; ++t) {
    float e = expf(lg[t] - mx);
    se += e;
    acc += e * vv[t];
  }
  comp[i] = acc / se;
}

// LayerNorm over C=64 -> bf16 row-major + bf16 transposed (for attention MFMA)
__global__ void ln_kc_kernel(const float* __restrict__ in, const float* __restrict__ w,
                             const float* __restrict__ b, unsigned short* __restrict__ kcb,
                             unsigned short* __restrict__ kcbT) {
  int row = blockIdx.x * 4 + (threadIdx.x >> 6);
  int c = threadIdx.x & 63;
  float v = in[(size_t)row * C_ + c];
  float mu = wave_sum64(v) * (1.f / 64.f);
  float d = v - mu;
  float var = wave_sum64(d * d) * (1.f / 64.f);
  float y = d * (1.f / sqrtf(var + EPS_)) * w[c] + b[c];
  unsigned short h = f2bf(y);
  kcb[(size_t)row * C_ + c] = h;
  kcbT[(size_t)c * NC_ + row] = h;
}

// LN + RoPE for q -> bf16, pre-scaled by 1/sqrt(C)=0.125 (only attention uses q)
__global__ void ln_rope_q_kernel(const float* __restrict__ quq, const float* __restrict__ w,
                                 const float* __restrict__ b, unsigned short* __restrict__ qb) {
  int row = blockIdx.x * 4 + (threadIdx.x >> 6);  // s*16 + h
  int s = row >> 4;
  int c = threadIdx.x & 63;
  float v = quq[(size_t)row * C_ + c];
  float mu = wave_sum64(v) * (1.f / 64.f);
  float d = v - mu;
  float var = wave_sum64(d * d) * (1.f / 64.f);
  float y = d * (1.f / sqrtf(var + EPS_)) * w[c] + b[c];
  float outv;
  float partner = __shfl_xor(y, 1, 64);
  if (c < C_ - ROPE_) {
    outv = y;
  } else {
    int p = (c - (C_ - ROPE_)) >> 1;
    float inv = powf(10000.f, -(2.f * (float)p) / (float)ROPE_);
    float ang = (float)s * inv;
    float cs = cosf(ang), sn = sinf(ang);
    if ((c & 1) == 0)
      outv = y * cs - partner * sn;
    else
      outv = partner * sn + y * cs;
  }
  qb[(size_t)row * C_ + c] = f2bf(outv * 0.125f);
}

// ---------------------------------------------------------------------------
// Top-512-of-1024 exact radix-select -> selection bitmap.
// ---------------------------------------------------------------------------
__global__ __launch_bounds__(256) void topk_select_kernel(
    const float* __restrict__ isc, unsigned* __restrict__ sel) {
  __shared__ unsigned mv[NC_];
  __shared__ unsigned bins[256];
  __shared__ unsigned scan[256];
  __shared__ unsigned sB, sR;
  __shared__ unsigned selw[32];
  int s = blockIdx.x;
  int tid = threadIdx.x;
  for (int i = tid; i < NC_; i += 256) {
    unsigned u = __float_as_uint(isc[(size_t)s * NC_ + i]);
    mv[i] = (u & 0x80000000u) ? ~u : (u | 0x80000000u);
  }
  __syncthreads();
  unsigned K_rem = TOPK_;
  unsigned prefix = 0u;
  for (int lvl = 0; lvl < 4; ++lvl) {
    int shift = 24 - 8 * lvl;
    unsigned pm = (lvl == 0) ? 0u : (0xFFFFFFFFu << (32 - 8 * lvl));
    bins[tid] = 0u;
    __syncthreads();
    for (int i = tid; i < NC_; i += 256) {
      unsigned m = mv[i];
      if ((m & pm) == prefix) atomicAdd(&bins[(m >> shift) & 0xFFu], 1u);
    }
    __syncthreads();
    unsigned v = bins[tid];
    scan[tid] = v;
    __syncthreads();
    for (int off = 1; off < 256; off <<= 1) {
      unsigned add = (tid + off < 256) ? scan[tid + off] : 0u;
      __syncthreads();
      scan[tid] += add;
      __syncthreads();
    }
    unsigned gt = scan[tid] - v;
    if (gt < K_rem && K_rem <= gt + v) { sB = (unsigned)tid; sR = K_rem - gt; }
    __syncthreads();
    prefix |= (sB << shift);
    K_rem = sR;
    __syncthreads();
  }
  unsigned vstar = prefix;
  unsigned eq = 0;
#pragma unroll
  for (int j = 0; j < 4; ++j) eq += (mv[4 * tid + j] == vstar);
  scan[tid] = eq;
  __syncthreads();
  for (int off = 1; off < 256; off <<= 1) {
    unsigned add = (tid >= off) ? scan[tid - off] : 0u;
    __syncthreads();
    scan[tid] += add;
    __syncthreads();
  }
  unsigned rank0 = scan[tid] - eq;
  if (tid < 32) selw[tid] = 0u;
  __syncthreads();
  unsigned local = 0, bits = 0;
#pragma unroll
  for (int j = 0; j < 4; ++j) {
    unsigned m = mv[4 * tid + j];
    bool sb = (m > vstar) || (m == vstar && (rank0 + local) < K_rem);
    local += (m == vstar);
    if (sb) bits |= (1u << ((4 * tid + j) & 31));
  }
  if (bits) atomicOr(&selw[tid >> 3], bits);
  __syncthreads();
  if (tid < 32) sel[(size_t)s * 32 + tid] = selw[tid];
}

// ---------------------------------------------------------------------------
// Dense-masked flash attention on MFMA.
// ---------------------------------------------------------------------------
#define TS_ 8
__global__ __launch_bounds__(256) void attn_mfma_kernel(
    const unsigned short* __restrict__ qb, const unsigned short* __restrict__ kcb,
    const unsigned short* __restrict__ kcbT, const unsigned* __restrict__ sel,
    const float* __restrict__ sink, unsigned short* __restrict__ out) {
  __shared__ unsigned short kc_s[64 * 72];
  __shared__ unsigned short kct_s[64 * 72];
  __shared__ unsigned short p_s[128 * 72];
  __shared__ unsigned selw[TS_][32];
  __shared__ float dls[4][2][16];
  int tid = threadIdx.x;
  int s0 = blockIdx.x * TS_;
  int lane = tid & 63, w = tid >> 6;
  int qd = lane >> 4, m16 = lane & 15;

  for (int i = tid; i < TS_ * 32; i += 256)
    selw[i >> 5][i & 31] = sel[(size_t)(s0 + (i >> 5)) * 32 + (i & 31)];

  short8 qf[2][2];
#pragma unroll
  for (int tk = 0; tk < 2; ++tk)
#pragma unroll
    for (int ks = 0; ks < 2; ++ks)
      qf[tk][ks] = *(const short8*)&qb[(size_t)(s0 + 2 * w + tk) * 1024 + m16 * 64 + ks * 32 + qd * 8];

  floatx4 of[2][4];
#pragma unroll
  for (int i = 0; i < 2; ++i)
#pragma unroll
    for (int j = 0; j < 4; ++j) of[i][j] = (floatx4){0.f, 0.f, 0.f, 0.f};
  float dsum[2] = {0.f, 0.f};

  for (int ct = 0; ct < 16; ++ct) {
    int c0 = ct * 64;
    __syncthreads();
    {
      int r = tid >> 2, cc = (tid & 3) * 16;
      *(short8*)&kc_s[r * 72 + cc]      = *(const short8*)&kcb[(size_t)(c0 + r) * 64 + cc];
      *(short8*)&kc_s[r * 72 + cc + 8]  = *(const short8*)&kcb[(size_t)(c0 + r) * 64 + cc + 8];
      *(short8*)&kct_s[r * 72 + cc]     = *(const short8*)&kcbT[(size_t)r * NC_ + c0 + cc];
      *(short8*)&kct_s[r * 72 + cc + 8] = *(const short8*)&kcbT[(size_t)r * NC_ + c0 + cc + 8];
    }
    __syncthreads();
#pragma unroll
    for (int mc = 0; mc < 4; ++mc) {
      short8 a0 = *(const short8*)&kc_s[(mc * 16 + m16) * 72 + qd * 8];
      short8 a1 = *(const short8*)&kc_s[(mc * 16 + m16) * 72 + 32 + qd * 8];
#pragma unroll
      for (int nt = 0; nt < 2; ++nt) {
        floatx4 sc = (floatx4){0.f, 0.f, 0.f, 0.f};
        sc = __builtin_amdgcn_mfma_f32_16x16x32_bf16(a0, qf[nt][0], sc, 0, 0, 0);
        sc = __builtin_amdgcn_mfma_f32_16x16x32_bf16(a1, qf[nt][1], sc, 0, 0, 0);
        int tokL = 2 * w + nt;
        int sG = s0 + tokL;
        short4v pv;
#pragma unroll
        for (int rg = 0; rg < 4; ++rg) {
          int cG = c0 + mc * 16 + qd * 4 + rg;
          bool ok = (((selw[tokL][cG >> 5] >> (cG & 31)) & 1u) != 0u) && (sG < cG * 4);
          float e = ok ? __expf(sc[rg]) : 0.f;
          dsum[nt] += e;
          pv[rg] = (short)f2bf(e);
        }
        *(short4v*)&p_s[(tokL * 16 + m16) * 72 + mc * 16 + qd * 4] = pv;
      }
    }
#pragma unroll
    for (int ks = 0; ks < 2; ++ks) {
      short8 pa0 = *(const short8*)&p_s[((2 * w + 0) * 16 + m16) * 72 + ks * 32 + qd * 8];
      short8 pa1 = *(const short8*)&p_s[((2 * w + 1) * 16 + m16) * 72 + ks * 32 + qd * 8];
#pragma unroll
      for (int nt = 0; nt < 4; ++nt) {
        short8 bv = *(const short8*)&kct_s[(nt * 16 + m16) * 72 + ks * 32 + qd * 8];
        of[0][nt] = __builtin_amdgcn_mfma_f32_16x16x32_bf16(pa0, bv, of[0][nt], 0, 0, 0);
        of[1][nt] = __builtin_amdgcn_mfma_f32_16x16x32_bf16(pa1, bv, of[1][nt], 0, 0, 0);
      }
    }
  }
#pragma unroll
  for (int nt = 0; nt < 2; ++nt) {
    dsum[nt] += __shfl_xor(dsum[nt], 16, 64);
    dsum[nt] += __shfl_xor(dsum[nt], 32, 64);
  }
  if (lane < 16) {
    float sk = __expf(sink[lane]);
    dls[w][0][lane] = dsum[0] + sk;
    dls[w][1][lane] = dsum[1] + sk;
  }
#pragma unroll
  for (int tk = 0; tk < 2; ++tk)
#pragma unroll
    for (int nt = 0; nt < 4; ++nt) {
      floatx4 o = of[tk][nt];
#pragma unroll
      for (int rg = 0; rg < 4; ++rg) {
        int head = qd * 4 + rg;
        float dn = dls[w][tk][head];
        out[(size_t)(s0 + 2 * w + tk) * 1024 + head * 64 + nt * 16 + m16] = f2bf(o[rg] / dn);
      }
    }
}

// ---------------------------------------------------------------------------
// Workspace layout (float offsets). Key liveness windows:
//  [0, 8388608): c_q partials (early) -> quq (mid) -> isc (mid) -> qb region
//                ends at 8388608 -> o_up partial slice 0 (late, both dead)
//  [12582912, 20971520): xl (early) -> sel (mid) -> o_up partial slice 1 (late)
// ---------------------------------------------------------------------------
#define OFF_QUQ    0u          // quq fp32 / isc / c_q partials / o_up slice0
#define OFF_Q      4194304u    // qb bf16 / o_up slice0 upper half
#define OFF_XH     8388608u    // xh bf16 -> gb
#define OFF_XL     12582912u   // xl bf16 -> sel -> o_up slice1
#define OFF_PART   16777216u   // k_proj/c4/q_i partials; o_up slice1 upper
#define OFF_KO     18874368u   // k_or fp32 (early) -> attnb bf16 (mid)
#define OFF_C4     20971520u   // 1048576 f
#define OFF_CQF    22020096u   // qih/qil/kph/kpl overlays
#define OFF_QI     24117248u   // (spare)
#define OFF_CQH    25165824u   // 1048576 f
#define OFF_CQL    26214400u   // 1048576 f
#define OFF_WPACKT 27262976u   // 262144 f
#define OFF_WDQTH  27525120u   // 524288 f
#define OFF_WDQTL  28049408u   // 524288 f
#define OFF_WIUQTH 28573696u   // 65536 f
#define OFF_WIUQTL 28639232u   // 65536 f
#define OFF_WUQT   28704768u   // 262144 f
#define OFF_ODOWNT 28966912u   // 262144 f
#define OFF_OUPT   29229056u   // 2097152 f
#define OFF_HW     31326208u   // 16384 f
#define OFF_COMP   31342592u   // 65536 f
#define OFF_KC     31408128u   // 65536 f : kcb + kcbT
#define OFF_KPR    31473664u   // 65536 f

extern "C" void kernel_launch(void* const* d_in, const int* in_sizes, int n_in,
                              void* d_out, int out_size, void* d_ws, size_t ws_size,
                              hipStream_t stream) {
  const float* x      = (const float*)d_in[0];
  const float* w_kv_a = (const float*)d_in[1];
  const float* w_kv_b = (const float*)d_in[2];
  const float* w_z_a  = (const float*)d_in[3];
  const float* w_z_b  = (const float*)d_in[4];
  const float* b_a    = (const float*)d_in[5];
  const float* b_b    = (const float*)d_in[6];
  const float* w_dq   = (const float*)d_in[7];
  const float* w_iuq  = (const float*)d_in[8];
  const float* w_w    = (const float*)d_in[9];
  const float* w_k    = (const float*)d_in[10];
  const float* w_uq   = (const float*)d_in[11];
  const float* o_down = (const float*)d_in[12];
  const float* o_up   = (const float*)d_in[13];
  const float* kvn_w  = (const float*)d_in[14];
  const float* kvn_b  = (const float*)d_in[15];
  const float* qn_w   = (const float*)d_in[16];
  const float* qn_b   = (const float*)d_in[17];
  const float* sink   = (const float*)d_in[18];
  float* out = (float*)d_out;
  float* ws = (float*)d_ws;

  float* quq   = ws + OFF_QUQ;
  float* isc   = ws + OFF_QUQ;
  unsigned short* qb = (unsigned short*)(ws + OFF_Q);
  unsigned short* xh = (unsigned short*)(ws + OFF_XH);
  unsigned short* gb = (unsigned short*)(ws + OFF_XH);
  unsigned short* xl = (unsigned short*)(ws + OFF_XL);
  unsigned* sel = (unsigned*)(ws + OFF_XL);
  float* part  = ws + OFF_PART;
  float* k_or  = ws + OFF_KO;
  unsigned short* attnb = (unsigned short*)(ws + OFF_KO);
  float* c4    = ws + OFF_C4;
  unsigned short* qih = (unsigned short*)(ws + OFF_CQF);
  unsigned short* qil = qih + S_ * NHI_ * CI_;
  unsigned short* kph = qil + S_ * NHI_ * CI_;
  unsigned short* kpl = kph + NC_ * CI_;
  unsigned short* cqh = (unsigned short*)(ws + OFF_CQH);
  unsigned short* cql = (unsigned short*)(ws + OFF_CQL);
  unsigned short* wpackT = (unsigned short*)(ws + OFF_WPACKT);
  unsigned short* wdqTh  = (unsigned short*)(ws + OFF_WDQTH);
  unsigned short* wdqTl  = (unsigned short*)(ws + OFF_WDQTL);
  unsigned short* wiuqTh = (unsigned short*)(ws + OFF_WIUQTH);
  unsigned short* wiuqTl = (unsigned short*)(ws + OFF_WIUQTL);
  unsigned short* wuqT   = (unsigned short*)(ws + OFF_WUQT);
  unsigned short* odownT = (unsigned short*)(ws + OFF_ODOWNT);
  unsigned short* oupT   = (unsigned short*)(ws + OFF_OUPT);
  float* hw    = ws + OFF_HW;
  float* comp  = ws + OFF_COMP;
  unsigned short* kcb  = (unsigned short*)(ws + OFF_KC);
  unsigned short* kcbT = kcb + NC_ * C_;
  float* k_pr  = ws + OFF_KPR;

  dim3 blk(256);

  // --- casts & weight transposes ---
  cast_split<<<8192, blk, 0, stream>>>(x, xh, xl, S_ * D_);
  transpose_cast<<<dim3(64, 2), blk, 0, stream>>>(w_kv_a, wpackT + 0 * 64 * 2048, D_, C_, 0, 0);
  transpose_cast<<<dim3(64, 2), blk, 0, stream>>>(w_kv_b, wpackT + 1 * 64 * 2048, D_, C_, 0, 0);
  transpose_cast<<<dim3(64, 2), blk, 0, stream>>>(w_z_a,  wpackT + 2 * 64 * 2048, D_, C_, 0, 0);
  transpose_cast<<<dim3(64, 2), blk, 0, stream>>>(w_z_b,  wpackT + 3 * 64 * 2048, D_, C_, 0, 0);
  transpose_cast_split<<<dim3(64, 16), blk, 0, stream>>>(w_dq, wdqTh, wdqTl, D_, DC_);
  transpose_cast_split<<<dim3(16, 8), blk, 0, stream>>>(w_iuq, wiuqTh, wiuqTl, DC_, NHI_ * CI_);
  transpose_cast<<<dim3(16, 32), blk, 0, stream>>>(w_uq, wuqT, DC_, NH_ * C_, 0, 0);
  transpose_cast<<<dim3(8, 16, 4), blk, 0, stream>>>(o_down, odownT, 256, DG_,
                                                     (long long)256 * DG_, (long long)DG_ * 256);
  transpose_cast<<<dim3(64, 64), blk, 0, stream>>>(o_up, oupT, NG_ * DG_, D_, 0, 0);

  // --- fp32 indexer-side path: k_orig -> k_proj (split-K), hw ---
  mean4_kernel<<<8192, blk, 0, stream>>>(x, k_or);
  gemm_f32_splitk<<<dim3(KSL_, 16), blk, 0, stream>>>(k_or, w_k, part, D_, CI_);
  reduce_splitk<<<256, blk, 0, stream>>>(part, k_pr);
  hw_kernel<<<1024, blk, 0, stream>>>(x, w_w, hw);

  // --- MFMA GEMMs (all >=256 blocks via split-K / batching) ---
  // c_q: K=2048 -> 4 slices of 512 (512 blocks); partials in [0, 8388608)
  gemm_bf16_split<<<dim3(4, 32, 4), blk, 0, stream>>>(xh, xl, wdqTh, wdqTl, ws,
                                                      512, D_, D_, DC_, 512, 512, (long long)S_ * DC_);
  reduce_cast_split<<<2048, blk, 0, stream>>>(ws, cqh, cql, S_ * DC_, 4);
  // c4: K=2048 -> 4 slices of 512 (grid 2x32x4); partials in PART
  gemm_bf16<<<dim3(2, 32, 4), blk, 0, stream>>>(xh, wpackT, part, nullptr,
                                                512, D_, D_, 256, 512, 512, (long long)S_ * 256);
  reduce_f32<<<1024, blk, 0, stream>>>(part, c4, S_ * 256, 4);
  // q_i: K=512 -> 4 slices of 128; partials in PART
  gemm_bf16_split<<<dim3(2, 32, 4), blk, 0, stream>>>(cqh, cql, wiuqTh, wiuqTl, part,
                                                      128, DC_, DC_, 256, 128, 128, (long long)S_ * 256);
  reduce_cast_split<<<1024, blk, 0, stream>>>(part, qih, qil, S_ * 256, 4);
  // quq: 256 blocks (writes quq over dead c_q partials)
  gemm_bf16<<<dim3(8, 32, 1), blk, 0, stream>>>(cqh, wuqT, quq, nullptr,
                                                DC_, DC_, DC_, NH_ * C_, 0, 0, 0);

  // --- gating -> compressed -> kc (LN, bf16 row-major + transposed) ---
  gate_kernel<<<256, blk, 0, stream>>>(c4, b_a, b_b, comp);
  ln_kc_kernel<<<256, blk, 0, stream>>>(comp, kvn_w, kvn_b, kcb, kcbT);

  // --- q: LN + RoPE -> bf16 scaled by 1/8 ---
  ln_rope_q_kernel<<<16384, blk, 0, stream>>>(quq, qn_w, qn_b, qb);

  // --- indexer scores (split-bf16 MFMA) + exact radix-select bitmap ---
  cast_split<<<64, blk, 0, stream>>>(k_pr, kph, kpl, NC_ * CI_);
  iscores_mfma<<<dim3(8, 128), blk, 0, stream>>>(qih, qil, kph, kpl, hw, isc);
  topk_select_kernel<<<S_, blk, 0, stream>>>(isc, sel);

  // --- dense-masked flash attention (MFMA) ---
  attn_mfma_kernel<<<S_ / TS_, blk, 0, stream>>>(qb, kcb, kcbT, sel, sink, attnb);

  // --- o_down: 4 groups batched via grid.z (512 blocks) ---
  gemm_bf16<<<dim3(4, 32, 4), blk, 0, stream>>>(attnb, odownT, nullptr, gb,
                                                256, NH_ * C_, 256, NG_ * DG_,
                                                256, (long long)DG_ * 256, DG_);
  // --- o_up: split-K z=2 (1024 blocks); slice0 at ws[0..8.4M), slice1 at
  // ws[12582912..21M) — isc/qb/sel/attnb all dead here. Then pair-reduce.
  gemm_bf16<<<dim3(16, 32, 2), blk, 0, stream>>>(gb, oupT, ws, nullptr,
                                                 1024, NG_ * DG_, NG_ * DG_, D_,
                                                 1024, 1024, 12582912LL);
  reduce_f32_pair<<<8192, blk, 0, stream>>>(ws, out, S_ * D_, 12582912LL);
}

// Round 9
// 474.632 us; speedup vs baseline: 4.7459x; 1.0680x over previous
//
#include <hip/hip_runtime.h>
#include <math.h>

// Problem constants (B=1 throughout)
#define S_   4096
#define D_   2048
#define M_   4
#define NC_  1024
#define TOPK_ 512
#define NH_  16
#define C_   64
#define DC_  512
#define NG_  4
#define DG_  512
#define CI_  64
#define NHI_ 4
#define ROPE_ 32
#define EPS_ 1e-6f

typedef __attribute__((ext_vector_type(8))) short short8;
typedef __attribute__((ext_vector_type(4))) short short4v;
typedef __attribute__((ext_vector_type(4))) float floatx4;

__device__ inline unsigned short f2bf(float f) {
  unsigned u = __float_as_uint(f);
  u += 0x7fff + ((u >> 16) & 1);   // round-to-nearest-even
  return (unsigned short)(u >> 16);
}
__device__ inline float bf2f(unsigned short h) {
  return __uint_as_float(((unsigned)h) << 16);
}

// ---------------------------------------------------------------------------
// bf16 MFMA GEMM (m97 structure): C = A @ Bt^T, with grid.z batching/split-K.
// ---------------------------------------------------------------------------
__global__ __launch_bounds__(256) void gemm_bf16(
    const unsigned short* __restrict__ A, const unsigned short* __restrict__ Bt,
    float* __restrict__ Cf, unsigned short* __restrict__ Cb,
    int K, int lda, int ldb, int ldc,
    long long Az, long long Bz, long long Cz) {
  int zz = blockIdx.z;
  A += (size_t)zz * Az;
  Bt += (size_t)zz * Bz;
  if (Cf) Cf += (size_t)zz * Cz;
  if (Cb) Cb += (size_t)zz * Cz;
  __shared__ unsigned short As[128 * 32];
  __shared__ unsigned short Bs[128 * 32];
  int tid = threadIdx.x;
  int bm = blockIdx.y * 128, bn = blockIdx.x * 128;
  int lane = tid & 63, wid = tid >> 6;
  int wm = (wid >> 1) * 64, wn = (wid & 1) * 64;
  int qd = lane >> 4, m16 = lane & 15;

  floatx4 acc[4][4];
#pragma unroll
  for (int i = 0; i < 4; ++i)
#pragma unroll
    for (int j = 0; j < 4; ++j) acc[i][j] = (floatx4){0.f, 0.f, 0.f, 0.f};

  for (int k0 = 0; k0 < K; k0 += 32) {
#pragma unroll
    for (int i = 0; i < 2; ++i) {
      int idx = tid + 256 * i;
      int r = idx >> 2, s = idx & 3;
      int g = s ^ ((r >> 1) & 3);
      __builtin_amdgcn_global_load_lds(
          (const __attribute__((address_space(1))) unsigned int*)(A + (size_t)(bm + r) * lda + k0 + g * 8),
          (__attribute__((address_space(3))) unsigned int*)(&As[idx * 8]), 16, 0, 0);
    }
#pragma unroll
    for (int i = 0; i < 2; ++i) {
      int idx = tid + 256 * i;
      int r = idx >> 2, s = idx & 3;
      int g = s ^ ((r >> 1) & 3);
      __builtin_amdgcn_global_load_lds(
          (const __attribute__((address_space(1))) unsigned int*)(Bt + (size_t)(bn + r) * ldb + k0 + g * 8),
          (__attribute__((address_space(3))) unsigned int*)(&Bs[idx * 8]), 16, 0, 0);
    }
    __syncthreads();
    short8 af[4], bfr[4];
#pragma unroll
    for (int mi = 0; mi < 4; ++mi) {
      int r = wm + mi * 16 + m16;
      int slot = qd ^ ((r >> 1) & 3);
      af[mi] = *(const short8*)&As[r * 32 + slot * 8];
    }
#pragma unroll
    for (int ni = 0; ni < 4; ++ni) {
      int r = wn + ni * 16 + m16;
      int slot = qd ^ ((r >> 1) & 3);
      bfr[ni] = *(const short8*)&Bs[r * 32 + slot * 8];
    }
#pragma unroll
    for (int mi = 0; mi < 4; ++mi)
#pragma unroll
      for (int ni = 0; ni < 4; ++ni)
        acc[mi][ni] = __builtin_amdgcn_mfma_f32_16x16x32_bf16(af[mi], bfr[ni], acc[mi][ni], 0, 0, 0);
    __syncthreads();
  }
#pragma unroll
  for (int mi = 0; mi < 4; ++mi)
#pragma unroll
    for (int ni = 0; ni < 4; ++ni) {
      int col = bn + wn + ni * 16 + m16;
#pragma unroll
      for (int rg = 0; rg < 4; ++rg) {
        int row = bm + wm + mi * 16 + qd * 4 + rg;
        if (Cb)
          Cb[(size_t)row * ldc + col] = f2bf(acc[mi][ni][rg]);
        else
          Cf[(size_t)row * ldc + col] = acc[mi][ni][rg];
      }
    }
}

// ---------------------------------------------------------------------------
// Split-bf16 MFMA GEMM (fp32-accurate, 3 MFMA terms), grid.z split-K strides.
// ---------------------------------------------------------------------------
__global__ __launch_bounds__(256) void gemm_bf16_split(
    const unsigned short* __restrict__ Ah, const unsigned short* __restrict__ Al,
    const unsigned short* __restrict__ Bh, const unsigned short* __restrict__ Bl,
    float* __restrict__ Cf, int K, int lda, int ldb, int ldc,
    long long Az, long long Bz, long long Cz) {
  int zz = blockIdx.z;
  Ah += (size_t)zz * Az; Al += (size_t)zz * Az;
  Bh += (size_t)zz * Bz; Bl += (size_t)zz * Bz;
  Cf += (size_t)zz * Cz;
  __shared__ unsigned short Ash[128 * 32];
  __shared__ unsigned short Asl[128 * 32];
  __shared__ unsigned short Bsh[128 * 32];
  __shared__ unsigned short Bsl[128 * 32];
  int tid = threadIdx.x;
  int bm = blockIdx.y * 128, bn = blockIdx.x * 128;
  int lane = tid & 63, wid = tid >> 6;
  int wm = (wid >> 1) * 64, wn = (wid & 1) * 64;
  int qd = lane >> 4, m16 = lane & 15;

  floatx4 acc[4][4];
#pragma unroll
  for (int i = 0; i < 4; ++i)
#pragma unroll
    for (int j = 0; j < 4; ++j) acc[i][j] = (floatx4){0.f, 0.f, 0.f, 0.f};

  for (int k0 = 0; k0 < K; k0 += 32) {
#pragma unroll
    for (int i = 0; i < 2; ++i) {
      int idx = tid + 256 * i;
      int r = idx >> 2, s = idx & 3;
      int g = s ^ ((r >> 1) & 3);
      size_t aoff = (size_t)(bm + r) * lda + k0 + g * 8;
      size_t boff = (size_t)(bn + r) * ldb + k0 + g * 8;
      __builtin_amdgcn_global_load_lds(
          (const __attribute__((address_space(1))) unsigned int*)(Ah + aoff),
          (__attribute__((address_space(3))) unsigned int*)(&Ash[idx * 8]), 16, 0, 0);
      __builtin_amdgcn_global_load_lds(
          (const __attribute__((address_space(1))) unsigned int*)(Al + aoff),
          (__attribute__((address_space(3))) unsigned int*)(&Asl[idx * 8]), 16, 0, 0);
      __builtin_amdgcn_global_load_lds(
          (const __attribute__((address_space(1))) unsigned int*)(Bh + boff),
          (__attribute__((address_space(3))) unsigned int*)(&Bsh[idx * 8]), 16, 0, 0);
      __builtin_amdgcn_global_load_lds(
          (const __attribute__((address_space(1))) unsigned int*)(Bl + boff),
          (__attribute__((address_space(3))) unsigned int*)(&Bsl[idx * 8]), 16, 0, 0);
    }
    __syncthreads();
    short8 afh[4], afl[4], bfh[4], bfl[4];
#pragma unroll
    for (int mi = 0; mi < 4; ++mi) {
      int r = wm + mi * 16 + m16;
      int slot = qd ^ ((r >> 1) & 3);
      afh[mi] = *(const short8*)&Ash[r * 32 + slot * 8];
      afl[mi] = *(const short8*)&Asl[r * 32 + slot * 8];
    }
#pragma unroll
    for (int ni = 0; ni < 4; ++ni) {
      int r = wn + ni * 16 + m16;
      int slot = qd ^ ((r >> 1) & 3);
      bfh[ni] = *(const short8*)&Bsh[r * 32 + slot * 8];
      bfl[ni] = *(const short8*)&Bsl[r * 32 + slot * 8];
    }
#pragma unroll
    for (int mi = 0; mi < 4; ++mi)
#pragma unroll
      for (int ni = 0; ni < 4; ++ni) {
        acc[mi][ni] = __builtin_amdgcn_mfma_f32_16x16x32_bf16(afh[mi], bfh[ni], acc[mi][ni], 0, 0, 0);
        acc[mi][ni] = __builtin_amdgcn_mfma_f32_16x16x32_bf16(afh[mi], bfl[ni], acc[mi][ni], 0, 0, 0);
        acc[mi][ni] = __builtin_amdgcn_mfma_f32_16x16x32_bf16(afl[mi], bfh[ni], acc[mi][ni], 0, 0, 0);
      }
    __syncthreads();
  }
#pragma unroll
  for (int mi = 0; mi < 4; ++mi)
#pragma unroll
    for (int ni = 0; ni < 4; ++ni) {
      int col = bn + wn + ni * 16 + m16;
#pragma unroll
      for (int rg = 0; rg < 4; ++rg) {
        int row = bm + wm + mi * 16 + qd * 4 + rg;
        Cf[(size_t)row * ldc + col] = acc[mi][ni][rg];
      }
    }
}

// reduce z fp32 slices (contiguous stride n) -> fp32
__global__ void reduce_f32(const float* __restrict__ P, float* __restrict__ C, int n, int z) {
  int i = (blockIdx.x * 256 + threadIdx.x) * 4;
  if (i >= n) return;
  float4 a = *(const float4*)&P[i];
  for (int s = 1; s < z; ++s) {
    float4 b = *(const float4*)&P[(size_t)s * n + i];
    a.x += b.x; a.y += b.y; a.z += b.z; a.w += b.w;
  }
  *(float4*)&C[i] = a;
}

// reduce z fp32 slices -> (bf16 hi, bf16 lo)
__global__ void reduce_cast_split(const float* __restrict__ P, unsigned short* __restrict__ hi,
                                  unsigned short* __restrict__ lo, int n, int z) {
  int i = (blockIdx.x * 256 + threadIdx.x) * 4;
  if (i >= n) return;
  float4 a = *(const float4*)&P[i];
  for (int s = 1; s < z; ++s) {
    float4 b = *(const float4*)&P[(size_t)s * n + i];
    a.x += b.x; a.y += b.y; a.z += b.z; a.w += b.w;
  }
  ushort4 h = make_ushort4(f2bf(a.x), f2bf(a.y), f2bf(a.z), f2bf(a.w));
  ushort4 l = make_ushort4(f2bf(a.x - bf2f(h.x)), f2bf(a.y - bf2f(h.y)),
                           f2bf(a.z - bf2f(h.z)), f2bf(a.w - bf2f(h.w)));
  *(ushort4*)&hi[i] = h;
  *(ushort4*)&lo[i] = l;
}

// ---------------------------------------------------------------------------
// Indexer scores on split-bf16 MFMA (relu*hw epilogue in-register).
// Tiles with all cols > all toks are fully masked: skip GEMM AND write —
// topk_select synthesizes -inf for i >= s without reading.
// ---------------------------------------------------------------------------
__global__ __launch_bounds__(256) void iscores_mfma(
    const unsigned short* __restrict__ Ah, const unsigned short* __restrict__ Al,
    const unsigned short* __restrict__ Bh, const unsigned short* __restrict__ Bl,
    const float* __restrict__ hw, float* __restrict__ isc) {
  int bm = blockIdx.y * 128, bn = blockIdx.x * 128;
  // toks in tile: [bm/4, bm/4+31]; finite needs col < tok; skip if bn > bm/4+30
  if (bn > (bm >> 2) + 30) return;
  __shared__ unsigned short Ash[128 * 32];
  __shared__ unsigned short Asl[128 * 32];
  __shared__ unsigned short Bsh[128 * 32];
  __shared__ unsigned short Bsl[128 * 32];
  int tid = threadIdx.x;
  int lane = tid & 63, wid = tid >> 6;
  int wm = (wid >> 1) * 64, wn = (wid & 1) * 64;
  int qd = lane >> 4, m16 = lane & 15;

  floatx4 acc[4][4];
#pragma unroll
  for (int i = 0; i < 4; ++i)
#pragma unroll
    for (int j = 0; j < 4; ++j) acc[i][j] = (floatx4){0.f, 0.f, 0.f, 0.f};

#pragma unroll
  for (int k0 = 0; k0 < 64; k0 += 32) {
#pragma unroll
    for (int i = 0; i < 2; ++i) {
      int idx = tid + 256 * i;
      int r = idx >> 2, s = idx & 3;
      int g = s ^ ((r >> 1) & 3);
      size_t aoff = (size_t)(bm + r) * 64 + k0 + g * 8;
      size_t boff = (size_t)(bn + r) * 64 + k0 + g * 8;
      __builtin_amdgcn_global_load_lds(
          (const __attribute__((address_space(1))) unsigned int*)(Ah + aoff),
          (__attribute__((address_space(3))) unsigned int*)(&Ash[idx * 8]), 16, 0, 0);
      __builtin_amdgcn_global_load_lds(
          (const __attribute__((address_space(1))) unsigned int*)(Al + aoff),
          (__attribute__((address_space(3))) unsigned int*)(&Asl[idx * 8]), 16, 0, 0);
      __builtin_amdgcn_global_load_lds(
          (const __attribute__((address_space(1))) unsigned int*)(Bh + boff),
          (__attribute__((address_space(3))) unsigned int*)(&Bsh[idx * 8]), 16, 0, 0);
      __builtin_amdgcn_global_load_lds(
          (const __attribute__((address_space(1))) unsigned int*)(Bl + boff),
          (__attribute__((address_space(3))) unsigned int*)(&Bsl[idx * 8]), 16, 0, 0);
    }
    __syncthreads();
    short8 afh[4], afl[4], bfh[4], bfl[4];
#pragma unroll
    for (int mi = 0; mi < 4; ++mi) {
      int r = wm + mi * 16 + m16;
      int slot = qd ^ ((r >> 1) & 3);
      afh[mi] = *(const short8*)&Ash[r * 32 + slot * 8];
      afl[mi] = *(const short8*)&Asl[r * 32 + slot * 8];
    }
#pragma unroll
    for (int ni = 0; ni < 4; ++ni) {
      int r = wn + ni * 16 + m16;
      int slot = qd ^ ((r >> 1) & 3);
      bfh[ni] = *(const short8*)&Bsh[r * 32 + slot * 8];
      bfl[ni] = *(const short8*)&Bsl[r * 32 + slot * 8];
    }
#pragma unroll
    for (int mi = 0; mi < 4; ++mi)
#pragma unroll
      for (int ni = 0; ni < 4; ++ni) {
        acc[mi][ni] = __builtin_amdgcn_mfma_f32_16x16x32_bf16(afh[mi], bfh[ni], acc[mi][ni], 0, 0, 0);
        acc[mi][ni] = __builtin_amdgcn_mfma_f32_16x16x32_bf16(afh[mi], bfl[ni], acc[mi][ni], 0, 0, 0);
        acc[mi][ni] = __builtin_amdgcn_mfma_f32_16x16x32_bf16(afl[mi], bfh[ni], acc[mi][ni], 0, 0, 0);
      }
    __syncthreads();
  }
#pragma unroll
  for (int mi = 0; mi < 4; ++mi) {
    int tok = ((bm + wm + mi * 16) >> 2) + qd;
    float4 hwv = *(const float4*)&hw[tok * 4];
#pragma unroll
    for (int ni = 0; ni < 4; ++ni) {
      floatx4 a = acc[mi][ni];
      float v = fmaxf(a[0], 0.f) * hwv.x + fmaxf(a[1], 0.f) * hwv.y +
                fmaxf(a[2], 0.f) * hwv.z + fmaxf(a[3], 0.f) * hwv.w;
      int col = bn + wn + ni * 16 + m16;
      isc[(size_t)tok * NC_ + col] = (col < tok) ? v : -__builtin_inff();
    }
  }
}

// ---------------------------------------------------------------------------
// Split-K fp32 GEMM for k_proj (N=64) + reduce
// ---------------------------------------------------------------------------
#define BM 64
#define BN 64
#define BK 16
#define KSL_ 16
#define KSLICE_ 128
__global__ __launch_bounds__(256) void gemm_f32_splitk(
    const float* __restrict__ A, const float* __restrict__ B,
    float* __restrict__ P, int lda, int ldb) {
  __shared__ float As[BK][BM + 4];
  __shared__ float Bs[BK][BN + 4];
  int tid = threadIdx.x;
  int bm = blockIdx.y * BM;
  int kbase = blockIdx.x * KSLICE_;
  int tr = tid >> 4;
  int tc = tid & 15;
  float acc[4][4] = {{0.f}};
  for (int k0 = kbase; k0 < kbase + KSLICE_; k0 += BK) {
    int ac = tid & 15;
    int ar0 = tid >> 4;
#pragma unroll
    for (int i = 0; i < 4; ++i) {
      int r = ar0 + 16 * i;
      As[ac][r] = A[(size_t)(bm + r) * lda + k0 + ac];
    }
    int bc = tid & 63;
    int br0 = tid >> 6;
#pragma unroll
    for (int i = 0; i < 4; ++i) {
      int r = br0 + 4 * i;
      Bs[r][bc] = B[(size_t)(k0 + r) * ldb + bc];
    }
    __syncthreads();
#pragma unroll
    for (int kk = 0; kk < BK; ++kk) {
      float4 av = *(const float4*)&As[kk][tr * 4];
      float4 bv = *(const float4*)&Bs[kk][tc * 4];
      float a[4] = {av.x, av.y, av.z, av.w};
      float b[4] = {bv.x, bv.y, bv.z, bv.w};
#pragma unroll
      for (int i = 0; i < 4; ++i)
#pragma unroll
        for (int j = 0; j < 4; ++j) acc[i][j] += a[i] * b[j];
    }
    __syncthreads();
  }
  float* Pb = P + (size_t)blockIdx.x * (NC_ * CI_);
#pragma unroll
  for (int i = 0; i < 4; ++i) {
    float4 v = make_float4(acc[i][0], acc[i][1], acc[i][2], acc[i][3]);
    *(float4*)&Pb[(size_t)(bm + tr * 4 + i) * CI_ + tc * 4] = v;
  }
}

__global__ void reduce_splitk(const float* __restrict__ P, float* __restrict__ C) {
  int i = blockIdx.x * 256 + threadIdx.x;
  if (i >= NC_ * CI_) return;
  float a = 0.f;
#pragma unroll
  for (int s = 0; s < KSL_; ++s) a += P[(size_t)s * (NC_ * CI_) + i];
  C[i] = a;
}

// fp32 -> (bf16 hi, bf16 lo) element-wise split (n multiple of 4)
__global__ void cast_split(const float* __restrict__ in, unsigned short* __restrict__ hi,
                           unsigned short* __restrict__ lo, int n) {
  int i = (blockIdx.x * 256 + threadIdx.x) * 4;
  if (i >= n) return;
  float4 v = *(const float4*)&in[i];
  ushort4 h = make_ushort4(f2bf(v.x), f2bf(v.y), f2bf(v.z), f2bf(v.w));
  ushort4 l = make_ushort4(f2bf(v.x - bf2f(h.x)), f2bf(v.y - bf2f(h.y)),
                           f2bf(v.z - bf2f(h.z)), f2bf(v.w - bf2f(h.w)));
  *(ushort4*)&hi[i] = h;
  *(ushort4*)&lo[i] = l;
}

// fp32 (K x N) -> bf16 transpose (N x K). K,N multiples of 32. grid.z batching.
__global__ __launch_bounds__(256) void transpose_cast(
    const float* __restrict__ in, unsigned short* __restrict__ out, int K, int N,
    long long inz, long long outz) {
  in += (size_t)blockIdx.z * inz;
  out += (size_t)blockIdx.z * outz;
  __shared__ float t[32][33];
  int k0 = blockIdx.x * 32, n0 = blockIdx.y * 32;
  int tx = threadIdx.x & 31, ty = threadIdx.x >> 5;
#pragma unroll
  for (int i = 0; i < 4; ++i)
    t[ty * 4 + i][tx] = in[(size_t)(k0 + ty * 4 + i) * N + n0 + tx];
  __syncthreads();
#pragma unroll
  for (int i = 0; i < 4; ++i)
    out[(size_t)(n0 + ty * 4 + i) * K + k0 + tx] = f2bf(t[tx][ty * 4 + i]);
}

// fp32 (K x N) -> bf16 transpose split (N x K, hi+lo)
__global__ __launch_bounds__(256) void transpose_cast_split(
    const float* __restrict__ in, unsigned short* __restrict__ outh,
    unsigned short* __restrict__ outl, int K, int N) {
  __shared__ float t[32][33];
  int k0 = blockIdx.x * 32, n0 = blockIdx.y * 32;
  int tx = threadIdx.x & 31, ty = threadIdx.x >> 5;
#pragma unroll
  for (int i = 0; i < 4; ++i)
    t[ty * 4 + i][tx] = in[(size_t)(k0 + ty * 4 + i) * N + n0 + tx];
  __syncthreads();
#pragma unroll
  for (int i = 0; i < 4; ++i) {
    float v = t[tx][ty * 4 + i];
    unsigned short h = f2bf(v);
    outh[(size_t)(n0 + ty * 4 + i) * K + k0 + tx] = h;
    outl[(size_t)(n0 + ty * 4 + i) * K + k0 + tx] = f2bf(v - bf2f(h));
  }
}

// k_orig[j,d] = mean over 4 tokens
__global__ void mean4_kernel(const float* __restrict__ x, float* __restrict__ ko) {
  int i = blockIdx.x * 256 + threadIdx.x;
  if (i >= NC_ * D_) return;
  int j = i >> 11, d = i & (D_ - 1);
  const float* p = x + (size_t)j * 4 * D_ + d;
  ko[i] = 0.25f * (p[0] + p[D_] + p[2 * D_] + p[3 * D_]);
}

__device__ inline float wave_sum64(float v) {
#pragma unroll
  for (int off = 32; off > 0; off >>= 1) v += __shfl_xor(v, off, 64);
  return v;
}

// hw = x @ w_w (S x 4): one wave per token, coalesced x reads
__global__ void hw_kernel(const float* __restrict__ x, const float* __restrict__ ww,
                          float* __restrict__ hw) {
  int w = threadIdx.x >> 6, lane = threadIdx.x & 63;
  int s = blockIdx.x * 4 + w;
  const float* xr = x + (size_t)s * D_;
  float a0 = 0.f, a1 = 0.f, a2 = 0.f, a3 = 0.f;
  for (int k = lane; k < D_; k += 64) {
    float xv = xr[k];
    float4 wv = *(const float4*)&ww[k * 4];
    a0 += xv * wv.x; a1 += xv * wv.y; a2 += xv * wv.z; a3 += xv * wv.w;
  }
  a0 = wave_sum64(a0); a1 = wave_sum64(a1);
  a2 = wave_sum64(a2); a3 = wave_sum64(a3);
  if (lane == 0) {
    float4 o = make_float4(a0, a1, a2, a3);
    *(float4*)&hw[s * 4] = o;
  }
}

// gating softmax; reads packed c4 (S x 256: [c_a|c_b|z_a|z_b])
__global__ void gate_kernel(const float* __restrict__ c4,
                            const float* __restrict__ ba, const float* __restrict__ bb,
                            float* __restrict__ comp) {
  int i = blockIdx.x * 256 + threadIdx.x;
  if (i >= NC_ * C_) return;
  int j = i >> 6, c = i & 63;
  float lg[8], vv[8];
#pragma unroll
  for (int m = 0; m < 4; ++m) {
    if (j == 0) {
      lg[m] = -1e30f + bb[m * C_ + c];
      vv[m] = 0.f;
    } else {
      int row = (j - 1) * 4 + m;
      lg[m] = c4[(size_t)row * 256 + 192 + c] + bb[m * C_ + c];
      vv[m] = c4[(size_t)row * 256 + 64 + c];
    }
    int row2 = j * 4 + m;
    lg[4 + m] = c4[(size_t)row2 * 256 + 128 + c] + ba[m * C_ + c];
    vv[4 + m] = c4[(size_t)row2 * 256 + 0 + c];
  }
  float mx = lg[0];
#pragma unroll
  for (int t = 1; t < 8; ++t) mx = fmaxf(mx, lg[t]);
  float se = 0.f, acc = 0.f;
#pragma unroll
  for (int t = 0; t < 8; ++t) {
    float e = expf(lg[t] - mx);
    se += e;
    acc += e * vv[t];
  }
  comp[i] = acc / se;
}

// LayerNorm over C=64 -> bf16 row-major + bf16 transposed (for attention MFMA)
__global__ void ln_kc_kernel(const float* __restrict__ in, const float* __restrict__ w,
                             const float* __restrict__ b, unsigned short* __restrict__ kcb,
                             unsigned short* __restrict__ kcbT) {
  int row = blockIdx.x * 4 + (threadIdx.x >> 6);
  int c = threadIdx.x & 63;
  float v = in[(size_t)row * C_ + c];
  float mu = wave_sum64(v) * (1.f / 64.f);
  float d = v - mu;
  float var = wave_sum64(d * d) * (1.f / 64.f);
  float y = d * (1.f / sqrtf(var + EPS_)) * w[c] + b[c];
  unsigned short h = f2bf(y);
  kcb[(size_t)row * C_ + c] = h;
  kcbT[(size_t)c * NC_ + row] = h;
}

// LN + RoPE for q -> bf16, pre-scaled by 1/sqrt(C)=0.125 (only attention uses q)
__global__ void ln_rope_q_kernel(const float* __restrict__ quq, const float* __restrict__ w,
                                 const float* __restrict__ b, unsigned short* __restrict__ qb) {
  int row = blockIdx.x * 4 + (threadIdx.x >> 6);  // s*16 + h
  int s = row >> 4;
  int c = threadIdx.x & 63;
  float v = quq[(size_t)row * C_ + c];
  float mu = wave_sum64(v) * (1.f / 64.f);
  float d = v - mu;
  float var = wave_sum64(d * d) * (1.f / 64.f);
  float y = d * (1.f / sqrtf(var + EPS_)) * w[c] + b[c];
  float outv;
  float partner = __shfl_xor(y, 1, 64);
  if (c < C_ - ROPE_) {
    outv = y;
  } else {
    int p = (c - (C_ - ROPE_)) >> 1;
    float inv = powf(10000.f, -(2.f * (float)p) / (float)ROPE_);
    float ang = (float)s * inv;
    float cs = cosf(ang), sn = sinf(ang);
    if ((c & 1) == 0)
      outv = y * cs - partner * sn;
    else
      outv = partner * sn + y * cs;
  }
  qb[(size_t)row * C_ + c] = f2bf(outv * 0.125f);
}

// ---------------------------------------------------------------------------
// Top-512-of-1024 exact radix-select -> selection bitmap.
// Masked entries (i >= s) are synthesized as monotone(-inf)=0x007FFFFF
// (never loaded) — matches iscores' skipped tiles.
// ---------------------------------------------------------------------------
#define MINF_ 0x007FFFFFu
__global__ __launch_bounds__(256) void topk_select_kernel(
    const float* __restrict__ isc, unsigned* __restrict__ sel) {
  __shared__ unsigned mv[NC_];
  __shared__ unsigned bins[256];
  __shared__ unsigned scan[256];
  __shared__ unsigned sB, sR;
  __shared__ unsigned selw[32];
  int s = blockIdx.x;
  int tid = threadIdx.x;
  for (int i = tid; i < NC_; i += 256) {
    if (i < s) {
      unsigned u = __float_as_uint(isc[(size_t)s * NC_ + i]);
      mv[i] = (u & 0x80000000u) ? ~u : (u | 0x80000000u);
    } else {
      mv[i] = MINF_;
    }
  }
  __syncthreads();
  unsigned K_rem = TOPK_;
  unsigned prefix = 0u;
  for (int lvl = 0; lvl < 4; ++lvl) {
    int shift = 24 - 8 * lvl;
    unsigned pm = (lvl == 0) ? 0u : (0xFFFFFFFFu << (32 - 8 * lvl));
    bins[tid] = 0u;
    __syncthreads();
    for (int i = tid; i < NC_; i += 256) {
      unsigned m = mv[i];
      if ((m & pm) == prefix) atomicAdd(&bins[(m >> shift) & 0xFFu], 1u);
    }
    __syncthreads();
    unsigned v = bins[tid];
    scan[tid] = v;
    __syncthreads();
    for (int off = 1; off < 256; off <<= 1) {
      unsigned add = (tid + off < 256) ? scan[tid + off] : 0u;
      __syncthreads();
      scan[tid] += add;
      __syncthreads();
    }
    unsigned gt = scan[tid] - v;
    if (gt < K_rem && K_rem <= gt + v) { sB = (unsigned)tid; sR = K_rem - gt; }
    __syncthreads();
    prefix |= (sB << shift);
    K_rem = sR;
    __syncthreads();
  }
  unsigned vstar = prefix;
  unsigned eq = 0;
#pragma unroll
  for (int j = 0; j < 4; ++j) eq += (mv[4 * tid + j] == vstar);
  scan[tid] = eq;
  __syncthreads();
  for (int off = 1; off < 256; off <<= 1) {
    unsigned add = (tid >= off) ? scan[tid - off] : 0u;
    __syncthreads();
    scan[tid] += add;
    __syncthreads();
  }
  unsigned rank0 = scan[tid] - eq;
  if (tid < 32) selw[tid] = 0u;
  __syncthreads();
  unsigned local = 0, bits = 0;
#pragma unroll
  for (int j = 0; j < 4; ++j) {
    unsigned m = mv[4 * tid + j];
    bool sb = (m > vstar) || (m == vstar && (rank0 + local) < K_rem);
    local += (m == vstar);
    if (sb) bits |= (1u << ((4 * tid + j) & 31));
  }
  if (bits) atomicOr(&selw[tid >> 3], bits);
  __syncthreads();
  if (tid < 32) sel[(size_t)s * 32 + tid] = selw[tid];
}

// ---------------------------------------------------------------------------
// Dense-masked flash attention on MFMA, with exact causal/selection tile
// skipping: attended idx for token s lies in (s/4, max(511, s-1)] — tiles
// outside [(s0+4)>>8, max(511,s0+6)/64+1) contribute exactly zero.
// ---------------------------------------------------------------------------
#define TS_ 8
__global__ __launch_bounds__(256) void attn_mfma_kernel(
    const unsigned short* __restrict__ qb, const unsigned short* __restrict__ kcb,
    const unsigned short* __restrict__ kcbT, const unsigned* __restrict__ sel,
    const float* __restrict__ sink, unsigned short* __restrict__ out) {
  __shared__ unsigned short kc_s[64 * 72];
  __shared__ unsigned short kct_s[64 * 72];
  __shared__ unsigned short p_s[128 * 72];
  __shared__ unsigned selw[TS_][32];
  __shared__ float dls[4][2][16];
  int tid = threadIdx.x;
  int s0 = blockIdx.x * TS_;
  int lane = tid & 63, w = tid >> 6;
  int qd = lane >> 4, m16 = lane & 15;

  for (int i = tid; i < TS_ * 32; i += 256)
    selw[i >> 5][i & 31] = sel[(size_t)(s0 + (i >> 5)) * 32 + (i & 31)];

  short8 qf[2][2];
#pragma unroll
  for (int tk = 0; tk < 2; ++tk)
#pragma unroll
    for (int ks = 0; ks < 2; ++ks)
      qf[tk][ks] = *(const short8*)&qb[(size_t)(s0 + 2 * w + tk) * 1024 + m16 * 64 + ks * 32 + qd * 8];

  floatx4 of[2][4];
#pragma unroll
  for (int i = 0; i < 2; ++i)
#pragma unroll
    for (int j = 0; j < 4; ++j) of[i][j] = (floatx4){0.f, 0.f, 0.f, 0.f};
  float dsum[2] = {0.f, 0.f};

  // tile ct fully cmask-dead iff (ct*64+63)*4 <= s0; selection bound:
  // idx <= max(511, s0+6) for all tokens in block.
  int ub = max(511, s0 + TS_ - 2);
  int ct_start = max(0, (s0 + 4) >> 8);
  int ct_end = min(16, (ub >> 6) + 1);

  for (int ct = ct_start; ct < ct_end; ++ct) {
    int c0 = ct * 64;
    __syncthreads();
    {
      int r = tid >> 2, cc = (tid & 3) * 16;
      *(short8*)&kc_s[r * 72 + cc]      = *(const short8*)&kcb[(size_t)(c0 + r) * 64 + cc];
      *(short8*)&kc_s[r * 72 + cc + 8]  = *(const short8*)&kcb[(size_t)(c0 + r) * 64 + cc + 8];
      *(short8*)&kct_s[r * 72 + cc]     = *(const short8*)&kcbT[(size_t)r * NC_ + c0 + cc];
      *(short8*)&kct_s[r * 72 + cc + 8] = *(const short8*)&kcbT[(size_t)r * NC_ + c0 + cc + 8];
    }
    __syncthreads();
#pragma unroll
    for (int mc = 0; mc < 4; ++mc) {
      short8 a0 = *(const short8*)&kc_s[(mc * 16 + m16) * 72 + qd * 8];
      short8 a1 = *(const short8*)&kc_s[(mc * 16 + m16) * 72 + 32 + qd * 8];
#pragma unroll
      for (int nt = 0; nt < 2; ++nt) {
        floatx4 sc = (floatx4){0.f, 0.f, 0.f, 0.f};
        sc = __builtin_amdgcn_mfma_f32_16x16x32_bf16(a0, qf[nt][0], sc, 0, 0, 0);
        sc = __builtin_amdgcn_mfma_f32_16x16x32_bf16(a1, qf[nt][1], sc, 0, 0, 0);
        int tokL = 2 * w + nt;
        int sG = s0 + tokL;
        short4v pv;
#pragma unroll
        for (int rg = 0; rg < 4; ++rg) {
          int cG = c0 + mc * 16 + qd * 4 + rg;
          bool ok = (((selw[tokL][cG >> 5] >> (cG & 31)) & 1u) != 0u) && (sG < cG * 4);
          float e = ok ? __expf(sc[rg]) : 0.f;
          dsum[nt] += e;
          pv[rg] = (short)f2bf(e);
        }
        *(short4v*)&p_s[(tokL * 16 + m16) * 72 + mc * 16 + qd * 4] = pv;
      }
    }
#pragma unroll
    for (int ks = 0; ks < 2; ++ks) {
      short8 pa0 = *(const short8*)&p_s[((2 * w + 0) * 16 + m16) * 72 + ks * 32 + qd * 8];
      short8 pa1 = *(const short8*)&p_s[((2 * w + 1) * 16 + m16) * 72 + ks * 32 + qd * 8];
#pragma unroll
      for (int nt = 0; nt < 4; ++nt) {
        short8 bv = *(const short8*)&kct_s[(nt * 16 + m16) * 72 + ks * 32 + qd * 8];
        of[0][nt] = __builtin_amdgcn_mfma_f32_16x16x32_bf16(pa0, bv, of[0][nt], 0, 0, 0);
        of[1][nt] = __builtin_amdgcn_mfma_f32_16x16x32_bf16(pa1, bv, of[1][nt], 0, 0, 0);
      }
    }
  }
#pragma unroll
  for (int nt = 0; nt < 2; ++nt) {
    dsum[nt] += __shfl_xor(dsum[nt], 16, 64);
    dsum[nt] += __shfl_xor(dsum[nt], 32, 64);
  }
  if (lane < 16) {
    float sk = __expf(sink[lane]);
    dls[w][0][lane] = dsum[0] + sk;
    dls[w][1][lane] = dsum[1] + sk;
  }
  __syncthreads();
#pragma unroll
  for (int tk = 0; tk < 2; ++tk)
#pragma unroll
    for (int nt = 0; nt < 4; ++nt) {
      floatx4 o = of[tk][nt];
#pragma unroll
      for (int rg = 0; rg < 4; ++rg) {
        int head = qd * 4 + rg;
        float dn = dls[w][tk][head];
        out[(size_t)(s0 + 2 * w + tk) * 1024 + head * 64 + nt * 16 + m16] = f2bf(o[rg] / dn);
      }
    }
}

// ---------------------------------------------------------------------------
// Workspace layout (float offsets)
// ---------------------------------------------------------------------------
#define OFF_QUQ    0u          // quq fp32 / isc / c_q partials
#define OFF_Q      4194304u    // qb bf16
#define OFF_XH     8388608u    // xh bf16 -> gb
#define OFF_XL     12582912u   // xl bf16 -> sel
#define OFF_PART   16777216u   // k_proj/c4/q_i partials
#define OFF_KO     18874368u   // k_or fp32 (early) -> attnb bf16 (mid)
#define OFF_C4     20971520u   // 1048576 f
#define OFF_CQF    22020096u   // qih/qil/kph/kpl overlays
#define OFF_QI     24117248u   // (spare)
#define OFF_CQH    25165824u   // 1048576 f
#define OFF_CQL    26214400u   // 1048576 f
#define OFF_WPACKT 27262976u   // 262144 f
#define OFF_WDQTH  27525120u   // 524288 f
#define OFF_WDQTL  28049408u   // 524288 f
#define OFF_WIUQTH 28573696u   // 65536 f
#define OFF_WIUQTL 28639232u   // 65536 f
#define OFF_WUQT   28704768u   // 262144 f
#define OFF_ODOWNT 28966912u   // 262144 f
#define OFF_OUPT   29229056u   // 2097152 f
#define OFF_HW     31326208u   // 16384 f
#define OFF_COMP   31342592u   // 65536 f
#define OFF_KC     31408128u   // 65536 f : kcb + kcbT
#define OFF_KPR    31473664u   // 65536 f

extern "C" void kernel_launch(void* const* d_in, const int* in_sizes, int n_in,
                              void* d_out, int out_size, void* d_ws, size_t ws_size,
                              hipStream_t stream) {
  const float* x      = (const float*)d_in[0];
  const float* w_kv_a = (const float*)d_in[1];
  const float* w_kv_b = (const float*)d_in[2];
  const float* w_z_a  = (const float*)d_in[3];
  const float* w_z_b  = (const float*)d_in[4];
  const float* b_a    = (const float*)d_in[5];
  const float* b_b    = (const float*)d_in[6];
  const float* w_dq   = (const float*)d_in[7];
  const float* w_iuq  = (const float*)d_in[8];
  const float* w_w    = (const float*)d_in[9];
  const float* w_k    = (const float*)d_in[10];
  const float* w_uq   = (const float*)d_in[11];
  const float* o_down = (const float*)d_in[12];
  const float* o_up   = (const float*)d_in[13];
  const float* kvn_w  = (const float*)d_in[14];
  const float* kvn_b  = (const float*)d_in[15];
  const float* qn_w   = (const float*)d_in[16];
  const float* qn_b   = (const float*)d_in[17];
  const float* sink   = (const float*)d_in[18];
  float* out = (float*)d_out;
  float* ws = (float*)d_ws;

  float* quq   = ws + OFF_QUQ;
  float* isc   = ws + OFF_QUQ;
  unsigned short* qb = (unsigned short*)(ws + OFF_Q);
  unsigned short* xh = (unsigned short*)(ws + OFF_XH);
  unsigned short* gb = (unsigned short*)(ws + OFF_XH);
  unsigned short* xl = (unsigned short*)(ws + OFF_XL);
  unsigned* sel = (unsigned*)(ws + OFF_XL);
  float* part  = ws + OFF_PART;
  float* k_or  = ws + OFF_KO;
  unsigned short* attnb = (unsigned short*)(ws + OFF_KO);
  float* c4    = ws + OFF_C4;
  unsigned short* qih = (unsigned short*)(ws + OFF_CQF);
  unsigned short* qil = qih + S_ * NHI_ * CI_;
  unsigned short* kph = qil + S_ * NHI_ * CI_;
  unsigned short* kpl = kph + NC_ * CI_;
  unsigned short* cqh = (unsigned short*)(ws + OFF_CQH);
  unsigned short* cql = (unsigned short*)(ws + OFF_CQL);
  unsigned short* wpackT = (unsigned short*)(ws + OFF_WPACKT);
  unsigned short* wdqTh  = (unsigned short*)(ws + OFF_WDQTH);
  unsigned short* wdqTl  = (unsigned short*)(ws + OFF_WDQTL);
  unsigned short* wiuqTh = (unsigned short*)(ws + OFF_WIUQTH);
  unsigned short* wiuqTl = (unsigned short*)(ws + OFF_WIUQTL);
  unsigned short* wuqT   = (unsigned short*)(ws + OFF_WUQT);
  unsigned short* odownT = (unsigned short*)(ws + OFF_ODOWNT);
  unsigned short* oupT   = (unsigned short*)(ws + OFF_OUPT);
  float* hw    = ws + OFF_HW;
  float* comp  = ws + OFF_COMP;
  unsigned short* kcb  = (unsigned short*)(ws + OFF_KC);
  unsigned short* kcbT = kcb + NC_ * C_;
  float* k_pr  = ws + OFF_KPR;

  dim3 blk(256);

  // --- casts & weight transposes ---
  cast_split<<<8192, blk, 0, stream>>>(x, xh, xl, S_ * D_);
  transpose_cast<<<dim3(64, 2), blk, 0, stream>>>(w_kv_a, wpackT + 0 * 64 * 2048, D_, C_, 0, 0);
  transpose_cast<<<dim3(64, 2), blk, 0, stream>>>(w_kv_b, wpackT + 1 * 64 * 2048, D_, C_, 0, 0);
  transpose_cast<<<dim3(64, 2), blk, 0, stream>>>(w_z_a,  wpackT + 2 * 64 * 2048, D_, C_, 0, 0);
  transpose_cast<<<dim3(64, 2), blk, 0, stream>>>(w_z_b,  wpackT + 3 * 64 * 2048, D_, C_, 0, 0);
  transpose_cast_split<<<dim3(64, 16), blk, 0, stream>>>(w_dq, wdqTh, wdqTl, D_, DC_);
  transpose_cast_split<<<dim3(16, 8), blk, 0, stream>>>(w_iuq, wiuqTh, wiuqTl, DC_, NHI_ * CI_);
  transpose_cast<<<dim3(16, 32), blk, 0, stream>>>(w_uq, wuqT, DC_, NH_ * C_, 0, 0);
  transpose_cast<<<dim3(8, 16, 4), blk, 0, stream>>>(o_down, odownT, 256, DG_,
                                                     (long long)256 * DG_, (long long)DG_ * 256);
  transpose_cast<<<dim3(64, 64), blk, 0, stream>>>(o_up, oupT, NG_ * DG_, D_, 0, 0);

  // --- fp32 indexer-side path: k_orig -> k_proj (split-K), hw ---
  mean4_kernel<<<8192, blk, 0, stream>>>(x, k_or);
  gemm_f32_splitk<<<dim3(KSL_, 16), blk, 0, stream>>>(k_or, w_k, part, D_, CI_);
  reduce_splitk<<<256, blk, 0, stream>>>(part, k_pr);
  hw_kernel<<<1024, blk, 0, stream>>>(x, w_w, hw);

  // --- MFMA GEMMs ---
  // c_q: K=2048 -> 4 slices of 512 (512 blocks); partials in [0, 8388608)
  gemm_bf16_split<<<dim3(4, 32, 4), blk, 0, stream>>>(xh, xl, wdqTh, wdqTl, ws,
                                                      512, D_, D_, DC_, 512, 512, (long long)S_ * DC_);
  reduce_cast_split<<<2048, blk, 0, stream>>>(ws, cqh, cql, S_ * DC_, 4);
  // c4: K=2048 -> 4 slices of 512 (grid 2x32x4); partials in PART
  gemm_bf16<<<dim3(2, 32, 4), blk, 0, stream>>>(xh, wpackT, part, nullptr,
                                                512, D_, D_, 256, 512, 512, (long long)S_ * 256);
  reduce_f32<<<1024, blk, 0, stream>>>(part, c4, S_ * 256, 4);
  // q_i: K=512 -> 4 slices of 128; partials in PART
  gemm_bf16_split<<<dim3(2, 32, 4), blk, 0, stream>>>(cqh, cql, wiuqTh, wiuqTl, part,
                                                      128, DC_, DC_, 256, 128, 128, (long long)S_ * 256);
  reduce_cast_split<<<1024, blk, 0, stream>>>(part, qih, qil, S_ * 256, 4);
  // quq: 256 blocks (writes quq over dead c_q partials)
  gemm_bf16<<<dim3(8, 32, 1), blk, 0, stream>>>(cqh, wuqT, quq, nullptr,
                                                DC_, DC_, DC_, NH_ * C_, 0, 0, 0);

  // --- gating -> compressed -> kc (LN, bf16 row-major + transposed) ---
  gate_kernel<<<256, blk, 0, stream>>>(c4, b_a, b_b, comp);
  ln_kc_kernel<<<256, blk, 0, stream>>>(comp, kvn_w, kvn_b, kcb, kcbT);

  // --- q: LN + RoPE -> bf16 scaled by 1/8 ---
  ln_rope_q_kernel<<<16384, blk, 0, stream>>>(quq, qn_w, qn_b, qb);

  // --- indexer scores (split-bf16 MFMA, causal tile skip) + radix-select ---
  cast_split<<<64, blk, 0, stream>>>(k_pr, kph, kpl, NC_ * CI_);
  iscores_mfma<<<dim3(8, 128), blk, 0, stream>>>(qih, qil, kph, kpl, hw, isc);
  topk_select_kernel<<<S_, blk, 0, stream>>>(isc, sel);

  // --- dense-masked flash attention (MFMA, causal tile range) ---
  attn_mfma_kernel<<<S_ / TS_, blk, 0, stream>>>(qb, kcb, kcbT, sel, sink, attnb);

  // --- o_down: 4 groups batched via grid.z (512 blocks) ---
  gemm_bf16<<<dim3(4, 32, 4), blk, 0, stream>>>(attnb, odownT, nullptr, gb,
                                                256, NH_ * C_, 256, NG_ * DG_,
                                                256, (long long)DG_ * 256, DG_);
  // --- o_up: direct (split-K was net-negative in R8 — write traffic + reduce) ---
  gemm_bf16<<<dim3(16, 32, 1), blk, 0, stream>>>(gb, oupT, out, nullptr,
                                                 NG_ * DG_, NG_ * DG_, NG_ * DG_, D_, 0, 0, 0);
}

// Round 10
// 472.810 us; speedup vs baseline: 4.7642x; 1.0039x over previous
//
#include <hip/hip_runtime.h>
#include <math.h>

// Problem constants (B=1 throughout)
#define S_   4096
#define D_   2048
#define M_   4
#define NC_  1024
#define TOPK_ 512
#define NH_  16
#define C_   64
#define DC_  512
#define NG_  4
#define DG_  512
#define CI_  64
#define NHI_ 4
#define ROPE_ 32
#define EPS_ 1e-6f

typedef __attribute__((ext_vector_type(8))) short short8;
typedef __attribute__((ext_vector_type(4))) short short4v;
typedef __attribute__((ext_vector_type(4))) float floatx4;

__device__ inline unsigned short f2bf(float f) {
  unsigned u = __float_as_uint(f);
  u += 0x7fff + ((u >> 16) & 1);   // round-to-nearest-even
  return (unsigned short)(u >> 16);
}
__device__ inline float bf2f(unsigned short h) {
  return __uint_as_float(((unsigned)h) << 16);
}

// ---------------------------------------------------------------------------
// bf16 MFMA GEMM, 64x128 tile (4 waves x 32x64): double the block count of the
// 128x128 tile for the same output — fills 256 CUs at >=4 blocks/CU so
// cross-block wave overlap covers the m97 barrier-drain stalls.
// C = A @ Bt^T with grid.z batching/split-K strides.
// ---------------------------------------------------------------------------
__global__ __launch_bounds__(256) void gemm_bf16_64(
    const unsigned short* __restrict__ A, const unsigned short* __restrict__ Bt,
    float* __restrict__ Cf, unsigned short* __restrict__ Cb,
    int K, int lda, int ldb, int ldc,
    long long Az, long long Bz, long long Cz) {
  int zz = blockIdx.z;
  A += (size_t)zz * Az;
  Bt += (size_t)zz * Bz;
  if (Cf) Cf += (size_t)zz * Cz;
  if (Cb) Cb += (size_t)zz * Cz;
  __shared__ unsigned short As[64 * 32];
  __shared__ unsigned short Bs[128 * 32];
  int tid = threadIdx.x;
  int bm = blockIdx.y * 64, bn = blockIdx.x * 128;
  int lane = tid & 63, wid = tid >> 6;
  int wm = (wid & 1) * 32, wn = (wid >> 1) * 64;
  int qd = lane >> 4, m16 = lane & 15;

  floatx4 acc[2][4];
#pragma unroll
  for (int i = 0; i < 2; ++i)
#pragma unroll
    for (int j = 0; j < 4; ++j) acc[i][j] = (floatx4){0.f, 0.f, 0.f, 0.f};

  for (int k0 = 0; k0 < K; k0 += 32) {
    {
      int r = tid >> 2, sl = tid & 3;
      int g = sl ^ ((r >> 1) & 3);
      __builtin_amdgcn_global_load_lds(
          (const __attribute__((address_space(1))) unsigned int*)(A + (size_t)(bm + r) * lda + k0 + g * 8),
          (__attribute__((address_space(3))) unsigned int*)(&As[tid * 8]), 16, 0, 0);
    }
#pragma unroll
    for (int i = 0; i < 2; ++i) {
      int idx = tid + 256 * i;
      int r = idx >> 2, sl = idx & 3;
      int g = sl ^ ((r >> 1) & 3);
      __builtin_amdgcn_global_load_lds(
          (const __attribute__((address_space(1))) unsigned int*)(Bt + (size_t)(bn + r) * ldb + k0 + g * 8),
          (__attribute__((address_space(3))) unsigned int*)(&Bs[idx * 8]), 16, 0, 0);
    }
    __syncthreads();
    short8 af[2], bfr[4];
#pragma unroll
    for (int mi = 0; mi < 2; ++mi) {
      int r = wm + mi * 16 + m16;
      int slot = qd ^ ((r >> 1) & 3);
      af[mi] = *(const short8*)&As[r * 32 + slot * 8];
    }
#pragma unroll
    for (int ni = 0; ni < 4; ++ni) {
      int r = wn + ni * 16 + m16;
      int slot = qd ^ ((r >> 1) & 3);
      bfr[ni] = *(const short8*)&Bs[r * 32 + slot * 8];
    }
#pragma unroll
    for (int mi = 0; mi < 2; ++mi)
#pragma unroll
      for (int ni = 0; ni < 4; ++ni)
        acc[mi][ni] = __builtin_amdgcn_mfma_f32_16x16x32_bf16(af[mi], bfr[ni], acc[mi][ni], 0, 0, 0);
    __syncthreads();
  }
#pragma unroll
  for (int mi = 0; mi < 2; ++mi)
#pragma unroll
    for (int ni = 0; ni < 4; ++ni) {
      int col = bn + wn + ni * 16 + m16;
#pragma unroll
      for (int rg = 0; rg < 4; ++rg) {
        int row = bm + wm + mi * 16 + qd * 4 + rg;
        if (Cb)
          Cb[(size_t)row * ldc + col] = f2bf(acc[mi][ni][rg]);
        else
          Cf[(size_t)row * ldc + col] = acc[mi][ni][rg];
      }
    }
}

// ---------------------------------------------------------------------------
// Split-bf16 MFMA GEMM, 64x128 tile (fp32-accurate, 3 MFMA terms).
// ---------------------------------------------------------------------------
__global__ __launch_bounds__(256) void gemm_bf16_split_64(
    const unsigned short* __restrict__ Ah, const unsigned short* __restrict__ Al,
    const unsigned short* __restrict__ Bh, const unsigned short* __restrict__ Bl,
    float* __restrict__ Cf, int K, int lda, int ldb, int ldc,
    long long Az, long long Bz, long long Cz) {
  int zz = blockIdx.z;
  Ah += (size_t)zz * Az; Al += (size_t)zz * Az;
  Bh += (size_t)zz * Bz; Bl += (size_t)zz * Bz;
  Cf += (size_t)zz * Cz;
  __shared__ unsigned short Ash[64 * 32];
  __shared__ unsigned short Asl[64 * 32];
  __shared__ unsigned short Bsh[128 * 32];
  __shared__ unsigned short Bsl[128 * 32];
  int tid = threadIdx.x;
  int bm = blockIdx.y * 64, bn = blockIdx.x * 128;
  int lane = tid & 63, wid = tid >> 6;
  int wm = (wid & 1) * 32, wn = (wid >> 1) * 64;
  int qd = lane >> 4, m16 = lane & 15;

  floatx4 acc[2][4];
#pragma unroll
  for (int i = 0; i < 2; ++i)
#pragma unroll
    for (int j = 0; j < 4; ++j) acc[i][j] = (floatx4){0.f, 0.f, 0.f, 0.f};

  for (int k0 = 0; k0 < K; k0 += 32) {
    {
      int r = tid >> 2, sl = tid & 3;
      int g = sl ^ ((r >> 1) & 3);
      size_t aoff = (size_t)(bm + r) * lda + k0 + g * 8;
      __builtin_amdgcn_global_load_lds(
          (const __attribute__((address_space(1))) unsigned int*)(Ah + aoff),
          (__attribute__((address_space(3))) unsigned int*)(&Ash[tid * 8]), 16, 0, 0);
      __builtin_amdgcn_global_load_lds(
          (const __attribute__((address_space(1))) unsigned int*)(Al + aoff),
          (__attribute__((address_space(3))) unsigned int*)(&Asl[tid * 8]), 16, 0, 0);
    }
#pragma unroll
    for (int i = 0; i < 2; ++i) {
      int idx = tid + 256 * i;
      int r = idx >> 2, sl = idx & 3;
      int g = sl ^ ((r >> 1) & 3);
      size_t boff = (size_t)(bn + r) * ldb + k0 + g * 8;
      __builtin_amdgcn_global_load_lds(
          (const __attribute__((address_space(1))) unsigned int*)(Bh + boff),
          (__attribute__((address_space(3))) unsigned int*)(&Bsh[idx * 8]), 16, 0, 0);
      __builtin_amdgcn_global_load_lds(
          (const __attribute__((address_space(1))) unsigned int*)(Bl + boff),
          (__attribute__((address_space(3))) unsigned int*)(&Bsl[idx * 8]), 16, 0, 0);
    }
    __syncthreads();
    short8 afh[2], afl[2], bfh[4], bfl[4];
#pragma unroll
    for (int mi = 0; mi < 2; ++mi) {
      int r = wm + mi * 16 + m16;
      int slot = qd ^ ((r >> 1) & 3);
      afh[mi] = *(const short8*)&Ash[r * 32 + slot * 8];
      afl[mi] = *(const short8*)&Asl[r * 32 + slot * 8];
    }
#pragma unroll
    for (int ni = 0; ni < 4; ++ni) {
      int r = wn + ni * 16 + m16;
      int slot = qd ^ ((r >> 1) & 3);
      bfh[ni] = *(const short8*)&Bsh[r * 32 + slot * 8];
      bfl[ni] = *(const short8*)&Bsl[r * 32 + slot * 8];
    }
#pragma unroll
    for (int mi = 0; mi < 2; ++mi)
#pragma unroll
      for (int ni = 0; ni < 4; ++ni) {
        acc[mi][ni] = __builtin_amdgcn_mfma_f32_16x16x32_bf16(afh[mi], bfh[ni], acc[mi][ni], 0, 0, 0);
        acc[mi][ni] = __builtin_amdgcn_mfma_f32_16x16x32_bf16(afh[mi], bfl[ni], acc[mi][ni], 0, 0, 0);
        acc[mi][ni] = __builtin_amdgcn_mfma_f32_16x16x32_bf16(afl[mi], bfh[ni], acc[mi][ni], 0, 0, 0);
      }
    __syncthreads();
  }
#pragma unroll
  for (int mi = 0; mi < 2; ++mi)
#pragma unroll
    for (int ni = 0; ni < 4; ++ni) {
      int col = bn + wn + ni * 16 + m16;
#pragma unroll
      for (int rg = 0; rg < 4; ++rg) {
        int row = bm + wm + mi * 16 + qd * 4 + rg;
        Cf[(size_t)row * ldc + col] = acc[mi][ni][rg];
      }
    }
}

// reduce z fp32 slices (contiguous stride n) -> fp32
__global__ void reduce_f32(const float* __restrict__ P, float* __restrict__ C, int n, int z) {
  int i = (blockIdx.x * 256 + threadIdx.x) * 4;
  if (i >= n) return;
  float4 a = *(const float4*)&P[i];
  for (int s = 1; s < z; ++s) {
    float4 b = *(const float4*)&P[(size_t)s * n + i];
    a.x += b.x; a.y += b.y; a.z += b.z; a.w += b.w;
  }
  *(float4*)&C[i] = a;
}

// reduce z fp32 slices -> (bf16 hi, bf16 lo)
__global__ void reduce_cast_split(const float* __restrict__ P, unsigned short* __restrict__ hi,
                                  unsigned short* __restrict__ lo, int n, int z) {
  int i = (blockIdx.x * 256 + threadIdx.x) * 4;
  if (i >= n) return;
  float4 a = *(const float4*)&P[i];
  for (int s = 1; s < z; ++s) {
    float4 b = *(const float4*)&P[(size_t)s * n + i];
    a.x += b.x; a.y += b.y; a.z += b.z; a.w += b.w;
  }
  ushort4 h = make_ushort4(f2bf(a.x), f2bf(a.y), f2bf(a.z), f2bf(a.w));
  ushort4 l = make_ushort4(f2bf(a.x - bf2f(h.x)), f2bf(a.y - bf2f(h.y)),
                           f2bf(a.z - bf2f(h.z)), f2bf(a.w - bf2f(h.w)));
  *(ushort4*)&hi[i] = h;
  *(ushort4*)&lo[i] = l;
}

// ---------------------------------------------------------------------------
// Indexer scores on split-bf16 MFMA (relu*hw epilogue in-register).
// Fully-masked tiles skipped (topk synthesizes -inf for i >= s).
// ---------------------------------------------------------------------------
__global__ __launch_bounds__(256) void iscores_mfma(
    const unsigned short* __restrict__ Ah, const unsigned short* __restrict__ Al,
    const unsigned short* __restrict__ Bh, const unsigned short* __restrict__ Bl,
    const float* __restrict__ hw, float* __restrict__ isc) {
  int bm = blockIdx.y * 128, bn = blockIdx.x * 128;
  if (bn > (bm >> 2) + 30) return;
  __shared__ unsigned short Ash[128 * 32];
  __shared__ unsigned short Asl[128 * 32];
  __shared__ unsigned short Bsh[128 * 32];
  __shared__ unsigned short Bsl[128 * 32];
  int tid = threadIdx.x;
  int lane = tid & 63, wid = tid >> 6;
  int wm = (wid >> 1) * 64, wn = (wid & 1) * 64;
  int qd = lane >> 4, m16 = lane & 15;

  floatx4 acc[4][4];
#pragma unroll
  for (int i = 0; i < 4; ++i)
#pragma unroll
    for (int j = 0; j < 4; ++j) acc[i][j] = (floatx4){0.f, 0.f, 0.f, 0.f};

#pragma unroll
  for (int k0 = 0; k0 < 64; k0 += 32) {
#pragma unroll
    for (int i = 0; i < 2; ++i) {
      int idx = tid + 256 * i;
      int r = idx >> 2, s = idx & 3;
      int g = s ^ ((r >> 1) & 3);
      size_t aoff = (size_t)(bm + r) * 64 + k0 + g * 8;
      size_t boff = (size_t)(bn + r) * 64 + k0 + g * 8;
      __builtin_amdgcn_global_load_lds(
          (const __attribute__((address_space(1))) unsigned int*)(Ah + aoff),
          (__attribute__((address_space(3))) unsigned int*)(&Ash[idx * 8]), 16, 0, 0);
      __builtin_amdgcn_global_load_lds(
          (const __attribute__((address_space(1))) unsigned int*)(Al + aoff),
          (__attribute__((address_space(3))) unsigned int*)(&Asl[idx * 8]), 16, 0, 0);
      __builtin_amdgcn_global_load_lds(
          (const __attribute__((address_space(1))) unsigned int*)(Bh + boff),
          (__attribute__((address_space(3))) unsigned int*)(&Bsh[idx * 8]), 16, 0, 0);
      __builtin_amdgcn_global_load_lds(
          (const __attribute__((address_space(1))) unsigned int*)(Bl + boff),
          (__attribute__((address_space(3))) unsigned int*)(&Bsl[idx * 8]), 16, 0, 0);
    }
    __syncthreads();
    short8 afh[4], afl[4], bfh[4], bfl[4];
#pragma unroll
    for (int mi = 0; mi < 4; ++mi) {
      int r = wm + mi * 16 + m16;
      int slot = qd ^ ((r >> 1) & 3);
      afh[mi] = *(const short8*)&Ash[r * 32 + slot * 8];
      afl[mi] = *(const short8*)&Asl[r * 32 + slot * 8];
    }
#pragma unroll
    for (int ni = 0; ni < 4; ++ni) {
      int r = wn + ni * 16 + m16;
      int slot = qd ^ ((r >> 1) & 3);
      bfh[ni] = *(const short8*)&Bsh[r * 32 + slot * 8];
      bfl[ni] = *(const short8*)&Bsl[r * 32 + slot * 8];
    }
#pragma unroll
    for (int mi = 0; mi < 4; ++mi)
#pragma unroll
      for (int ni = 0; ni < 4; ++ni) {
        acc[mi][ni] = __builtin_amdgcn_mfma_f32_16x16x32_bf16(afh[mi], bfh[ni], acc[mi][ni], 0, 0, 0);
        acc[mi][ni] = __builtin_amdgcn_mfma_f32_16x16x32_bf16(afh[mi], bfl[ni], acc[mi][ni], 0, 0, 0);
        acc[mi][ni] = __builtin_amdgcn_mfma_f32_16x16x32_bf16(afl[mi], bfh[ni], acc[mi][ni], 0, 0, 0);
      }
    __syncthreads();
  }
#pragma unroll
  for (int mi = 0; mi < 4; ++mi) {
    int tok = ((bm + wm + mi * 16) >> 2) + qd;
    float4 hwv = *(const float4*)&hw[tok * 4];
#pragma unroll
    for (int ni = 0; ni < 4; ++ni) {
      floatx4 a = acc[mi][ni];
      float v = fmaxf(a[0], 0.f) * hwv.x + fmaxf(a[1], 0.f) * hwv.y +
                fmaxf(a[2], 0.f) * hwv.z + fmaxf(a[3], 0.f) * hwv.w;
      int col = bn + wn + ni * 16 + m16;
      isc[(size_t)tok * NC_ + col] = (col < tok) ? v : -__builtin_inff();
    }
  }
}

// ---------------------------------------------------------------------------
// Split-K fp32 GEMM for k_proj (N=64) + reduce
// ---------------------------------------------------------------------------
#define BM 64
#define BN 64
#define BK 16
#define KSL_ 16
#define KSLICE_ 128
__global__ __launch_bounds__(256) void gemm_f32_splitk(
    const float* __restrict__ A, const float* __restrict__ B,
    float* __restrict__ P, int lda, int ldb) {
  __shared__ float As[BK][BM + 4];
  __shared__ float Bs[BK][BN + 4];
  int tid = threadIdx.x;
  int bm = blockIdx.y * BM;
  int kbase = blockIdx.x * KSLICE_;
  int tr = tid >> 4;
  int tc = tid & 15;
  float acc[4][4] = {{0.f}};
  for (int k0 = kbase; k0 < kbase + KSLICE_; k0 += BK) {
    int ac = tid & 15;
    int ar0 = tid >> 4;
#pragma unroll
    for (int i = 0; i < 4; ++i) {
      int r = ar0 + 16 * i;
      As[ac][r] = A[(size_t)(bm + r) * lda + k0 + ac];
    }
    int bc = tid & 63;
    int br0 = tid >> 6;
#pragma unroll
    for (int i = 0; i < 4; ++i) {
      int r = br0 + 4 * i;
      Bs[r][bc] = B[(size_t)(k0 + r) * ldb + bc];
    }
    __syncthreads();
#pragma unroll
    for (int kk = 0; kk < BK; ++kk) {
      float4 av = *(const float4*)&As[kk][tr * 4];
      float4 bv = *(const float4*)&Bs[kk][tc * 4];
      float a[4] = {av.x, av.y, av.z, av.w};
      float b[4] = {bv.x, bv.y, bv.z, bv.w};
#pragma unroll
      for (int i = 0; i < 4; ++i)
#pragma unroll
        for (int j = 0; j < 4; ++j) acc[i][j] += a[i] * b[j];
    }
    __syncthreads();
  }
  float* Pb = P + (size_t)blockIdx.x * (NC_ * CI_);
#pragma unroll
  for (int i = 0; i < 4; ++i) {
    float4 v = make_float4(acc[i][0], acc[i][1], acc[i][2], acc[i][3]);
    *(float4*)&Pb[(size_t)(bm + tr * 4 + i) * CI_ + tc * 4] = v;
  }
}

__global__ void reduce_splitk(const float* __restrict__ P, float* __restrict__ C) {
  int i = blockIdx.x * 256 + threadIdx.x;
  if (i >= NC_ * CI_) return;
  float a = 0.f;
#pragma unroll
  for (int s = 0; s < KSL_; ++s) a += P[(size_t)s * (NC_ * CI_) + i];
  C[i] = a;
}

// fp32 -> (bf16 hi, bf16 lo) element-wise split (n multiple of 4)
__global__ void cast_split(const float* __restrict__ in, unsigned short* __restrict__ hi,
                           unsigned short* __restrict__ lo, int n) {
  int i = (blockIdx.x * 256 + threadIdx.x) * 4;
  if (i >= n) return;
  float4 v = *(const float4*)&in[i];
  ushort4 h = make_ushort4(f2bf(v.x), f2bf(v.y), f2bf(v.z), f2bf(v.w));
  ushort4 l = make_ushort4(f2bf(v.x - bf2f(h.x)), f2bf(v.y - bf2f(h.y)),
                           f2bf(v.z - bf2f(h.z)), f2bf(v.w - bf2f(h.w)));
  *(ushort4*)&hi[i] = h;
  *(ushort4*)&lo[i] = l;
}

__device__ inline float wave_sum64(float v) {
#pragma unroll
  for (int off = 32; off > 0; off >>= 1) v += __shfl_xor(v, off, 64);
  return v;
}

// Fused: x -> (hi, lo) split AND hw = x @ w_w. One block (512 thr) per token —
// saves a full 33.5 MB re-read of x vs a separate hw kernel.
__global__ __launch_bounds__(512) void cast_split_hw(
    const float* __restrict__ x, unsigned short* __restrict__ hi,
    unsigned short* __restrict__ lo, const float* __restrict__ ww,
    float* __restrict__ hw) {
  int s = blockIdx.x, tid = threadIdx.x;
  size_t i = (size_t)s * D_ + tid * 4;
  float4 v = *(const float4*)&x[i];
  ushort4 h = make_ushort4(f2bf(v.x), f2bf(v.y), f2bf(v.z), f2bf(v.w));
  ushort4 l = make_ushort4(f2bf(v.x - bf2f(h.x)), f2bf(v.y - bf2f(h.y)),
                           f2bf(v.z - bf2f(h.z)), f2bf(v.w - bf2f(h.w)));
  *(ushort4*)&hi[i] = h;
  *(ushort4*)&lo[i] = l;
  const float* wr = ww + tid * 16;  // rows tid*4 .. tid*4+3 of (D x 4)
  float a0 = v.x * wr[0] + v.y * wr[4] + v.z * wr[8]  + v.w * wr[12];
  float a1 = v.x * wr[1] + v.y * wr[5] + v.z * wr[9]  + v.w * wr[13];
  float a2 = v.x * wr[2] + v.y * wr[6] + v.z * wr[10] + v.w * wr[14];
  float a3 = v.x * wr[3] + v.y * wr[7] + v.z * wr[11] + v.w * wr[15];
  a0 = wave_sum64(a0); a1 = wave_sum64(a1);
  a2 = wave_sum64(a2); a3 = wave_sum64(a3);
  __shared__ float red[8][4];
  int wid = tid >> 6, lane = tid & 63;
  if (lane == 0) { red[wid][0] = a0; red[wid][1] = a1; red[wid][2] = a2; red[wid][3] = a3; }
  __syncthreads();
  if (tid < 4) {
    float acc = 0.f;
#pragma unroll
    for (int w2 = 0; w2 < 8; ++w2) acc += red[w2][tid];
    hw[s * 4 + tid] = acc;
  }
}

// fp32 (K x N) -> bf16 transpose (N x K). K,N multiples of 32. grid.z batching.
__global__ __launch_bounds__(256) void transpose_cast(
    const float* __restrict__ in, unsigned short* __restrict__ out, int K, int N,
    long long inz, long long outz) {
  in += (size_t)blockIdx.z * inz;
  out += (size_t)blockIdx.z * outz;
  __shared__ float t[32][33];
  int k0 = blockIdx.x * 32, n0 = blockIdx.y * 32;
  int tx = threadIdx.x & 31, ty = threadIdx.x >> 5;
#pragma unroll
  for (int i = 0; i < 4; ++i)
    t[ty * 4 + i][tx] = in[(size_t)(k0 + ty * 4 + i) * N + n0 + tx];
  __syncthreads();
#pragma unroll
  for (int i = 0; i < 4; ++i)
    out[(size_t)(n0 + ty * 4 + i) * K + k0 + tx] = f2bf(t[tx][ty * 4 + i]);
}

// fp32 (K x N) -> bf16 transpose split (N x K, hi+lo)
__global__ __launch_bounds__(256) void transpose_cast_split(
    const float* __restrict__ in, unsigned short* __restrict__ outh,
    unsigned short* __restrict__ outl, int K, int N) {
  __shared__ float t[32][33];
  int k0 = blockIdx.x * 32, n0 = blockIdx.y * 32;
  int tx = threadIdx.x & 31, ty = threadIdx.x >> 5;
#pragma unroll
  for (int i = 0; i < 4; ++i)
    t[ty * 4 + i][tx] = in[(size_t)(k0 + ty * 4 + i) * N + n0 + tx];
  __syncthreads();
#pragma unroll
  for (int i = 0; i < 4; ++i) {
    float v = t[tx][ty * 4 + i];
    unsigned short h = f2bf(v);
    outh[(size_t)(n0 + ty * 4 + i) * K + k0 + tx] = h;
    outl[(size_t)(n0 + ty * 4 + i) * K + k0 + tx] = f2bf(v - bf2f(h));
  }
}

// k_orig[j,d] = mean over 4 tokens
__global__ void mean4_kernel(const float* __restrict__ x, float* __restrict__ ko) {
  int i = blockIdx.x * 256 + threadIdx.x;
  if (i >= NC_ * D_) return;
  int j = i >> 11, d = i & (D_ - 1);
  const float* p = x + (size_t)j * 4 * D_ + d;
  ko[i] = 0.25f * (p[0] + p[D_] + p[2 * D_] + p[3 * D_]);
}

// gating softmax; reads packed c4 (S x 256: [c_a|c_b|z_a|z_b])
__global__ void gate_kernel(const float* __restrict__ c4,
                            const float* __restrict__ ba, const float* __restrict__ bb,
                            float* __restrict__ comp) {
  int i = blockIdx.x * 256 + threadIdx.x;
  if (i >= NC_ * C_) return;
  int j = i >> 6, c = i & 63;
  float lg[8], vv[8];
#pragma unroll
  for (int m = 0; m < 4; ++m) {
    if (j == 0) {
      lg[m] = -1e30f + bb[m * C_ + c];
      vv[m] = 0.f;
    } else {
      int row = (j - 1) * 4 + m;
      lg[m] = c4[(size_t)row * 256 + 192 + c] + bb[m * C_ + c];
      vv[m] = c4[(size_t)row * 256 + 64 + c];
    }
    int row2 = j * 4 + m;
    lg[4 + m] = c4[(size_t)row2 * 256 + 128 + c] + ba[m * C_ + c];
    vv[4 + m] = c4[(size_t)row2 * 256 + 0 + c];
  }
  float mx = lg[0];
#pragma unroll
  for (int t = 1; t < 8; ++t) mx = fmaxf(mx, lg[t]);
  float se = 0.f, acc = 0.f;
#pragma unroll
  for (int t = 0; t < 8; ++t) {
    float e = expf(lg[t] - mx);
    se += e;
    acc += e * vv[t];
  }
  comp[i] = acc / se;
}

// LayerNorm over C=64 -> bf16 row-major + bf16 transposed (for attention MFMA)
__global__ void ln_kc_kernel(const float* __restrict__ in, const float* __restrict__ w,
                             const float* __restrict__ b, unsigned short* __restrict__ kcb,
                             unsigned short* __restrict__ kcbT) {
  int row = blockIdx.x * 4 + (threadIdx.x >> 6);
  int c = threadIdx.x & 63;
  float v = in[(size_t)row * C_ + c];
  float mu = wave_sum64(v) * (1.f / 64.f);
  float d = v - mu;
  float var = wave_sum64(d * d) * (1.f / 64.f);
  float y = d * (1.f / sqrtf(var + EPS_)) * w[c] + b[c];
  unsigned short h = f2bf(y);
  kcb[(size_t)row * C_ + c] = h;
  kcbT[(size_t)c * NC_ + row] = h;
}

// LN + RoPE for q -> bf16, pre-scaled by 1/sqrt(C)=0.125 (only attention uses q)
__global__ void ln_rope_q_kernel(const float* __restrict__ quq, const float* __restrict__ w,
                                 const float* __restrict__ b, unsigned short* __restrict__ qb) {
  int row = blockIdx.x * 4 + (threadIdx.x >> 6);  // s*16 + h
  int s = row >> 4;
  int c = threadIdx.x & 63;
  float v = quq[(size_t)row * C_ + c];
  float mu = wave_sum64(v) * (1.f / 64.f);
  float d = v - mu;
  float var = wave_sum64(d * d) * (1.f / 64.f);
  float y = d * (1.f / sqrtf(var + EPS_)) * w[c] + b[c];
  float outv;
  float partner = __shfl_xor(y, 1, 64);
  if (c < C_ - ROPE_) {
    outv = y;
  } else {
    int p = (c - (C_ - ROPE_)) >> 1;
    float inv = powf(10000.f, -(2.f * (float)p) / (float)ROPE_);
    float ang = (float)s * inv;
    float cs = cosf(ang), sn = sinf(ang);
    if ((c & 1) == 0)
      outv = y * cs - partner * sn;
    else
      outv = partner * sn + y * cs;
  }
  qb[(size_t)row * C_ + c] = f2bf(outv * 0.125f);
}

// ---------------------------------------------------------------------------
// Top-512-of-1024 exact radix-select -> selection bitmap.
// ---------------------------------------------------------------------------
#define MINF_ 0x007FFFFFu
__global__ __launch_bounds__(256) void topk_select_kernel(
    const float* __restrict__ isc, unsigned* __restrict__ sel) {
  __shared__ unsigned mv[NC_];
  __shared__ unsigned bins[256];
  __shared__ unsigned scan[256];
  __shared__ unsigned sB, sR;
  __shared__ unsigned selw[32];
  int s = blockIdx.x;
  int tid = threadIdx.x;
  for (int i = tid; i < NC_; i += 256) {
    if (i < s) {
      unsigned u = __float_as_uint(isc[(size_t)s * NC_ + i]);
      mv[i] = (u & 0x80000000u) ? ~u : (u | 0x80000000u);
    } else {
      mv[i] = MINF_;
    }
  }
  __syncthreads();
  unsigned K_rem = TOPK_;
  unsigned prefix = 0u;
  for (int lvl = 0; lvl < 4; ++lvl) {
    int shift = 24 - 8 * lvl;
    unsigned pm = (lvl == 0) ? 0u : (0xFFFFFFFFu << (32 - 8 * lvl));
    bins[tid] = 0u;
    __syncthreads();
    for (int i = tid; i < NC_; i += 256) {
      unsigned m = mv[i];
      if ((m & pm) == prefix) atomicAdd(&bins[(m >> shift) & 0xFFu], 1u);
    }
    __syncthreads();
    unsigned v = bins[tid];
    scan[tid] = v;
    __syncthreads();
    for (int off = 1; off < 256; off <<= 1) {
      unsigned add = (tid + off < 256) ? scan[tid + off] : 0u;
      __syncthreads();
      scan[tid] += add;
      __syncthreads();
    }
    unsigned gt = scan[tid] - v;
    if (gt < K_rem && K_rem <= gt + v) { sB = (unsigned)tid; sR = K_rem - gt; }
    __syncthreads();
    prefix |= (sB << shift);
    K_rem = sR;
    __syncthreads();
  }
  unsigned vstar = prefix;
  unsigned eq = 0;
#pragma unroll
  for (int j = 0; j < 4; ++j) eq += (mv[4 * tid + j] == vstar);
  scan[tid] = eq;
  __syncthreads();
  for (int off = 1; off < 256; off <<= 1) {
    unsigned add = (tid >= off) ? scan[tid - off] : 0u;
    __syncthreads();
    scan[tid] += add;
    __syncthreads();
  }
  unsigned rank0 = scan[tid] - eq;
  if (tid < 32) selw[tid] = 0u;
  __syncthreads();
  unsigned local = 0, bits = 0;
#pragma unroll
  for (int j = 0; j < 4; ++j) {
    unsigned m = mv[4 * tid + j];
    bool sb = (m > vstar) || (m == vstar && (rank0 + local) < K_rem);
    local += (m == vstar);
    if (sb) bits |= (1u << ((4 * tid + j) & 31));
  }
  if (bits) atomicOr(&selw[tid >> 3], bits);
  __syncthreads();
  if (tid < 32) sel[(size_t)s * 32 + tid] = selw[tid];
}

// ---------------------------------------------------------------------------
// Dense-masked flash attention on MFMA with exact causal/selection tile range.
// ---------------------------------------------------------------------------
#define TS_ 8
__global__ __launch_bounds__(256) void attn_mfma_kernel(
    const unsigned short* __restrict__ qb, const unsigned short* __restrict__ kcb,
    const unsigned short* __restrict__ kcbT, const unsigned* __restrict__ sel,
    const float* __restrict__ sink, unsigned short* __restrict__ out) {
  __shared__ unsigned short kc_s[64 * 72];
  __shared__ unsigned short kct_s[64 * 72];
  __shared__ unsigned short p_s[128 * 72];
  __shared__ unsigned selw[TS_][32];
  __shared__ float dls[4][2][16];
  int tid = threadIdx.x;
  int s0 = blockIdx.x * TS_;
  int lane = tid & 63, w = tid >> 6;
  int qd = lane >> 4, m16 = lane & 15;

  for (int i = tid; i < TS_ * 32; i += 256)
    selw[i >> 5][i & 31] = sel[(size_t)(s0 + (i >> 5)) * 32 + (i & 31)];

  short8 qf[2][2];
#pragma unroll
  for (int tk = 0; tk < 2; ++tk)
#pragma unroll
    for (int ks = 0; ks < 2; ++ks)
      qf[tk][ks] = *(const short8*)&qb[(size_t)(s0 + 2 * w + tk) * 1024 + m16 * 64 + ks * 32 + qd * 8];

  floatx4 of[2][4];
#pragma unroll
  for (int i = 0; i < 2; ++i)
#pragma unroll
    for (int j = 0; j < 4; ++j) of[i][j] = (floatx4){0.f, 0.f, 0.f, 0.f};
  float dsum[2] = {0.f, 0.f};

  int ub = max(511, s0 + TS_ - 2);
  int ct_start = max(0, (s0 + 4) >> 8);
  int ct_end = min(16, (ub >> 6) + 1);

  for (int ct = ct_start; ct < ct_end; ++ct) {
    int c0 = ct * 64;
    __syncthreads();
    {
      int r = tid >> 2, cc = (tid & 3) * 16;
      *(short8*)&kc_s[r * 72 + cc]      = *(const short8*)&kcb[(size_t)(c0 + r) * 64 + cc];
      *(short8*)&kc_s[r * 72 + cc + 8]  = *(const short8*)&kcb[(size_t)(c0 + r) * 64 + cc + 8];
      *(short8*)&kct_s[r * 72 + cc]     = *(const short8*)&kcbT[(size_t)r * NC_ + c0 + cc];
      *(short8*)&kct_s[r * 72 + cc + 8] = *(const short8*)&kcbT[(size_t)r * NC_ + c0 + cc + 8];
    }
    __syncthreads();
#pragma unroll
    for (int mc = 0; mc < 4; ++mc) {
      short8 a0 = *(const short8*)&kc_s[(mc * 16 + m16) * 72 + qd * 8];
      short8 a1 = *(const short8*)&kc_s[(mc * 16 + m16) * 72 + 32 + qd * 8];
#pragma unroll
      for (int nt = 0; nt < 2; ++nt) {
        floatx4 sc = (floatx4){0.f, 0.f, 0.f, 0.f};
        sc = __builtin_amdgcn_mfma_f32_16x16x32_bf16(a0, qf[nt][0], sc, 0, 0, 0);
        sc = __builtin_amdgcn_mfma_f32_16x16x32_bf16(a1, qf[nt][1], sc, 0, 0, 0);
        int tokL = 2 * w + nt;
        int sG = s0 + tokL;
        short4v pv;
#pragma unroll
        for (int rg = 0; rg < 4; ++rg) {
          int cG = c0 + mc * 16 + qd * 4 + rg;
          bool ok = (((selw[tokL][cG >> 5] >> (cG & 31)) & 1u) != 0u) && (sG < cG * 4);
          float e = ok ? __expf(sc[rg]) : 0.f;
          dsum[nt] += e;
          pv[rg] = (short)f2bf(e);
        }
        *(short4v*)&p_s[(tokL * 16 + m16) * 72 + mc * 16 + qd * 4] = pv;
      }
    }
#pragma unroll
    for (int ks = 0; ks < 2; ++ks) {
      short8 pa0 = *(const short8*)&p_s[((2 * w + 0) * 16 + m16) * 72 + ks * 32 + qd * 8];
      short8 pa1 = *(const short8*)&p_s[((2 * w + 1) * 16 + m16) * 72 + ks * 32 + qd * 8];
#pragma unroll
      for (int nt = 0; nt < 4; ++nt) {
        short8 bv = *(const short8*)&kct_s[(nt * 16 + m16) * 72 + ks * 32 + qd * 8];
        of[0][nt] = __builtin_amdgcn_mfma_f32_16x16x32_bf16(pa0, bv, of[0][nt], 0, 0, 0);
        of[1][nt] = __builtin_amdgcn_mfma_f32_16x16x32_bf16(pa1, bv, of[1][nt], 0, 0, 0);
      }
    }
  }
#pragma unroll
  for (int nt = 0; nt < 2; ++nt) {
    dsum[nt] += __shfl_xor(dsum[nt], 16, 64);
    dsum[nt] += __shfl_xor(dsum[nt], 32, 64);
  }
  if (lane < 16) {
    float sk = __expf(sink[lane]);
    dls[w][0][lane] = dsum[0] + sk;
    dls[w][1][lane] = dsum[1] + sk;
  }
  __syncthreads();
#pragma unroll
  for (int tk = 0; tk < 2; ++tk)
#pragma unroll
    for (int nt = 0; nt < 4; ++nt) {
      floatx4 o = of[tk][nt];
#pragma unroll
      for (int rg = 0; rg < 4; ++rg) {
        int head = qd * 4 + rg;
        float dn = dls[w][tk][head];
        out[(size_t)(s0 + 2 * w + tk) * 1024 + head * 64 + nt * 16 + m16] = f2bf(o[rg] / dn);
      }
    }
}

// ---------------------------------------------------------------------------
// Workspace layout (float offsets)
// ---------------------------------------------------------------------------
#define OFF_QUQ    0u          // quq fp32 / isc / c_q partials
#define OFF_Q      4194304u    // qb bf16
#define OFF_XH     8388608u    // xh bf16 -> gb
#define OFF_XL     12582912u   // xl bf16 -> sel
#define OFF_PART   16777216u   // k_proj/c4/q_i partials
#define OFF_KO     18874368u   // k_or fp32 (early) -> attnb bf16 (mid)
#define OFF_C4     20971520u   // 1048576 f
#define OFF_CQF    22020096u   // qih/qil/kph/kpl overlays
#define OFF_QI     24117248u   // (spare)
#define OFF_CQH    25165824u   // 1048576 f
#define OFF_CQL    26214400u   // 1048576 f
#define OFF_WPACKT 27262976u   // 262144 f
#define OFF_WDQTH  27525120u   // 524288 f
#define OFF_WDQTL  28049408u   // 524288 f
#define OFF_WIUQTH 28573696u   // 65536 f
#define OFF_WIUQTL 28639232u   // 65536 f
#define OFF_WUQT   28704768u   // 262144 f
#define OFF_ODOWNT 28966912u   // 262144 f
#define OFF_OUPT   29229056u   // 2097152 f
#define OFF_HW     31326208u   // 16384 f
#define OFF_COMP   31342592u   // 65536 f
#define OFF_KC     31408128u   // 65536 f : kcb + kcbT
#define OFF_KPR    31473664u   // 65536 f

extern "C" void kernel_launch(void* const* d_in, const int* in_sizes, int n_in,
                              void* d_out, int out_size, void* d_ws, size_t ws_size,
                              hipStream_t stream) {
  const float* x      = (const float*)d_in[0];
  const float* w_kv_a = (const float*)d_in[1];
  const float* w_kv_b = (const float*)d_in[2];
  const float* w_z_a  = (const float*)d_in[3];
  const float* w_z_b  = (const float*)d_in[4];
  const float* b_a    = (const float*)d_in[5];
  const float* b_b    = (const float*)d_in[6];
  const float* w_dq   = (const float*)d_in[7];
  const float* w_iuq  = (const float*)d_in[8];
  const float* w_w    = (const float*)d_in[9];
  const float* w_k    = (const float*)d_in[10];
  const float* w_uq   = (const float*)d_in[11];
  const float* o_down = (const float*)d_in[12];
  const float* o_up   = (const float*)d_in[13];
  const float* kvn_w  = (const float*)d_in[14];
  const float* kvn_b  = (const float*)d_in[15];
  const float* qn_w   = (const float*)d_in[16];
  const float* qn_b   = (const float*)d_in[17];
  const float* sink   = (const float*)d_in[18];
  float* out = (float*)d_out;
  float* ws = (float*)d_ws;

  float* quq   = ws + OFF_QUQ;
  float* isc   = ws + OFF_QUQ;
  unsigned short* qb = (unsigned short*)(ws + OFF_Q);
  unsigned short* xh = (unsigned short*)(ws + OFF_XH);
  unsigned short* gb = (unsigned short*)(ws + OFF_XH);
  unsigned short* xl = (unsigned short*)(ws + OFF_XL);
  unsigned* sel = (unsigned*)(ws + OFF_XL);
  float* part  = ws + OFF_PART;
  float* k_or  = ws + OFF_KO;
  unsigned short* attnb = (unsigned short*)(ws + OFF_KO);
  float* c4    = ws + OFF_C4;
  unsigned short* qih = (unsigned short*)(ws + OFF_CQF);
  unsigned short* qil = qih + S_ * NHI_ * CI_;
  unsigned short* kph = qil + S_ * NHI_ * CI_;
  unsigned short* kpl = kph + NC_ * CI_;
  unsigned short* cqh = (unsigned short*)(ws + OFF_CQH);
  unsigned short* cql = (unsigned short*)(ws + OFF_CQL);
  unsigned short* wpackT = (unsigned short*)(ws + OFF_WPACKT);
  unsigned short* wdqTh  = (unsigned short*)(ws + OFF_WDQTH);
  unsigned short* wdqTl  = (unsigned short*)(ws + OFF_WDQTL);
  unsigned short* wiuqTh = (unsigned short*)(ws + OFF_WIUQTH);
  unsigned short* wiuqTl = (unsigned short*)(ws + OFF_WIUQTL);
  unsigned short* wuqT   = (unsigned short*)(ws + OFF_WUQT);
  unsigned short* odownT = (unsigned short*)(ws + OFF_ODOWNT);
  unsigned short* oupT   = (unsigned short*)(ws + OFF_OUPT);
  float* hw    = ws + OFF_HW;
  float* comp  = ws + OFF_COMP;
  unsigned short* kcb  = (unsigned short*)(ws + OFF_KC);
  unsigned short* kcbT = kcb + NC_ * C_;
  float* k_pr  = ws + OFF_KPR;

  dim3 blk(256);

  // --- casts & weight transposes (x cast fused with hw) ---
  cast_split_hw<<<S_, dim3(512), 0, stream>>>(x, xh, xl, w_w, hw);
  transpose_cast<<<dim3(64, 2), blk, 0, stream>>>(w_kv_a, wpackT + 0 * 64 * 2048, D_, C_, 0, 0);
  transpose_cast<<<dim3(64, 2), blk, 0, stream>>>(w_kv_b, wpackT + 1 * 64 * 2048, D_, C_, 0, 0);
  transpose_cast<<<dim3(64, 2), blk, 0, stream>>>(w_z_a,  wpackT + 2 * 64 * 2048, D_, C_, 0, 0);
  transpose_cast<<<dim3(64, 2), blk, 0, stream>>>(w_z_b,  wpackT + 3 * 64 * 2048, D_, C_, 0, 0);
  transpose_cast_split<<<dim3(64, 16), blk, 0, stream>>>(w_dq, wdqTh, wdqTl, D_, DC_);
  transpose_cast_split<<<dim3(16, 8), blk, 0, stream>>>(w_iuq, wiuqTh, wiuqTl, DC_, NHI_ * CI_);
  transpose_cast<<<dim3(16, 32), blk, 0, stream>>>(w_uq, wuqT, DC_, NH_ * C_, 0, 0);
  transpose_cast<<<dim3(8, 16, 4), blk, 0, stream>>>(o_down, odownT, 256, DG_,
                                                     (long long)256 * DG_, (long long)DG_ * 256);
  transpose_cast<<<dim3(64, 64), blk, 0, stream>>>(o_up, oupT, NG_ * DG_, D_, 0, 0);

  // --- fp32 indexer-side path: k_orig -> k_proj (split-K) ---
  mean4_kernel<<<8192, blk, 0, stream>>>(x, k_or);
  gemm_f32_splitk<<<dim3(KSL_, 16), blk, 0, stream>>>(k_or, w_k, part, D_, CI_);
  reduce_splitk<<<256, blk, 0, stream>>>(part, k_pr);

  // --- MFMA GEMMs (64x128 tiles: >=512 blocks each) ---
  // c_q: K=2048 -> 4 slices of 512 (grid 4x64x4 = 1024 blocks)
  gemm_bf16_split_64<<<dim3(4, 64, 4), blk, 0, stream>>>(xh, xl, wdqTh, wdqTl, ws,
                                                         512, D_, D_, DC_, 512, 512, (long long)S_ * DC_);
  reduce_cast_split<<<2048, blk, 0, stream>>>(ws, cqh, cql, S_ * DC_, 4);
  // c4: K=2048 -> 4 slices of 512 (grid 2x64x4 = 512 blocks)
  gemm_bf16_64<<<dim3(2, 64, 4), blk, 0, stream>>>(xh, wpackT, part, nullptr,
                                                   512, D_, D_, 256, 512, 512, (long long)S_ * 256);
  reduce_f32<<<1024, blk, 0, stream>>>(part, c4, S_ * 256, 4);
  // q_i: K=512 -> 4 slices of 128 (grid 2x64x4 = 512 blocks)
  gemm_bf16_split_64<<<dim3(2, 64, 4), blk, 0, stream>>>(cqh, cql, wiuqTh, wiuqTl, part,
                                                         128, DC_, DC_, 256, 128, 128, (long long)S_ * 256);
  reduce_cast_split<<<1024, blk, 0, stream>>>(part, qih, qil, S_ * 256, 4);
  // quq: grid 8x64 = 512 blocks
  gemm_bf16_64<<<dim3(8, 64, 1), blk, 0, stream>>>(cqh, wuqT, quq, nullptr,
                                                   DC_, DC_, DC_, NH_ * C_, 0, 0, 0);

  // --- gating -> compressed -> kc (LN, bf16 row-major + transposed) ---
  gate_kernel<<<256, blk, 0, stream>>>(c4, b_a, b_b, comp);
  ln_kc_kernel<<<256, blk, 0, stream>>>(comp, kvn_w, kvn_b, kcb, kcbT);

  // --- q: LN + RoPE -> bf16 scaled by 1/8 ---
  ln_rope_q_kernel<<<16384, blk, 0, stream>>>(quq, qn_w, qn_b, qb);

  // --- indexer scores (split-bf16 MFMA, causal tile skip) + radix-select ---
  cast_split<<<64, blk, 0, stream>>>(k_pr, kph, kpl, NC_ * CI_);
  iscores_mfma<<<dim3(8, 128), blk, 0, stream>>>(qih, qil, kph, kpl, hw, isc);
  topk_select_kernel<<<S_, blk, 0, stream>>>(isc, sel);

  // --- dense-masked flash attention (MFMA, causal tile range) ---
  attn_mfma_kernel<<<S_ / TS_, blk, 0, stream>>>(qb, kcb, kcbT, sel, sink, attnb);

  // --- o_down: 4 groups batched via grid.z (grid 4x64x4 = 1024 blocks) ---
  gemm_bf16_64<<<dim3(4, 64, 4), blk, 0, stream>>>(attnb, odownT, nullptr, gb,
                                                   256, NH_ * C_, 256, NG_ * DG_,
                                                   256, (long long)DG_ * 256, DG_);
  // --- o_up: grid 16x64 = 1024 blocks (4 blocks/CU) ---
  gemm_bf16_64<<<dim3(16, 64, 1), blk, 0, stream>>>(gb, oupT, out, nullptr,
                                                    NG_ * DG_, NG_ * DG_, NG_ * DG_, D_, 0, 0, 0);
}

// Round 11
// 440.863 us; speedup vs baseline: 5.1094x; 1.0725x over previous
//
#include <hip/hip_runtime.h>
#include <math.h>

// Problem constants (B=1 throughout)
#define S_   4096
#define D_   2048
#define M_   4
#define NC_  1024
#define TOPK_ 512
#define NH_  16
#define C_   64
#define DC_  512
#define NG_  4
#define DG_  512
#define CI_  64
#define NHI_ 4
#define ROPE_ 32
#define EPS_ 1e-6f

typedef __attribute__((ext_vector_type(8))) short short8;
typedef __attribute__((ext_vector_type(4))) short short4v;
typedef __attribute__((ext_vector_type(4))) float floatx4;

__device__ inline unsigned short f2bf(float f) {
  unsigned u = __float_as_uint(f);
  u += 0x7fff + ((u >> 16) & 1);   // round-to-nearest-even
  return (unsigned short)(u >> 16);
}
__device__ inline float bf2f(unsigned short h) {
  return __uint_as_float(((unsigned)h) << 16);
}

// ---------------------------------------------------------------------------
// bf16 MFMA GEMM, 64x128 tile (4 waves x 32x64). C = A @ Bt^T, grid.z strides.
// ---------------------------------------------------------------------------
__global__ __launch_bounds__(256) void gemm_bf16_64(
    const unsigned short* __restrict__ A, const unsigned short* __restrict__ Bt,
    float* __restrict__ Cf, unsigned short* __restrict__ Cb,
    int K, int lda, int ldb, int ldc,
    long long Az, long long Bz, long long Cz) {
  int zz = blockIdx.z;
  A += (size_t)zz * Az;
  Bt += (size_t)zz * Bz;
  if (Cf) Cf += (size_t)zz * Cz;
  if (Cb) Cb += (size_t)zz * Cz;
  __shared__ unsigned short As[64 * 32];
  __shared__ unsigned short Bs[128 * 32];
  int tid = threadIdx.x;
  int bm = blockIdx.y * 64, bn = blockIdx.x * 128;
  int lane = tid & 63, wid = tid >> 6;
  int wm = (wid & 1) * 32, wn = (wid >> 1) * 64;
  int qd = lane >> 4, m16 = lane & 15;

  floatx4 acc[2][4];
#pragma unroll
  for (int i = 0; i < 2; ++i)
#pragma unroll
    for (int j = 0; j < 4; ++j) acc[i][j] = (floatx4){0.f, 0.f, 0.f, 0.f};

  for (int k0 = 0; k0 < K; k0 += 32) {
    {
      int r = tid >> 2, sl = tid & 3;
      int g = sl ^ ((r >> 1) & 3);
      __builtin_amdgcn_global_load_lds(
          (const __attribute__((address_space(1))) unsigned int*)(A + (size_t)(bm + r) * lda + k0 + g * 8),
          (__attribute__((address_space(3))) unsigned int*)(&As[tid * 8]), 16, 0, 0);
    }
#pragma unroll
    for (int i = 0; i < 2; ++i) {
      int idx = tid + 256 * i;
      int r = idx >> 2, sl = idx & 3;
      int g = sl ^ ((r >> 1) & 3);
      __builtin_amdgcn_global_load_lds(
          (const __attribute__((address_space(1))) unsigned int*)(Bt + (size_t)(bn + r) * ldb + k0 + g * 8),
          (__attribute__((address_space(3))) unsigned int*)(&Bs[idx * 8]), 16, 0, 0);
    }
    __syncthreads();
    short8 af[2], bfr[4];
#pragma unroll
    for (int mi = 0; mi < 2; ++mi) {
      int r = wm + mi * 16 + m16;
      int slot = qd ^ ((r >> 1) & 3);
      af[mi] = *(const short8*)&As[r * 32 + slot * 8];
    }
#pragma unroll
    for (int ni = 0; ni < 4; ++ni) {
      int r = wn + ni * 16 + m16;
      int slot = qd ^ ((r >> 1) & 3);
      bfr[ni] = *(const short8*)&Bs[r * 32 + slot * 8];
    }
#pragma unroll
    for (int mi = 0; mi < 2; ++mi)
#pragma unroll
      for (int ni = 0; ni < 4; ++ni)
        acc[mi][ni] = __builtin_amdgcn_mfma_f32_16x16x32_bf16(af[mi], bfr[ni], acc[mi][ni], 0, 0, 0);
    __syncthreads();
  }
#pragma unroll
  for (int mi = 0; mi < 2; ++mi)
#pragma unroll
    for (int ni = 0; ni < 4; ++ni) {
      int col = bn + wn + ni * 16 + m16;
#pragma unroll
      for (int rg = 0; rg < 4; ++rg) {
        int row = bm + wm + mi * 16 + qd * 4 + rg;
        if (Cb)
          Cb[(size_t)row * ldc + col] = f2bf(acc[mi][ni][rg]);
        else
          Cf[(size_t)row * ldc + col] = acc[mi][ni][rg];
      }
    }
}

// ---------------------------------------------------------------------------
// Split-bf16 MFMA GEMM, 64x128 tile (fp32-accurate, 3 MFMA terms).
// ---------------------------------------------------------------------------
__global__ __launch_bounds__(256) void gemm_bf16_split_64(
    const unsigned short* __restrict__ Ah, const unsigned short* __restrict__ Al,
    const unsigned short* __restrict__ Bh, const unsigned short* __restrict__ Bl,
    float* __restrict__ Cf, int K, int lda, int ldb, int ldc,
    long long Az, long long Bz, long long Cz) {
  int zz = blockIdx.z;
  Ah += (size_t)zz * Az; Al += (size_t)zz * Az;
  Bh += (size_t)zz * Bz; Bl += (size_t)zz * Bz;
  Cf += (size_t)zz * Cz;
  __shared__ unsigned short Ash[64 * 32];
  __shared__ unsigned short Asl[64 * 32];
  __shared__ unsigned short Bsh[128 * 32];
  __shared__ unsigned short Bsl[128 * 32];
  int tid = threadIdx.x;
  int bm = blockIdx.y * 64, bn = blockIdx.x * 128;
  int lane = tid & 63, wid = tid >> 6;
  int wm = (wid & 1) * 32, wn = (wid >> 1) * 64;
  int qd = lane >> 4, m16 = lane & 15;

  floatx4 acc[2][4];
#pragma unroll
  for (int i = 0; i < 2; ++i)
#pragma unroll
    for (int j = 0; j < 4; ++j) acc[i][j] = (floatx4){0.f, 0.f, 0.f, 0.f};

  for (int k0 = 0; k0 < K; k0 += 32) {
    {
      int r = tid >> 2, sl = tid & 3;
      int g = sl ^ ((r >> 1) & 3);
      size_t aoff = (size_t)(bm + r) * lda + k0 + g * 8;
      __builtin_amdgcn_global_load_lds(
          (const __attribute__((address_space(1))) unsigned int*)(Ah + aoff),
          (__attribute__((address_space(3))) unsigned int*)(&Ash[tid * 8]), 16, 0, 0);
      __builtin_amdgcn_global_load_lds(
          (const __attribute__((address_space(1))) unsigned int*)(Al + aoff),
          (__attribute__((address_space(3))) unsigned int*)(&Asl[tid * 8]), 16, 0, 0);
    }
#pragma unroll
    for (int i = 0; i < 2; ++i) {
      int idx = tid + 256 * i;
      int r = idx >> 2, sl = idx & 3;
      int g = sl ^ ((r >> 1) & 3);
      size_t boff = (size_t)(bn + r) * ldb + k0 + g * 8;
      __builtin_amdgcn_global_load_lds(
          (const __attribute__((address_space(1))) unsigned int*)(Bh + boff),
          (__attribute__((address_space(3))) unsigned int*)(&Bsh[idx * 8]), 16, 0, 0);
      __builtin_amdgcn_global_load_lds(
          (const __attribute__((address_space(1))) unsigned int*)(Bl + boff),
          (__attribute__((address_space(3))) unsigned int*)(&Bsl[idx * 8]), 16, 0, 0);
    }
    __syncthreads();
    short8 afh[2], afl[2], bfh[4], bfl[4];
#pragma unroll
    for (int mi = 0; mi < 2; ++mi) {
      int r = wm + mi * 16 + m16;
      int slot = qd ^ ((r >> 1) & 3);
      afh[mi] = *(const short8*)&Ash[r * 32 + slot * 8];
      afl[mi] = *(const short8*)&Asl[r * 32 + slot * 8];
    }
#pragma unroll
    for (int ni = 0; ni < 4; ++ni) {
      int r = wn + ni * 16 + m16;
      int slot = qd ^ ((r >> 1) & 3);
      bfh[ni] = *(const short8*)&Bsh[r * 32 + slot * 8];
      bfl[ni] = *(const short8*)&Bsl[r * 32 + slot * 8];
    }
#pragma unroll
    for (int mi = 0; mi < 2; ++mi)
#pragma unroll
      for (int ni = 0; ni < 4; ++ni) {
        acc[mi][ni] = __builtin_amdgcn_mfma_f32_16x16x32_bf16(afh[mi], bfh[ni], acc[mi][ni], 0, 0, 0);
        acc[mi][ni] = __builtin_amdgcn_mfma_f32_16x16x32_bf16(afh[mi], bfl[ni], acc[mi][ni], 0, 0, 0);
        acc[mi][ni] = __builtin_amdgcn_mfma_f32_16x16x32_bf16(afl[mi], bfh[ni], acc[mi][ni], 0, 0, 0);
      }
    __syncthreads();
  }
#pragma unroll
  for (int mi = 0; mi < 2; ++mi)
#pragma unroll
    for (int ni = 0; ni < 4; ++ni) {
      int col = bn + wn + ni * 16 + m16;
#pragma unroll
      for (int rg = 0; rg < 4; ++rg) {
        int row = bm + wm + mi * 16 + qd * 4 + rg;
        Cf[(size_t)row * ldc + col] = acc[mi][ni][rg];
      }
    }
}

// reduce z fp32 slices (contiguous stride n) -> fp32
__global__ void reduce_f32(const float* __restrict__ P, float* __restrict__ C, int n, int z) {
  int i = (blockIdx.x * 256 + threadIdx.x) * 4;
  if (i >= n) return;
  float4 a = *(const float4*)&P[i];
  for (int s = 1; s < z; ++s) {
    float4 b = *(const float4*)&P[(size_t)s * n + i];
    a.x += b.x; a.y += b.y; a.z += b.z; a.w += b.w;
  }
  *(float4*)&C[i] = a;
}

// reduce z fp32 slices -> (bf16 hi, bf16 lo)
__global__ void reduce_cast_split(const float* __restrict__ P, unsigned short* __restrict__ hi,
                                  unsigned short* __restrict__ lo, int n, int z) {
  int i = (blockIdx.x * 256 + threadIdx.x) * 4;
  if (i >= n) return;
  float4 a = *(const float4*)&P[i];
  for (int s = 1; s < z; ++s) {
    float4 b = *(const float4*)&P[(size_t)s * n + i];
    a.x += b.x; a.y += b.y; a.z += b.z; a.w += b.w;
  }
  ushort4 h = make_ushort4(f2bf(a.x), f2bf(a.y), f2bf(a.z), f2bf(a.w));
  ushort4 l = make_ushort4(f2bf(a.x - bf2f(h.x)), f2bf(a.y - bf2f(h.y)),
                           f2bf(a.z - bf2f(h.z)), f2bf(a.w - bf2f(h.w)));
  *(ushort4*)&hi[i] = h;
  *(ushort4*)&lo[i] = l;
}

// ---------------------------------------------------------------------------
// Indexer scores on split-bf16 MFMA (relu*hw epilogue in-register).
// ---------------------------------------------------------------------------
__global__ __launch_bounds__(256) void iscores_mfma(
    const unsigned short* __restrict__ Ah, const unsigned short* __restrict__ Al,
    const unsigned short* __restrict__ Bh, const unsigned short* __restrict__ Bl,
    const float* __restrict__ hw, float* __restrict__ isc) {
  int bm = blockIdx.y * 128, bn = blockIdx.x * 128;
  if (bn > (bm >> 2) + 30) return;
  __shared__ unsigned short Ash[128 * 32];
  __shared__ unsigned short Asl[128 * 32];
  __shared__ unsigned short Bsh[128 * 32];
  __shared__ unsigned short Bsl[128 * 32];
  int tid = threadIdx.x;
  int lane = tid & 63, wid = tid >> 6;
  int wm = (wid >> 1) * 64, wn = (wid & 1) * 64;
  int qd = lane >> 4, m16 = lane & 15;

  floatx4 acc[4][4];
#pragma unroll
  for (int i = 0; i < 4; ++i)
#pragma unroll
    for (int j = 0; j < 4; ++j) acc[i][j] = (floatx4){0.f, 0.f, 0.f, 0.f};

#pragma unroll
  for (int k0 = 0; k0 < 64; k0 += 32) {
#pragma unroll
    for (int i = 0; i < 2; ++i) {
      int idx = tid + 256 * i;
      int r = idx >> 2, s = idx & 3;
      int g = s ^ ((r >> 1) & 3);
      size_t aoff = (size_t)(bm + r) * 64 + k0 + g * 8;
      size_t boff = (size_t)(bn + r) * 64 + k0 + g * 8;
      __builtin_amdgcn_global_load_lds(
          (const __attribute__((address_space(1))) unsigned int*)(Ah + aoff),
          (__attribute__((address_space(3))) unsigned int*)(&Ash[idx * 8]), 16, 0, 0);
      __builtin_amdgcn_global_load_lds(
          (const __attribute__((address_space(1))) unsigned int*)(Al + aoff),
          (__attribute__((address_space(3))) unsigned int*)(&Asl[idx * 8]), 16, 0, 0);
      __builtin_amdgcn_global_load_lds(
          (const __attribute__((address_space(1))) unsigned int*)(Bh + boff),
          (__attribute__((address_space(3))) unsigned int*)(&Bsh[idx * 8]), 16, 0, 0);
      __builtin_amdgcn_global_load_lds(
          (const __attribute__((address_space(1))) unsigned int*)(Bl + boff),
          (__attribute__((address_space(3))) unsigned int*)(&Bsl[idx * 8]), 16, 0, 0);
    }
    __syncthreads();
    short8 afh[4], afl[4], bfh[4], bfl[4];
#pragma unroll
    for (int mi = 0; mi < 4; ++mi) {
      int r = wm + mi * 16 + m16;
      int slot = qd ^ ((r >> 1) & 3);
      afh[mi] = *(const short8*)&Ash[r * 32 + slot * 8];
      afl[mi] = *(const short8*)&Asl[r * 32 + slot * 8];
    }
#pragma unroll
    for (int ni = 0; ni < 4; ++ni) {
      int r = wn + ni * 16 + m16;
      int slot = qd ^ ((r >> 1) & 3);
      bfh[ni] = *(const short8*)&Bsh[r * 32 + slot * 8];
      bfl[ni] = *(const short8*)&Bsl[r * 32 + slot * 8];
    }
#pragma unroll
    for (int mi = 0; mi < 4; ++mi)
#pragma unroll
      for (int ni = 0; ni < 4; ++ni) {
        acc[mi][ni] = __builtin_amdgcn_mfma_f32_16x16x32_bf16(afh[mi], bfh[ni], acc[mi][ni], 0, 0, 0);
        acc[mi][ni] = __builtin_amdgcn_mfma_f32_16x16x32_bf16(afh[mi], bfl[ni], acc[mi][ni], 0, 0, 0);
        acc[mi][ni] = __builtin_amdgcn_mfma_f32_16x16x32_bf16(afl[mi], bfh[ni], acc[mi][ni], 0, 0, 0);
      }
    __syncthreads();
  }
#pragma unroll
  for (int mi = 0; mi < 4; ++mi) {
    int tok = ((bm + wm + mi * 16) >> 2) + qd;
    float4 hwv = *(const float4*)&hw[tok * 4];
#pragma unroll
    for (int ni = 0; ni < 4; ++ni) {
      floatx4 a = acc[mi][ni];
      float v = fmaxf(a[0], 0.f) * hwv.x + fmaxf(a[1], 0.f) * hwv.y +
                fmaxf(a[2], 0.f) * hwv.z + fmaxf(a[3], 0.f) * hwv.w;
      int col = bn + wn + ni * 16 + m16;
      isc[(size_t)tok * NC_ + col] = (col < tok) ? v : -__builtin_inff();
    }
  }
}

// ---------------------------------------------------------------------------
// Split-K fp32 GEMM for k_proj (N=64) + reduce
// ---------------------------------------------------------------------------
#define BM 64
#define BN 64
#define BK 16
#define KSL_ 16
#define KSLICE_ 128
__global__ __launch_bounds__(256) void gemm_f32_splitk(
    const float* __restrict__ A, const float* __restrict__ B,
    float* __restrict__ P, int lda, int ldb) {
  __shared__ float As[BK][BM + 4];
  __shared__ float Bs[BK][BN + 4];
  int tid = threadIdx.x;
  int bm = blockIdx.y * BM;
  int kbase = blockIdx.x * KSLICE_;
  int tr = tid >> 4;
  int tc = tid & 15;
  float acc[4][4] = {{0.f}};
  for (int k0 = kbase; k0 < kbase + KSLICE_; k0 += BK) {
    int ac = tid & 15;
    int ar0 = tid >> 4;
#pragma unroll
    for (int i = 0; i < 4; ++i) {
      int r = ar0 + 16 * i;
      As[ac][r] = A[(size_t)(bm + r) * lda + k0 + ac];
    }
    int bc = tid & 63;
    int br0 = tid >> 6;
#pragma unroll
    for (int i = 0; i < 4; ++i) {
      int r = br0 + 4 * i;
      Bs[r][bc] = B[(size_t)(k0 + r) * ldb + bc];
    }
    __syncthreads();
#pragma unroll
    for (int kk = 0; kk < BK; ++kk) {
      float4 av = *(const float4*)&As[kk][tr * 4];
      float4 bv = *(const float4*)&Bs[kk][tc * 4];
      float a[4] = {av.x, av.y, av.z, av.w};
      float b[4] = {bv.x, bv.y, bv.z, bv.w};
#pragma unroll
      for (int i = 0; i < 4; ++i)
#pragma unroll
        for (int j = 0; j < 4; ++j) acc[i][j] += a[i] * b[j];
    }
    __syncthreads();
  }
  float* Pb = P + (size_t)blockIdx.x * (NC_ * CI_);
#pragma unroll
  for (int i = 0; i < 4; ++i) {
    float4 v = make_float4(acc[i][0], acc[i][1], acc[i][2], acc[i][3]);
    *(float4*)&Pb[(size_t)(bm + tr * 4 + i) * CI_ + tc * 4] = v;
  }
}

__global__ void reduce_splitk(const float* __restrict__ P, float* __restrict__ C) {
  int i = blockIdx.x * 256 + threadIdx.x;
  if (i >= NC_ * CI_) return;
  float a = 0.f;
#pragma unroll
  for (int s = 0; s < KSL_; ++s) a += P[(size_t)s * (NC_ * CI_) + i];
  C[i] = a;
}

// fp32 -> bf16 plain cast (n multiple of 4)
__global__ void cast_bf16(const float* __restrict__ in, unsigned short* __restrict__ out, int n) {
  int i = (blockIdx.x * 256 + threadIdx.x) * 4;
  if (i >= n) return;
  float4 v = *(const float4*)&in[i];
  ushort4 o = make_ushort4(f2bf(v.x), f2bf(v.y), f2bf(v.z), f2bf(v.w));
  *(ushort4*)&out[i] = o;
}

// fp32 -> (bf16 hi, bf16 lo) element-wise split (n multiple of 4)
__global__ void cast_split(const float* __restrict__ in, unsigned short* __restrict__ hi,
                           unsigned short* __restrict__ lo, int n) {
  int i = (blockIdx.x * 256 + threadIdx.x) * 4;
  if (i >= n) return;
  float4 v = *(const float4*)&in[i];
  ushort4 h = make_ushort4(f2bf(v.x), f2bf(v.y), f2bf(v.z), f2bf(v.w));
  ushort4 l = make_ushort4(f2bf(v.x - bf2f(h.x)), f2bf(v.y - bf2f(h.y)),
                           f2bf(v.z - bf2f(h.z)), f2bf(v.w - bf2f(h.w)));
  *(ushort4*)&hi[i] = h;
  *(ushort4*)&lo[i] = l;
}

__device__ inline float wave_sum64(float v) {
#pragma unroll
  for (int off = 32; off > 0; off >>= 1) v += __shfl_xor(v, off, 64);
  return v;
}

// Fused: x -> (hi, lo) split AND hw = x @ w_w. One block (512 thr) per token.
__global__ __launch_bounds__(512) void cast_split_hw(
    const float* __restrict__ x, unsigned short* __restrict__ hi,
    unsigned short* __restrict__ lo, const float* __restrict__ ww,
    float* __restrict__ hw) {
  int s = blockIdx.x, tid = threadIdx.x;
  size_t i = (size_t)s * D_ + tid * 4;
  float4 v = *(const float4*)&x[i];
  ushort4 h = make_ushort4(f2bf(v.x), f2bf(v.y), f2bf(v.z), f2bf(v.w));
  ushort4 l = make_ushort4(f2bf(v.x - bf2f(h.x)), f2bf(v.y - bf2f(h.y)),
                           f2bf(v.z - bf2f(h.z)), f2bf(v.w - bf2f(h.w)));
  *(ushort4*)&hi[i] = h;
  *(ushort4*)&lo[i] = l;
  const float* wr = ww + tid * 16;
  float a0 = v.x * wr[0] + v.y * wr[4] + v.z * wr[8]  + v.w * wr[12];
  float a1 = v.x * wr[1] + v.y * wr[5] + v.z * wr[9]  + v.w * wr[13];
  float a2 = v.x * wr[2] + v.y * wr[6] + v.z * wr[10] + v.w * wr[14];
  float a3 = v.x * wr[3] + v.y * wr[7] + v.z * wr[11] + v.w * wr[15];
  a0 = wave_sum64(a0); a1 = wave_sum64(a1);
  a2 = wave_sum64(a2); a3 = wave_sum64(a3);
  __shared__ float red[8][4];
  int wid = tid >> 6, lane = tid & 63;
  if (lane == 0) { red[wid][0] = a0; red[wid][1] = a1; red[wid][2] = a2; red[wid][3] = a3; }
  __syncthreads();
  if (tid < 4) {
    float acc = 0.f;
#pragma unroll
    for (int w2 = 0; w2 < 8; ++w2) acc += red[w2][tid];
    hw[s * 4 + tid] = acc;
  }
}

// fp32 (K x N) -> bf16 transpose (N x K). K,N multiples of 32. grid.z batching.
__global__ __launch_bounds__(256) void transpose_cast(
    const float* __restrict__ in, unsigned short* __restrict__ out, int K, int N,
    long long inz, long long outz) {
  in += (size_t)blockIdx.z * inz;
  out += (size_t)blockIdx.z * outz;
  __shared__ float t[32][33];
  int k0 = blockIdx.x * 32, n0 = blockIdx.y * 32;
  int tx = threadIdx.x & 31, ty = threadIdx.x >> 5;
#pragma unroll
  for (int i = 0; i < 4; ++i)
    t[ty * 4 + i][tx] = in[(size_t)(k0 + ty * 4 + i) * N + n0 + tx];
  __syncthreads();
#pragma unroll
  for (int i = 0; i < 4; ++i)
    out[(size_t)(n0 + ty * 4 + i) * K + k0 + tx] = f2bf(t[tx][ty * 4 + i]);
}

// fp32 (K x N) -> bf16 transpose split (N x K, hi+lo)
__global__ __launch_bounds__(256) void transpose_cast_split(
    const float* __restrict__ in, unsigned short* __restrict__ outh,
    unsigned short* __restrict__ outl, int K, int N) {
  __shared__ float t[32][33];
  int k0 = blockIdx.x * 32, n0 = blockIdx.y * 32;
  int tx = threadIdx.x & 31, ty = threadIdx.x >> 5;
#pragma unroll
  for (int i = 0; i < 4; ++i)
    t[ty * 4 + i][tx] = in[(size_t)(k0 + ty * 4 + i) * N + n0 + tx];
  __syncthreads();
#pragma unroll
  for (int i = 0; i < 4; ++i) {
    float v = t[tx][ty * 4 + i];
    unsigned short h = f2bf(v);
    outh[(size_t)(n0 + ty * 4 + i) * K + k0 + tx] = h;
    outl[(size_t)(n0 + ty * 4 + i) * K + k0 + tx] = f2bf(v - bf2f(h));
  }
}

// k_orig[j,d] = mean over 4 tokens
__global__ void mean4_kernel(const float* __restrict__ x, float* __restrict__ ko) {
  int i = blockIdx.x * 256 + threadIdx.x;
  if (i >= NC_ * D_) return;
  int j = i >> 11, d = i & (D_ - 1);
  const float* p = x + (size_t)j * 4 * D_ + d;
  ko[i] = 0.25f * (p[0] + p[D_] + p[2 * D_] + p[3 * D_]);
}

// gating softmax; reads packed c4 (S x 256: [c_a|c_b|z_a|z_b])
__global__ void gate_kernel(const float* __restrict__ c4,
                            const float* __restrict__ ba, const float* __restrict__ bb,
                            float* __restrict__ comp) {
  int i = blockIdx.x * 256 + threadIdx.x;
  if (i >= NC_ * C_) return;
  int j = i >> 6, c = i & 63;
  float lg[8], vv[8];
#pragma unroll
  for (int m = 0; m < 4; ++m) {
    if (j == 0) {
      lg[m] = -1e30f + bb[m * C_ + c];
      vv[m] = 0.f;
    } else {
      int row = (j - 1) * 4 + m;
      lg[m] = c4[(size_t)row * 256 + 192 + c] + bb[m * C_ + c];
      vv[m] = c4[(size_t)row * 256 + 64 + c];
    }
    int row2 = j * 4 + m;
    lg[4 + m] = c4[(size_t)row2 * 256 + 128 + c] + ba[m * C_ + c];
    vv[4 + m] = c4[(size_t)row2 * 256 + 0 + c];
  }
  float mx = lg[0];
#pragma unroll
  for (int t = 1; t < 8; ++t) mx = fmaxf(mx, lg[t]);
  float se = 0.f, acc = 0.f;
#pragma unroll
  for (int t = 0; t < 8; ++t) {
    float e = expf(lg[t] - mx);
    se += e;
    acc += e * vv[t];
  }
  comp[i] = acc / se;
}

// LayerNorm over C=64 -> bf16 row-major + bf16 transposed (for attention MFMA)
__global__ void ln_kc_kernel(const float* __restrict__ in, const float* __restrict__ w,
                             const float* __restrict__ b, unsigned short* __restrict__ kcb,
                             unsigned short* __restrict__ kcbT) {
  int row = blockIdx.x * 4 + (threadIdx.x >> 6);
  int c = threadIdx.x & 63;
  float v = in[(size_t)row * C_ + c];
  float mu = wave_sum64(v) * (1.f / 64.f);
  float d = v - mu;
  float var = wave_sum64(d * d) * (1.f / 64.f);
  float y = d * (1.f / sqrtf(var + EPS_)) * w[c] + b[c];
  unsigned short h = f2bf(y);
  kcb[(size_t)row * C_ + c] = h;
  kcbT[(size_t)c * NC_ + row] = h;
}

// LN + RoPE for q -> bf16, pre-scaled by 1/sqrt(C)=0.125 (only attention uses q)
__global__ void ln_rope_q_kernel(const float* __restrict__ quq, const float* __restrict__ w,
                                 const float* __restrict__ b, unsigned short* __restrict__ qb) {
  int row = blockIdx.x * 4 + (threadIdx.x >> 6);  // s*16 + h
  int s = row >> 4;
  int c = threadIdx.x & 63;
  float v = quq[(size_t)row * C_ + c];
  float mu = wave_sum64(v) * (1.f / 64.f);
  float d = v - mu;
  float var = wave_sum64(d * d) * (1.f / 64.f);
  float y = d * (1.f / sqrtf(var + EPS_)) * w[c] + b[c];
  float outv;
  float partner = __shfl_xor(y, 1, 64);
  if (c < C_ - ROPE_) {
    outv = y;
  } else {
    int p = (c - (C_ - ROPE_)) >> 1;
    float inv = powf(10000.f, -(2.f * (float)p) / (float)ROPE_);
    float ang = (float)s * inv;
    float cs = cosf(ang), sn = sinf(ang);
    if ((c & 1) == 0)
      outv = y * cs - partner * sn;
    else
      outv = partner * sn + y * cs;
  }
  qb[(size_t)row * C_ + c] = f2bf(outv * 0.125f);
}

// ---------------------------------------------------------------------------
// Top-512-of-1024 exact radix-select -> selection bitmap.
// ---------------------------------------------------------------------------
#define MINF_ 0x007FFFFFu
__global__ __launch_bounds__(256) void topk_select_kernel(
    const float* __restrict__ isc, unsigned* __restrict__ sel) {
  __shared__ unsigned mv[NC_];
  __shared__ unsigned bins[256];
  __shared__ unsigned scan[256];
  __shared__ unsigned sB, sR;
  __shared__ unsigned selw[32];
  int s = blockIdx.x;
  int tid = threadIdx.x;
  for (int i = tid; i < NC_; i += 256) {
    if (i < s) {
      unsigned u = __float_as_uint(isc[(size_t)s * NC_ + i]);
      mv[i] = (u & 0x80000000u) ? ~u : (u | 0x80000000u);
    } else {
      mv[i] = MINF_;
    }
  }
  __syncthreads();
  unsigned K_rem = TOPK_;
  unsigned prefix = 0u;
  for (int lvl = 0; lvl < 4; ++lvl) {
    int shift = 24 - 8 * lvl;
    unsigned pm = (lvl == 0) ? 0u : (0xFFFFFFFFu << (32 - 8 * lvl));
    bins[tid] = 0u;
    __syncthreads();
    for (int i = tid; i < NC_; i += 256) {
      unsigned m = mv[i];
      if ((m & pm) == prefix) atomicAdd(&bins[(m >> shift) & 0xFFu], 1u);
    }
    __syncthreads();
    unsigned v = bins[tid];
    scan[tid] = v;
    __syncthreads();
    for (int off = 1; off < 256; off <<= 1) {
      unsigned add = (tid + off < 256) ? scan[tid + off] : 0u;
      __syncthreads();
      scan[tid] += add;
      __syncthreads();
    }
    unsigned gt = scan[tid] - v;
    if (gt < K_rem && K_rem <= gt + v) { sB = (unsigned)tid; sR = K_rem - gt; }
    __syncthreads();
    prefix |= (sB << shift);
    K_rem = sR;
    __syncthreads();
  }
  unsigned vstar = prefix;
  unsigned eq = 0;
#pragma unroll
  for (int j = 0; j < 4; ++j) eq += (mv[4 * tid + j] == vstar);
  scan[tid] = eq;
  __syncthreads();
  for (int off = 1; off < 256; off <<= 1) {
    unsigned add = (tid >= off) ? scan[tid - off] : 0u;
    __syncthreads();
    scan[tid] += add;
    __syncthreads();
  }
  unsigned rank0 = scan[tid] - eq;
  if (tid < 32) selw[tid] = 0u;
  __syncthreads();
  unsigned local = 0, bits = 0;
#pragma unroll
  for (int j = 0; j < 4; ++j) {
    unsigned m = mv[4 * tid + j];
    bool sb = (m > vstar) || (m == vstar && (rank0 + local) < K_rem);
    local += (m == vstar);
    if (sb) bits |= (1u << ((4 * tid + j) & 31));
  }
  if (bits) atomicOr(&selw[tid >> 3], bits);
  __syncthreads();
  if (tid < 32) sel[(size_t)s * 32 + tid] = selw[tid];
}

// ---------------------------------------------------------------------------
// Dense-masked flash attention on MFMA with exact causal/selection tile range.
// ---------------------------------------------------------------------------
#define TS_ 8
__global__ __launch_bounds__(256) void attn_mfma_kernel(
    const unsigned short* __restrict__ qb, const unsigned short* __restrict__ kcb,
    const unsigned short* __restrict__ kcbT, const unsigned* __restrict__ sel,
    const float* __restrict__ sink, unsigned short* __restrict__ out) {
  __shared__ unsigned short kc_s[64 * 72];
  __shared__ unsigned short kct_s[64 * 72];
  __shared__ unsigned short p_s[128 * 72];
  __shared__ unsigned selw[TS_][32];
  __shared__ float dls[4][2][16];
  int tid = threadIdx.x;
  int s0 = blockIdx.x * TS_;
  int lane = tid & 63, w = tid >> 6;
  int qd = lane >> 4, m16 = lane & 15;

  for (int i = tid; i < TS_ * 32; i += 256)
    selw[i >> 5][i & 31] = sel[(size_t)(s0 + (i >> 5)) * 32 + (i & 31)];

  short8 qf[2][2];
#pragma unroll
  for (int tk = 0; tk < 2; ++tk)
#pragma unroll
    for (int ks = 0; ks < 2; ++ks)
      qf[tk][ks] = *(const short8*)&qb[(size_t)(s0 + 2 * w + tk) * 1024 + m16 * 64 + ks * 32 + qd * 8];

  floatx4 of[2][4];
#pragma unroll
  for (int i = 0; i < 2; ++i)
#pragma unroll
    for (int j = 0; j < 4; ++j) of[i][j] = (floatx4){0.f, 0.f, 0.f, 0.f};
  float dsum[2] = {0.f, 0.f};

  int ub = max(511, s0 + TS_ - 2);
  int ct_start = max(0, (s0 + 4) >> 8);
  int ct_end = min(16, (ub >> 6) + 1);

  for (int ct = ct_start; ct < ct_end; ++ct) {
    int c0 = ct * 64;
    __syncthreads();
    {
      int r = tid >> 2, cc = (tid & 3) * 16;
      *(short8*)&kc_s[r * 72 + cc]      = *(const short8*)&kcb[(size_t)(c0 + r) * 64 + cc];
      *(short8*)&kc_s[r * 72 + cc + 8]  = *(const short8*)&kcb[(size_t)(c0 + r) * 64 + cc + 8];
      *(short8*)&kct_s[r * 72 + cc]     = *(const short8*)&kcbT[(size_t)r * NC_ + c0 + cc];
      *(short8*)&kct_s[r * 72 + cc + 8] = *(const short8*)&kcbT[(size_t)r * NC_ + c0 + cc + 8];
    }
    __syncthreads();
#pragma unroll
    for (int mc = 0; mc < 4; ++mc) {
      short8 a0 = *(const short8*)&kc_s[(mc * 16 + m16) * 72 + qd * 8];
      short8 a1 = *(const short8*)&kc_s[(mc * 16 + m16) * 72 + 32 + qd * 8];
#pragma unroll
      for (int nt = 0; nt < 2; ++nt) {
        floatx4 sc = (floatx4){0.f, 0.f, 0.f, 0.f};
        sc = __builtin_amdgcn_mfma_f32_16x16x32_bf16(a0, qf[nt][0], sc, 0, 0, 0);
        sc = __builtin_amdgcn_mfma_f32_16x16x32_bf16(a1, qf[nt][1], sc, 0, 0, 0);
        int tokL = 2 * w + nt;
        int sG = s0 + tokL;
        short4v pv;
#pragma unroll
        for (int rg = 0; rg < 4; ++rg) {
          int cG = c0 + mc * 16 + qd * 4 + rg;
          bool ok = (((selw[tokL][cG >> 5] >> (cG & 31)) & 1u) != 0u) && (sG < cG * 4);
          float e = ok ? __expf(sc[rg]) : 0.f;
          dsum[nt] += e;
          pv[rg] = (short)f2bf(e);
        }
        *(short4v*)&p_s[(tokL * 16 + m16) * 72 + mc * 16 + qd * 4] = pv;
      }
    }
#pragma unroll
    for (int ks = 0; ks < 2; ++ks) {
      short8 pa0 = *(const short8*)&p_s[((2 * w + 0) * 16 + m16) * 72 + ks * 32 + qd * 8];
      short8 pa1 = *(const short8*)&p_s[((2 * w + 1) * 16 + m16) * 72 + ks * 32 + qd * 8];
#pragma unroll
      for (int nt = 0; nt < 4; ++nt) {
        short8 bv = *(const short8*)&kct_s[(nt * 16 + m16) * 72 + ks * 32 + qd * 8];
        of[0][nt] = __builtin_amdgcn_mfma_f32_16x16x32_bf16(pa0, bv, of[0][nt], 0, 0, 0);
        of[1][nt] = __builtin_amdgcn_mfma_f32_16x16x32_bf16(pa1, bv, of[1][nt], 0, 0, 0);
      }
    }
  }
#pragma unroll
  for (int nt = 0; nt < 2; ++nt) {
    dsum[nt] += __shfl_xor(dsum[nt], 16, 64);
    dsum[nt] += __shfl_xor(dsum[nt], 32, 64);
  }
  if (lane < 16) {
    float sk = __expf(sink[lane]);
    dls[w][0][lane] = dsum[0] + sk;
    dls[w][1][lane] = dsum[1] + sk;
  }
  __syncthreads();
#pragma unroll
  for (int tk = 0; tk < 2; ++tk)
#pragma unroll
    for (int nt = 0; nt < 4; ++nt) {
      floatx4 o = of[tk][nt];
#pragma unroll
      for (int rg = 0; rg < 4; ++rg) {
        int head = qd * 4 + rg;
        float dn = dls[w][tk][head];
        out[(size_t)(s0 + 2 * w + tk) * 1024 + head * 64 + nt * 16 + m16] = f2bf(o[rg] / dn);
      }
    }
}

// ---------------------------------------------------------------------------
// Workspace layout (float offsets)
// ---------------------------------------------------------------------------
#define OFF_QUQ    0u          // quq fp32 / isc / c_q partials
#define OFF_Q      4194304u    // qb bf16
#define OFF_XH     8388608u    // xh bf16
#define OFF_XL     12582912u   // xl bf16 -> sel
#define OFF_PART   16777216u   // k_proj/c4/q_i partials
#define OFF_KO     18874368u   // k_or fp32 (early) -> attnb bf16 (mid)
#define OFF_C4     20971520u   // 1048576 f
#define OFF_CQF    22020096u   // qih/qil/kph/kpl overlays
#define OFF_WTB    24117248u   // 1048576 f : fused W^T bf16 (2048 x 1024)
#define OFF_CQH    25165824u   // 1048576 f
#define OFF_CQL    26214400u   // 1048576 f
#define OFF_WPACKT 27262976u   // 262144 f
#define OFF_WDQTH  27525120u   // 524288 f
#define OFF_WDQTL  28049408u   // 524288 f
#define OFF_WIUQTH 28573696u   // 65536 f
#define OFF_WIUQTL 28639232u   // 65536 f
#define OFF_WUQT   28704768u   // 262144 f
#define OFF_ODB    28966912u   // 262144 f : o_down bf16 (no transpose)
#define OFF_OUPT   29229056u   // 2097152 f
#define OFF_HW     31326208u   // 16384 f
#define OFF_COMP   31342592u   // 65536 f
#define OFF_KC     31408128u   // 65536 f : kcb + kcbT
#define OFF_KPR    31473664u   // 65536 f

extern "C" void kernel_launch(void* const* d_in, const int* in_sizes, int n_in,
                              void* d_out, int out_size, void* d_ws, size_t ws_size,
                              hipStream_t stream) {
  const float* x      = (const float*)d_in[0];
  const float* w_kv_a = (const float*)d_in[1];
  const float* w_kv_b = (const float*)d_in[2];
  const float* w_z_a  = (const float*)d_in[3];
  const float* w_z_b  = (const float*)d_in[4];
  const float* b_a    = (const float*)d_in[5];
  const float* b_b    = (const float*)d_in[6];
  const float* w_dq   = (const float*)d_in[7];
  const float* w_iuq  = (const float*)d_in[8];
  const float* w_w    = (const float*)d_in[9];
  const float* w_k    = (const float*)d_in[10];
  const float* w_uq   = (const float*)d_in[11];
  const float* o_down = (const float*)d_in[12];
  const float* o_up   = (const float*)d_in[13];
  const float* kvn_w  = (const float*)d_in[14];
  const float* kvn_b  = (const float*)d_in[15];
  const float* qn_w   = (const float*)d_in[16];
  const float* qn_b   = (const float*)d_in[17];
  const float* sink   = (const float*)d_in[18];
  float* out = (float*)d_out;
  float* ws = (float*)d_ws;

  float* quq   = ws + OFF_QUQ;
  float* isc   = ws + OFF_QUQ;
  unsigned short* qb = (unsigned short*)(ws + OFF_Q);
  unsigned short* xh = (unsigned short*)(ws + OFF_XH);
  unsigned short* xl = (unsigned short*)(ws + OFF_XL);
  unsigned* sel = (unsigned*)(ws + OFF_XL);
  float* part  = ws + OFF_PART;
  float* k_or  = ws + OFF_KO;
  unsigned short* attnb = (unsigned short*)(ws + OFF_KO);
  float* c4    = ws + OFF_C4;
  unsigned short* qih = (unsigned short*)(ws + OFF_CQF);
  unsigned short* qil = qih + S_ * NHI_ * CI_;
  unsigned short* kph = qil + S_ * NHI_ * CI_;
  unsigned short* kpl = kph + NC_ * CI_;
  unsigned short* wtb = (unsigned short*)(ws + OFF_WTB);
  unsigned short* cqh = (unsigned short*)(ws + OFF_CQH);
  unsigned short* cql = (unsigned short*)(ws + OFF_CQL);
  unsigned short* wpackT = (unsigned short*)(ws + OFF_WPACKT);
  unsigned short* wdqTh  = (unsigned short*)(ws + OFF_WDQTH);
  unsigned short* wdqTl  = (unsigned short*)(ws + OFF_WDQTL);
  unsigned short* wiuqTh = (unsigned short*)(ws + OFF_WIUQTH);
  unsigned short* wiuqTl = (unsigned short*)(ws + OFF_WIUQTL);
  unsigned short* wuqT   = (unsigned short*)(ws + OFF_WUQT);
  unsigned short* odb    = (unsigned short*)(ws + OFF_ODB);
  unsigned short* oupT   = (unsigned short*)(ws + OFF_OUPT);
  float* hw    = ws + OFF_HW;
  float* comp  = ws + OFF_COMP;
  unsigned short* kcb  = (unsigned short*)(ws + OFF_KC);
  unsigned short* kcbT = kcb + NC_ * C_;
  float* k_pr  = ws + OFF_KPR;

  dim3 blk(256);

  // --- casts & weight transposes (x cast fused with hw) ---
  cast_split_hw<<<S_, dim3(512), 0, stream>>>(x, xh, xl, w_w, hw);
  transpose_cast<<<dim3(64, 2), blk, 0, stream>>>(w_kv_a, wpackT + 0 * 64 * 2048, D_, C_, 0, 0);
  transpose_cast<<<dim3(64, 2), blk, 0, stream>>>(w_kv_b, wpackT + 1 * 64 * 2048, D_, C_, 0, 0);
  transpose_cast<<<dim3(64, 2), blk, 0, stream>>>(w_z_a,  wpackT + 2 * 64 * 2048, D_, C_, 0, 0);
  transpose_cast<<<dim3(64, 2), blk, 0, stream>>>(w_z_b,  wpackT + 3 * 64 * 2048, D_, C_, 0, 0);
  transpose_cast_split<<<dim3(64, 16), blk, 0, stream>>>(w_dq, wdqTh, wdqTl, D_, DC_);
  transpose_cast_split<<<dim3(16, 8), blk, 0, stream>>>(w_iuq, wiuqTh, wiuqTl, DC_, NHI_ * CI_);
  transpose_cast<<<dim3(16, 32), blk, 0, stream>>>(w_uq, wuqT, DC_, NH_ * C_, 0, 0);
  cast_bf16<<<512, blk, 0, stream>>>(o_down, odb, NG_ * 256 * DG_);
  transpose_cast<<<dim3(64, 64), blk, 0, stream>>>(o_up, oupT, NG_ * DG_, D_, 0, 0);

  // --- fused output weight: WT[j][g*256+i] = sum_d o_up[g*512+d][j]*od[g][i][d]
  // (algebraic fusion of o_down+o_up: out = attn @ W). M=2048(j), N=256(i), K=512.
  gemm_bf16_64<<<dim3(2, 32, 4), blk, 0, stream>>>(
      oupT, odb, nullptr, wtb, DG_, D_, DG_, NG_ * 256,
      (long long)DG_, (long long)256 * DG_, 256LL);

  // --- fp32 indexer-side path: k_orig -> k_proj (split-K) ---
  mean4_kernel<<<8192, blk, 0, stream>>>(x, k_or);
  gemm_f32_splitk<<<dim3(KSL_, 16), blk, 0, stream>>>(k_or, w_k, part, D_, CI_);
  reduce_splitk<<<256, blk, 0, stream>>>(part, k_pr);

  // --- MFMA GEMMs (64x128 tiles) ---
  // c_q: K=2048 -> 2 slices of 1024 (grid 4x64x2 = 512 blocks, half partial traffic)
  gemm_bf16_split_64<<<dim3(4, 64, 2), blk, 0, stream>>>(xh, xl, wdqTh, wdqTl, ws,
                                                         1024, D_, D_, DC_, 1024, 1024, (long long)S_ * DC_);
  reduce_cast_split<<<2048, blk, 0, stream>>>(ws, cqh, cql, S_ * DC_, 2);
  // c4: K=2048 -> 4 slices of 512 (grid 2x64x4 = 512 blocks)
  gemm_bf16_64<<<dim3(2, 64, 4), blk, 0, stream>>>(xh, wpackT, part, nullptr,
                                                   512, D_, D_, 256, 512, 512, (long long)S_ * 256);
  reduce_f32<<<1024, blk, 0, stream>>>(part, c4, S_ * 256, 4);
  // q_i: K=512 -> 4 slices of 128 (grid 2x64x4 = 512 blocks)
  gemm_bf16_split_64<<<dim3(2, 64, 4), blk, 0, stream>>>(cqh, cql, wiuqTh, wiuqTl, part,
                                                         128, DC_, DC_, 256, 128, 128, (long long)S_ * 256);
  reduce_cast_split<<<1024, blk, 0, stream>>>(part, qih, qil, S_ * 256, 4);
  // quq: grid 8x64 = 512 blocks
  gemm_bf16_64<<<dim3(8, 64, 1), blk, 0, stream>>>(cqh, wuqT, quq, nullptr,
                                                   DC_, DC_, DC_, NH_ * C_, 0, 0, 0);

  // --- gating -> compressed -> kc (LN, bf16 row-major + transposed) ---
  gate_kernel<<<256, blk, 0, stream>>>(c4, b_a, b_b, comp);
  ln_kc_kernel<<<256, blk, 0, stream>>>(comp, kvn_w, kvn_b, kcb, kcbT);

  // --- q: LN + RoPE -> bf16 scaled by 1/8 ---
  ln_rope_q_kernel<<<16384, blk, 0, stream>>>(quq, qn_w, qn_b, qb);

  // --- indexer scores (split-bf16 MFMA, causal tile skip) + radix-select ---
  cast_split<<<64, blk, 0, stream>>>(k_pr, kph, kpl, NC_ * CI_);
  iscores_mfma<<<dim3(8, 128), blk, 0, stream>>>(qih, qil, kph, kpl, hw, isc);
  topk_select_kernel<<<S_, blk, 0, stream>>>(isc, sel);

  // --- dense-masked flash attention (MFMA, causal tile range) ---
  attn_mfma_kernel<<<S_ / TS_, blk, 0, stream>>>(qb, kcb, kcbT, sel, sink, attnb);

  // --- fused output projection: out = attn @ W  (4096x2048x1024, 1024 blocks) ---
  gemm_bf16_64<<<dim3(16, 64, 1), blk, 0, stream>>>(attnb, wtb, out, nullptr,
                                                    NG_ * 256, NH_ * C_, NG_ * 256, D_, 0, 0, 0);
}